// Round 1
// baseline (22008.765 us; speedup 1.0000x reference)
//
#include <hip/hip_runtime.h>
#include <math.h>

// Problem constants
// B=32, L_IN=511, L=512, D_IN=64, D=256, H=8, dh=32, N_LAYERS=3, D_FF=1024
// tokens = B*L = 16384

__device__ __forceinline__ float gelu_f(float v) {
    return v * 0.5f * (1.0f + erff(v * 0.70710678118654752f));
}

// ---------------------------------------------------------------------------
// Transpose W_in [256,64] -> W_int [64,256] and pe_proj_W [256,276] -> peWt [276,256]
__global__ __launch_bounds__(256) void transpose_kernel(
    const float* __restrict__ W_in, const float* __restrict__ peW,
    float* __restrict__ W_int, float* __restrict__ peWt)
{
    int idx = blockIdx.x * 256 + threadIdx.x;
    if (idx < 16384) {
        int i = idx >> 8, dd = idx & 255;
        W_int[idx] = W_in[dd * 64 + i];
    } else if (idx < 16384 + 70656) {
        int j = idx - 16384;
        int f = j >> 8, dd = j & 255;
        peWt[j] = peW[dd * 276 + f];
    }
}

// ---------------------------------------------------------------------------
// prep: h0 = [CLS; x@W_in^T + b_in] + PE ;  also cl, csf, padf arrays
// 8 tokens per block, 256 threads (t == output channel d)
__global__ __launch_bounds__(256) void prep_kernel(
    const float* __restrict__ x, const float* __restrict__ c_local,
    const float* __restrict__ c_sink, const float* __restrict__ W_int,
    const float* __restrict__ b_in, const float* __restrict__ cls_tok,
    const float* __restrict__ peWt, const float* __restrict__ pe_b,
    const float* __restrict__ pe_g, const float* __restrict__ pe_bb,
    const float* __restrict__ pe_gain_p, const float* __restrict__ corr_floor_p,
    const int* __restrict__ lengths,
    float* __restrict__ h, float* __restrict__ clb, float* __restrict__ csfb,
    float* __restrict__ padfb)
{
    __shared__ __align__(16) float xs[8][64];
    __shared__ __align__(16) float zs[8][276];
    __shared__ __align__(16) float pes[8][256];
    __shared__ float mn[8], rsd[8];
    const int t = threadIdx.x;
    const int tok0 = blockIdx.x * 8;
    const int b = tok0 >> 9;
    const int len_b = lengths[b];
    const float cf = *corr_floor_p;
    const float gain = *pe_gain_p;

    float clv[8], csv[8];
    bool mk[8];
#pragma unroll
    for (int k = 0; k < 8; ++k) {
        int l = (tok0 + k) & 511;
        if (l == 0) { clv[k] = 1.f; csv[k] = 1.f; mk[k] = false; }
        else {
            float a = c_local[b * 511 + l - 1];
            float s = c_sink[b * 511 + l - 1];
            clv[k] = fminf(fmaxf(a, 0.f), 1.f);
            csv[k] = fminf(fmaxf(s, 0.f), 1.f);
            mk[k] = (l - 1) >= len_b;
        }
    }
    if (t < 8) {
        int tok = tok0 + t;
        clb[tok] = clv[t];
        csfb[tok] = cf + (1.f - cf) * csv[t];
        padfb[tok] = mk[t] ? 1.f : 0.f;
    }
    // stage x rows (zeros for CLS)
    for (int idx = t; idx < 512; idx += 256) {
        int k = idx >> 6, i = idx & 63;
        int l = (tok0 + k) & 511;
        xs[k][i] = (l == 0) ? 0.f : x[((size_t)b * 511 + l - 1) * 64 + i];
    }
    // sinusoidal PE features into zs[:, 0:256]
    {
        int kk = t >> 1;
        float div = expf((float)(2 * kk) * -0.035977892078032f); // -ln(10000)/256
#pragma unroll
        for (int k = 0; k < 8; ++k) {
            int l = (tok0 + k) & 511;
            float a = (float)l * div;
            zs[k][t] = (t & 1) ? cosf(a) : sinf(a);
        }
    }
    // raw + RBF features into zs[:, 256:276]
    if (t < 20) {
#pragma unroll
        for (int k = 0; k < 8; ++k) {
            float cl = clv[k], cs = csv[k];
            float v;
            if (t == 0) v = cl;
            else if (t == 1) v = cs;
            else if (t == 2) v = cl * cs;
            else if (t == 3) v = fabsf(cl - cs);
            else if (t < 12) {
                float c = (float)(t - 4) * (1.f / 7.f);
                float dd = (cl - c) / 0.200001f;
                v = expf(-0.5f * dd * dd);
            } else {
                float c = (float)(t - 12) * (1.f / 7.f);
                float dd = (cs - c) / 0.200001f;
                v = expf(-0.5f * dd * dd);
            }
            zs[k][256 + t] = v;
        }
    }
    __syncthreads();

    // base = b_in + x @ W_in^T  (CLS rows overridden)
    float base[8];
#pragma unroll
    for (int k = 0; k < 8; ++k) base[k] = b_in[t];
    for (int i = 0; i < 64; ++i) {
        float wv = W_int[i * 256 + t];
#pragma unroll
        for (int k = 0; k < 8; ++k) base[k] += xs[k][i] * wv;
    }
#pragma unroll
    for (int k = 0; k < 8; ++k) {
        int l = (tok0 + k) & 511;
        if (l == 0) base[k] = cls_tok[t];
    }
    // PE projection
    float acc[8];
#pragma unroll
    for (int k = 0; k < 8; ++k) acc[k] = pe_b[t];
    for (int f = 0; f < 276; ++f) {
        float wv = peWt[f * 256 + t];
#pragma unroll
        for (int k = 0; k < 8; ++k) acc[k] += zs[k][f] * wv;
    }
#pragma unroll
    for (int k = 0; k < 8; ++k) pes[k][t] = acc[k];
    __syncthreads();

    // PE layernorm stats: wave w handles tokens w and w+4
    {
        int w = t >> 6, lane = t & 63;
#pragma unroll
        for (int p = 0; p < 2; ++p) {
            int k = w + p * 4;
            float4 v = *(const float4*)&pes[k][lane * 4];
            float s = v.x + v.y + v.z + v.w;
            float sq = v.x * v.x + v.y * v.y + v.z * v.z + v.w * v.w;
#pragma unroll
            for (int off = 32; off; off >>= 1) {
                s += __shfl_xor(s, off);
                sq += __shfl_xor(sq, off);
            }
            if (lane == 0) {
                float mean = s * (1.f / 256.f);
                mn[k] = mean;
                rsd[k] = rsqrtf(sq * (1.f / 256.f) - mean * mean + 1e-5f);
            }
        }
    }
    __syncthreads();
    float gv = pe_g[t], bv = pe_bb[t];
#pragma unroll
    for (int k = 0; k < 8; ++k) {
        float pe = (pes[k][t] - mn[k]) * rsd[k] * gv + bv;
        pe *= gain;
        if (mk[k]) pe = 0.f;
        h[(size_t)(tok0 + k) * 256 + t] = base[k] + pe;
    }
}

// ---------------------------------------------------------------------------
// LayerNorm over D=256: one wave per token, 4 tokens per block
__global__ __launch_bounds__(256) void ln_kernel(
    const float* __restrict__ x, const float* __restrict__ g,
    const float* __restrict__ b, float* __restrict__ y)
{
    int tok = blockIdx.x * 4 + (threadIdx.x >> 6);
    int lane = threadIdx.x & 63;
    const float* row = x + (size_t)tok * 256;
    float4 v = *(const float4*)(row + lane * 4);
    float s = v.x + v.y + v.z + v.w;
    float sq = v.x * v.x + v.y * v.y + v.z * v.z + v.w * v.w;
#pragma unroll
    for (int off = 32; off; off >>= 1) {
        s += __shfl_xor(s, off);
        sq += __shfl_xor(sq, off);
    }
    float mean = s * (1.f / 256.f);
    float rs = rsqrtf(sq * (1.f / 256.f) - mean * mean + 1e-5f);
    float4 gv = *(const float4*)(g + lane * 4);
    float4 bv = *(const float4*)(b + lane * 4);
    float4 o;
    o.x = (v.x - mean) * rs * gv.x + bv.x;
    o.y = (v.y - mean) * rs * gv.y + bv.y;
    o.z = (v.z - mean) * rs * gv.z + bv.z;
    o.w = (v.w - mean) * rs * gv.w + bv.w;
    *(float4*)(y + (size_t)tok * 256 + lane * 4) = o;
}

// Final LN on the 32 CLS rows only
__global__ __launch_bounds__(256) void out_ln_kernel(
    const float* __restrict__ h, const float* __restrict__ g,
    const float* __restrict__ b, float* __restrict__ out)
{
    int tok = blockIdx.x * 4 + (threadIdx.x >> 6); // 0..31 == batch index
    int lane = threadIdx.x & 63;
    const float* row = h + (size_t)tok * 512 * 256;
    float4 v = *(const float4*)(row + lane * 4);
    float s = v.x + v.y + v.z + v.w;
    float sq = v.x * v.x + v.y * v.y + v.z * v.z + v.w * v.w;
#pragma unroll
    for (int off = 32; off; off >>= 1) {
        s += __shfl_xor(s, off);
        sq += __shfl_xor(sq, off);
    }
    float mean = s * (1.f / 256.f);
    float rs = rsqrtf(sq * (1.f / 256.f) - mean * mean + 1e-5f);
    float4 gv = *(const float4*)(g + lane * 4);
    float4 bv = *(const float4*)(b + lane * 4);
    float4 o;
    o.x = (v.x - mean) * rs * gv.x + bv.x;
    o.y = (v.y - mean) * rs * gv.y + bv.y;
    o.z = (v.z - mean) * rs * gv.z + bv.z;
    o.w = (v.w - mean) * rs * gv.w + bv.w;
    *(float4*)(out + (size_t)tok * 256 + lane * 4) = o;
}

// ---------------------------------------------------------------------------
// Generic f32 GEMM: C[M,N] = act(A[M,K] @ W[N,K]^T + bias) (+ R)
// 64x64 tile, BK=32, 256 threads, 4x4 per thread (stride-16 lane mapping)
template <int ACT, int RES>
__global__ __launch_bounds__(256) void gemm_kernel(
    const float* __restrict__ A, const float* __restrict__ W,
    const float* __restrict__ bias, const float* R,
    float* C, int M, int N, int K)
{
    __shared__ __align__(16) float As[64][36];
    __shared__ __align__(16) float Ws[64][36];
    const int t = threadIdx.x;
    const int m0 = blockIdx.y * 64;
    const int n0 = blockIdx.x * 64;
    const int lm = t >> 3;   // 0..31
    const int lk4 = t & 7;   // 0..7
    const int ty = t >> 4, tx = t & 15;
    float acc[4][4] = {};
    for (int k0 = 0; k0 < K; k0 += 32) {
        __syncthreads();
        {
            float4 va = *(const float4*)(A + (size_t)(m0 + lm) * K + k0 + lk4 * 4);
            *(float4*)&As[lm][lk4 * 4] = va;
            float4 va2 = *(const float4*)(A + (size_t)(m0 + lm + 32) * K + k0 + lk4 * 4);
            *(float4*)&As[lm + 32][lk4 * 4] = va2;
            float4 vw = *(const float4*)(W + (size_t)(n0 + lm) * K + k0 + lk4 * 4);
            *(float4*)&Ws[lm][lk4 * 4] = vw;
            float4 vw2 = *(const float4*)(W + (size_t)(n0 + lm + 32) * K + k0 + lk4 * 4);
            *(float4*)&Ws[lm + 32][lk4 * 4] = vw2;
        }
        __syncthreads();
#pragma unroll
        for (int kk4 = 0; kk4 < 8; ++kk4) {
            float4 a4[4], b4[4];
#pragma unroll
            for (int i = 0; i < 4; ++i) a4[i] = *(const float4*)&As[ty + 16 * i][kk4 * 4];
#pragma unroll
            for (int j = 0; j < 4; ++j) b4[j] = *(const float4*)&Ws[tx + 16 * j][kk4 * 4];
#pragma unroll
            for (int i = 0; i < 4; ++i)
#pragma unroll
                for (int j = 0; j < 4; ++j)
                    acc[i][j] += a4[i].x * b4[j].x + a4[i].y * b4[j].y +
                                 a4[i].z * b4[j].z + a4[i].w * b4[j].w;
        }
    }
#pragma unroll
    for (int i = 0; i < 4; ++i) {
        const size_t row = (size_t)(m0 + ty + 16 * i);
#pragma unroll
        for (int j = 0; j < 4; ++j) {
            const int col = n0 + tx + 16 * j;
            float v = acc[i][j] + bias[col];
            if (ACT == 1) v = gelu_f(v);
            if (RES) v += R[row * N + col];
            C[row * N + col] = v;
        }
    }
}

// ---------------------------------------------------------------------------
// Fused attention: one block per (b, head, 32-row tile); online softmax over
// 4 K/V tiles of 128 columns. Exactly reproduces reference up to the
// clip(-20) floor on ~0-weight columns (≈2e-9 relative, negligible).
__global__ __launch_bounds__(256) void attn_kernel(
    const float* __restrict__ qkv, const float* __restrict__ clb,
    const float* __restrict__ csfb, const float* __restrict__ padfb,
    const float* __restrict__ alpha_p, const float* __restrict__ beta_p,
    float* __restrict__ o_mat)
{
    __shared__ __align__(16) float kvs[2 * 128 * 36]; // K tile | V tile
    __shared__ __align__(16) float qs[32 * 32];
    __shared__ float pbuf[4 * 128];
    __shared__ float cls[512], csfs[512], padfs[512];
    const int t = threadIdx.x;
    const int tile = blockIdx.x & 15;
    const int bh = blockIdx.x >> 4;
    const int b = bh >> 3, hd = bh & 7;
    const float alpha = *alpha_p, beta = *beta_p;
    const int w = t >> 6, lane = t & 63;
    const size_t qkv_b = (size_t)b * 512 * 768;
    const int d = lane & 31, hh = lane >> 5;

    for (int idx = t; idx < 1024; idx += 256) {
        int il = idx >> 5, dd = idx & 31;
        qs[idx] = qkv[qkv_b + (size_t)(tile * 32 + il) * 768 + hd * 32 + dd];
    }
    for (int idx = t; idx < 512; idx += 256) {
        cls[idx] = clb[b * 512 + idx];
        csfs[idx] = csfb[b * 512 + idx];
        padfs[idx] = padfb[b * 512 + idx];
    }
    const float scale = 0.17677669529663687f;
    float mrow[8], lrow[8], oacc[8];
#pragma unroll
    for (int r = 0; r < 8; ++r) { mrow[r] = -1e30f; lrow[r] = 0.f; oacc[r] = 0.f; }

    for (int jt = 0; jt < 4; ++jt) {
        __syncthreads();
        for (int idx = t; idx < 1024; idx += 256) { // stage K and V tiles
            int jj = idx >> 3, c = idx & 7;
            *(float4*)&kvs[jj * 36 + c * 4] =
                *(const float4*)(qkv + qkv_b + (size_t)(jt * 128 + jj) * 768 + 256 + hd * 32 + c * 4);
            *(float4*)&kvs[128 * 36 + jj * 36 + c * 4] =
                *(const float4*)(qkv + qkv_b + (size_t)(jt * 128 + jj) * 768 + 512 + hd * 32 + c * 4);
        }
        __syncthreads();
#pragma unroll
        for (int r = 0; r < 8; ++r) {
            const int il = w * 8 + r;
            const int i = tile * 32 + il;
            float4 q4[8];
#pragma unroll
            for (int c = 0; c < 8; ++c) q4[c] = *(const float4*)&qs[il * 32 + c * 4];
            const float mi = padfs[i], csf_i = csfs[i];
            float s[2];
#pragma unroll
            for (int tt = 0; tt < 2; ++tt) {
                int jl = tt * 64 + lane;
                int j = jt * 128 + jl;
                float a = 0.f;
#pragma unroll
                for (int c = 0; c < 8; ++c) {
                    float4 k4 = *(const float4*)&kvs[jl * 36 + c * 4];
                    a += q4[c].x * k4.x + q4[c].y * k4.y + q4[c].z * k4.z + q4[c].w * k4.w;
                }
                a *= scale;
                float mj = padfs[j];
                if (mi < 0.5f && mj < 0.5f) {
                    float bb = beta * csf_i * csfs[j];
                    int dij = j - i;
                    if (dij == 1 || dij == -1) {
                        float ce;
                        if (i <= 510 && j >= 1) ce = cls[j];
                        else if (i >= 1 && j <= 510) ce = cls[i];
                        else ce = 0.f;
                        bb += alpha * ce;
                    }
                    a += bb;
                }
                a -= 10000.f * mj;
                s[tt] = a;
            }
            float tm = fmaxf(s[0], s[1]);
#pragma unroll
            for (int off = 32; off; off >>= 1) tm = fmaxf(tm, __shfl_xor(tm, off));
            float m_new = fmaxf(mrow[r], tm);
            float fs = expf(mrow[r] - m_new);
            mrow[r] = m_new;
            float p0 = expf(s[0] - m_new);
            float p1 = expf(s[1] - m_new);
            pbuf[w * 128 + lane] = p0;
            pbuf[w * 128 + 64 + lane] = p1;
            float ps = p0 + p1;
#pragma unroll
            for (int off = 32; off; off >>= 1) ps += __shfl_xor(ps, off);
            lrow[r] = lrow[r] * fs + ps;
            float a = oacc[r] * fs;
            for (int q = 0; q < 64; ++q) {
                int jj = hh * 64 + q;
                a += pbuf[w * 128 + jj] * kvs[128 * 36 + jj * 36 + d];
            }
            oacc[r] = a;
        }
    }
#pragma unroll
    for (int r = 0; r < 8; ++r) {
        float a = oacc[r] + __shfl_xor(oacc[r], 32);
        float o = a / lrow[r];
        if (lane < 32) {
            int i = tile * 32 + w * 8 + r;
            o_mat[((size_t)b * 512 + i) * 256 + hd * 32 + d] = o;
        }
    }
}

// ---------------------------------------------------------------------------
extern "C" void kernel_launch(void* const* d_in, const int* in_sizes, int n_in,
                              void* d_out, int out_size, void* d_ws, size_t ws_size,
                              hipStream_t stream) {
    const float* x         = (const float*)d_in[0];
    const float* c_local   = (const float*)d_in[1];
    const float* c_sink    = (const float*)d_in[2];
    const float* W_in      = (const float*)d_in[3];
    const float* b_in      = (const float*)d_in[4];
    const float* cls_token = (const float*)d_in[5];
    const float* pe_proj_W = (const float*)d_in[6];
    const float* pe_proj_b = (const float*)d_in[7];
    const float* pe_ln_g   = (const float*)d_in[8];
    const float* pe_ln_b   = (const float*)d_in[9];
    const float* pe_gain   = (const float*)d_in[10];
    const float* attn_Wqkv = (const float*)d_in[11];
    const float* attn_bqkv = (const float*)d_in[12];
    const float* attn_Wo   = (const float*)d_in[13];
    const float* attn_bo   = (const float*)d_in[14];
    const float* ff_W1     = (const float*)d_in[15];
    const float* ff_b1     = (const float*)d_in[16];
    const float* ff_W2     = (const float*)d_in[17];
    const float* ff_b2     = (const float*)d_in[18];
    const float* ln1_g     = (const float*)d_in[19];
    const float* ln1_b     = (const float*)d_in[20];
    const float* ln2_g     = (const float*)d_in[21];
    const float* ln2_b     = (const float*)d_in[22];
    const float* alpha     = (const float*)d_in[23];
    const float* beta      = (const float*)d_in[24];
    const float* corr_fl   = (const float*)d_in[25];
    const float* out_ln_g  = (const float*)d_in[26];
    const float* out_ln_b  = (const float*)d_in[27];
    const int*   lengths   = (const int*)d_in[28];
    float* out = (float*)d_out;
    float* ws = (float*)d_ws;

    // workspace layout (floats)
    float* h     = ws;                   // 16384*256 = 4,194,304
    float* u     = h + 4194304;          // LN scratch; also reused as o_mat
    float* big   = u + 4194304;          // 16,777,216: qkv [16384,768] / f [16384,1024]
    float* clb   = big + 16777216;       // 16384
    float* csfb  = clb + 16384;
    float* padfb = csfb + 16384;
    float* W_int = padfb + 16384;        // 64*256
    float* peWt  = W_int + 16384;        // 276*256 = 70656
    float* o_mat = u;                    // alias: u is dead once qkv is computed

    transpose_kernel<<<340, 256, 0, stream>>>(W_in, pe_proj_W, W_int, peWt);
    prep_kernel<<<2048, 256, 0, stream>>>(x, c_local, c_sink, W_int, b_in, cls_token,
                                          peWt, pe_proj_b, pe_ln_g, pe_ln_b, pe_gain,
                                          corr_fl, lengths, h, clb, csfb, padfb);
    for (int l = 0; l < 3; ++l) {
        ln_kernel<<<4096, 256, 0, stream>>>(h, ln1_g + 256 * l, ln1_b + 256 * l, u);
        gemm_kernel<0, 0><<<dim3(12, 256), 256, 0, stream>>>(
            u, attn_Wqkv + (size_t)l * 768 * 256, attn_bqkv + 768 * l, nullptr, big,
            16384, 768, 256);
        attn_kernel<<<4096, 256, 0, stream>>>(big, clb, csfb, padfb, alpha, beta, o_mat);
        gemm_kernel<0, 1><<<dim3(4, 256), 256, 0, stream>>>(
            o_mat, attn_Wo + (size_t)l * 65536, attn_bo + 256 * l, h, h,
            16384, 256, 256);
        ln_kernel<<<4096, 256, 0, stream>>>(h, ln2_g + 256 * l, ln2_b + 256 * l, u);
        gemm_kernel<1, 0><<<dim3(16, 256), 256, 0, stream>>>(
            u, ff_W1 + (size_t)l * 262144, ff_b1 + 1024 * l, nullptr, big,
            16384, 1024, 256);
        gemm_kernel<0, 1><<<dim3(4, 256), 256, 0, stream>>>(
            big, ff_W2 + (size_t)l * 262144, ff_b2 + 256 * l, h, h,
            16384, 256, 1024);
    }
    out_ln_kernel<<<8, 256, 0, stream>>>(h, out_ln_g, out_ln_b, out);
}

// Round 2
// 720.310 us; speedup vs baseline: 30.5546x; 30.5546x over previous
//
#include <hip/hip_runtime.h>
#include <math.h>

// B=32, L=512 (incl CLS), D=256, H=8, dh=32, N_LAYERS=3, D_FF=1024, tokens=16384

typedef __attribute__((ext_vector_type(4))) float f32x4;
typedef __attribute__((ext_vector_type(8))) short bf16x8;

__device__ __forceinline__ unsigned short f2bf(float f) {
    unsigned u = __builtin_bit_cast(unsigned, f);
    u += 0x7fff + ((u >> 16) & 1);
    return (unsigned short)(u >> 16);
}
__device__ __forceinline__ float gelu_f(float v) {
    return v * 0.5f * (1.0f + erff(v * 0.70710678118654752f));
}
__device__ __forceinline__ void gload16(const void* g, void* l) {
    __builtin_amdgcn_global_load_lds(
        (const __attribute__((address_space(1))) unsigned int*)g,
        (__attribute__((address_space(3))) unsigned int*)l, 16, 0, 0);
}

// ---------------------------------------------------------------------------
__global__ __launch_bounds__(256) void transpose_kernel(
    const float* __restrict__ W_in, const float* __restrict__ peW,
    float* __restrict__ W_int, float* __restrict__ peWt)
{
    int idx = blockIdx.x * 256 + threadIdx.x;
    if (idx < 16384) {
        int i = idx >> 8, dd = idx & 255;
        W_int[idx] = W_in[dd * 64 + i];
    } else if (idx < 16384 + 70656) {
        int j = idx - 16384;
        int f = j >> 8, dd = j & 255;
        peWt[j] = peW[dd * 276 + f];
    }
}

// ---------------------------------------------------------------------------
__global__ __launch_bounds__(256) void cvt_bf16_kernel(
    const float* __restrict__ s, unsigned short* __restrict__ d, int n)
{
    int i = (blockIdx.x * 256 + threadIdx.x) * 4;
    if (i >= n) return;
    float4 v = *(const float4*)(s + i);
    unsigned long long pk = (unsigned long long)f2bf(v.x)
        | ((unsigned long long)f2bf(v.y) << 16)
        | ((unsigned long long)f2bf(v.z) << 32)
        | ((unsigned long long)f2bf(v.w) << 48);
    *(unsigned long long*)(d + i) = pk;
}

// ---------------------------------------------------------------------------
// prep: h0 = [CLS; x@W_in^T + b_in] + PE ;  also cl, csf, padf arrays
__global__ __launch_bounds__(256) void prep_kernel(
    const float* __restrict__ x, const float* __restrict__ c_local,
    const float* __restrict__ c_sink, const float* __restrict__ W_int,
    const float* __restrict__ b_in, const float* __restrict__ cls_tok,
    const float* __restrict__ peWt, const float* __restrict__ pe_b,
    const float* __restrict__ pe_g, const float* __restrict__ pe_bb,
    const float* __restrict__ pe_gain_p, const float* __restrict__ corr_floor_p,
    const int* __restrict__ lengths,
    float* __restrict__ h, float* __restrict__ clb, float* __restrict__ csfb,
    float* __restrict__ padfb)
{
    __shared__ __align__(16) float xs[8][64];
    __shared__ __align__(16) float zs[8][276];
    __shared__ __align__(16) float pes[8][256];
    __shared__ float mn[8], rsd[8];
    const int t = threadIdx.x;
    const int tok0 = blockIdx.x * 8;
    const int b = tok0 >> 9;
    const int len_b = lengths[b];
    const float cf = *corr_floor_p;
    const float gain = *pe_gain_p;

    float clv[8], csv[8];
    bool mk[8];
#pragma unroll
    for (int k = 0; k < 8; ++k) {
        int l = (tok0 + k) & 511;
        if (l == 0) { clv[k] = 1.f; csv[k] = 1.f; mk[k] = false; }
        else {
            float a = c_local[b * 511 + l - 1];
            float s = c_sink[b * 511 + l - 1];
            clv[k] = fminf(fmaxf(a, 0.f), 1.f);
            csv[k] = fminf(fmaxf(s, 0.f), 1.f);
            mk[k] = (l - 1) >= len_b;
        }
    }
    if (t < 8) {
        int tok = tok0 + t;
        clb[tok] = clv[t];
        csfb[tok] = cf + (1.f - cf) * csv[t];
        padfb[tok] = mk[t] ? 1.f : 0.f;
    }
    for (int idx = t; idx < 512; idx += 256) {
        int k = idx >> 6, i = idx & 63;
        int l = (tok0 + k) & 511;
        xs[k][i] = (l == 0) ? 0.f : x[((size_t)b * 511 + l - 1) * 64 + i];
    }
    {
        int kk = t >> 1;
        float div = expf((float)(2 * kk) * -0.035977892078032f);
#pragma unroll
        for (int k = 0; k < 8; ++k) {
            int l = (tok0 + k) & 511;
            float a = (float)l * div;
            zs[k][t] = (t & 1) ? cosf(a) : sinf(a);
        }
    }
    if (t < 20) {
#pragma unroll
        for (int k = 0; k < 8; ++k) {
            float cl = clv[k], cs = csv[k];
            float v;
            if (t == 0) v = cl;
            else if (t == 1) v = cs;
            else if (t == 2) v = cl * cs;
            else if (t == 3) v = fabsf(cl - cs);
            else if (t < 12) {
                float c = (float)(t - 4) * (1.f / 7.f);
                float dd = (cl - c) / 0.200001f;
                v = expf(-0.5f * dd * dd);
            } else {
                float c = (float)(t - 12) * (1.f / 7.f);
                float dd = (cs - c) / 0.200001f;
                v = expf(-0.5f * dd * dd);
            }
            zs[k][256 + t] = v;
        }
    }
    __syncthreads();

    float base[8];
#pragma unroll
    for (int k = 0; k < 8; ++k) base[k] = b_in[t];
    for (int i = 0; i < 64; ++i) {
        float wv = W_int[i * 256 + t];
#pragma unroll
        for (int k = 0; k < 8; ++k) base[k] += xs[k][i] * wv;
    }
#pragma unroll
    for (int k = 0; k < 8; ++k) {
        int l = (tok0 + k) & 511;
        if (l == 0) base[k] = cls_tok[t];
    }
    float acc[8];
#pragma unroll
    for (int k = 0; k < 8; ++k) acc[k] = pe_b[t];
    for (int f = 0; f < 276; ++f) {
        float wv = peWt[f * 256 + t];
#pragma unroll
        for (int k = 0; k < 8; ++k) acc[k] += zs[k][f] * wv;
    }
#pragma unroll
    for (int k = 0; k < 8; ++k) pes[k][t] = acc[k];
    __syncthreads();

    {
        int w = t >> 6, lane = t & 63;
#pragma unroll
        for (int p = 0; p < 2; ++p) {
            int k = w + p * 4;
            float4 v = *(const float4*)&pes[k][lane * 4];
            float s = v.x + v.y + v.z + v.w;
            float sq = v.x * v.x + v.y * v.y + v.z * v.z + v.w * v.w;
#pragma unroll
            for (int off = 32; off; off >>= 1) {
                s += __shfl_xor(s, off);
                sq += __shfl_xor(sq, off);
            }
            if (lane == 0) {
                float mean = s * (1.f / 256.f);
                mn[k] = mean;
                rsd[k] = rsqrtf(sq * (1.f / 256.f) - mean * mean + 1e-5f);
            }
        }
    }
    __syncthreads();
    float gv = pe_g[t], bv = pe_bb[t];
#pragma unroll
    for (int k = 0; k < 8; ++k) {
        float pe = (pes[k][t] - mn[k]) * rsd[k] * gv + bv;
        pe *= gain;
        if (mk[k]) pe = 0.f;
        h[(size_t)(tok0 + k) * 256 + t] = base[k] + pe;
    }
}

// ---------------------------------------------------------------------------
// LayerNorm D=256, bf16 output: one wave per token, 4 tokens per block
__global__ __launch_bounds__(256) void ln_bf_kernel(
    const float* __restrict__ x, const float* __restrict__ g,
    const float* __restrict__ b, unsigned short* __restrict__ y)
{
    int tok = blockIdx.x * 4 + (threadIdx.x >> 6);
    int lane = threadIdx.x & 63;
    const float* row = x + (size_t)tok * 256;
    float4 v = *(const float4*)(row + lane * 4);
    float s = v.x + v.y + v.z + v.w;
    float sq = v.x * v.x + v.y * v.y + v.z * v.z + v.w * v.w;
#pragma unroll
    for (int off = 32; off; off >>= 1) {
        s += __shfl_xor(s, off);
        sq += __shfl_xor(sq, off);
    }
    float mean = s * (1.f / 256.f);
    float rs = rsqrtf(sq * (1.f / 256.f) - mean * mean + 1e-5f);
    float4 gv = *(const float4*)(g + lane * 4);
    float4 bv = *(const float4*)(b + lane * 4);
    unsigned long long pk =
          (unsigned long long)f2bf((v.x - mean) * rs * gv.x + bv.x)
        | ((unsigned long long)f2bf((v.y - mean) * rs * gv.y + bv.y) << 16)
        | ((unsigned long long)f2bf((v.z - mean) * rs * gv.z + bv.z) << 32)
        | ((unsigned long long)f2bf((v.w - mean) * rs * gv.w + bv.w) << 48);
    *(unsigned long long*)(y + (size_t)tok * 256 + lane * 4) = pk;
}

// Final LN on the 32 CLS rows only (f32 out)
__global__ __launch_bounds__(256) void out_ln_kernel(
    const float* __restrict__ h, const float* __restrict__ g,
    const float* __restrict__ b, float* __restrict__ out)
{
    int tok = blockIdx.x * 4 + (threadIdx.x >> 6);
    int lane = threadIdx.x & 63;
    const float* row = h + (size_t)tok * 512 * 256;
    float4 v = *(const float4*)(row + lane * 4);
    float s = v.x + v.y + v.z + v.w;
    float sq = v.x * v.x + v.y * v.y + v.z * v.z + v.w * v.w;
#pragma unroll
    for (int off = 32; off; off >>= 1) {
        s += __shfl_xor(s, off);
        sq += __shfl_xor(sq, off);
    }
    float mean = s * (1.f / 256.f);
    float rs = rsqrtf(sq * (1.f / 256.f) - mean * mean + 1e-5f);
    float4 gv = *(const float4*)(g + lane * 4);
    float4 bv = *(const float4*)(b + lane * 4);
    float4 o;
    o.x = (v.x - mean) * rs * gv.x + bv.x;
    o.y = (v.y - mean) * rs * gv.y + bv.y;
    o.z = (v.z - mean) * rs * gv.z + bv.z;
    o.w = (v.w - mean) * rs * gv.w + bv.w;
    *(float4*)(out + (size_t)tok * 256 + lane * 4) = o;
}

// ---------------------------------------------------------------------------
// bf16 MFMA GEMM: C[M,N] = epi(A[M,K] @ W[N,K]^T + bias)
// 128x64 tile, BK=64, 4 waves (2Mx2N), 16x16x32 MFMA, global_load_lds staging
// with pre-swizzled source (XOR slot^(row&7)) so ds_read_b128 is 2-way (free).
// EPI: 0 = QKV 3-way bf16 split store, 1 = f32 residual accumulate into hres,
//      2 = GELU -> bf16
template <int EPI>
__global__ __launch_bounds__(256) void gemm_bf16_kernel(
    const unsigned short* __restrict__ A, const unsigned short* __restrict__ W,
    const float* __restrict__ bias, float* __restrict__ hres,
    unsigned short* __restrict__ o0, unsigned short* __restrict__ o1,
    unsigned short* __restrict__ o2, int M, int N, int K)
{
    __shared__ __align__(16) unsigned short As[128 * 64];
    __shared__ __align__(16) unsigned short Bs[64 * 64];
    const int t = threadIdx.x;
    const int wid = t >> 6, lane = t & 63;
    const int lo = lane & 15, hi = lane >> 4;
    const int wm = wid >> 1, wn = wid & 1;
    const int m0 = blockIdx.y * 128, n0 = blockIdx.x * 64;
    const int lrow = lane >> 3, lc = lane & 7;
    f32x4 acc[4][2] = {};
    for (int k0 = 0; k0 < K; k0 += 64) {
        __syncthreads();
#pragma unroll
        for (int is = 0; is < 4; ++is) {
            int r = wid * 32 + is * 8 + lrow;
            const unsigned short* g = A + (size_t)(m0 + r) * K + k0 + ((lc ^ (r & 7)) * 8);
            gload16(g, &As[(wid * 32 + is * 8) * 64]);
        }
#pragma unroll
        for (int is = 0; is < 2; ++is) {
            int r = wid * 16 + is * 8 + lrow;
            const unsigned short* g = W + (size_t)(n0 + r) * K + k0 + ((lc ^ (r & 7)) * 8);
            gload16(g, &Bs[(wid * 16 + is * 8) * 64]);
        }
        __syncthreads();
#pragma unroll
        for (int kh = 0; kh < 2; ++kh) {
            bf16x8 bfr[2];
#pragma unroll
            for (int nf = 0; nf < 2; ++nf) {
                int r = wn * 32 + nf * 16 + lo;
                bfr[nf] = *(const bf16x8*)&Bs[r * 64 + (((kh * 4 + hi) ^ (r & 7)) * 8)];
            }
#pragma unroll
            for (int mf = 0; mf < 4; ++mf) {
                int r = wm * 64 + mf * 16 + lo;
                bf16x8 afr = *(const bf16x8*)&As[r * 64 + (((kh * 4 + hi) ^ (r & 7)) * 8)];
                acc[mf][0] = __builtin_amdgcn_mfma_f32_16x16x32_bf16(afr, bfr[0], acc[mf][0], 0, 0, 0);
                acc[mf][1] = __builtin_amdgcn_mfma_f32_16x16x32_bf16(afr, bfr[1], acc[mf][1], 0, 0, 0);
            }
        }
    }
#pragma unroll
    for (int mf = 0; mf < 4; ++mf) {
        const int mbase = m0 + wm * 64 + mf * 16 + hi * 4;
#pragma unroll
        for (int nf = 0; nf < 2; ++nf) {
            const int n = n0 + wn * 32 + nf * 16 + lo;
            const float bv = bias[n];
            f32x4 v = acc[mf][nf];
            if constexpr (EPI == 1) {
#pragma unroll
                for (int rg = 0; rg < 4; ++rg) {
                    size_t idx = (size_t)(mbase + rg) * N + n;
                    hres[idx] += v[rg] + bv;
                }
            } else if constexpr (EPI == 0) {
                unsigned short* dst = (n0 < 256) ? o0 : ((n0 < 512) ? o1 : o2);
                const int c = n & 255;
#pragma unroll
                for (int rg = 0; rg < 4; ++rg)
                    dst[(size_t)(mbase + rg) * 256 + c] = f2bf(v[rg] + bv);
            } else {
#pragma unroll
                for (int rg = 0; rg < 4; ++rg)
                    o0[(size_t)(mbase + rg) * N + n] = f2bf(gelu_f(v[rg] + bv));
            }
        }
    }
}

// ---------------------------------------------------------------------------
// MFMA flash attention, swapped operands. Block = (b, head, half of q-tiles).
// S^T = K.Q^T  -> per-lane q-column stats -> P^T in-register -> O^T = V^T.P^T
__global__ __launch_bounds__(256) void attn_mfma_kernel(
    const unsigned short* __restrict__ Qb, const unsigned short* __restrict__ Kb,
    const unsigned short* __restrict__ Vb,
    const float* __restrict__ clb, const float* __restrict__ csfb,
    const float* __restrict__ padfb, const float* __restrict__ alpha_p,
    const float* __restrict__ beta_p, unsigned short* __restrict__ Ob)
{
    __shared__ __align__(16) unsigned short Kl[512 * 40];  // 80B rows (pad 8)
    __shared__ __align__(16) unsigned short Vt[32 * 516];  // V^T, stride 516
    __shared__ __align__(16) float cls[512];
    __shared__ __align__(16) float csfs[512];
    __shared__ __align__(16) float pads[512];
    const int t = threadIdx.x;
    const int bh = blockIdx.x >> 1, hf = blockIdx.x & 1;
    const int b = bh >> 3, hd = bh & 7;
    const size_t base = ((size_t)b * 512) * 256 + hd * 32;
    for (int i = t; i < 4096; i += 256) {
        int row = i >> 3, c4 = i & 7;
        *(unsigned long long*)(Kl + row * 40 + c4 * 4) =
            *(const unsigned long long*)(Kb + base + (size_t)row * 256 + c4 * 4);
        unsigned long long vv =
            *(const unsigned long long*)(Vb + base + (size_t)row * 256 + c4 * 4);
#pragma unroll
        for (int e = 0; e < 4; ++e)
            Vt[(c4 * 4 + e) * 516 + row] = (unsigned short)(vv >> (16 * e));
    }
    for (int i = t; i < 512; i += 256) {
        cls[i] = clb[b * 512 + i];
        csfs[i] = csfb[b * 512 + i];
        pads[i] = padfb[b * 512 + i];
    }
    __syncthreads();
    const int w = t >> 6, lane = t & 63, lo = lane & 15, hi = lane >> 4;
    const float alpha = *alpha_p, beta = *beta_p;
    const float scale = 0.17677669529663687f;
    for (int qi = 0; qi < 4; ++qi) {
        const int q0 = (hf * 16 + w * 4 + qi) * 16;
        const int i = q0 + lo;
        bf16x8 qf = *(const bf16x8*)(Qb + base + (size_t)i * 256 + hi * 8);
        const float mi = pads[i];
        const bool iv = mi < 0.5f;
        const float csb = beta * csfs[i];
        const float cli = cls[i];
        f32x4 acc0 = {0.f, 0.f, 0.f, 0.f}, acc1 = {0.f, 0.f, 0.f, 0.f};
        float m = -1e30f, lsum = 0.f;
        for (int ktp = 0; ktp < 16; ++ktp) {
            const int k16 = ktp * 32;
            bf16x8 kf0 = *(const bf16x8*)&Kl[(k16 + lo) * 40 + hi * 8];
            bf16x8 kf1 = *(const bf16x8*)&Kl[(k16 + 16 + lo) * 40 + hi * 8];
            f32x4 z = {0.f, 0.f, 0.f, 0.f};
            f32x4 s0 = __builtin_amdgcn_mfma_f32_16x16x32_bf16(kf0, qf, z, 0, 0, 0);
            f32x4 s1 = __builtin_amdgcn_mfma_f32_16x16x32_bf16(kf1, qf, z, 0, 0, 0);
            f32x4 csf0 = *(const f32x4*)&csfs[k16 + hi * 4];
            f32x4 csf1 = *(const f32x4*)&csfs[k16 + 16 + hi * 4];
            f32x4 pad0 = *(const f32x4*)&pads[k16 + hi * 4];
            f32x4 pad1 = *(const f32x4*)&pads[k16 + 16 + hi * 4];
            f32x4 cl0 = *(const f32x4*)&cls[k16 + hi * 4];
            f32x4 cl1 = *(const f32x4*)&cls[k16 + 16 + hi * 4];
            float sc[8];
#pragma unroll
            for (int r = 0; r < 8; ++r) {
                const int j = k16 + (r < 4 ? 0 : 16) + hi * 4 + (r & 3);
                float sv = (r < 4 ? s0[r & 3] : s1[r & 3]) * scale;
                const float padj = (r < 4 ? pad0[r & 3] : pad1[r & 3]);
                const float csfj = (r < 4 ? csf0[r & 3] : csf1[r & 3]);
                const float clj = (r < 4 ? cl0[r & 3] : cl1[r & 3]);
                if (iv && padj < 0.5f) {
                    float bb = csb * csfj;
                    const int dij = j - i;
                    if (dij == 1 || dij == -1) {
                        float ce;
                        if (i <= 510 && j >= 1) ce = clj;
                        else if (i >= 1 && j <= 510) ce = cli;
                        else ce = 0.f;
                        bb += alpha * ce;
                    }
                    sv += bb;
                }
                sv -= 10000.f * padj;
                sc[r] = sv;
            }
            float tm = sc[0];
#pragma unroll
            for (int r = 1; r < 8; ++r) tm = fmaxf(tm, sc[r]);
            tm = fmaxf(tm, __shfl_xor(tm, 16));
            tm = fmaxf(tm, __shfl_xor(tm, 32));
            const float mnw = fmaxf(m, tm);
            const float fs = expf(m - mnw);
            m = mnw;
            float ps = 0.f;
            unsigned long long plo = 0, phi2 = 0;
#pragma unroll
            for (int r = 0; r < 4; ++r) {
                float p = expf(sc[r] - mnw);
                ps += p;
                plo |= ((unsigned long long)f2bf(p)) << (16 * r);
            }
#pragma unroll
            for (int r = 0; r < 4; ++r) {
                float p = expf(sc[4 + r] - mnw);
                ps += p;
                phi2 |= ((unsigned long long)f2bf(p)) << (16 * r);
            }
            ps += __shfl_xor(ps, 16);
            ps += __shfl_xor(ps, 32);
            lsum = lsum * fs + ps;
#pragma unroll
            for (int c = 0; c < 4; ++c) { acc0[c] *= fs; acc1[c] *= fs; }
            union U16 { unsigned long long q[2]; bf16x8 v; } pu, vu0, vu1;
            pu.q[0] = plo; pu.q[1] = phi2;
            vu0.q[0] = *(const unsigned long long*)&Vt[lo * 516 + k16 + hi * 4];
            vu0.q[1] = *(const unsigned long long*)&Vt[lo * 516 + k16 + 16 + hi * 4];
            vu1.q[0] = *(const unsigned long long*)&Vt[(16 + lo) * 516 + k16 + hi * 4];
            vu1.q[1] = *(const unsigned long long*)&Vt[(16 + lo) * 516 + k16 + 16 + hi * 4];
            acc0 = __builtin_amdgcn_mfma_f32_16x16x32_bf16(vu0.v, pu.v, acc0, 0, 0, 0);
            acc1 = __builtin_amdgcn_mfma_f32_16x16x32_bf16(vu1.v, pu.v, acc1, 0, 0, 0);
        }
        const float inv = 1.f / lsum;
        unsigned long long oa = 0, ob = 0;
#pragma unroll
        for (int rg = 0; rg < 4; ++rg) {
            oa |= ((unsigned long long)f2bf(acc0[rg] * inv)) << (16 * rg);
            ob |= ((unsigned long long)f2bf(acc1[rg] * inv)) << (16 * rg);
        }
        *(unsigned long long*)(Ob + base + (size_t)i * 256 + hi * 4) = oa;
        *(unsigned long long*)(Ob + base + (size_t)i * 256 + 16 + hi * 4) = ob;
    }
}

// ---------------------------------------------------------------------------
extern "C" void kernel_launch(void* const* d_in, const int* in_sizes, int n_in,
                              void* d_out, int out_size, void* d_ws, size_t ws_size,
                              hipStream_t stream) {
    const float* x         = (const float*)d_in[0];
    const float* c_local   = (const float*)d_in[1];
    const float* c_sink    = (const float*)d_in[2];
    const float* W_in      = (const float*)d_in[3];
    const float* b_in      = (const float*)d_in[4];
    const float* cls_token = (const float*)d_in[5];
    const float* pe_proj_W = (const float*)d_in[6];
    const float* pe_proj_b = (const float*)d_in[7];
    const float* pe_ln_g   = (const float*)d_in[8];
    const float* pe_ln_b   = (const float*)d_in[9];
    const float* pe_gain   = (const float*)d_in[10];
    const float* attn_Wqkv = (const float*)d_in[11];
    const float* attn_bqkv = (const float*)d_in[12];
    const float* attn_Wo   = (const float*)d_in[13];
    const float* attn_bo   = (const float*)d_in[14];
    const float* ff_W1     = (const float*)d_in[15];
    const float* ff_b1     = (const float*)d_in[16];
    const float* ff_W2     = (const float*)d_in[17];
    const float* ff_b2     = (const float*)d_in[18];
    const float* ln1_g     = (const float*)d_in[19];
    const float* ln1_b     = (const float*)d_in[20];
    const float* ln2_g     = (const float*)d_in[21];
    const float* ln2_b     = (const float*)d_in[22];
    const float* alpha     = (const float*)d_in[23];
    const float* beta      = (const float*)d_in[24];
    const float* corr_fl   = (const float*)d_in[25];
    const float* out_ln_g  = (const float*)d_in[26];
    const float* out_ln_b  = (const float*)d_in[27];
    const int*   lengths   = (const int*)d_in[28];
    float* out = (float*)d_out;

    float* h     = (float*)d_ws;              // 4194304 f
    float* clb   = h + 4194304;               // 16384
    float* csfb  = clb + 16384;
    float* padfb = csfb + 16384;
    float* W_int = padfb + 16384;             // 16384
    float* peWt  = W_int + 16384;             // 70656
    unsigned short* u_bf = (unsigned short*)(peWt + 70656);
    unsigned short* Q_bf = u_bf + 4194304;
    unsigned short* K_bf = Q_bf + 4194304;
    unsigned short* V_bf = K_bf + 4194304;
    unsigned short* o_bf = V_bf + 4194304;
    unsigned short* f_bf = o_bf + 4194304;    // 16777216
    unsigned short* wq_bf = f_bf + 16777216;  // 589824
    unsigned short* wo_bf = wq_bf + 589824;   // 196608
    unsigned short* w1_bf = wo_bf + 196608;   // 786432
    unsigned short* w2_bf = w1_bf + 786432;   // 786432

    transpose_kernel<<<340, 256, 0, stream>>>(W_in, pe_proj_W, W_int, peWt);
    prep_kernel<<<2048, 256, 0, stream>>>(x, c_local, c_sink, W_int, b_in, cls_token,
                                          peWt, pe_proj_b, pe_ln_g, pe_ln_b, pe_gain,
                                          corr_fl, lengths, h, clb, csfb, padfb);
    cvt_bf16_kernel<<<576, 256, 0, stream>>>(attn_Wqkv, wq_bf, 589824);
    cvt_bf16_kernel<<<192, 256, 0, stream>>>(attn_Wo, wo_bf, 196608);
    cvt_bf16_kernel<<<768, 256, 0, stream>>>(ff_W1, w1_bf, 786432);
    cvt_bf16_kernel<<<768, 256, 0, stream>>>(ff_W2, w2_bf, 786432);

    for (int l = 0; l < 3; ++l) {
        ln_bf_kernel<<<4096, 256, 0, stream>>>(h, ln1_g + 256 * l, ln1_b + 256 * l, u_bf);
        gemm_bf16_kernel<0><<<dim3(12, 128), 256, 0, stream>>>(
            u_bf, wq_bf + (size_t)l * 196608, attn_bqkv + 768 * l, nullptr,
            Q_bf, K_bf, V_bf, 16384, 768, 256);
        attn_mfma_kernel<<<512, 256, 0, stream>>>(Q_bf, K_bf, V_bf, clb, csfb, padfb,
                                                  alpha, beta, o_bf);
        gemm_bf16_kernel<1><<<dim3(4, 128), 256, 0, stream>>>(
            o_bf, wo_bf + (size_t)l * 65536, attn_bo + 256 * l, h,
            nullptr, nullptr, nullptr, 16384, 256, 256);
        ln_bf_kernel<<<4096, 256, 0, stream>>>(h, ln2_g + 256 * l, ln2_b + 256 * l, u_bf);
        gemm_bf16_kernel<2><<<dim3(16, 128), 256, 0, stream>>>(
            u_bf, w1_bf + (size_t)l * 262144, ff_b1 + 1024 * l, nullptr,
            f_bf, nullptr, nullptr, 16384, 1024, 256);
        gemm_bf16_kernel<1><<<dim3(4, 128), 256, 0, stream>>>(
            f_bf, w2_bf + (size_t)l * 262144, ff_b2 + 256 * l, h,
            nullptr, nullptr, nullptr, 16384, 256, 1024);
    }
    out_ln_kernel<<<8, 256, 0, stream>>>(h, out_ln_g, out_ln_b, out);
}

// Round 3
// 601.116 us; speedup vs baseline: 36.6132x; 1.1983x over previous
//
#include <hip/hip_runtime.h>
#include <math.h>

// B=32, L=512 (incl CLS), D=256, H=8, dh=32, N_LAYERS=3, D_FF=1024, tokens=16384

typedef __attribute__((ext_vector_type(4))) float f32x4;
typedef __attribute__((ext_vector_type(8))) short bf16x8;

__device__ __forceinline__ unsigned short f2bf(float f) {
    unsigned u = __builtin_bit_cast(unsigned, f);
    u += 0x7fff + ((u >> 16) & 1);
    return (unsigned short)(u >> 16);
}
__device__ __forceinline__ unsigned cvt_pk_bf16(float a, float b) {
    unsigned r;
    asm("v_cvt_pk_bf16_f32 %0, %1, %2" : "=v"(r) : "v"(a), "v"(b));
    return r;
}
__device__ __forceinline__ float gelu_f(float v) {
    return v * 0.5f * (1.0f + erff(v * 0.70710678118654752f));
}
__device__ __forceinline__ void gload16(const void* g, void* l) {
    __builtin_amdgcn_global_load_lds(
        (const __attribute__((address_space(1))) unsigned int*)g,
        (__attribute__((address_space(3))) unsigned int*)l, 16, 0, 0);
}

// ---------------------------------------------------------------------------
__global__ __launch_bounds__(256) void transpose_kernel(
    const float* __restrict__ W_in, const float* __restrict__ peW,
    float* __restrict__ W_int, float* __restrict__ peWt)
{
    int idx = blockIdx.x * 256 + threadIdx.x;
    if (idx < 16384) {
        int i = idx >> 8, dd = idx & 255;
        W_int[idx] = W_in[dd * 64 + i];
    } else if (idx < 16384 + 70656) {
        int j = idx - 16384;
        int f = j >> 8, dd = j & 255;
        peWt[j] = peW[dd * 276 + f];
    }
}

// ---------------------------------------------------------------------------
__global__ __launch_bounds__(256) void cvt_bf16_kernel(
    const float* __restrict__ s, unsigned short* __restrict__ d, int n)
{
    int i = (blockIdx.x * 256 + threadIdx.x) * 4;
    if (i >= n) return;
    float4 v = *(const float4*)(s + i);
    unsigned long long pk = (unsigned long long)f2bf(v.x)
        | ((unsigned long long)f2bf(v.y) << 16)
        | ((unsigned long long)f2bf(v.z) << 32)
        | ((unsigned long long)f2bf(v.w) << 48);
    *(unsigned long long*)(d + i) = pk;
}

// ---------------------------------------------------------------------------
// prep: h0 = [CLS; x@W_in^T + b_in] + PE ;  also cl, csf, padf arrays
__global__ __launch_bounds__(256) void prep_kernel(
    const float* __restrict__ x, const float* __restrict__ c_local,
    const float* __restrict__ c_sink, const float* __restrict__ W_int,
    const float* __restrict__ b_in, const float* __restrict__ cls_tok,
    const float* __restrict__ peWt, const float* __restrict__ pe_b,
    const float* __restrict__ pe_g, const float* __restrict__ pe_bb,
    const float* __restrict__ pe_gain_p, const float* __restrict__ corr_floor_p,
    const int* __restrict__ lengths,
    float* __restrict__ h, float* __restrict__ clb, float* __restrict__ csfb,
    float* __restrict__ padfb)
{
    __shared__ __align__(16) float xs[8][64];
    __shared__ __align__(16) float zs[8][276];
    __shared__ __align__(16) float pes[8][256];
    __shared__ float mn[8], rsd[8];
    const int t = threadIdx.x;
    const int tok0 = blockIdx.x * 8;
    const int b = tok0 >> 9;
    const int len_b = lengths[b];
    const float cf = *corr_floor_p;
    const float gain = *pe_gain_p;

    float clv[8], csv[8];
    bool mk[8];
#pragma unroll
    for (int k = 0; k < 8; ++k) {
        int l = (tok0 + k) & 511;
        if (l == 0) { clv[k] = 1.f; csv[k] = 1.f; mk[k] = false; }
        else {
            float a = c_local[b * 511 + l - 1];
            float s = c_sink[b * 511 + l - 1];
            clv[k] = fminf(fmaxf(a, 0.f), 1.f);
            csv[k] = fminf(fmaxf(s, 0.f), 1.f);
            mk[k] = (l - 1) >= len_b;
        }
    }
    if (t < 8) {
        int tok = tok0 + t;
        clb[tok] = clv[t];
        csfb[tok] = cf + (1.f - cf) * csv[t];
        padfb[tok] = mk[t] ? 1.f : 0.f;
    }
    for (int idx = t; idx < 512; idx += 256) {
        int k = idx >> 6, i = idx & 63;
        int l = (tok0 + k) & 511;
        xs[k][i] = (l == 0) ? 0.f : x[((size_t)b * 511 + l - 1) * 64 + i];
    }
    {
        int kk = t >> 1;
        float div = expf((float)(2 * kk) * -0.035977892078032f);
#pragma unroll
        for (int k = 0; k < 8; ++k) {
            int l = (tok0 + k) & 511;
            float a = (float)l * div;
            zs[k][t] = (t & 1) ? cosf(a) : sinf(a);
        }
    }
    if (t < 20) {
#pragma unroll
        for (int k = 0; k < 8; ++k) {
            float cl = clv[k], cs = csv[k];
            float v;
            if (t == 0) v = cl;
            else if (t == 1) v = cs;
            else if (t == 2) v = cl * cs;
            else if (t == 3) v = fabsf(cl - cs);
            else if (t < 12) {
                float c = (float)(t - 4) * (1.f / 7.f);
                float dd = (cl - c) / 0.200001f;
                v = expf(-0.5f * dd * dd);
            } else {
                float c = (float)(t - 12) * (1.f / 7.f);
                float dd = (cs - c) / 0.200001f;
                v = expf(-0.5f * dd * dd);
            }
            zs[k][256 + t] = v;
        }
    }
    __syncthreads();

    float base[8];
#pragma unroll
    for (int k = 0; k < 8; ++k) base[k] = b_in[t];
    for (int i = 0; i < 64; ++i) {
        float wv = W_int[i * 256 + t];
#pragma unroll
        for (int k = 0; k < 8; ++k) base[k] += xs[k][i] * wv;
    }
#pragma unroll
    for (int k = 0; k < 8; ++k) {
        int l = (tok0 + k) & 511;
        if (l == 0) base[k] = cls_tok[t];
    }
    float acc[8];
#pragma unroll
    for (int k = 0; k < 8; ++k) acc[k] = pe_b[t];
    for (int f = 0; f < 276; ++f) {
        float wv = peWt[f * 256 + t];
#pragma unroll
        for (int k = 0; k < 8; ++k) acc[k] += zs[k][f] * wv;
    }
#pragma unroll
    for (int k = 0; k < 8; ++k) pes[k][t] = acc[k];
    __syncthreads();

    {
        int w = t >> 6, lane = t & 63;
#pragma unroll
        for (int p = 0; p < 2; ++p) {
            int k = w + p * 4;
            float4 v = *(const float4*)&pes[k][lane * 4];
            float s = v.x + v.y + v.z + v.w;
            float sq = v.x * v.x + v.y * v.y + v.z * v.z + v.w * v.w;
#pragma unroll
            for (int off = 32; off; off >>= 1) {
                s += __shfl_xor(s, off);
                sq += __shfl_xor(sq, off);
            }
            if (lane == 0) {
                float mean = s * (1.f / 256.f);
                mn[k] = mean;
                rsd[k] = rsqrtf(sq * (1.f / 256.f) - mean * mean + 1e-5f);
            }
        }
    }
    __syncthreads();
    float gv = pe_g[t], bv = pe_bb[t];
#pragma unroll
    for (int k = 0; k < 8; ++k) {
        float pe = (pes[k][t] - mn[k]) * rsd[k] * gv + bv;
        pe *= gain;
        if (mk[k]) pe = 0.f;
        h[(size_t)(tok0 + k) * 256 + t] = base[k] + pe;
    }
}

// ---------------------------------------------------------------------------
// ADD[b][i][j] = log2(e) * (bias_masked(i,j) - 10000*pad_j)  (layer-invariant)
__global__ __launch_bounds__(256) void add_bias_kernel(
    const float* __restrict__ clb, const float* __restrict__ csfb,
    const float* __restrict__ padfb, const float* __restrict__ alpha_p,
    const float* __restrict__ beta_p, float* __restrict__ ADD)
{
    const int b = blockIdx.x >> 9, i = blockIdx.x & 511;
    const int t = threadIdx.x;
    const float alpha = *alpha_p;
    const float pad_i = padfb[b * 512 + i];
    const float csb = (*beta_p) * csfb[b * 512 + i];
    const bool iv = pad_i < 0.5f;
    const float L2E = 1.4426950408889634f;
    float2 o;
#pragma unroll
    for (int u = 0; u < 2; ++u) {
        int j = 2 * t + u;
        float padj = padfb[b * 512 + j];
        float v = -10000.f * padj;
        if (iv && padj < 0.5f) {
            float bb = csb * csfb[b * 512 + j];
            int d = j - i;
            if (d == 1 || d == -1) {
                float ce;
                if (i <= 510 && j >= 1) ce = clb[b * 512 + j];
                else if (i >= 1 && j <= 510) ce = clb[b * 512 + i];
                else ce = 0.f;
                bb += alpha * ce;
            }
            v += bb;
        }
        ((float*)&o)[u] = v * L2E;
    }
    *(float2*)(ADD + (size_t)b * 262144 + (size_t)i * 512 + 2 * t) = o;
}

// ---------------------------------------------------------------------------
// LayerNorm D=256, bf16 output: one wave per token, 4 tokens per block
__global__ __launch_bounds__(256) void ln_bf_kernel(
    const float* __restrict__ x, const float* __restrict__ g,
    const float* __restrict__ b, unsigned short* __restrict__ y)
{
    int tok = blockIdx.x * 4 + (threadIdx.x >> 6);
    int lane = threadIdx.x & 63;
    const float* row = x + (size_t)tok * 256;
    float4 v = *(const float4*)(row + lane * 4);
    float s = v.x + v.y + v.z + v.w;
    float sq = v.x * v.x + v.y * v.y + v.z * v.z + v.w * v.w;
#pragma unroll
    for (int off = 32; off; off >>= 1) {
        s += __shfl_xor(s, off);
        sq += __shfl_xor(sq, off);
    }
    float mean = s * (1.f / 256.f);
    float rs = rsqrtf(sq * (1.f / 256.f) - mean * mean + 1e-5f);
    float4 gv = *(const float4*)(g + lane * 4);
    float4 bv = *(const float4*)(b + lane * 4);
    unsigned long long pk =
          (unsigned long long)f2bf((v.x - mean) * rs * gv.x + bv.x)
        | ((unsigned long long)f2bf((v.y - mean) * rs * gv.y + bv.y) << 16)
        | ((unsigned long long)f2bf((v.z - mean) * rs * gv.z + bv.z) << 32)
        | ((unsigned long long)f2bf((v.w - mean) * rs * gv.w + bv.w) << 48);
    *(unsigned long long*)(y + (size_t)tok * 256 + lane * 4) = pk;
}

// Final LN on the 32 CLS rows only (f32 out)
__global__ __launch_bounds__(256) void out_ln_kernel(
    const float* __restrict__ h, const float* __restrict__ g,
    const float* __restrict__ b, float* __restrict__ out)
{
    int tok = blockIdx.x * 4 + (threadIdx.x >> 6);
    int lane = threadIdx.x & 63;
    const float* row = h + (size_t)tok * 512 * 256;
    float4 v = *(const float4*)(row + lane * 4);
    float s = v.x + v.y + v.z + v.w;
    float sq = v.x * v.x + v.y * v.y + v.z * v.z + v.w * v.w;
#pragma unroll
    for (int off = 32; off; off >>= 1) {
        s += __shfl_xor(s, off);
        sq += __shfl_xor(sq, off);
    }
    float mean = s * (1.f / 256.f);
    float rs = rsqrtf(sq * (1.f / 256.f) - mean * mean + 1e-5f);
    float4 gv = *(const float4*)(g + lane * 4);
    float4 bv = *(const float4*)(b + lane * 4);
    float4 o;
    o.x = (v.x - mean) * rs * gv.x + bv.x;
    o.y = (v.y - mean) * rs * gv.y + bv.y;
    o.z = (v.z - mean) * rs * gv.z + bv.z;
    o.w = (v.w - mean) * rs * gv.w + bv.w;
    *(float4*)(out + (size_t)tok * 256 + lane * 4) = o;
}

// ---------------------------------------------------------------------------
// bf16 MFMA GEMM: C[M,N] = epi(A[M,K] @ W[N,K]^T + bias)
// EPI: 0 = QKV 3-way bf16 split store (Q scaled by scale*log2e),
//      1 = f32 residual accumulate into hres, 2 = GELU -> bf16
template <int EPI>
__global__ __launch_bounds__(256) void gemm_bf16_kernel(
    const unsigned short* __restrict__ A, const unsigned short* __restrict__ W,
    const float* __restrict__ bias, float* __restrict__ hres,
    unsigned short* __restrict__ o0, unsigned short* __restrict__ o1,
    unsigned short* __restrict__ o2, int M, int N, int K)
{
    __shared__ __align__(16) unsigned short As[128 * 64];
    __shared__ __align__(16) unsigned short Bs[64 * 64];
    const int t = threadIdx.x;
    const int wid = t >> 6, lane = t & 63;
    const int lo = lane & 15, hi = lane >> 4;
    const int wm = wid >> 1, wn = wid & 1;
    const int m0 = blockIdx.y * 128, n0 = blockIdx.x * 64;
    const int lrow = lane >> 3, lc = lane & 7;
    f32x4 acc[4][2] = {};
    for (int k0 = 0; k0 < K; k0 += 64) {
        __syncthreads();
#pragma unroll
        for (int is = 0; is < 4; ++is) {
            int r = wid * 32 + is * 8 + lrow;
            const unsigned short* g = A + (size_t)(m0 + r) * K + k0 + ((lc ^ (r & 7)) * 8);
            gload16(g, &As[(wid * 32 + is * 8) * 64]);
        }
#pragma unroll
        for (int is = 0; is < 2; ++is) {
            int r = wid * 16 + is * 8 + lrow;
            const unsigned short* g = W + (size_t)(n0 + r) * K + k0 + ((lc ^ (r & 7)) * 8);
            gload16(g, &Bs[(wid * 16 + is * 8) * 64]);
        }
        __syncthreads();
#pragma unroll
        for (int kh = 0; kh < 2; ++kh) {
            bf16x8 bfr[2];
#pragma unroll
            for (int nf = 0; nf < 2; ++nf) {
                int r = wn * 32 + nf * 16 + lo;
                bfr[nf] = *(const bf16x8*)&Bs[r * 64 + (((kh * 4 + hi) ^ (r & 7)) * 8)];
            }
#pragma unroll
            for (int mf = 0; mf < 4; ++mf) {
                int r = wm * 64 + mf * 16 + lo;
                bf16x8 afr = *(const bf16x8*)&As[r * 64 + (((kh * 4 + hi) ^ (r & 7)) * 8)];
                acc[mf][0] = __builtin_amdgcn_mfma_f32_16x16x32_bf16(afr, bfr[0], acc[mf][0], 0, 0, 0);
                acc[mf][1] = __builtin_amdgcn_mfma_f32_16x16x32_bf16(afr, bfr[1], acc[mf][1], 0, 0, 0);
            }
        }
    }
#pragma unroll
    for (int mf = 0; mf < 4; ++mf) {
        const int mbase = m0 + wm * 64 + mf * 16 + hi * 4;
#pragma unroll
        for (int nf = 0; nf < 2; ++nf) {
            const int n = n0 + wn * 32 + nf * 16 + lo;
            const float bv = bias[n];
            f32x4 v = acc[mf][nf];
            if constexpr (EPI == 1) {
#pragma unroll
                for (int rg = 0; rg < 4; ++rg) {
                    size_t idx = (size_t)(mbase + rg) * N + n;
                    hres[idx] += v[rg] + bv;
                }
            } else if constexpr (EPI == 0) {
                unsigned short* dst = (n0 < 256) ? o0 : ((n0 < 512) ? o1 : o2);
                const float qsc = (n0 < 256)
                    ? (0.17677669529663687f * 1.4426950408889634f) : 1.f;
                const int c = n & 255;
#pragma unroll
                for (int rg = 0; rg < 4; ++rg)
                    dst[(size_t)(mbase + rg) * 256 + c] = f2bf((v[rg] + bv) * qsc);
            } else {
#pragma unroll
                for (int rg = 0; rg < 4; ++rg)
                    o0[(size_t)(mbase + rg) * N + n] = f2bf(gelu_f(v[rg] + bv));
            }
        }
    }
}

// ---------------------------------------------------------------------------
// MFMA flash attention, swapped operands, bias via C-operand init.
// S^T = K.Q^T + ADD -> per-lane q-column online softmax (base 2) -> O^T = V^T.P^T
__global__ __launch_bounds__(256) void attn_mfma_kernel(
    const unsigned short* __restrict__ Qb, const unsigned short* __restrict__ Kb,
    const unsigned short* __restrict__ Vb, const float* __restrict__ ADD,
    unsigned short* __restrict__ Ob)
{
    __shared__ __align__(16) unsigned short Kl[256 * 40];  // 80B rows (pad 8)
    __shared__ __align__(16) unsigned short Vt[32 * 260];  // V^T, stride 260
    const int t = threadIdx.x;
    const int swz = ((blockIdx.x & 7) << 6) | (blockIdx.x >> 3);  // XCD chunking
    const int bh = swz >> 1, hf = swz & 1;
    const int b = bh >> 3, hd = bh & 7;
    const size_t base = ((size_t)b * 512) * 256 + hd * 32;
    const int w = t >> 6, lane = t & 63, lo = lane & 15, hi = lane >> 4;
    const float* ADDb = ADD + (size_t)b * 262144;

    int iq[4];
    bf16x8 qf[4];
#pragma unroll
    for (int qi = 0; qi < 4; ++qi) {
        iq[qi] = (hf * 16 + w * 4 + qi) * 16 + lo;
        qf[qi] = *(const bf16x8*)(Qb + base + (size_t)iq[qi] * 256 + hi * 8);
    }
    f32x4 acc[4][2] = {};
    float m[4], lsum[4];
#pragma unroll
    for (int qi = 0; qi < 4; ++qi) { m[qi] = -3e38f; lsum[qi] = 0.f; }

    for (int jt = 0; jt < 2; ++jt) {
        __syncthreads();
        for (int idx = t; idx < 1024; idx += 256) {       // K tile, 16B
            int row = idx >> 2, c4 = idx & 3;
            *(uint4*)&Kl[row * 40 + c4 * 8] =
                *(const uint4*)(Kb + base + (size_t)(jt * 256 + row) * 256 + c4 * 8);
        }
        for (int idx = t; idx < 1024; idx += 256) {       // V^T, paired rows
            int pr = idx >> 3, c4 = idx & 7;
            unsigned long long v0 = *(const unsigned long long*)
                (Vb + base + (size_t)(jt * 256 + 2 * pr) * 256 + c4 * 4);
            unsigned long long v1 = *(const unsigned long long*)
                (Vb + base + (size_t)(jt * 256 + 2 * pr + 1) * 256 + c4 * 4);
#pragma unroll
            for (int e = 0; e < 4; ++e) {
                unsigned a = (unsigned)((v0 >> (16 * e)) & 0xffffu);
                unsigned c = (unsigned)((v1 >> (16 * e)) & 0xffffu);
                *(unsigned*)&Vt[(c4 * 4 + e) * 260 + 2 * pr] = a | (c << 16);
            }
        }
        __syncthreads();
        for (int ktp = 0; ktp < 8; ++ktp) {
            const int k16 = ktp * 32;
            const int gj = jt * 256 + k16;
            bf16x8 kf0 = *(const bf16x8*)&Kl[(k16 + lo) * 40 + hi * 8];
            bf16x8 kf1 = *(const bf16x8*)&Kl[(k16 + 16 + lo) * 40 + hi * 8];
            union U16 { unsigned long long q[2]; unsigned w[4]; bf16x8 v; } vu0, vu1, pu;
            vu0.q[0] = *(const unsigned long long*)&Vt[lo * 260 + k16 + hi * 4];
            vu0.q[1] = *(const unsigned long long*)&Vt[lo * 260 + k16 + 16 + hi * 4];
            vu1.q[0] = *(const unsigned long long*)&Vt[(16 + lo) * 260 + k16 + hi * 4];
            vu1.q[1] = *(const unsigned long long*)&Vt[(16 + lo) * 260 + k16 + 16 + hi * 4];
#pragma unroll
            for (int qi = 0; qi < 4; ++qi) {
                f32x4 a0 = *(const f32x4*)(ADDb + (size_t)iq[qi] * 512 + gj + hi * 4);
                f32x4 a1 = *(const f32x4*)(ADDb + (size_t)iq[qi] * 512 + gj + 16 + hi * 4);
                f32x4 s0 = __builtin_amdgcn_mfma_f32_16x16x32_bf16(kf0, qf[qi], a0, 0, 0, 0);
                f32x4 s1 = __builtin_amdgcn_mfma_f32_16x16x32_bf16(kf1, qf[qi], a1, 0, 0, 0);
                float tm = fmaxf(fmaxf(fmaxf(s0[0], s0[1]), fmaxf(s0[2], s0[3])),
                                 fmaxf(fmaxf(s1[0], s1[1]), fmaxf(s1[2], s1[3])));
                tm = fmaxf(tm, __shfl_xor(tm, 16));
                tm = fmaxf(tm, __shfl_xor(tm, 32));
                const float mn2 = fmaxf(m[qi], tm);
                const float fs = exp2f(m[qi] - mn2);
                m[qi] = mn2;
                float p0 = exp2f(s0[0] - mn2), p1 = exp2f(s0[1] - mn2);
                float p2 = exp2f(s0[2] - mn2), p3 = exp2f(s0[3] - mn2);
                float p4 = exp2f(s1[0] - mn2), p5 = exp2f(s1[1] - mn2);
                float p6 = exp2f(s1[2] - mn2), p7 = exp2f(s1[3] - mn2);
                float ps = ((p0 + p1) + (p2 + p3)) + ((p4 + p5) + (p6 + p7));
                ps += __shfl_xor(ps, 16);
                ps += __shfl_xor(ps, 32);
                lsum[qi] = lsum[qi] * fs + ps;
                pu.w[0] = cvt_pk_bf16(p0, p1);
                pu.w[1] = cvt_pk_bf16(p2, p3);
                pu.w[2] = cvt_pk_bf16(p4, p5);
                pu.w[3] = cvt_pk_bf16(p6, p7);
#pragma unroll
                for (int c = 0; c < 4; ++c) { acc[qi][0][c] *= fs; acc[qi][1][c] *= fs; }
                acc[qi][0] = __builtin_amdgcn_mfma_f32_16x16x32_bf16(vu0.v, pu.v, acc[qi][0], 0, 0, 0);
                acc[qi][1] = __builtin_amdgcn_mfma_f32_16x16x32_bf16(vu1.v, pu.v, acc[qi][1], 0, 0, 0);
            }
        }
    }
#pragma unroll
    for (int qi = 0; qi < 4; ++qi) {
        const float inv = 1.f / lsum[qi];
        unsigned long long oa =
              (unsigned long long)cvt_pk_bf16(acc[qi][0][0] * inv, acc[qi][0][1] * inv)
            | ((unsigned long long)cvt_pk_bf16(acc[qi][0][2] * inv, acc[qi][0][3] * inv) << 32);
        unsigned long long ob2 =
              (unsigned long long)cvt_pk_bf16(acc[qi][1][0] * inv, acc[qi][1][1] * inv)
            | ((unsigned long long)cvt_pk_bf16(acc[qi][1][2] * inv, acc[qi][1][3] * inv) << 32);
        *(unsigned long long*)(Ob + base + (size_t)iq[qi] * 256 + hi * 4) = oa;
        *(unsigned long long*)(Ob + base + (size_t)iq[qi] * 256 + 16 + hi * 4) = ob2;
    }
}

// ---------------------------------------------------------------------------
extern "C" void kernel_launch(void* const* d_in, const int* in_sizes, int n_in,
                              void* d_out, int out_size, void* d_ws, size_t ws_size,
                              hipStream_t stream) {
    const float* x         = (const float*)d_in[0];
    const float* c_local   = (const float*)d_in[1];
    const float* c_sink    = (const float*)d_in[2];
    const float* W_in      = (const float*)d_in[3];
    const float* b_in      = (const float*)d_in[4];
    const float* cls_token = (const float*)d_in[5];
    const float* pe_proj_W = (const float*)d_in[6];
    const float* pe_proj_b = (const float*)d_in[7];
    const float* pe_ln_g   = (const float*)d_in[8];
    const float* pe_ln_b   = (const float*)d_in[9];
    const float* pe_gain   = (const float*)d_in[10];
    const float* attn_Wqkv = (const float*)d_in[11];
    const float* attn_bqkv = (const float*)d_in[12];
    const float* attn_Wo   = (const float*)d_in[13];
    const float* attn_bo   = (const float*)d_in[14];
    const float* ff_W1     = (const float*)d_in[15];
    const float* ff_b1     = (const float*)d_in[16];
    const float* ff_W2     = (const float*)d_in[17];
    const float* ff_b2     = (const float*)d_in[18];
    const float* ln1_g     = (const float*)d_in[19];
    const float* ln1_b     = (const float*)d_in[20];
    const float* ln2_g     = (const float*)d_in[21];
    const float* ln2_b     = (const float*)d_in[22];
    const float* alpha     = (const float*)d_in[23];
    const float* beta      = (const float*)d_in[24];
    const float* corr_fl   = (const float*)d_in[25];
    const float* out_ln_g  = (const float*)d_in[26];
    const float* out_ln_b  = (const float*)d_in[27];
    const int*   lengths   = (const int*)d_in[28];
    float* out = (float*)d_out;

    // float region
    float* h     = (float*)d_ws;              // 4,194,304
    float* clb   = h + 4194304;               // 16384
    float* csfb  = clb + 16384;
    float* padfb = csfb + 16384;
    float* W_int = padfb + 16384;             // 16384
    float* peWt  = W_int + 16384;             // 70656
    float* ADDf  = peWt + 70656;              // 8,388,608
    // bf16 region (o aliases u; f aliases QKV region)
    unsigned short* u_bf = (unsigned short*)(ADDf + 8388608);
    unsigned short* Q_bf = u_bf + 4194304;    // region of 16,777,216 shorts
    unsigned short* K_bf = Q_bf + 4194304;
    unsigned short* V_bf = K_bf + 4194304;
    unsigned short* f_bf = Q_bf;              // alias (lifetimes disjoint)
    unsigned short* o_bf = u_bf;              // alias (lifetimes disjoint)
    unsigned short* wq_bf = Q_bf + 16777216;  // 589824
    unsigned short* wo_bf = wq_bf + 589824;   // 196608
    unsigned short* w1_bf = wo_bf + 196608;   // 786432
    unsigned short* w2_bf = w1_bf + 786432;   // 786432

    transpose_kernel<<<340, 256, 0, stream>>>(W_in, pe_proj_W, W_int, peWt);
    prep_kernel<<<2048, 256, 0, stream>>>(x, c_local, c_sink, W_int, b_in, cls_token,
                                          peWt, pe_proj_b, pe_ln_g, pe_ln_b, pe_gain,
                                          corr_fl, lengths, h, clb, csfb, padfb);
    add_bias_kernel<<<16384, 256, 0, stream>>>(clb, csfb, padfb, alpha, beta, ADDf);
    cvt_bf16_kernel<<<576, 256, 0, stream>>>(attn_Wqkv, wq_bf, 589824);
    cvt_bf16_kernel<<<192, 256, 0, stream>>>(attn_Wo, wo_bf, 196608);
    cvt_bf16_kernel<<<768, 256, 0, stream>>>(ff_W1, w1_bf, 786432);
    cvt_bf16_kernel<<<768, 256, 0, stream>>>(ff_W2, w2_bf, 786432);

    for (int l = 0; l < 3; ++l) {
        ln_bf_kernel<<<4096, 256, 0, stream>>>(h, ln1_g + 256 * l, ln1_b + 256 * l, u_bf);
        gemm_bf16_kernel<0><<<dim3(12, 128), 256, 0, stream>>>(
            u_bf, wq_bf + (size_t)l * 196608, attn_bqkv + 768 * l, nullptr,
            Q_bf, K_bf, V_bf, 16384, 768, 256);
        attn_mfma_kernel<<<512, 256, 0, stream>>>(Q_bf, K_bf, V_bf, ADDf, o_bf);
        gemm_bf16_kernel<1><<<dim3(4, 128), 256, 0, stream>>>(
            o_bf, wo_bf + (size_t)l * 65536, attn_bo + 256 * l, h,
            nullptr, nullptr, nullptr, 16384, 256, 256);
        ln_bf_kernel<<<4096, 256, 0, stream>>>(h, ln2_g + 256 * l, ln2_b + 256 * l, u_bf);
        gemm_bf16_kernel<2><<<dim3(16, 128), 256, 0, stream>>>(
            u_bf, w1_bf + (size_t)l * 262144, ff_b1 + 1024 * l, nullptr,
            f_bf, nullptr, nullptr, 16384, 1024, 256);
        gemm_bf16_kernel<1><<<dim3(4, 128), 256, 0, stream>>>(
            f_bf, w2_bf + (size_t)l * 262144, ff_b2 + 256 * l, h,
            nullptr, nullptr, nullptr, 16384, 256, 1024);
    }
    out_ln_kernel<<<8, 256, 0, stream>>>(h, out_ln_g, out_ln_b, out);
}

// Round 6
// 547.860 us; speedup vs baseline: 40.1723x; 1.0972x over previous
//
#include <hip/hip_runtime.h>
#include <math.h>

// B=32, L=512 (incl CLS), D=256, H=8, dh=32, N_LAYERS=3, D_FF=1024, tokens=16384

typedef __attribute__((ext_vector_type(4))) float f32x4;
typedef __attribute__((ext_vector_type(8))) short bf16x8;

__device__ __forceinline__ unsigned short f2bf(float f) {
    unsigned u = __builtin_bit_cast(unsigned, f);
    u += 0x7fff + ((u >> 16) & 1);
    return (unsigned short)(u >> 16);
}
__device__ __forceinline__ unsigned cvt_pk_bf16(float a, float b) {
    unsigned r;
    asm("v_cvt_pk_bf16_f32 %0, %1, %2" : "=v"(r) : "v"(a), "v"(b));
    return r;
}
__device__ __forceinline__ float gelu_f(float v) {
    return v * 0.5f * (1.0f + erff(v * 0.70710678118654752f));
}
__device__ __forceinline__ void gload16(const void* g, void* l) {
    __builtin_amdgcn_global_load_lds(
        (const __attribute__((address_space(1))) unsigned int*)g,
        (__attribute__((address_space(3))) unsigned int*)l, 16, 0, 0);
}

// ---------------------------------------------------------------------------
// Transpose pe_proj_W [256,276] -> peWt [276,256]
__global__ __launch_bounds__(256) void transpose_kernel(
    const float* __restrict__ peW, float* __restrict__ peWt)
{
    int j = blockIdx.x * 256 + threadIdx.x;
    if (j < 70656) {
        int f = j >> 8, dd = j & 255;
        peWt[j] = peW[dd * 276 + f];
    }
}

// ---------------------------------------------------------------------------
__global__ __launch_bounds__(256) void cvt_bf16_kernel(
    const float* __restrict__ s, unsigned short* __restrict__ d, int n)
{
    int i = (blockIdx.x * 256 + threadIdx.x) * 4;
    if (i >= n) return;
    float4 v = *(const float4*)(s + i);
    unsigned long long pk = (unsigned long long)f2bf(v.x)
        | ((unsigned long long)f2bf(v.y) << 16)
        | ((unsigned long long)f2bf(v.z) << 32)
        | ((unsigned long long)f2bf(v.w) << 48);
    *(unsigned long long*)(d + i) = pk;
}

// ---------------------------------------------------------------------------
// xb [16384,64] bf16 = x rows (CLS rows zero)
__global__ __launch_bounds__(256) void xb_kernel(
    const float* __restrict__ x, unsigned short* __restrict__ xb)
{
    int idx = blockIdx.x * 256 + threadIdx.x;   // over 524288 u32 pairs
    int tok = idx >> 5, c2 = idx & 31;
    int b = tok >> 9, l = tok & 511;
    unsigned r = 0;
    if (l > 0) {
        float2 v = *(const float2*)(x + ((size_t)b * 511 + l - 1) * 64 + 2 * c2);
        r = cvt_pk_bf16(v.x, v.y);
    }
    *(unsigned*)(xb + (size_t)tok * 64 + 2 * c2) = r;
}

// ---------------------------------------------------------------------------
// PEpos[l][d] = pe_b[d] + sum_f sinusoid(l,f) * peWt[f][d]   (position-only part)
__global__ __launch_bounds__(256) void pepos_kernel(
    const float* __restrict__ peWt, const float* __restrict__ pe_b,
    float* __restrict__ PEpos)
{
    __shared__ float ls[256];
    const int l = blockIdx.x, t = threadIdx.x;
    int kk = t >> 1;
    float div = expf((float)(2 * kk) * -0.035977892078032f); // -ln(10000)/256
    float a = (float)l * div;
    ls[t] = (t & 1) ? cosf(a) : sinf(a);
    __syncthreads();
    float acc = pe_b[t];
    for (int f = 0; f < 256; ++f) acc += ls[f] * peWt[f * 256 + t];
    PEpos[l * 256 + t] = acc;
}

// ---------------------------------------------------------------------------
// prep_lite: h = base(bb or cls) + mask * gain * LN(PEpos + feats@W20)
__global__ __launch_bounds__(256) void prep_lite_kernel(
    const float* __restrict__ c_local, const float* __restrict__ c_sink,
    const float* __restrict__ bb, const float* __restrict__ cls_tok,
    const float* __restrict__ PEpos, const float* __restrict__ W20t,
    const float* __restrict__ pe_g, const float* __restrict__ pe_bb,
    const float* __restrict__ pe_gain_p, const float* __restrict__ corr_floor_p,
    const int* __restrict__ lengths,
    float* __restrict__ h, float* __restrict__ clb, float* __restrict__ csfb,
    float* __restrict__ padfb)
{
    __shared__ float zs[8][20];
    __shared__ __align__(16) float pes[8][256];
    __shared__ float mn[8], rsd[8];
    const int t = threadIdx.x;
    const int tok0 = blockIdx.x * 8;
    const int b = tok0 >> 9;
    const int len_b = lengths[b];
    const float cf = *corr_floor_p;
    const float gain = *pe_gain_p;

    float clv[8], csv[8];
    bool mk[8];
#pragma unroll
    for (int k = 0; k < 8; ++k) {
        int l = (tok0 + k) & 511;
        if (l == 0) { clv[k] = 1.f; csv[k] = 1.f; mk[k] = false; }
        else {
            float a = c_local[b * 511 + l - 1];
            float s = c_sink[b * 511 + l - 1];
            clv[k] = fminf(fmaxf(a, 0.f), 1.f);
            csv[k] = fminf(fmaxf(s, 0.f), 1.f);
            mk[k] = (l - 1) >= len_b;
        }
    }
    if (t < 8) {
        int tok = tok0 + t;
        clb[tok] = clv[t];
        csfb[tok] = cf + (1.f - cf) * csv[t];
        padfb[tok] = mk[t] ? 1.f : 0.f;
    }
    if (t < 20) {
#pragma unroll
        for (int k = 0; k < 8; ++k) {
            float cl = clv[k], cs = csv[k];
            float v;
            if (t == 0) v = cl;
            else if (t == 1) v = cs;
            else if (t == 2) v = cl * cs;
            else if (t == 3) v = fabsf(cl - cs);
            else if (t < 12) {
                float c = (float)(t - 4) * (1.f / 7.f);
                float dd = (cl - c) / 0.200001f;
                v = expf(-0.5f * dd * dd);
            } else {
                float c = (float)(t - 12) * (1.f / 7.f);
                float dd = (cs - c) / 0.200001f;
                v = expf(-0.5f * dd * dd);
            }
            zs[k][t] = v;
        }
    }
    __syncthreads();

    float acc[8];
#pragma unroll
    for (int k = 0; k < 8; ++k)
        acc[k] = PEpos[((tok0 + k) & 511) * 256 + t];
    for (int f = 0; f < 20; ++f) {
        float wv = W20t[f * 256 + t];
#pragma unroll
        for (int k = 0; k < 8; ++k) acc[k] += zs[k][f] * wv;
    }
#pragma unroll
    for (int k = 0; k < 8; ++k) pes[k][t] = acc[k];
    __syncthreads();

    {
        int w = t >> 6, lane = t & 63;
#pragma unroll
        for (int p = 0; p < 2; ++p) {
            int k = w + p * 4;
            float4 v = *(const float4*)&pes[k][lane * 4];
            float s = v.x + v.y + v.z + v.w;
            float sq = v.x * v.x + v.y * v.y + v.z * v.z + v.w * v.w;
#pragma unroll
            for (int off = 32; off; off >>= 1) {
                s += __shfl_xor(s, off);
                sq += __shfl_xor(sq, off);
            }
            if (lane == 0) {
                float mean = s * (1.f / 256.f);
                mn[k] = mean;
                rsd[k] = rsqrtf(sq * (1.f / 256.f) - mean * mean + 1e-5f);
            }
        }
    }
    __syncthreads();
    float gv = pe_g[t], bv = pe_bb[t];
#pragma unroll
    for (int k = 0; k < 8; ++k) {
        int l = (tok0 + k) & 511;
        float base = (l == 0) ? cls_tok[t] : bb[(size_t)(tok0 + k) * 256 + t];
        float pe = (pes[k][t] - mn[k]) * rsd[k] * gv + bv;
        pe *= gain;
        if (mk[k]) pe = 0.f;
        h[(size_t)(tok0 + k) * 256 + t] = base + pe;
    }
}

// ---------------------------------------------------------------------------
// ADD[b][i][j] = log2(e) * (bias_masked(i,j) - 10000*pad_j)  (layer-invariant)
__global__ __launch_bounds__(256) void add_bias_kernel(
    const float* __restrict__ clb, const float* __restrict__ csfb,
    const float* __restrict__ padfb, const float* __restrict__ alpha_p,
    const float* __restrict__ beta_p, float* __restrict__ ADD)
{
    const int b = blockIdx.x >> 9, i = blockIdx.x & 511;
    const int t = threadIdx.x;
    const float alpha = *alpha_p;
    const float pad_i = padfb[b * 512 + i];
    const float csb = (*beta_p) * csfb[b * 512 + i];
    const bool iv = pad_i < 0.5f;
    const float L2E = 1.4426950408889634f;
    float2 o;
#pragma unroll
    for (int u = 0; u < 2; ++u) {
        int j = 2 * t + u;
        float padj = padfb[b * 512 + j];
        float v = -10000.f * padj;
        if (iv && padj < 0.5f) {
            float bb = csb * csfb[b * 512 + j];
            int d = j - i;
            if (d == 1 || d == -1) {
                float ce;
                if (i <= 510 && j >= 1) ce = clb[b * 512 + j];
                else if (i >= 1 && j <= 510) ce = clb[b * 512 + i];
                else ce = 0.f;
                bb += alpha * ce;
            }
            v += bb;
        }
        ((float*)&o)[u] = v * L2E;
    }
    *(float2*)(ADD + (size_t)b * 262144 + (size_t)i * 512 + 2 * t) = o;
}

// ---------------------------------------------------------------------------
// LayerNorm D=256, bf16 output: one wave per token, 4 tokens per block
__global__ __launch_bounds__(256) void ln_bf_kernel(
    const float* __restrict__ x, const float* __restrict__ g,
    const float* __restrict__ b, unsigned short* __restrict__ y)
{
    int tok = blockIdx.x * 4 + (threadIdx.x >> 6);
    int lane = threadIdx.x & 63;
    const float* row = x + (size_t)tok * 256;
    float4 v = *(const float4*)(row + lane * 4);
    float s = v.x + v.y + v.z + v.w;
    float sq = v.x * v.x + v.y * v.y + v.z * v.z + v.w * v.w;
#pragma unroll
    for (int off = 32; off; off >>= 1) {
        s += __shfl_xor(s, off);
        sq += __shfl_xor(sq, off);
    }
    float mean = s * (1.f / 256.f);
    float rs = rsqrtf(sq * (1.f / 256.f) - mean * mean + 1e-5f);
    float4 gv = *(const float4*)(g + lane * 4);
    float4 bv = *(const float4*)(b + lane * 4);
    unsigned long long pk =
          (unsigned long long)f2bf((v.x - mean) * rs * gv.x + bv.x)
        | ((unsigned long long)f2bf((v.y - mean) * rs * gv.y + bv.y) << 16)
        | ((unsigned long long)f2bf((v.z - mean) * rs * gv.z + bv.z) << 32)
        | ((unsigned long long)f2bf((v.w - mean) * rs * gv.w + bv.w) << 48);
    *(unsigned long long*)(y + (size_t)tok * 256 + lane * 4) = pk;
}

// Final LN on the 32 CLS rows only (f32 out)
__global__ __launch_bounds__(256) void out_ln_kernel(
    const float* __restrict__ h, const float* __restrict__ g,
    const float* __restrict__ b, float* __restrict__ out)
{
    int tok = blockIdx.x * 4 + (threadIdx.x >> 6);
    int lane = threadIdx.x & 63;
    const float* row = h + (size_t)tok * 512 * 256;
    float4 v = *(const float4*)(row + lane * 4);
    float s = v.x + v.y + v.z + v.w;
    float sq = v.x * v.x + v.y * v.y + v.z * v.z + v.w * v.w;
#pragma unroll
    for (int off = 32; off; off >>= 1) {
        s += __shfl_xor(s, off);
        sq += __shfl_xor(sq, off);
    }
    float mean = s * (1.f / 256.f);
    float rs = rsqrtf(sq * (1.f / 256.f) - mean * mean + 1e-5f);
    float4 gv = *(const float4*)(g + lane * 4);
    float4 bv = *(const float4*)(b + lane * 4);
    float4 o;
    o.x = (v.x - mean) * rs * gv.x + bv.x;
    o.y = (v.y - mean) * rs * gv.y + bv.y;
    o.z = (v.z - mean) * rs * gv.z + bv.z;
    o.w = (v.w - mean) * rs * gv.w + bv.w;
    *(float4*)(out + (size_t)tok * 256 + lane * 4) = o;
}

// ---------------------------------------------------------------------------
// bf16 MFMA GEMM: C[M,N] = epi(A[M,K] @ W[N,K]^T + bias)
// EPI: 0 = QKV 3-way bf16 split store (Q scaled by scale*log2e),
//      1 = f32 residual accumulate, 2 = GELU -> bf16, 3 = plain f32 store
template <int EPI>
__global__ __launch_bounds__(256) void gemm_bf16_kernel(
    const unsigned short* __restrict__ A, const unsigned short* __restrict__ W,
    const float* __restrict__ bias, float* __restrict__ hres,
    unsigned short* __restrict__ o0, unsigned short* __restrict__ o1,
    unsigned short* __restrict__ o2, int M, int N, int K)
{
    __shared__ __align__(16) unsigned short As[128 * 64];
    __shared__ __align__(16) unsigned short Bs[64 * 64];
    const int t = threadIdx.x;
    const int wid = t >> 6, lane = t & 63;
    const int lo = lane & 15, hi = lane >> 4;
    const int wm = wid >> 1, wn = wid & 1;
    const int m0 = blockIdx.y * 128, n0 = blockIdx.x * 64;
    const int lrow = lane >> 3, lc = lane & 7;
    f32x4 acc[4][2] = {};
    for (int k0 = 0; k0 < K; k0 += 64) {
        __syncthreads();
#pragma unroll
        for (int is = 0; is < 4; ++is) {
            int r = wid * 32 + is * 8 + lrow;
            const unsigned short* g = A + (size_t)(m0 + r) * K + k0 + ((lc ^ (r & 7)) * 8);
            gload16(g, &As[(wid * 32 + is * 8) * 64]);
        }
#pragma unroll
        for (int is = 0; is < 2; ++is) {
            int r = wid * 16 + is * 8 + lrow;
            const unsigned short* g = W + (size_t)(n0 + r) * K + k0 + ((lc ^ (r & 7)) * 8);
            gload16(g, &Bs[(wid * 16 + is * 8) * 64]);
        }
        __syncthreads();
#pragma unroll
        for (int kh = 0; kh < 2; ++kh) {
            bf16x8 bfr[2];
#pragma unroll
            for (int nf = 0; nf < 2; ++nf) {
                int r = wn * 32 + nf * 16 + lo;
                bfr[nf] = *(const bf16x8*)&Bs[r * 64 + (((kh * 4 + hi) ^ (r & 7)) * 8)];
            }
#pragma unroll
            for (int mf = 0; mf < 4; ++mf) {
                int r = wm * 64 + mf * 16 + lo;
                bf16x8 afr = *(const bf16x8*)&As[r * 64 + (((kh * 4 + hi) ^ (r & 7)) * 8)];
                acc[mf][0] = __builtin_amdgcn_mfma_f32_16x16x32_bf16(afr, bfr[0], acc[mf][0], 0, 0, 0);
                acc[mf][1] = __builtin_amdgcn_mfma_f32_16x16x32_bf16(afr, bfr[1], acc[mf][1], 0, 0, 0);
            }
        }
    }
#pragma unroll
    for (int mf = 0; mf < 4; ++mf) {
        const int mbase = m0 + wm * 64 + mf * 16 + hi * 4;
#pragma unroll
        for (int nf = 0; nf < 2; ++nf) {
            const int n = n0 + wn * 32 + nf * 16 + lo;
            const float bv = bias[n];
            f32x4 v = acc[mf][nf];
            if constexpr (EPI == 1) {
#pragma unroll
                for (int rg = 0; rg < 4; ++rg) {
                    size_t idx = (size_t)(mbase + rg) * N + n;
                    hres[idx] += v[rg] + bv;
                }
            } else if constexpr (EPI == 3) {
#pragma unroll
                for (int rg = 0; rg < 4; ++rg)
                    hres[(size_t)(mbase + rg) * N + n] = v[rg] + bv;
            } else if constexpr (EPI == 0) {
                unsigned short* dst = (n0 < 256) ? o0 : ((n0 < 512) ? o1 : o2);
                const float qsc = (n0 < 256)
                    ? (0.17677669529663687f * 1.4426950408889634f) : 1.f;
                const int c = n & 255;
#pragma unroll
                for (int rg = 0; rg < 4; ++rg)
                    dst[(size_t)(mbase + rg) * 256 + c] = f2bf((v[rg] + bv) * qsc);
            } else {
#pragma unroll
                for (int rg = 0; rg < 4; ++rg)
                    o0[(size_t)(mbase + rg) * N + n] = f2bf(gelu_f(v[rg] + bv));
            }
        }
    }
}

// ---------------------------------------------------------------------------
// MFMA flash attention (round-2-proven v2): block = (b, head, half of q-rows),
// 256 threads. S^T = K.Q^T + ADD (C-operand) -> per-lane online softmax
// (base 2) -> O^T = V^T.P^T. K rows 80B-padded; V^T stride 260.
__global__ __launch_bounds__(256) void attn_mfma_kernel(
    const unsigned short* __restrict__ Qb, const unsigned short* __restrict__ Kb,
    const unsigned short* __restrict__ Vb, const float* __restrict__ ADD,
    unsigned short* __restrict__ Ob)
{
    __shared__ __align__(16) unsigned short Kl[256 * 40];  // 80B rows (pad 8)
    __shared__ __align__(16) unsigned short Vt[32 * 260];  // V^T, stride 260
    const int t = threadIdx.x;
    const int swz = ((blockIdx.x & 7) << 6) | (blockIdx.x >> 3);  // XCD chunking
    const int bh = swz >> 1, hf = swz & 1;
    const int b = bh >> 3, hd = bh & 7;
    const size_t base = ((size_t)b * 512) * 256 + hd * 32;
    const int w = t >> 6, lane = t & 63, lo = lane & 15, hi = lane >> 4;
    const float* ADDb = ADD + (size_t)b * 262144;

    int iq[4];
    bf16x8 qf[4];
#pragma unroll
    for (int qi = 0; qi < 4; ++qi) {
        iq[qi] = (hf * 16 + w * 4 + qi) * 16 + lo;
        qf[qi] = *(const bf16x8*)(Qb + base + (size_t)iq[qi] * 256 + hi * 8);
    }
    f32x4 acc[4][2] = {};
    float m[4], lsum[4];
#pragma unroll
    for (int qi = 0; qi < 4; ++qi) { m[qi] = -3e38f; lsum[qi] = 0.f; }

    for (int jt = 0; jt < 2; ++jt) {
        __syncthreads();
        for (int idx = t; idx < 1024; idx += 256) {       // K tile, 16B
            int row = idx >> 2, c4 = idx & 3;
            *(uint4*)&Kl[row * 40 + c4 * 8] =
                *(const uint4*)(Kb + base + (size_t)(jt * 256 + row) * 256 + c4 * 8);
        }
        for (int idx = t; idx < 1024; idx += 256) {       // V^T, paired rows
            int pr = idx >> 3, c4 = idx & 7;
            unsigned long long v0 = *(const unsigned long long*)
                (Vb + base + (size_t)(jt * 256 + 2 * pr) * 256 + c4 * 4);
            unsigned long long v1 = *(const unsigned long long*)
                (Vb + base + (size_t)(jt * 256 + 2 * pr + 1) * 256 + c4 * 4);
#pragma unroll
            for (int e = 0; e < 4; ++e) {
                unsigned a = (unsigned)((v0 >> (16 * e)) & 0xffffu);
                unsigned c = (unsigned)((v1 >> (16 * e)) & 0xffffu);
                *(unsigned*)&Vt[(c4 * 4 + e) * 260 + 2 * pr] = a | (c << 16);
            }
        }
        __syncthreads();
        for (int ktp = 0; ktp < 8; ++ktp) {
            const int k16 = ktp * 32;
            const int gj = jt * 256 + k16;
            bf16x8 kf0 = *(const bf16x8*)&Kl[(k16 + lo) * 40 + hi * 8];
            bf16x8 kf1 = *(const bf16x8*)&Kl[(k16 + 16 + lo) * 40 + hi * 8];
            union U16 { unsigned long long q[2]; unsigned wd[4]; bf16x8 v; } vu0, vu1, pu;
            vu0.q[0] = *(const unsigned long long*)&Vt[lo * 260 + k16 + hi * 4];
            vu0.q[1] = *(const unsigned long long*)&Vt[lo * 260 + k16 + 16 + hi * 4];
            vu1.q[0] = *(const unsigned long long*)&Vt[(16 + lo) * 260 + k16 + hi * 4];
            vu1.q[1] = *(const unsigned long long*)&Vt[(16 + lo) * 260 + k16 + 16 + hi * 4];
#pragma unroll
            for (int qi = 0; qi < 4; ++qi) {
                f32x4 a0 = *(const f32x4*)(ADDb + (size_t)iq[qi] * 512 + gj + hi * 4);
                f32x4 a1 = *(const f32x4*)(ADDb + (size_t)iq[qi] * 512 + gj + 16 + hi * 4);
                f32x4 s0 = __builtin_amdgcn_mfma_f32_16x16x32_bf16(kf0, qf[qi], a0, 0, 0, 0);
                f32x4 s1 = __builtin_amdgcn_mfma_f32_16x16x32_bf16(kf1, qf[qi], a1, 0, 0, 0);
                float tm = fmaxf(fmaxf(fmaxf(s0[0], s0[1]), fmaxf(s0[2], s0[3])),
                                 fmaxf(fmaxf(s1[0], s1[1]), fmaxf(s1[2], s1[3])));
                tm = fmaxf(tm, __shfl_xor(tm, 16));
                tm = fmaxf(tm, __shfl_xor(tm, 32));
                const float mn2 = fmaxf(m[qi], tm);
                const float fs = exp2f(m[qi] - mn2);
                m[qi] = mn2;
                float p0 = exp2f(s0[0] - mn2), p1 = exp2f(s0[1] - mn2);
                float p2 = exp2f(s0[2] - mn2), p3 = exp2f(s0[3] - mn2);
                float p4 = exp2f(s1[0] - mn2), p5 = exp2f(s1[1] - mn2);
                float p6 = exp2f(s1[2] - mn2), p7 = exp2f(s1[3] - mn2);
                float ps = ((p0 + p1) + (p2 + p3)) + ((p4 + p5) + (p6 + p7));
                ps += __shfl_xor(ps, 16);
                ps += __shfl_xor(ps, 32);
                lsum[qi] = lsum[qi] * fs + ps;
                pu.wd[0] = cvt_pk_bf16(p0, p1);
                pu.wd[1] = cvt_pk_bf16(p2, p3);
                pu.wd[2] = cvt_pk_bf16(p4, p5);
                pu.wd[3] = cvt_pk_bf16(p6, p7);
#pragma unroll
                for (int c = 0; c < 4; ++c) { acc[qi][0][c] *= fs; acc[qi][1][c] *= fs; }
                acc[qi][0] = __builtin_amdgcn_mfma_f32_16x16x32_bf16(vu0.v, pu.v, acc[qi][0], 0, 0, 0);
                acc[qi][1] = __builtin_amdgcn_mfma_f32_16x16x32_bf16(vu1.v, pu.v, acc[qi][1], 0, 0, 0);
            }
        }
    }
#pragma unroll
    for (int qi = 0; qi < 4; ++qi) {
        const float inv = 1.f / lsum[qi];
        unsigned long long oa =
              (unsigned long long)cvt_pk_bf16(acc[qi][0][0] * inv, acc[qi][0][1] * inv)
            | ((unsigned long long)cvt_pk_bf16(acc[qi][0][2] * inv, acc[qi][0][3] * inv) << 32);
        unsigned long long ob2 =
              (unsigned long long)cvt_pk_bf16(acc[qi][1][0] * inv, acc[qi][1][1] * inv)
            | ((unsigned long long)cvt_pk_bf16(acc[qi][1][2] * inv, acc[qi][1][3] * inv) << 32);
        *(unsigned long long*)(Ob + base + (size_t)iq[qi] * 256 + hi * 4) = oa;
        *(unsigned long long*)(Ob + base + (size_t)iq[qi] * 256 + 16 + hi * 4) = ob2;
    }
}

// ---------------------------------------------------------------------------
extern "C" void kernel_launch(void* const* d_in, const int* in_sizes, int n_in,
                              void* d_out, int out_size, void* d_ws, size_t ws_size,
                              hipStream_t stream) {
    const float* x         = (const float*)d_in[0];
    const float* c_local   = (const float*)d_in[1];
    const float* c_sink    = (const float*)d_in[2];
    const float* W_in      = (const float*)d_in[3];
    const float* b_in      = (const float*)d_in[4];
    const float* cls_token = (const float*)d_in[5];
    const float* pe_proj_W = (const float*)d_in[6];
    const float* pe_proj_b = (const float*)d_in[7];
    const float* pe_ln_g   = (const float*)d_in[8];
    const float* pe_ln_b   = (const float*)d_in[9];
    const float* pe_gain   = (const float*)d_in[10];
    const float* attn_Wqkv = (const float*)d_in[11];
    const float* attn_bqkv = (const float*)d_in[12];
    const float* attn_Wo   = (const float*)d_in[13];
    const float* attn_bo   = (const float*)d_in[14];
    const float* ff_W1     = (const float*)d_in[15];
    const float* ff_b1     = (const float*)d_in[16];
    const float* ff_W2     = (const float*)d_in[17];
    const float* ff_b2     = (const float*)d_in[18];
    const float* ln1_g     = (const float*)d_in[19];
    const float* ln1_b     = (const float*)d_in[20];
    const float* ln2_g     = (const float*)d_in[21];
    const float* ln2_b     = (const float*)d_in[22];
    const float* alpha     = (const float*)d_in[23];
    const float* beta      = (const float*)d_in[24];
    const float* corr_fl   = (const float*)d_in[25];
    const float* out_ln_g  = (const float*)d_in[26];
    const float* out_ln_b  = (const float*)d_in[27];
    const int*   lengths   = (const int*)d_in[28];
    float* out = (float*)d_out;

    // float region
    float* h     = (float*)d_ws;              // 4,194,304
    float* clb   = h + 4194304;               // 16384
    float* csfb  = clb + 16384;
    float* padfb = csfb + 16384;
    float* peWt  = padfb + 16384;             // 70656
    float* PEpos = peWt + 70656;              // 131072
    float* ADDf  = PEpos + 131072;            // 8,388,608
    float* bbf   = ADDf;                      // alias: bb dead before add_bias
    // bf16 region — weights AFTER the full 16,777,216-short f-span at Q_bf
    unsigned short* u_bf = (unsigned short*)(ADDf + 8388608);
    unsigned short* xb_bf = u_bf;             // alias: xb dead before layer loop
    unsigned short* Q_bf = u_bf + 4194304;
    unsigned short* K_bf = Q_bf + 4194304;
    unsigned short* V_bf = K_bf + 4194304;
    unsigned short* f_bf = Q_bf;              // alias: spans Q..Q+16777216
    unsigned short* o_bf = u_bf;              // alias (lifetimes disjoint)
    unsigned short* wq_bf = Q_bf + 16777216;  // after f's span
    unsigned short* wo_bf = wq_bf + 589824;
    unsigned short* w1_bf = wo_bf + 196608;
    unsigned short* w2_bf = w1_bf + 786432;
    unsigned short* win_bf = w2_bf + 786432;  // 16384

    transpose_kernel<<<276, 256, 0, stream>>>(pe_proj_W, peWt);
    cvt_bf16_kernel<<<576, 256, 0, stream>>>(attn_Wqkv, wq_bf, 589824);
    cvt_bf16_kernel<<<192, 256, 0, stream>>>(attn_Wo, wo_bf, 196608);
    cvt_bf16_kernel<<<768, 256, 0, stream>>>(ff_W1, w1_bf, 786432);
    cvt_bf16_kernel<<<768, 256, 0, stream>>>(ff_W2, w2_bf, 786432);
    cvt_bf16_kernel<<<16, 256, 0, stream>>>(W_in, win_bf, 16384);
    xb_kernel<<<2048, 256, 0, stream>>>(x, xb_bf);
    pepos_kernel<<<512, 256, 0, stream>>>(peWt, pe_proj_b, PEpos);
    gemm_bf16_kernel<3><<<dim3(4, 128), 256, 0, stream>>>(
        xb_bf, win_bf, b_in, bbf, nullptr, nullptr, nullptr, 16384, 256, 64);
    prep_lite_kernel<<<2048, 256, 0, stream>>>(
        c_local, c_sink, bbf, cls_token, PEpos, peWt + 65536,
        pe_ln_g, pe_ln_b, pe_gain, corr_fl, lengths, h, clb, csfb, padfb);
    add_bias_kernel<<<16384, 256, 0, stream>>>(clb, csfb, padfb, alpha, beta, ADDf);

    for (int l = 0; l < 3; ++l) {
        ln_bf_kernel<<<4096, 256, 0, stream>>>(h, ln1_g + 256 * l, ln1_b + 256 * l, u_bf);
        gemm_bf16_kernel<0><<<dim3(12, 128), 256, 0, stream>>>(
            u_bf, wq_bf + (size_t)l * 196608, attn_bqkv + 768 * l, nullptr,
            Q_bf, K_bf, V_bf, 16384, 768, 256);
        attn_mfma_kernel<<<512, 256, 0, stream>>>(Q_bf, K_bf, V_bf, ADDf, o_bf);
        gemm_bf16_kernel<1><<<dim3(4, 128), 256, 0, stream>>>(
            o_bf, wo_bf + (size_t)l * 65536, attn_bo + 256 * l, h,
            nullptr, nullptr, nullptr, 16384, 256, 256);
        ln_bf_kernel<<<4096, 256, 0, stream>>>(h, ln2_g + 256 * l, ln2_b + 256 * l, u_bf);
        gemm_bf16_kernel<2><<<dim3(16, 128), 256, 0, stream>>>(
            u_bf, w1_bf + (size_t)l * 262144, ff_b1 + 1024 * l, nullptr,
            f_bf, nullptr, nullptr, 16384, 1024, 256);
        gemm_bf16_kernel<1><<<dim3(4, 128), 256, 0, stream>>>(
            f_bf, w2_bf + (size_t)l * 262144, ff_b2 + 256 * l, h,
            nullptr, nullptr, nullptr, 16384, 256, 1024);
    }
    out_ln_kernel<<<8, 256, 0, stream>>>(h, out_ln_g, out_ln_b, out);
}

// Round 7
// 514.476 us; speedup vs baseline: 42.7790x; 1.0649x over previous
//
#include <hip/hip_runtime.h>
#include <math.h>

// B=32, L=512 (incl CLS), D=256, H=8, dh=32, N_LAYERS=3, D_FF=1024, tokens=16384

typedef __attribute__((ext_vector_type(4))) float f32x4;
typedef __attribute__((ext_vector_type(8))) short bf16x8;

__device__ __forceinline__ unsigned short f2bf(float f) {
    unsigned u = __builtin_bit_cast(unsigned, f);
    u += 0x7fff + ((u >> 16) & 1);
    return (unsigned short)(u >> 16);
}
__device__ __forceinline__ unsigned cvt_pk_bf16(float a, float b) {
    unsigned r;
    asm("v_cvt_pk_bf16_f32 %0, %1, %2" : "=v"(r) : "v"(a), "v"(b));
    return r;
}
__device__ __forceinline__ float gelu_f(float v) {
    return v * 0.5f * (1.0f + erff(v * 0.70710678118654752f));
}
__device__ __forceinline__ void gload16(const void* g, void* l) {
    __builtin_amdgcn_global_load_lds(
        (const __attribute__((address_space(1))) unsigned int*)g,
        (__attribute__((address_space(3))) unsigned int*)l, 16, 0, 0);
}

// ---------------------------------------------------------------------------
// Transpose pe_proj_W [256,276] -> peWt [276,256]
__global__ __launch_bounds__(256) void transpose_kernel(
    const float* __restrict__ peW, float* __restrict__ peWt)
{
    int j = blockIdx.x * 256 + threadIdx.x;
    if (j < 70656) {
        int f = j >> 8, dd = j & 255;
        peWt[j] = peW[dd * 276 + f];
    }
}

// ---------------------------------------------------------------------------
__global__ __launch_bounds__(256) void cvt_bf16_kernel(
    const float* __restrict__ s, unsigned short* __restrict__ d, int n)
{
    int i = (blockIdx.x * 256 + threadIdx.x) * 4;
    if (i >= n) return;
    float4 v = *(const float4*)(s + i);
    unsigned long long pk = (unsigned long long)f2bf(v.x)
        | ((unsigned long long)f2bf(v.y) << 16)
        | ((unsigned long long)f2bf(v.z) << 32)
        | ((unsigned long long)f2bf(v.w) << 48);
    *(unsigned long long*)(d + i) = pk;
}

// ---------------------------------------------------------------------------
// xb [16384,64] bf16 = x rows (CLS rows zero)
__global__ __launch_bounds__(256) void xb_kernel(
    const float* __restrict__ x, unsigned short* __restrict__ xb)
{
    int idx = blockIdx.x * 256 + threadIdx.x;   // over 524288 u32 pairs
    int tok = idx >> 5, c2 = idx & 31;
    int b = tok >> 9, l = tok & 511;
    unsigned r = 0;
    if (l > 0) {
        float2 v = *(const float2*)(x + ((size_t)b * 511 + l - 1) * 64 + 2 * c2);
        r = cvt_pk_bf16(v.x, v.y);
    }
    *(unsigned*)(xb + (size_t)tok * 64 + 2 * c2) = r;
}

// ---------------------------------------------------------------------------
// PEpos[l][d] = pe_b[d] + sum_f sinusoid(l,f) * peWt[f][d]   (position-only part)
__global__ __launch_bounds__(256) void pepos_kernel(
    const float* __restrict__ peWt, const float* __restrict__ pe_b,
    float* __restrict__ PEpos)
{
    __shared__ float ls[256];
    const int l = blockIdx.x, t = threadIdx.x;
    int kk = t >> 1;
    float div = expf((float)(2 * kk) * -0.035977892078032f); // -ln(10000)/256
    float a = (float)l * div;
    ls[t] = (t & 1) ? cosf(a) : sinf(a);
    __syncthreads();
    float acc = pe_b[t];
    for (int f = 0; f < 256; ++f) acc += ls[f] * peWt[f * 256 + t];
    PEpos[l * 256 + t] = acc;
}

// ---------------------------------------------------------------------------
// prep_lite: h = base(bb or cls) + mask * gain * LN(PEpos + feats@W20)
__global__ __launch_bounds__(256) void prep_lite_kernel(
    const float* __restrict__ c_local, const float* __restrict__ c_sink,
    const float* __restrict__ bb, const float* __restrict__ cls_tok,
    const float* __restrict__ PEpos, const float* __restrict__ W20t,
    const float* __restrict__ pe_g, const float* __restrict__ pe_bb,
    const float* __restrict__ pe_gain_p, const float* __restrict__ corr_floor_p,
    const int* __restrict__ lengths,
    float* __restrict__ h, float* __restrict__ clb, float* __restrict__ csfb,
    float* __restrict__ padfb)
{
    __shared__ float zs[8][20];
    __shared__ __align__(16) float pes[8][256];
    __shared__ float mn[8], rsd[8];
    const int t = threadIdx.x;
    const int tok0 = blockIdx.x * 8;
    const int b = tok0 >> 9;
    const int len_b = lengths[b];
    const float cf = *corr_floor_p;
    const float gain = *pe_gain_p;

    float clv[8], csv[8];
    bool mk[8];
#pragma unroll
    for (int k = 0; k < 8; ++k) {
        int l = (tok0 + k) & 511;
        if (l == 0) { clv[k] = 1.f; csv[k] = 1.f; mk[k] = false; }
        else {
            float a = c_local[b * 511 + l - 1];
            float s = c_sink[b * 511 + l - 1];
            clv[k] = fminf(fmaxf(a, 0.f), 1.f);
            csv[k] = fminf(fmaxf(s, 0.f), 1.f);
            mk[k] = (l - 1) >= len_b;
        }
    }
    if (t < 8) {
        int tok = tok0 + t;
        clb[tok] = clv[t];
        csfb[tok] = cf + (1.f - cf) * csv[t];
        padfb[tok] = mk[t] ? 1.f : 0.f;
    }
    if (t < 20) {
#pragma unroll
        for (int k = 0; k < 8; ++k) {
            float cl = clv[k], cs = csv[k];
            float v;
            if (t == 0) v = cl;
            else if (t == 1) v = cs;
            else if (t == 2) v = cl * cs;
            else if (t == 3) v = fabsf(cl - cs);
            else if (t < 12) {
                float c = (float)(t - 4) * (1.f / 7.f);
                float dd = (cl - c) / 0.200001f;
                v = expf(-0.5f * dd * dd);
            } else {
                float c = (float)(t - 12) * (1.f / 7.f);
                float dd = (cs - c) / 0.200001f;
                v = expf(-0.5f * dd * dd);
            }
            zs[k][t] = v;
        }
    }
    __syncthreads();

    float acc[8];
#pragma unroll
    for (int k = 0; k < 8; ++k)
        acc[k] = PEpos[((tok0 + k) & 511) * 256 + t];
    for (int f = 0; f < 20; ++f) {
        float wv = W20t[f * 256 + t];
#pragma unroll
        for (int k = 0; k < 8; ++k) acc[k] += zs[k][f] * wv;
    }
#pragma unroll
    for (int k = 0; k < 8; ++k) pes[k][t] = acc[k];
    __syncthreads();

    {
        int w = t >> 6, lane = t & 63;
#pragma unroll
        for (int p = 0; p < 2; ++p) {
            int k = w + p * 4;
            float4 v = *(const float4*)&pes[k][lane * 4];
            float s = v.x + v.y + v.z + v.w;
            float sq = v.x * v.x + v.y * v.y + v.z * v.z + v.w * v.w;
#pragma unroll
            for (int off = 32; off; off >>= 1) {
                s += __shfl_xor(s, off);
                sq += __shfl_xor(sq, off);
            }
            if (lane == 0) {
                float mean = s * (1.f / 256.f);
                mn[k] = mean;
                rsd[k] = rsqrtf(sq * (1.f / 256.f) - mean * mean + 1e-5f);
            }
        }
    }
    __syncthreads();
    float gv = pe_g[t], bv = pe_bb[t];
#pragma unroll
    for (int k = 0; k < 8; ++k) {
        int l = (tok0 + k) & 511;
        float base = (l == 0) ? cls_tok[t] : bb[(size_t)(tok0 + k) * 256 + t];
        float pe = (pes[k][t] - mn[k]) * rsd[k] * gv + bv;
        pe *= gain;
        if (mk[k]) pe = 0.f;
        h[(size_t)(tok0 + k) * 256 + t] = base + pe;
    }
}

// ---------------------------------------------------------------------------
// ADD[b][i][j] = log2(e) * (bias_masked(i,j) - 10000*pad_j)  (layer-invariant)
__global__ __launch_bounds__(256) void add_bias_kernel(
    const float* __restrict__ clb, const float* __restrict__ csfb,
    const float* __restrict__ padfb, const float* __restrict__ alpha_p,
    const float* __restrict__ beta_p, float* __restrict__ ADD)
{
    const int b = blockIdx.x >> 9, i = blockIdx.x & 511;
    const int t = threadIdx.x;
    const float alpha = *alpha_p;
    const float pad_i = padfb[b * 512 + i];
    const float csb = (*beta_p) * csfb[b * 512 + i];
    const bool iv = pad_i < 0.5f;
    const float L2E = 1.4426950408889634f;
    float2 o;
#pragma unroll
    for (int u = 0; u < 2; ++u) {
        int j = 2 * t + u;
        float padj = padfb[b * 512 + j];
        float v = -10000.f * padj;
        if (iv && padj < 0.5f) {
            float bb = csb * csfb[b * 512 + j];
            int d = j - i;
            if (d == 1 || d == -1) {
                float ce;
                if (i <= 510 && j >= 1) ce = clb[b * 512 + j];
                else if (i >= 1 && j <= 510) ce = clb[b * 512 + i];
                else ce = 0.f;
                bb += alpha * ce;
            }
            v += bb;
        }
        ((float*)&o)[u] = v * L2E;
    }
    *(float2*)(ADD + (size_t)b * 262144 + (size_t)i * 512 + 2 * t) = o;
}

// ---------------------------------------------------------------------------
// LayerNorm D=256, bf16 output: one wave per token, 4 tokens per block
__global__ __launch_bounds__(256) void ln_bf_kernel(
    const float* __restrict__ x, const float* __restrict__ g,
    const float* __restrict__ b, unsigned short* __restrict__ y)
{
    int tok = blockIdx.x * 4 + (threadIdx.x >> 6);
    int lane = threadIdx.x & 63;
    const float* row = x + (size_t)tok * 256;
    float4 v = *(const float4*)(row + lane * 4);
    float s = v.x + v.y + v.z + v.w;
    float sq = v.x * v.x + v.y * v.y + v.z * v.z + v.w * v.w;
#pragma unroll
    for (int off = 32; off; off >>= 1) {
        s += __shfl_xor(s, off);
        sq += __shfl_xor(sq, off);
    }
    float mean = s * (1.f / 256.f);
    float rs = rsqrtf(sq * (1.f / 256.f) - mean * mean + 1e-5f);
    float4 gv = *(const float4*)(g + lane * 4);
    float4 bv = *(const float4*)(b + lane * 4);
    unsigned long long pk =
          (unsigned long long)f2bf((v.x - mean) * rs * gv.x + bv.x)
        | ((unsigned long long)f2bf((v.y - mean) * rs * gv.y + bv.y) << 16)
        | ((unsigned long long)f2bf((v.z - mean) * rs * gv.z + bv.z) << 32)
        | ((unsigned long long)f2bf((v.w - mean) * rs * gv.w + bv.w) << 48);
    *(unsigned long long*)(y + (size_t)tok * 256 + lane * 4) = pk;
}

// Final LN on the 32 CLS rows only (f32 out)
__global__ __launch_bounds__(256) void out_ln_kernel(
    const float* __restrict__ h, const float* __restrict__ g,
    const float* __restrict__ b, float* __restrict__ out)
{
    int tok = blockIdx.x * 4 + (threadIdx.x >> 6);
    int lane = threadIdx.x & 63;
    const float* row = h + (size_t)tok * 512 * 256;
    float4 v = *(const float4*)(row + lane * 4);
    float s = v.x + v.y + v.z + v.w;
    float sq = v.x * v.x + v.y * v.y + v.z * v.z + v.w * v.w;
#pragma unroll
    for (int off = 32; off; off >>= 1) {
        s += __shfl_xor(s, off);
        sq += __shfl_xor(sq, off);
    }
    float mean = s * (1.f / 256.f);
    float rs = rsqrtf(sq * (1.f / 256.f) - mean * mean + 1e-5f);
    float4 gv = *(const float4*)(g + lane * 4);
    float4 bv = *(const float4*)(b + lane * 4);
    float4 o;
    o.x = (v.x - mean) * rs * gv.x + bv.x;
    o.y = (v.y - mean) * rs * gv.y + bv.y;
    o.z = (v.z - mean) * rs * gv.z + bv.z;
    o.w = (v.w - mean) * rs * gv.w + bv.w;
    *(float4*)(out + (size_t)tok * 256 + lane * 4) = o;
}

// ---------------------------------------------------------------------------
// bf16 MFMA GEMM: C[M,N] = epi(A[M,K] @ W[N,K]^T + bias)
// EPI: 0 = QKV 3-way bf16 split store (Q scaled by scale*log2e),
//      1 = f32 residual accumulate, 2 = GELU -> bf16, 3 = plain f32 store
template <int EPI>
__global__ __launch_bounds__(256) void gemm_bf16_kernel(
    const unsigned short* __restrict__ A, const unsigned short* __restrict__ W,
    const float* __restrict__ bias, float* __restrict__ hres,
    unsigned short* __restrict__ o0, unsigned short* __restrict__ o1,
    unsigned short* __restrict__ o2, int M, int N, int K)
{
    __shared__ __align__(16) unsigned short As[128 * 64];
    __shared__ __align__(16) unsigned short Bs[64 * 64];
    const int t = threadIdx.x;
    const int wid = t >> 6, lane = t & 63;
    const int lo = lane & 15, hi = lane >> 4;
    const int wm = wid >> 1, wn = wid & 1;
    const int m0 = blockIdx.y * 128, n0 = blockIdx.x * 64;
    const int lrow = lane >> 3, lc = lane & 7;
    f32x4 acc[4][2] = {};
    for (int k0 = 0; k0 < K; k0 += 64) {
        __syncthreads();
#pragma unroll
        for (int is = 0; is < 4; ++is) {
            int r = wid * 32 + is * 8 + lrow;
            const unsigned short* g = A + (size_t)(m0 + r) * K + k0 + ((lc ^ (r & 7)) * 8);
            gload16(g, &As[(wid * 32 + is * 8) * 64]);
        }
#pragma unroll
        for (int is = 0; is < 2; ++is) {
            int r = wid * 16 + is * 8 + lrow;
            const unsigned short* g = W + (size_t)(n0 + r) * K + k0 + ((lc ^ (r & 7)) * 8);
            gload16(g, &Bs[(wid * 16 + is * 8) * 64]);
        }
        __syncthreads();
#pragma unroll
        for (int kh = 0; kh < 2; ++kh) {
            bf16x8 bfr[2];
#pragma unroll
            for (int nf = 0; nf < 2; ++nf) {
                int r = wn * 32 + nf * 16 + lo;
                bfr[nf] = *(const bf16x8*)&Bs[r * 64 + (((kh * 4 + hi) ^ (r & 7)) * 8)];
            }
#pragma unroll
            for (int mf = 0; mf < 4; ++mf) {
                int r = wm * 64 + mf * 16 + lo;
                bf16x8 afr = *(const bf16x8*)&As[r * 64 + (((kh * 4 + hi) ^ (r & 7)) * 8)];
                acc[mf][0] = __builtin_amdgcn_mfma_f32_16x16x32_bf16(afr, bfr[0], acc[mf][0], 0, 0, 0);
                acc[mf][1] = __builtin_amdgcn_mfma_f32_16x16x32_bf16(afr, bfr[1], acc[mf][1], 0, 0, 0);
            }
        }
    }
#pragma unroll
    for (int mf = 0; mf < 4; ++mf) {
        const int mbase = m0 + wm * 64 + mf * 16 + hi * 4;
#pragma unroll
        for (int nf = 0; nf < 2; ++nf) {
            const int n = n0 + wn * 32 + nf * 16 + lo;
            const float bv = bias[n];
            f32x4 v = acc[mf][nf];
            if constexpr (EPI == 1) {
#pragma unroll
                for (int rg = 0; rg < 4; ++rg) {
                    size_t idx = (size_t)(mbase + rg) * N + n;
                    hres[idx] += v[rg] + bv;
                }
            } else if constexpr (EPI == 3) {
#pragma unroll
                for (int rg = 0; rg < 4; ++rg)
                    hres[(size_t)(mbase + rg) * N + n] = v[rg] + bv;
            } else if constexpr (EPI == 0) {
                unsigned short* dst = (n0 < 256) ? o0 : ((n0 < 512) ? o1 : o2);
                const float qsc = (n0 < 256)
                    ? (0.17677669529663687f * 1.4426950408889634f) : 1.f;
                const int c = n & 255;
#pragma unroll
                for (int rg = 0; rg < 4; ++rg)
                    dst[(size_t)(mbase + rg) * 256 + c] = f2bf((v[rg] + bv) * qsc);
            } else {
#pragma unroll
                for (int rg = 0; rg < 4; ++rg)
                    o0[(size_t)(mbase + rg) * N + n] = f2bf(gelu_f(v[rg] + bv));
            }
        }
    }
}

// ---------------------------------------------------------------------------
// MFMA flash attention v4: no-max softmax (scores provably small; masked cols
// underflow to exactly 0 via ADD=-14400*log2e in the exp2 argument), per-lane
// partial lsum with ONE cross-lane reduce at the end. Block = (b, head,
// quarter of q-rows): grid 1024 -> 4 blocks/CU. Staging identical to proven v2.
__global__ __launch_bounds__(256) void attn_mfma_kernel(
    const unsigned short* __restrict__ Qb, const unsigned short* __restrict__ Kb,
    const unsigned short* __restrict__ Vb, const float* __restrict__ ADD,
    unsigned short* __restrict__ Ob)
{
    __shared__ __align__(16) unsigned short Kl[256 * 40];  // 80B rows (pad 8)
    __shared__ __align__(16) unsigned short Vt[32 * 260];  // V^T, stride 260
    const int t = threadIdx.x;
    const int swz = ((blockIdx.x & 7) << 7) | (blockIdx.x >> 3);  // XCD chunking
    const int bh = swz >> 2, hf = swz & 3;
    const int b = bh >> 3, hd = bh & 7;
    const size_t base = ((size_t)b * 512) * 256 + hd * 32;
    const int w = t >> 6, lane = t & 63, lo = lane & 15, hi = lane >> 4;
    const float* ADDb = ADD + (size_t)b * 262144;

    int iq[2];
    bf16x8 qf[2];
#pragma unroll
    for (int qi = 0; qi < 2; ++qi) {
        iq[qi] = (hf * 8 + w * 2 + qi) * 16 + lo;
        qf[qi] = *(const bf16x8*)(Qb + base + (size_t)iq[qi] * 256 + hi * 8);
    }
    f32x4 acc[2][2] = {};
    float lsum[2] = {0.f, 0.f};

    for (int jt = 0; jt < 2; ++jt) {
        __syncthreads();
        for (int idx = t; idx < 1024; idx += 256) {       // K tile, 16B
            int row = idx >> 2, c4 = idx & 3;
            *(uint4*)&Kl[row * 40 + c4 * 8] =
                *(const uint4*)(Kb + base + (size_t)(jt * 256 + row) * 256 + c4 * 8);
        }
        for (int idx = t; idx < 1024; idx += 256) {       // V^T, paired rows
            int pr = idx >> 3, c4 = idx & 7;
            unsigned long long v0 = *(const unsigned long long*)
                (Vb + base + (size_t)(jt * 256 + 2 * pr) * 256 + c4 * 4);
            unsigned long long v1 = *(const unsigned long long*)
                (Vb + base + (size_t)(jt * 256 + 2 * pr + 1) * 256 + c4 * 4);
#pragma unroll
            for (int e = 0; e < 4; ++e) {
                unsigned a = (unsigned)((v0 >> (16 * e)) & 0xffffu);
                unsigned c = (unsigned)((v1 >> (16 * e)) & 0xffffu);
                *(unsigned*)&Vt[(c4 * 4 + e) * 260 + 2 * pr] = a | (c << 16);
            }
        }
        __syncthreads();
        for (int ktp = 0; ktp < 8; ++ktp) {
            const int k16 = ktp * 32;
            const int gj = jt * 256 + k16;
            bf16x8 kf0 = *(const bf16x8*)&Kl[(k16 + lo) * 40 + hi * 8];
            bf16x8 kf1 = *(const bf16x8*)&Kl[(k16 + 16 + lo) * 40 + hi * 8];
            union U16 { unsigned long long q[2]; unsigned wd[4]; bf16x8 v; } vu0, vu1, pu;
            vu0.q[0] = *(const unsigned long long*)&Vt[lo * 260 + k16 + hi * 4];
            vu0.q[1] = *(const unsigned long long*)&Vt[lo * 260 + k16 + 16 + hi * 4];
            vu1.q[0] = *(const unsigned long long*)&Vt[(16 + lo) * 260 + k16 + hi * 4];
            vu1.q[1] = *(const unsigned long long*)&Vt[(16 + lo) * 260 + k16 + 16 + hi * 4];
#pragma unroll
            for (int qi = 0; qi < 2; ++qi) {
                f32x4 a0 = *(const f32x4*)(ADDb + (size_t)iq[qi] * 512 + gj + hi * 4);
                f32x4 a1 = *(const f32x4*)(ADDb + (size_t)iq[qi] * 512 + gj + 16 + hi * 4);
                f32x4 s0 = __builtin_amdgcn_mfma_f32_16x16x32_bf16(kf0, qf[qi], a0, 0, 0, 0);
                f32x4 s1 = __builtin_amdgcn_mfma_f32_16x16x32_bf16(kf1, qf[qi], a1, 0, 0, 0);
                float p0 = exp2f(s0[0]), p1 = exp2f(s0[1]);
                float p2 = exp2f(s0[2]), p3 = exp2f(s0[3]);
                float p4 = exp2f(s1[0]), p5 = exp2f(s1[1]);
                float p6 = exp2f(s1[2]), p7 = exp2f(s1[3]);
                lsum[qi] += ((p0 + p1) + (p2 + p3)) + ((p4 + p5) + (p6 + p7));
                pu.wd[0] = cvt_pk_bf16(p0, p1);
                pu.wd[1] = cvt_pk_bf16(p2, p3);
                pu.wd[2] = cvt_pk_bf16(p4, p5);
                pu.wd[3] = cvt_pk_bf16(p6, p7);
                acc[qi][0] = __builtin_amdgcn_mfma_f32_16x16x32_bf16(vu0.v, pu.v, acc[qi][0], 0, 0, 0);
                acc[qi][1] = __builtin_amdgcn_mfma_f32_16x16x32_bf16(vu1.v, pu.v, acc[qi][1], 0, 0, 0);
            }
        }
    }
#pragma unroll
    for (int qi = 0; qi < 2; ++qi) {
        float ls = lsum[qi];
        ls += __shfl_xor(ls, 16);
        ls += __shfl_xor(ls, 32);
        const float inv = 1.f / fmaxf(ls, 1e-35f);
        unsigned long long oa =
              (unsigned long long)cvt_pk_bf16(acc[qi][0][0] * inv, acc[qi][0][1] * inv)
            | ((unsigned long long)cvt_pk_bf16(acc[qi][0][2] * inv, acc[qi][0][3] * inv) << 32);
        unsigned long long ob2 =
              (unsigned long long)cvt_pk_bf16(acc[qi][1][0] * inv, acc[qi][1][1] * inv)
            | ((unsigned long long)cvt_pk_bf16(acc[qi][1][2] * inv, acc[qi][1][3] * inv) << 32);
        *(unsigned long long*)(Ob + base + (size_t)iq[qi] * 256 + hi * 4) = oa;
        *(unsigned long long*)(Ob + base + (size_t)iq[qi] * 256 + 16 + hi * 4) = ob2;
    }
}

// ---------------------------------------------------------------------------
extern "C" void kernel_launch(void* const* d_in, const int* in_sizes, int n_in,
                              void* d_out, int out_size, void* d_ws, size_t ws_size,
                              hipStream_t stream) {
    const float* x         = (const float*)d_in[0];
    const float* c_local   = (const float*)d_in[1];
    const float* c_sink    = (const float*)d_in[2];
    const float* W_in      = (const float*)d_in[3];
    const float* b_in      = (const float*)d_in[4];
    const float* cls_token = (const float*)d_in[5];
    const float* pe_proj_W = (const float*)d_in[6];
    const float* pe_proj_b = (const float*)d_in[7];
    const float* pe_ln_g   = (const float*)d_in[8];
    const float* pe_ln_b   = (const float*)d_in[9];
    const float* pe_gain   = (const float*)d_in[10];
    const float* attn_Wqkv = (const float*)d_in[11];
    const float* attn_bqkv = (const float*)d_in[12];
    const float* attn_Wo   = (const float*)d_in[13];
    const float* attn_bo   = (const float*)d_in[14];
    const float* ff_W1     = (const float*)d_in[15];
    const float* ff_b1     = (const float*)d_in[16];
    const float* ff_W2     = (const float*)d_in[17];
    const float* ff_b2     = (const float*)d_in[18];
    const float* ln1_g     = (const float*)d_in[19];
    const float* ln1_b     = (const float*)d_in[20];
    const float* ln2_g     = (const float*)d_in[21];
    const float* ln2_b     = (const float*)d_in[22];
    const float* alpha     = (const float*)d_in[23];
    const float* beta      = (const float*)d_in[24];
    const float* corr_fl   = (const float*)d_in[25];
    const float* out_ln_g  = (const float*)d_in[26];
    const float* out_ln_b  = (const float*)d_in[27];
    const int*   lengths   = (const int*)d_in[28];
    float* out = (float*)d_out;

    // float region
    float* h     = (float*)d_ws;              // 4,194,304
    float* clb   = h + 4194304;               // 16384
    float* csfb  = clb + 16384;
    float* padfb = csfb + 16384;
    float* peWt  = padfb + 16384;             // 70656
    float* PEpos = peWt + 70656;              // 131072
    float* ADDf  = PEpos + 131072;            // 8,388,608
    float* bbf   = ADDf;                      // alias: bb dead before add_bias
    // bf16 region — weights AFTER the full 16,777,216-short f-span at Q_bf
    unsigned short* u_bf = (unsigned short*)(ADDf + 8388608);
    unsigned short* xb_bf = u_bf;             // alias: xb dead before layer loop
    unsigned short* Q_bf = u_bf + 4194304;
    unsigned short* K_bf = Q_bf + 4194304;
    unsigned short* V_bf = K_bf + 4194304;
    unsigned short* f_bf = Q_bf;              // alias: spans Q..Q+16777216
    unsigned short* o_bf = u_bf;              // alias (lifetimes disjoint)
    unsigned short* wq_bf = Q_bf + 16777216;  // after f's span
    unsigned short* wo_bf = wq_bf + 589824;
    unsigned short* w1_bf = wo_bf + 196608;
    unsigned short* w2_bf = w1_bf + 786432;
    unsigned short* win_bf = w2_bf + 786432;  // 16384

    transpose_kernel<<<276, 256, 0, stream>>>(pe_proj_W, peWt);
    cvt_bf16_kernel<<<576, 256, 0, stream>>>(attn_Wqkv, wq_bf, 589824);
    cvt_bf16_kernel<<<192, 256, 0, stream>>>(attn_Wo, wo_bf, 196608);
    cvt_bf16_kernel<<<768, 256, 0, stream>>>(ff_W1, w1_bf, 786432);
    cvt_bf16_kernel<<<768, 256, 0, stream>>>(ff_W2, w2_bf, 786432);
    cvt_bf16_kernel<<<16, 256, 0, stream>>>(W_in, win_bf, 16384);
    xb_kernel<<<2048, 256, 0, stream>>>(x, xb_bf);
    pepos_kernel<<<512, 256, 0, stream>>>(peWt, pe_proj_b, PEpos);
    gemm_bf16_kernel<3><<<dim3(4, 128), 256, 0, stream>>>(
        xb_bf, win_bf, b_in, bbf, nullptr, nullptr, nullptr, 16384, 256, 64);
    prep_lite_kernel<<<2048, 256, 0, stream>>>(
        c_local, c_sink, bbf, cls_token, PEpos, peWt + 65536,
        pe_ln_g, pe_ln_b, pe_gain, corr_fl, lengths, h, clb, csfb, padfb);
    add_bias_kernel<<<16384, 256, 0, stream>>>(clb, csfb, padfb, alpha, beta, ADDf);

    for (int l = 0; l < 3; ++l) {
        ln_bf_kernel<<<4096, 256, 0, stream>>>(h, ln1_g + 256 * l, ln1_b + 256 * l, u_bf);
        gemm_bf16_kernel<0><<<dim3(12, 128), 256, 0, stream>>>(
            u_bf, wq_bf + (size_t)l * 196608, attn_bqkv + 768 * l, nullptr,
            Q_bf, K_bf, V_bf, 16384, 768, 256);
        attn_mfma_kernel<<<1024, 256, 0, stream>>>(Q_bf, K_bf, V_bf, ADDf, o_bf);
        gemm_bf16_kernel<1><<<dim3(4, 128), 256, 0, stream>>>(
            o_bf, wo_bf + (size_t)l * 65536, attn_bo + 256 * l, h,
            nullptr, nullptr, nullptr, 16384, 256, 256);
        ln_bf_kernel<<<4096, 256, 0, stream>>>(h, ln2_g + 256 * l, ln2_b + 256 * l, u_bf);
        gemm_bf16_kernel<2><<<dim3(16, 128), 256, 0, stream>>>(
            u_bf, w1_bf + (size_t)l * 262144, ff_b1 + 1024 * l, nullptr,
            f_bf, nullptr, nullptr, 16384, 1024, 256);
        gemm_bf16_kernel<1><<<dim3(4, 128), 256, 0, stream>>>(
            f_bf, w2_bf + (size_t)l * 262144, ff_b2 + 256 * l, h,
            nullptr, nullptr, nullptr, 16384, 256, 1024);
    }
    out_ln_kernel<<<8, 256, 0, stream>>>(h, out_ln_g, out_ln_b, out);
}

// Round 8
// 508.319 us; speedup vs baseline: 43.2971x; 1.0121x over previous
//
#include <hip/hip_runtime.h>
#include <math.h>

// B=32, L=512 (incl CLS), D=256, H=8, dh=32, N_LAYERS=3, D_FF=1024, tokens=16384

typedef __attribute__((ext_vector_type(4))) float f32x4;
typedef __attribute__((ext_vector_type(8))) short bf16x8;

__device__ __forceinline__ unsigned short f2bf(float f) {
    unsigned u = __builtin_bit_cast(unsigned, f);
    u += 0x7fff + ((u >> 16) & 1);
    return (unsigned short)(u >> 16);
}
__device__ __forceinline__ unsigned cvt_pk_bf16(float a, float b) {
    unsigned r;
    asm("v_cvt_pk_bf16_f32 %0, %1, %2" : "=v"(r) : "v"(a), "v"(b));
    return r;
}
__device__ __forceinline__ float gelu_f(float v) {
    return v * 0.5f * (1.0f + erff(v * 0.70710678118654752f));
}
__device__ __forceinline__ void gload16(const void* g, void* l) {
    __builtin_amdgcn_global_load_lds(
        (const __attribute__((address_space(1))) unsigned int*)g,
        (__attribute__((address_space(3))) unsigned int*)l, 16, 0, 0);
}

// ---------------------------------------------------------------------------
// Transpose pe_proj_W [256,276] -> peWt [276,256]
__global__ __launch_bounds__(256) void transpose_kernel(
    const float* __restrict__ peW, float* __restrict__ peWt)
{
    int j = blockIdx.x * 256 + threadIdx.x;
    if (j < 70656) {
        int f = j >> 8, dd = j & 255;
        peWt[j] = peW[dd * 276 + f];
    }
}

// ---------------------------------------------------------------------------
__global__ __launch_bounds__(256) void cvt_bf16_kernel(
    const float* __restrict__ s, unsigned short* __restrict__ d, int n)
{
    int i = (blockIdx.x * 256 + threadIdx.x) * 4;
    if (i >= n) return;
    float4 v = *(const float4*)(s + i);
    unsigned long long pk = (unsigned long long)f2bf(v.x)
        | ((unsigned long long)f2bf(v.y) << 16)
        | ((unsigned long long)f2bf(v.z) << 32)
        | ((unsigned long long)f2bf(v.w) << 48);
    *(unsigned long long*)(d + i) = pk;
}

// ---------------------------------------------------------------------------
// xb [16384,64] bf16 = x rows (CLS rows zero)
__global__ __launch_bounds__(256) void xb_kernel(
    const float* __restrict__ x, unsigned short* __restrict__ xb)
{
    int idx = blockIdx.x * 256 + threadIdx.x;   // over 524288 u32 pairs
    int tok = idx >> 5, c2 = idx & 31;
    int b = tok >> 9, l = tok & 511;
    unsigned r = 0;
    if (l > 0) {
        float2 v = *(const float2*)(x + ((size_t)b * 511 + l - 1) * 64 + 2 * c2);
        r = cvt_pk_bf16(v.x, v.y);
    }
    *(unsigned*)(xb + (size_t)tok * 64 + 2 * c2) = r;
}

// ---------------------------------------------------------------------------
// PEpos[l][d] = pe_b[d] + sum_f sinusoid(l,f) * peWt[f][d]   (position-only part)
__global__ __launch_bounds__(256) void pepos_kernel(
    const float* __restrict__ peWt, const float* __restrict__ pe_b,
    float* __restrict__ PEpos)
{
    __shared__ float ls[256];
    const int l = blockIdx.x, t = threadIdx.x;
    int kk = t >> 1;
    float div = expf((float)(2 * kk) * -0.035977892078032f); // -ln(10000)/256
    float a = (float)l * div;
    ls[t] = (t & 1) ? cosf(a) : sinf(a);
    __syncthreads();
    float acc = pe_b[t];
    for (int f = 0; f < 256; ++f) acc += ls[f] * peWt[f * 256 + t];
    PEpos[l * 256 + t] = acc;
}

// ---------------------------------------------------------------------------
// prep_lite: h = base(bb or cls) + mask * gain * LN(PEpos + feats@W20)
__global__ __launch_bounds__(256) void prep_lite_kernel(
    const float* __restrict__ c_local, const float* __restrict__ c_sink,
    const float* __restrict__ bb, const float* __restrict__ cls_tok,
    const float* __restrict__ PEpos, const float* __restrict__ W20t,
    const float* __restrict__ pe_g, const float* __restrict__ pe_bb,
    const float* __restrict__ pe_gain_p, const float* __restrict__ corr_floor_p,
    const int* __restrict__ lengths,
    float* __restrict__ h, float* __restrict__ clb, float* __restrict__ csfb,
    float* __restrict__ padfb)
{
    __shared__ float zs[8][20];
    __shared__ __align__(16) float pes[8][256];
    __shared__ float mn[8], rsd[8];
    const int t = threadIdx.x;
    const int tok0 = blockIdx.x * 8;
    const int b = tok0 >> 9;
    const int len_b = lengths[b];
    const float cf = *corr_floor_p;
    const float gain = *pe_gain_p;

    float clv[8], csv[8];
    bool mk[8];
#pragma unroll
    for (int k = 0; k < 8; ++k) {
        int l = (tok0 + k) & 511;
        if (l == 0) { clv[k] = 1.f; csv[k] = 1.f; mk[k] = false; }
        else {
            float a = c_local[b * 511 + l - 1];
            float s = c_sink[b * 511 + l - 1];
            clv[k] = fminf(fmaxf(a, 0.f), 1.f);
            csv[k] = fminf(fmaxf(s, 0.f), 1.f);
            mk[k] = (l - 1) >= len_b;
        }
    }
    if (t < 8) {
        int tok = tok0 + t;
        clb[tok] = clv[t];
        csfb[tok] = cf + (1.f - cf) * csv[t];
        padfb[tok] = mk[t] ? 1.f : 0.f;
    }
    if (t < 20) {
#pragma unroll
        for (int k = 0; k < 8; ++k) {
            float cl = clv[k], cs = csv[k];
            float v;
            if (t == 0) v = cl;
            else if (t == 1) v = cs;
            else if (t == 2) v = cl * cs;
            else if (t == 3) v = fabsf(cl - cs);
            else if (t < 12) {
                float c = (float)(t - 4) * (1.f / 7.f);
                float dd = (cl - c) / 0.200001f;
                v = expf(-0.5f * dd * dd);
            } else {
                float c = (float)(t - 12) * (1.f / 7.f);
                float dd = (cs - c) / 0.200001f;
                v = expf(-0.5f * dd * dd);
            }
            zs[k][t] = v;
        }
    }
    __syncthreads();

    float acc[8];
#pragma unroll
    for (int k = 0; k < 8; ++k)
        acc[k] = PEpos[((tok0 + k) & 511) * 256 + t];
    for (int f = 0; f < 20; ++f) {
        float wv = W20t[f * 256 + t];
#pragma unroll
        for (int k = 0; k < 8; ++k) acc[k] += zs[k][f] * wv;
    }
#pragma unroll
    for (int k = 0; k < 8; ++k) pes[k][t] = acc[k];
    __syncthreads();

    {
        int w = t >> 6, lane = t & 63;
#pragma unroll
        for (int p = 0; p < 2; ++p) {
            int k = w + p * 4;
            float4 v = *(const float4*)&pes[k][lane * 4];
            float s = v.x + v.y + v.z + v.w;
            float sq = v.x * v.x + v.y * v.y + v.z * v.z + v.w * v.w;
#pragma unroll
            for (int off = 32; off; off >>= 1) {
                s += __shfl_xor(s, off);
                sq += __shfl_xor(sq, off);
            }
            if (lane == 0) {
                float mean = s * (1.f / 256.f);
                mn[k] = mean;
                rsd[k] = rsqrtf(sq * (1.f / 256.f) - mean * mean + 1e-5f);
            }
        }
    }
    __syncthreads();
    float gv = pe_g[t], bv = pe_bb[t];
#pragma unroll
    for (int k = 0; k < 8; ++k) {
        int l = (tok0 + k) & 511;
        float base = (l == 0) ? cls_tok[t] : bb[(size_t)(tok0 + k) * 256 + t];
        float pe = (pes[k][t] - mn[k]) * rsd[k] * gv + bv;
        pe *= gain;
        if (mk[k]) pe = 0.f;
        h[(size_t)(tok0 + k) * 256 + t] = base + pe;
    }
}

// ---------------------------------------------------------------------------
// LayerNorm D=256, bf16 output: one wave per token, 4 tokens per block
__global__ __launch_bounds__(256) void ln_bf_kernel(
    const float* __restrict__ x, const float* __restrict__ g,
    const float* __restrict__ b, unsigned short* __restrict__ y)
{
    int tok = blockIdx.x * 4 + (threadIdx.x >> 6);
    int lane = threadIdx.x & 63;
    const float* row = x + (size_t)tok * 256;
    float4 v = *(const float4*)(row + lane * 4);
    float s = v.x + v.y + v.z + v.w;
    float sq = v.x * v.x + v.y * v.y + v.z * v.z + v.w * v.w;
#pragma unroll
    for (int off = 32; off; off >>= 1) {
        s += __shfl_xor(s, off);
        sq += __shfl_xor(sq, off);
    }
    float mean = s * (1.f / 256.f);
    float rs = rsqrtf(sq * (1.f / 256.f) - mean * mean + 1e-5f);
    float4 gv = *(const float4*)(g + lane * 4);
    float4 bv = *(const float4*)(b + lane * 4);
    unsigned long long pk =
          (unsigned long long)f2bf((v.x - mean) * rs * gv.x + bv.x)
        | ((unsigned long long)f2bf((v.y - mean) * rs * gv.y + bv.y) << 16)
        | ((unsigned long long)f2bf((v.z - mean) * rs * gv.z + bv.z) << 32)
        | ((unsigned long long)f2bf((v.w - mean) * rs * gv.w + bv.w) << 48);
    *(unsigned long long*)(y + (size_t)tok * 256 + lane * 4) = pk;
}

// Final LN on the 32 CLS rows only (f32 out)
__global__ __launch_bounds__(256) void out_ln_kernel(
    const float* __restrict__ h, const float* __restrict__ g,
    const float* __restrict__ b, float* __restrict__ out)
{
    int tok = blockIdx.x * 4 + (threadIdx.x >> 6);
    int lane = threadIdx.x & 63;
    const float* row = h + (size_t)tok * 512 * 256;
    float4 v = *(const float4*)(row + lane * 4);
    float s = v.x + v.y + v.z + v.w;
    float sq = v.x * v.x + v.y * v.y + v.z * v.z + v.w * v.w;
#pragma unroll
    for (int off = 32; off; off >>= 1) {
        s += __shfl_xor(s, off);
        sq += __shfl_xor(sq, off);
    }
    float mean = s * (1.f / 256.f);
    float rs = rsqrtf(sq * (1.f / 256.f) - mean * mean + 1e-5f);
    float4 gv = *(const float4*)(g + lane * 4);
    float4 bv = *(const float4*)(b + lane * 4);
    float4 o;
    o.x = (v.x - mean) * rs * gv.x + bv.x;
    o.y = (v.y - mean) * rs * gv.y + bv.y;
    o.z = (v.z - mean) * rs * gv.z + bv.z;
    o.w = (v.w - mean) * rs * gv.w + bv.w;
    *(float4*)(out + (size_t)tok * 256 + lane * 4) = o;
}

// ---------------------------------------------------------------------------
// bf16 MFMA GEMM: C[M,N] = epi(A[M,K] @ W[N,K]^T + bias)
// EPI: 0 = QKV 3-way bf16 split store (Q scaled by scale*log2e),
//      1 = f32 residual accumulate, 2 = GELU -> bf16, 3 = plain f32 store
template <int EPI>
__global__ __launch_bounds__(256) void gemm_bf16_kernel(
    const unsigned short* __restrict__ A, const unsigned short* __restrict__ W,
    const float* __restrict__ bias, float* __restrict__ hres,
    unsigned short* __restrict__ o0, unsigned short* __restrict__ o1,
    unsigned short* __restrict__ o2, int M, int N, int K)
{
    __shared__ __align__(16) unsigned short As[128 * 64];
    __shared__ __align__(16) unsigned short Bs[64 * 64];
    const int t = threadIdx.x;
    const int wid = t >> 6, lane = t & 63;
    const int lo = lane & 15, hi = lane >> 4;
    const int wm = wid >> 1, wn = wid & 1;
    const int m0 = blockIdx.y * 128, n0 = blockIdx.x * 64;
    const int lrow = lane >> 3, lc = lane & 7;
    f32x4 acc[4][2] = {};
    for (int k0 = 0; k0 < K; k0 += 64) {
        __syncthreads();
#pragma unroll
        for (int is = 0; is < 4; ++is) {
            int r = wid * 32 + is * 8 + lrow;
            const unsigned short* g = A + (size_t)(m0 + r) * K + k0 + ((lc ^ (r & 7)) * 8);
            gload16(g, &As[(wid * 32 + is * 8) * 64]);
        }
#pragma unroll
        for (int is = 0; is < 2; ++is) {
            int r = wid * 16 + is * 8 + lrow;
            const unsigned short* g = W + (size_t)(n0 + r) * K + k0 + ((lc ^ (r & 7)) * 8);
            gload16(g, &Bs[(wid * 16 + is * 8) * 64]);
        }
        __syncthreads();
#pragma unroll
        for (int kh = 0; kh < 2; ++kh) {
            bf16x8 bfr[2];
#pragma unroll
            for (int nf = 0; nf < 2; ++nf) {
                int r = wn * 32 + nf * 16 + lo;
                bfr[nf] = *(const bf16x8*)&Bs[r * 64 + (((kh * 4 + hi) ^ (r & 7)) * 8)];
            }
#pragma unroll
            for (int mf = 0; mf < 4; ++mf) {
                int r = wm * 64 + mf * 16 + lo;
                bf16x8 afr = *(const bf16x8*)&As[r * 64 + (((kh * 4 + hi) ^ (r & 7)) * 8)];
                acc[mf][0] = __builtin_amdgcn_mfma_f32_16x16x32_bf16(afr, bfr[0], acc[mf][0], 0, 0, 0);
                acc[mf][1] = __builtin_amdgcn_mfma_f32_16x16x32_bf16(afr, bfr[1], acc[mf][1], 0, 0, 0);
            }
        }
    }
#pragma unroll
    for (int mf = 0; mf < 4; ++mf) {
        const int mbase = m0 + wm * 64 + mf * 16 + hi * 4;
#pragma unroll
        for (int nf = 0; nf < 2; ++nf) {
            const int n = n0 + wn * 32 + nf * 16 + lo;
            const float bv = bias[n];
            f32x4 v = acc[mf][nf];
            if constexpr (EPI == 1) {
#pragma unroll
                for (int rg = 0; rg < 4; ++rg) {
                    size_t idx = (size_t)(mbase + rg) * N + n;
                    hres[idx] += v[rg] + bv;
                }
            } else if constexpr (EPI == 3) {
#pragma unroll
                for (int rg = 0; rg < 4; ++rg)
                    hres[(size_t)(mbase + rg) * N + n] = v[rg] + bv;
            } else if constexpr (EPI == 0) {
                unsigned short* dst = (n0 < 256) ? o0 : ((n0 < 512) ? o1 : o2);
                const float qsc = (n0 < 256)
                    ? (0.17677669529663687f * 1.4426950408889634f) : 1.f;
                const int c = n & 255;
#pragma unroll
                for (int rg = 0; rg < 4; ++rg)
                    dst[(size_t)(mbase + rg) * 256 + c] = f2bf((v[rg] + bv) * qsc);
            } else {
#pragma unroll
                for (int rg = 0; rg < 4; ++rg)
                    o0[(size_t)(mbase + rg) * N + n] = f2bf(gelu_f(v[rg] + bv));
            }
        }
    }
}

// ---------------------------------------------------------------------------
// MFMA flash attention v5: bias folded into the MFMA C-operand on the fly
// (C = csb_i * csf_j + mk_j, from 2KB LDS arrays), tridiagonal alpha term as a
// rare in-loop correction behind a scalar window test, no-max exp2 softmax.
// No precomputed ADD matrix at all. K/V tiled 128 rows (4 jt), LDS 22.8 KB.
__global__ __launch_bounds__(256) void attn_mfma_kernel(
    const unsigned short* __restrict__ Qb, const unsigned short* __restrict__ Kb,
    const unsigned short* __restrict__ Vb, const float* __restrict__ clb,
    const float* __restrict__ csfb, const float* __restrict__ padfb,
    const float* __restrict__ alpha_p, const float* __restrict__ beta_p,
    unsigned short* __restrict__ Ob)
{
    __shared__ __align__(16) unsigned short Kl[128 * 40];   // 10240 B
    __shared__ __align__(16) unsigned short Vt[32 * 132];   // 8448 B
    __shared__ __align__(16) float csfl[512];               // 2 KB
    __shared__ __align__(16) float mkl[512];                // 2 KB
    const int t = threadIdx.x;
    const int swz = ((blockIdx.x & 7) << 7) | (blockIdx.x >> 3);  // XCD chunking
    const int bh = swz >> 2, hf = swz & 3;
    const int b = bh >> 3, hd = bh & 7;
    const size_t base = ((size_t)b * 512) * 256 + hd * 32;
    const int w = t >> 6, lane = t & 63, lo = lane & 15, hi = lane >> 4;
    const float L2E = 1.4426950408889634f;
    const float kb = L2E * (*beta_p);
    const float ka = L2E * (*alpha_p);
    const float* clg = clb + b * 512;

    for (int idx = t; idx < 512; idx += 256) {
        csfl[idx] = csfb[b * 512 + idx];
        mkl[idx] = (padfb[b * 512 + idx] > 0.5f) ? -20000.f : 0.f;
    }

    int iq[2];
    bf16x8 qf[2];
    float csb[2];
#pragma unroll
    for (int qi = 0; qi < 2; ++qi) {
        iq[qi] = (hf * 8 + w * 2 + qi) * 16 + lo;
        qf[qi] = *(const bf16x8*)(Qb + base + (size_t)iq[qi] * 256 + hi * 8);
        csb[qi] = kb * csfb[b * 512 + iq[qi]];
    }
    f32x4 acc[2][2] = {};
    float lsum[2] = {0.f, 0.f};

    for (int jt = 0; jt < 4; ++jt) {
        __syncthreads();
        for (int idx = t; idx < 512; idx += 256) {       // K tile: 128 rows
            int row = idx >> 2, c4 = idx & 3;
            *(uint4*)&Kl[row * 40 + c4 * 8] =
                *(const uint4*)(Kb + base + (size_t)(jt * 128 + row) * 256 + c4 * 8);
        }
        for (int idx = t; idx < 512; idx += 256) {       // V^T, paired rows
            int pr = idx & 63, c4 = idx >> 6;
            unsigned long long v0 = *(const unsigned long long*)
                (Vb + base + (size_t)(jt * 128 + 2 * pr) * 256 + c4 * 4);
            unsigned long long v1 = *(const unsigned long long*)
                (Vb + base + (size_t)(jt * 128 + 2 * pr + 1) * 256 + c4 * 4);
#pragma unroll
            for (int e = 0; e < 4; ++e) {
                unsigned a = (unsigned)((v0 >> (16 * e)) & 0xffffu);
                unsigned c = (unsigned)((v1 >> (16 * e)) & 0xffffu);
                *(unsigned*)&Vt[(c4 * 4 + e) * 132 + 2 * pr] = a | (c << 16);
            }
        }
        __syncthreads();
#pragma unroll
        for (int ktp = 0; ktp < 4; ++ktp) {
            const int k16 = ktp * 32;             // local j base
            const int gj = jt * 128 + k16;        // global j base
            bf16x8 kf0 = *(const bf16x8*)&Kl[(k16 + lo) * 40 + hi * 8];
            bf16x8 kf1 = *(const bf16x8*)&Kl[(k16 + 16 + lo) * 40 + hi * 8];
            union U16 { unsigned long long q[2]; unsigned wd[4]; bf16x8 v; } vu0, vu1, pu;
            vu0.q[0] = *(const unsigned long long*)&Vt[lo * 132 + k16 + hi * 4];
            vu0.q[1] = *(const unsigned long long*)&Vt[lo * 132 + k16 + 16 + hi * 4];
            vu1.q[0] = *(const unsigned long long*)&Vt[(16 + lo) * 132 + k16 + hi * 4];
            vu1.q[1] = *(const unsigned long long*)&Vt[(16 + lo) * 132 + k16 + 16 + hi * 4];
            f32x4 csf0 = *(const f32x4*)&csfl[gj + hi * 4];
            f32x4 csf1 = *(const f32x4*)&csfl[gj + 16 + hi * 4];
            f32x4 mk0 = *(const f32x4*)&mkl[gj + hi * 4];
            f32x4 mk1 = *(const f32x4*)&mkl[gj + 16 + hi * 4];
#pragma unroll
            for (int qi = 0; qi < 2; ++qi) {
                f32x4 c0, c1;
#pragma unroll
                for (int e = 0; e < 4; ++e) {
                    c0[e] = fmaf(csb[qi], csf0[e], mk0[e]);
                    c1[e] = fmaf(csb[qi], csf1[e], mk1[e]);
                }
                f32x4 s0 = __builtin_amdgcn_mfma_f32_16x16x32_bf16(kf0, qf[qi], c0, 0, 0, 0);
                f32x4 s1 = __builtin_amdgcn_mfma_f32_16x16x32_bf16(kf1, qf[qi], c1, 0, 0, 0);
                float p[8];
#pragma unroll
                for (int r = 0; r < 4; ++r) p[r] = exp2f(s0[r]);
#pragma unroll
                for (int r = 0; r < 4; ++r) p[4 + r] = exp2f(s1[r]);
                // tridiagonal alpha correction (rare; scalar window test)
                const int i0 = (hf * 8 + w * 2 + qi) * 16;
                if (gj <= i0 + 16 && gj + 32 >= i0) {
                    const int i = iq[qi];
#pragma unroll
                    for (int r = 0; r < 8; ++r) {
                        int jr = gj + ((r & 4) ? 16 : 0) + hi * 4 + (r & 3);
                        int dij = jr - i;
                        if (dij == 1 || dij == -1) {
                            float ce = (jr >= 1 && i <= 510) ? clg[jr] : clg[i];
                            p[r] *= exp2f(ka * ce);
                        }
                    }
                }
                lsum[qi] += ((p[0] + p[1]) + (p[2] + p[3]))
                          + ((p[4] + p[5]) + (p[6] + p[7]));
                pu.wd[0] = cvt_pk_bf16(p[0], p[1]);
                pu.wd[1] = cvt_pk_bf16(p[2], p[3]);
                pu.wd[2] = cvt_pk_bf16(p[4], p[5]);
                pu.wd[3] = cvt_pk_bf16(p[6], p[7]);
                acc[qi][0] = __builtin_amdgcn_mfma_f32_16x16x32_bf16(vu0.v, pu.v, acc[qi][0], 0, 0, 0);
                acc[qi][1] = __builtin_amdgcn_mfma_f32_16x16x32_bf16(vu1.v, pu.v, acc[qi][1], 0, 0, 0);
            }
        }
    }
#pragma unroll
    for (int qi = 0; qi < 2; ++qi) {
        float ls = lsum[qi];
        ls += __shfl_xor(ls, 16);
        ls += __shfl_xor(ls, 32);
        const float inv = 1.f / fmaxf(ls, 1e-35f);
        unsigned long long oa =
              (unsigned long long)cvt_pk_bf16(acc[qi][0][0] * inv, acc[qi][0][1] * inv)
            | ((unsigned long long)cvt_pk_bf16(acc[qi][0][2] * inv, acc[qi][0][3] * inv) << 32);
        unsigned long long ob2 =
              (unsigned long long)cvt_pk_bf16(acc[qi][1][0] * inv, acc[qi][1][1] * inv)
            | ((unsigned long long)cvt_pk_bf16(acc[qi][1][2] * inv, acc[qi][1][3] * inv) << 32);
        *(unsigned long long*)(Ob + base + (size_t)iq[qi] * 256 + hi * 4) = oa;
        *(unsigned long long*)(Ob + base + (size_t)iq[qi] * 256 + 16 + hi * 4) = ob2;
    }
}

// ---------------------------------------------------------------------------
extern "C" void kernel_launch(void* const* d_in, const int* in_sizes, int n_in,
                              void* d_out, int out_size, void* d_ws, size_t ws_size,
                              hipStream_t stream) {
    const float* x         = (const float*)d_in[0];
    const float* c_local   = (const float*)d_in[1];
    const float* c_sink    = (const float*)d_in[2];
    const float* W_in      = (const float*)d_in[3];
    const float* b_in      = (const float*)d_in[4];
    const float* cls_token = (const float*)d_in[5];
    const float* pe_proj_W = (const float*)d_in[6];
    const float* pe_proj_b = (const float*)d_in[7];
    const float* pe_ln_g   = (const float*)d_in[8];
    const float* pe_ln_b   = (const float*)d_in[9];
    const float* pe_gain   = (const float*)d_in[10];
    const float* attn_Wqkv = (const float*)d_in[11];
    const float* attn_bqkv = (const float*)d_in[12];
    const float* attn_Wo   = (const float*)d_in[13];
    const float* attn_bo   = (const float*)d_in[14];
    const float* ff_W1     = (const float*)d_in[15];
    const float* ff_b1     = (const float*)d_in[16];
    const float* ff_W2     = (const float*)d_in[17];
    const float* ff_b2     = (const float*)d_in[18];
    const float* ln1_g     = (const float*)d_in[19];
    const float* ln1_b     = (const float*)d_in[20];
    const float* ln2_g     = (const float*)d_in[21];
    const float* ln2_b     = (const float*)d_in[22];
    const float* alpha     = (const float*)d_in[23];
    const float* beta      = (const float*)d_in[24];
    const float* corr_fl   = (const float*)d_in[25];
    const float* out_ln_g  = (const float*)d_in[26];
    const float* out_ln_b  = (const float*)d_in[27];
    const int*   lengths   = (const int*)d_in[28];
    float* out = (float*)d_out;

    // float region (bbf occupies the old ADD slot; all downstream addresses
    // identical to the round-6/7 passing layout)
    float* h     = (float*)d_ws;              // 4,194,304
    float* clb   = h + 4194304;               // 16384
    float* csfb  = clb + 16384;
    float* padfb = csfb + 16384;
    float* peWt  = padfb + 16384;             // 70656
    float* PEpos = peWt + 70656;              // 131072
    float* bbf   = PEpos + 131072;            // in old 8,388,608-float region
    // bf16 region — weights AFTER the full 16,777,216-short f-span at Q_bf
    unsigned short* u_bf = (unsigned short*)(bbf + 8388608);
    unsigned short* xb_bf = u_bf;             // alias: xb dead before layer loop
    unsigned short* Q_bf = u_bf + 4194304;
    unsigned short* K_bf = Q_bf + 4194304;
    unsigned short* V_bf = K_bf + 4194304;
    unsigned short* f_bf = Q_bf;              // alias: spans Q..Q+16777216
    unsigned short* o_bf = u_bf;              // alias (lifetimes disjoint)
    unsigned short* wq_bf = Q_bf + 16777216;  // after f's span
    unsigned short* wo_bf = wq_bf + 589824;
    unsigned short* w1_bf = wo_bf + 196608;
    unsigned short* w2_bf = w1_bf + 786432;
    unsigned short* win_bf = w2_bf + 786432;  // 16384

    transpose_kernel<<<276, 256, 0, stream>>>(pe_proj_W, peWt);
    cvt_bf16_kernel<<<576, 256, 0, stream>>>(attn_Wqkv, wq_bf, 589824);
    cvt_bf16_kernel<<<192, 256, 0, stream>>>(attn_Wo, wo_bf, 196608);
    cvt_bf16_kernel<<<768, 256, 0, stream>>>(ff_W1, w1_bf, 786432);
    cvt_bf16_kernel<<<768, 256, 0, stream>>>(ff_W2, w2_bf, 786432);
    cvt_bf16_kernel<<<16, 256, 0, stream>>>(W_in, win_bf, 16384);
    xb_kernel<<<2048, 256, 0, stream>>>(x, xb_bf);
    pepos_kernel<<<512, 256, 0, stream>>>(peWt, pe_proj_b, PEpos);
    gemm_bf16_kernel<3><<<dim3(4, 128), 256, 0, stream>>>(
        xb_bf, win_bf, b_in, bbf, nullptr, nullptr, nullptr, 16384, 256, 64);
    prep_lite_kernel<<<2048, 256, 0, stream>>>(
        c_local, c_sink, bbf, cls_token, PEpos, peWt + 65536,
        pe_ln_g, pe_ln_b, pe_gain, corr_fl, lengths, h, clb, csfb, padfb);

    for (int l = 0; l < 3; ++l) {
        ln_bf_kernel<<<4096, 256, 0, stream>>>(h, ln1_g + 256 * l, ln1_b + 256 * l, u_bf);
        gemm_bf16_kernel<0><<<dim3(12, 128), 256, 0, stream>>>(
            u_bf, wq_bf + (size_t)l * 196608, attn_bqkv + 768 * l, nullptr,
            Q_bf, K_bf, V_bf, 16384, 768, 256);
        attn_mfma_kernel<<<1024, 256, 0, stream>>>(Q_bf, K_bf, V_bf, clb, csfb,
                                                   padfb, alpha, beta, o_bf);
        gemm_bf16_kernel<1><<<dim3(4, 128), 256, 0, stream>>>(
            o_bf, wo_bf + (size_t)l * 65536, attn_bo + 256 * l, h,
            nullptr, nullptr, nullptr, 16384, 256, 256);
        ln_bf_kernel<<<4096, 256, 0, stream>>>(h, ln2_g + 256 * l, ln2_b + 256 * l, u_bf);
        gemm_bf16_kernel<2><<<dim3(16, 128), 256, 0, stream>>>(
            u_bf, w1_bf + (size_t)l * 262144, ff_b1 + 1024 * l, nullptr,
            f_bf, nullptr, nullptr, 16384, 1024, 256);
        gemm_bf16_kernel<1><<<dim3(4, 128), 256, 0, stream>>>(
            f_bf, w2_bf + (size_t)l * 262144, ff_b2 + 256 * l, h,
            nullptr, nullptr, nullptr, 16384, 256, 1024);
    }
    out_ln_kernel<<<8, 256, 0, stream>>>(h, out_ln_g, out_ln_b, out);
}

// Round 9
// 507.582 us; speedup vs baseline: 43.3600x; 1.0015x over previous
//
#include <hip/hip_runtime.h>
#include <math.h>

// B=32, L=512 (incl CLS), D=256, H=8, dh=32, N_LAYERS=3, D_FF=1024, tokens=16384

typedef __attribute__((ext_vector_type(4))) float f32x4;
typedef __attribute__((ext_vector_type(8))) short bf16x8;

__device__ __forceinline__ unsigned short f2bf(float f) {
    unsigned u = __builtin_bit_cast(unsigned, f);
    u += 0x7fff + ((u >> 16) & 1);
    return (unsigned short)(u >> 16);
}
__device__ __forceinline__ unsigned cvt_pk_bf16(float a, float b) {
    unsigned r;
    asm("v_cvt_pk_bf16_f32 %0, %1, %2" : "=v"(r) : "v"(a), "v"(b));
    return r;
}
__device__ __forceinline__ float gelu_f(float v) {
    return v * 0.5f * (1.0f + erff(v * 0.70710678118654752f));
}
__device__ __forceinline__ void gload16(const void* g, void* l) {
    __builtin_amdgcn_global_load_lds(
        (const __attribute__((address_space(1))) unsigned int*)g,
        (__attribute__((address_space(3))) unsigned int*)l, 16, 0, 0);
}

// ---------------------------------------------------------------------------
// Transpose pe_proj_W [256,276] -> peWt [276,256]
__global__ __launch_bounds__(256) void transpose_kernel(
    const float* __restrict__ peW, float* __restrict__ peWt)
{
    int j = blockIdx.x * 256 + threadIdx.x;
    if (j < 70656) {
        int f = j >> 8, dd = j & 255;
        peWt[j] = peW[dd * 276 + f];
    }
}

// ---------------------------------------------------------------------------
__global__ __launch_bounds__(256) void cvt_bf16_kernel(
    const float* __restrict__ s, unsigned short* __restrict__ d, int n)
{
    int i = (blockIdx.x * 256 + threadIdx.x) * 4;
    if (i >= n) return;
    float4 v = *(const float4*)(s + i);
    unsigned long long pk = (unsigned long long)f2bf(v.x)
        | ((unsigned long long)f2bf(v.y) << 16)
        | ((unsigned long long)f2bf(v.z) << 32)
        | ((unsigned long long)f2bf(v.w) << 48);
    *(unsigned long long*)(d + i) = pk;
}

// ---------------------------------------------------------------------------
// xb [16384,64] bf16 = x rows (CLS rows zero)
__global__ __launch_bounds__(256) void xb_kernel(
    const float* __restrict__ x, unsigned short* __restrict__ xb)
{
    int idx = blockIdx.x * 256 + threadIdx.x;   // over 524288 u32 pairs
    int tok = idx >> 5, c2 = idx & 31;
    int b = tok >> 9, l = tok & 511;
    unsigned r = 0;
    if (l > 0) {
        float2 v = *(const float2*)(x + ((size_t)b * 511 + l - 1) * 64 + 2 * c2);
        r = cvt_pk_bf16(v.x, v.y);
    }
    *(unsigned*)(xb + (size_t)tok * 64 + 2 * c2) = r;
}

// ---------------------------------------------------------------------------
// PEpos[l][d] = pe_b[d] + sum_f sinusoid(l,f) * peWt[f][d]   (position-only part)
__global__ __launch_bounds__(256) void pepos_kernel(
    const float* __restrict__ peWt, const float* __restrict__ pe_b,
    float* __restrict__ PEpos)
{
    __shared__ float ls[256];
    const int l = blockIdx.x, t = threadIdx.x;
    int kk = t >> 1;
    float div = expf((float)(2 * kk) * -0.035977892078032f); // -ln(10000)/256
    float a = (float)l * div;
    ls[t] = (t & 1) ? cosf(a) : sinf(a);
    __syncthreads();
    float acc = pe_b[t];
    for (int f = 0; f < 256; ++f) acc += ls[f] * peWt[f * 256 + t];
    PEpos[l * 256 + t] = acc;
}

// ---------------------------------------------------------------------------
// prep_lite: h = base(bb or cls) + mask * gain * LN(PEpos + feats@W20)
__global__ __launch_bounds__(256) void prep_lite_kernel(
    const float* __restrict__ c_local, const float* __restrict__ c_sink,
    const float* __restrict__ bb, const float* __restrict__ cls_tok,
    const float* __restrict__ PEpos, const float* __restrict__ W20t,
    const float* __restrict__ pe_g, const float* __restrict__ pe_bb,
    const float* __restrict__ pe_gain_p, const float* __restrict__ corr_floor_p,
    const int* __restrict__ lengths,
    float* __restrict__ h, float* __restrict__ clb, float* __restrict__ csfb,
    float* __restrict__ padfb)
{
    __shared__ float zs[8][20];
    __shared__ __align__(16) float pes[8][256];
    __shared__ float mn[8], rsd[8];
    const int t = threadIdx.x;
    const int tok0 = blockIdx.x * 8;
    const int b = tok0 >> 9;
    const int len_b = lengths[b];
    const float cf = *corr_floor_p;
    const float gain = *pe_gain_p;

    float clv[8], csv[8];
    bool mk[8];
#pragma unroll
    for (int k = 0; k < 8; ++k) {
        int l = (tok0 + k) & 511;
        if (l == 0) { clv[k] = 1.f; csv[k] = 1.f; mk[k] = false; }
        else {
            float a = c_local[b * 511 + l - 1];
            float s = c_sink[b * 511 + l - 1];
            clv[k] = fminf(fmaxf(a, 0.f), 1.f);
            csv[k] = fminf(fmaxf(s, 0.f), 1.f);
            mk[k] = (l - 1) >= len_b;
        }
    }
    if (t < 8) {
        int tok = tok0 + t;
        clb[tok] = clv[t];
        csfb[tok] = cf + (1.f - cf) * csv[t];
        padfb[tok] = mk[t] ? 1.f : 0.f;
    }
    if (t < 20) {
#pragma unroll
        for (int k = 0; k < 8; ++k) {
            float cl = clv[k], cs = csv[k];
            float v;
            if (t == 0) v = cl;
            else if (t == 1) v = cs;
            else if (t == 2) v = cl * cs;
            else if (t == 3) v = fabsf(cl - cs);
            else if (t < 12) {
                float c = (float)(t - 4) * (1.f / 7.f);
                float dd = (cl - c) / 0.200001f;
                v = expf(-0.5f * dd * dd);
            } else {
                float c = (float)(t - 12) * (1.f / 7.f);
                float dd = (cs - c) / 0.200001f;
                v = expf(-0.5f * dd * dd);
            }
            zs[k][t] = v;
        }
    }
    __syncthreads();

    float acc[8];
#pragma unroll
    for (int k = 0; k < 8; ++k)
        acc[k] = PEpos[((tok0 + k) & 511) * 256 + t];
    for (int f = 0; f < 20; ++f) {
        float wv = W20t[f * 256 + t];
#pragma unroll
        for (int k = 0; k < 8; ++k) acc[k] += zs[k][f] * wv;
    }
#pragma unroll
    for (int k = 0; k < 8; ++k) pes[k][t] = acc[k];
    __syncthreads();

    {
        int w = t >> 6, lane = t & 63;
#pragma unroll
        for (int p = 0; p < 2; ++p) {
            int k = w + p * 4;
            float4 v = *(const float4*)&pes[k][lane * 4];
            float s = v.x + v.y + v.z + v.w;
            float sq = v.x * v.x + v.y * v.y + v.z * v.z + v.w * v.w;
#pragma unroll
            for (int off = 32; off; off >>= 1) {
                s += __shfl_xor(s, off);
                sq += __shfl_xor(sq, off);
            }
            if (lane == 0) {
                float mean = s * (1.f / 256.f);
                mn[k] = mean;
                rsd[k] = rsqrtf(sq * (1.f / 256.f) - mean * mean + 1e-5f);
            }
        }
    }
    __syncthreads();
    float gv = pe_g[t], bv = pe_bb[t];
#pragma unroll
    for (int k = 0; k < 8; ++k) {
        int l = (tok0 + k) & 511;
        float base = (l == 0) ? cls_tok[t] : bb[(size_t)(tok0 + k) * 256 + t];
        float pe = (pes[k][t] - mn[k]) * rsd[k] * gv + bv;
        pe *= gain;
        if (mk[k]) pe = 0.f;
        h[(size_t)(tok0 + k) * 256 + t] = base + pe;
    }
}

// ---------------------------------------------------------------------------
// LayerNorm D=256, bf16 output: one wave per token, 4 tokens per block
__global__ __launch_bounds__(256) void ln_bf_kernel(
    const float* __restrict__ x, const float* __restrict__ g,
    const float* __restrict__ b, unsigned short* __restrict__ y)
{
    int tok = blockIdx.x * 4 + (threadIdx.x >> 6);
    int lane = threadIdx.x & 63;
    const float* row = x + (size_t)tok * 256;
    float4 v = *(const float4*)(row + lane * 4);
    float s = v.x + v.y + v.z + v.w;
    float sq = v.x * v.x + v.y * v.y + v.z * v.z + v.w * v.w;
#pragma unroll
    for (int off = 32; off; off >>= 1) {
        s += __shfl_xor(s, off);
        sq += __shfl_xor(sq, off);
    }
    float mean = s * (1.f / 256.f);
    float rs = rsqrtf(sq * (1.f / 256.f) - mean * mean + 1e-5f);
    float4 gv = *(const float4*)(g + lane * 4);
    float4 bv = *(const float4*)(b + lane * 4);
    unsigned long long pk =
          (unsigned long long)f2bf((v.x - mean) * rs * gv.x + bv.x)
        | ((unsigned long long)f2bf((v.y - mean) * rs * gv.y + bv.y) << 16)
        | ((unsigned long long)f2bf((v.z - mean) * rs * gv.z + bv.z) << 32)
        | ((unsigned long long)f2bf((v.w - mean) * rs * gv.w + bv.w) << 48);
    *(unsigned long long*)(y + (size_t)tok * 256 + lane * 4) = pk;
}

// Final LN on the 32 CLS rows only (f32 out)
__global__ __launch_bounds__(256) void out_ln_kernel(
    const float* __restrict__ h, const float* __restrict__ g,
    const float* __restrict__ b, float* __restrict__ out)
{
    int tok = blockIdx.x * 4 + (threadIdx.x >> 6);
    int lane = threadIdx.x & 63;
    const float* row = h + (size_t)tok * 512 * 256;
    float4 v = *(const float4*)(row + lane * 4);
    float s = v.x + v.y + v.z + v.w;
    float sq = v.x * v.x + v.y * v.y + v.z * v.z + v.w * v.w;
#pragma unroll
    for (int off = 32; off; off >>= 1) {
        s += __shfl_xor(s, off);
        sq += __shfl_xor(sq, off);
    }
    float mean = s * (1.f / 256.f);
    float rs = rsqrtf(sq * (1.f / 256.f) - mean * mean + 1e-5f);
    float4 gv = *(const float4*)(g + lane * 4);
    float4 bv = *(const float4*)(b + lane * 4);
    float4 o;
    o.x = (v.x - mean) * rs * gv.x + bv.x;
    o.y = (v.y - mean) * rs * gv.y + bv.y;
    o.z = (v.z - mean) * rs * gv.z + bv.z;
    o.w = (v.w - mean) * rs * gv.w + bv.w;
    *(float4*)(out + (size_t)tok * 256 + lane * 4) = o;
}

// ---------------------------------------------------------------------------
// bf16 MFMA GEMM, 128x64 tile (proven): C[M,N] = epi(A @ W^T + bias)
// EPI: 1 = f32 residual accumulate, 3 = plain f32 store
template <int EPI>
__global__ __launch_bounds__(256) void gemm_bf16_kernel(
    const unsigned short* __restrict__ A, const unsigned short* __restrict__ W,
    const float* __restrict__ bias, float* __restrict__ hres,
    unsigned short* __restrict__ o0, unsigned short* __restrict__ o1,
    unsigned short* __restrict__ o2, int M, int N, int K)
{
    __shared__ __align__(16) unsigned short As[128 * 64];
    __shared__ __align__(16) unsigned short Bs[64 * 64];
    const int t = threadIdx.x;
    const int wid = t >> 6, lane = t & 63;
    const int lo = lane & 15, hi = lane >> 4;
    const int wm = wid >> 1, wn = wid & 1;
    const int m0 = blockIdx.y * 128, n0 = blockIdx.x * 64;
    const int lrow = lane >> 3, lc = lane & 7;
    f32x4 acc[4][2] = {};
    for (int k0 = 0; k0 < K; k0 += 64) {
        __syncthreads();
#pragma unroll
        for (int is = 0; is < 4; ++is) {
            int r = wid * 32 + is * 8 + lrow;
            const unsigned short* g = A + (size_t)(m0 + r) * K + k0 + ((lc ^ (r & 7)) * 8);
            gload16(g, &As[(wid * 32 + is * 8) * 64]);
        }
#pragma unroll
        for (int is = 0; is < 2; ++is) {
            int r = wid * 16 + is * 8 + lrow;
            const unsigned short* g = W + (size_t)(n0 + r) * K + k0 + ((lc ^ (r & 7)) * 8);
            gload16(g, &Bs[(wid * 16 + is * 8) * 64]);
        }
        __syncthreads();
#pragma unroll
        for (int kh = 0; kh < 2; ++kh) {
            bf16x8 bfr[2];
#pragma unroll
            for (int nf = 0; nf < 2; ++nf) {
                int r = wn * 32 + nf * 16 + lo;
                bfr[nf] = *(const bf16x8*)&Bs[r * 64 + (((kh * 4 + hi) ^ (r & 7)) * 8)];
            }
#pragma unroll
            for (int mf = 0; mf < 4; ++mf) {
                int r = wm * 64 + mf * 16 + lo;
                bf16x8 afr = *(const bf16x8*)&As[r * 64 + (((kh * 4 + hi) ^ (r & 7)) * 8)];
                acc[mf][0] = __builtin_amdgcn_mfma_f32_16x16x32_bf16(afr, bfr[0], acc[mf][0], 0, 0, 0);
                acc[mf][1] = __builtin_amdgcn_mfma_f32_16x16x32_bf16(afr, bfr[1], acc[mf][1], 0, 0, 0);
            }
        }
    }
#pragma unroll
    for (int mf = 0; mf < 4; ++mf) {
        const int mbase = m0 + wm * 64 + mf * 16 + hi * 4;
#pragma unroll
        for (int nf = 0; nf < 2; ++nf) {
            const int n = n0 + wn * 32 + nf * 16 + lo;
            const float bv = bias[n];
            f32x4 v = acc[mf][nf];
            if constexpr (EPI == 1) {
#pragma unroll
                for (int rg = 0; rg < 4; ++rg) {
                    size_t idx = (size_t)(mbase + rg) * N + n;
                    hres[idx] += v[rg] + bv;
                }
            } else {
#pragma unroll
                for (int rg = 0; rg < 4; ++rg)
                    hres[(size_t)(mbase + rg) * N + n] = v[rg] + bv;
            }
        }
    }
}

// ---------------------------------------------------------------------------
// bf16 MFMA GEMM, 128x128 tile (4 waves, each 64x64): for QKV (EPI=0) and
// FF1 GELU (EPI=2). Same both-sides XOR swizzle staging as the 128x64 kernel.
template <int EPI>
__global__ __launch_bounds__(256) void gemm128_kernel(
    const unsigned short* __restrict__ A, const unsigned short* __restrict__ W,
    const float* __restrict__ bias,
    unsigned short* __restrict__ o0, unsigned short* __restrict__ o1,
    unsigned short* __restrict__ o2, int M, int N, int K)
{
    __shared__ __align__(16) unsigned short As[128 * 64];
    __shared__ __align__(16) unsigned short Bs[128 * 64];
    const int t = threadIdx.x;
    const int wid = t >> 6, lane = t & 63;
    const int lo = lane & 15, hi = lane >> 4;
    const int wm = wid >> 1, wn = wid & 1;
    const int m0 = blockIdx.y * 128, n0 = blockIdx.x * 128;
    const int lrow = lane >> 3, lc = lane & 7;
    f32x4 acc[4][4] = {};
    for (int k0 = 0; k0 < K; k0 += 64) {
        __syncthreads();
#pragma unroll
        for (int is = 0; is < 4; ++is) {
            int r = wid * 32 + is * 8 + lrow;
            const unsigned short* g = A + (size_t)(m0 + r) * K + k0 + ((lc ^ (r & 7)) * 8);
            gload16(g, &As[(wid * 32 + is * 8) * 64]);
        }
#pragma unroll
        for (int is = 0; is < 4; ++is) {
            int r = wid * 32 + is * 8 + lrow;
            const unsigned short* g = W + (size_t)(n0 + r) * K + k0 + ((lc ^ (r & 7)) * 8);
            gload16(g, &Bs[(wid * 32 + is * 8) * 64]);
        }
        __syncthreads();
#pragma unroll
        for (int kh = 0; kh < 2; ++kh) {
            bf16x8 bfr[4];
#pragma unroll
            for (int nf = 0; nf < 4; ++nf) {
                int r = wn * 64 + nf * 16 + lo;
                bfr[nf] = *(const bf16x8*)&Bs[r * 64 + (((kh * 4 + hi) ^ (r & 7)) * 8)];
            }
#pragma unroll
            for (int mf = 0; mf < 4; ++mf) {
                int r = wm * 64 + mf * 16 + lo;
                bf16x8 afr = *(const bf16x8*)&As[r * 64 + (((kh * 4 + hi) ^ (r & 7)) * 8)];
#pragma unroll
                for (int nf = 0; nf < 4; ++nf)
                    acc[mf][nf] = __builtin_amdgcn_mfma_f32_16x16x32_bf16(afr, bfr[nf], acc[mf][nf], 0, 0, 0);
            }
        }
    }
#pragma unroll
    for (int mf = 0; mf < 4; ++mf) {
        const int mbase = m0 + wm * 64 + mf * 16 + hi * 4;
#pragma unroll
        for (int nf = 0; nf < 4; ++nf) {
            const int n = n0 + wn * 64 + nf * 16 + lo;
            const float bv = bias[n];
            f32x4 v = acc[mf][nf];
            if constexpr (EPI == 0) {
                unsigned short* dst = (n < 256) ? o0 : ((n < 512) ? o1 : o2);
                const float qsc = (n < 256)
                    ? (0.17677669529663687f * 1.4426950408889634f) : 1.f;
                const int c = n & 255;
#pragma unroll
                for (int rg = 0; rg < 4; ++rg)
                    dst[(size_t)(mbase + rg) * 256 + c] = f2bf((v[rg] + bv) * qsc);
            } else {
#pragma unroll
                for (int rg = 0; rg < 4; ++rg)
                    o0[(size_t)(mbase + rg) * N + n] = f2bf(gelu_f(v[rg] + bv));
            }
        }
    }
}

// ---------------------------------------------------------------------------
// MFMA flash attention v6: same math as proven v5, but 1 q-group per wave
// (grid 2048, 8 blocks/CU) for latency hiding via TLP.
__global__ __launch_bounds__(256) void attn_mfma_kernel(
    const unsigned short* __restrict__ Qb, const unsigned short* __restrict__ Kb,
    const unsigned short* __restrict__ Vb, const float* __restrict__ clb,
    const float* __restrict__ csfb, const float* __restrict__ padfb,
    const float* __restrict__ alpha_p, const float* __restrict__ beta_p,
    unsigned short* __restrict__ Ob)
{
    __shared__ __align__(16) unsigned short Kl[128 * 40];   // 10240 B
    __shared__ __align__(16) unsigned short Vt[32 * 132];   // 8448 B
    __shared__ __align__(16) float csfl[512];               // 2 KB
    __shared__ __align__(16) float mkl[512];                // 2 KB
    const int t = threadIdx.x;
    const int swz = ((blockIdx.x & 7) << 8) | (blockIdx.x >> 3);  // XCD chunking
    const int bh = swz >> 3, hf = swz & 7;
    const int b = bh >> 3, hd = bh & 7;
    const size_t base = ((size_t)b * 512) * 256 + hd * 32;
    const int w = t >> 6, lane = t & 63, lo = lane & 15, hi = lane >> 4;
    const float L2E = 1.4426950408889634f;
    const float kb = L2E * (*beta_p);
    const float ka = L2E * (*alpha_p);
    const float* clg = clb + b * 512;

    for (int idx = t; idx < 512; idx += 256) {
        csfl[idx] = csfb[b * 512 + idx];
        mkl[idx] = (padfb[b * 512 + idx] > 0.5f) ? -20000.f : 0.f;
    }

    const int i0 = (hf * 4 + w) * 16;
    const int iq = i0 + lo;
    const bf16x8 qf = *(const bf16x8*)(Qb + base + (size_t)iq * 256 + hi * 8);
    const float csb = kb * csfb[b * 512 + iq];
    f32x4 acc0 = {0.f, 0.f, 0.f, 0.f}, acc1 = {0.f, 0.f, 0.f, 0.f};
    float lsum = 0.f;

    for (int jt = 0; jt < 4; ++jt) {
        __syncthreads();
        for (int idx = t; idx < 512; idx += 256) {       // K tile: 128 rows
            int row = idx >> 2, c4 = idx & 3;
            *(uint4*)&Kl[row * 40 + c4 * 8] =
                *(const uint4*)(Kb + base + (size_t)(jt * 128 + row) * 256 + c4 * 8);
        }
        for (int idx = t; idx < 512; idx += 256) {       // V^T, paired rows
            int pr = idx & 63, c4 = idx >> 6;
            unsigned long long v0 = *(const unsigned long long*)
                (Vb + base + (size_t)(jt * 128 + 2 * pr) * 256 + c4 * 4);
            unsigned long long v1 = *(const unsigned long long*)
                (Vb + base + (size_t)(jt * 128 + 2 * pr + 1) * 256 + c4 * 4);
#pragma unroll
            for (int e = 0; e < 4; ++e) {
                unsigned a = (unsigned)((v0 >> (16 * e)) & 0xffffu);
                unsigned c = (unsigned)((v1 >> (16 * e)) & 0xffffu);
                *(unsigned*)&Vt[(c4 * 4 + e) * 132 + 2 * pr] = a | (c << 16);
            }
        }
        __syncthreads();
#pragma unroll
        for (int ktp = 0; ktp < 4; ++ktp) {
            const int k16 = ktp * 32;             // local j base
            const int gj = jt * 128 + k16;        // global j base
            bf16x8 kf0 = *(const bf16x8*)&Kl[(k16 + lo) * 40 + hi * 8];
            bf16x8 kf1 = *(const bf16x8*)&Kl[(k16 + 16 + lo) * 40 + hi * 8];
            union U16 { unsigned long long q[2]; unsigned wd[4]; bf16x8 v; } vu0, vu1, pu;
            vu0.q[0] = *(const unsigned long long*)&Vt[lo * 132 + k16 + hi * 4];
            vu0.q[1] = *(const unsigned long long*)&Vt[lo * 132 + k16 + 16 + hi * 4];
            vu1.q[0] = *(const unsigned long long*)&Vt[(16 + lo) * 132 + k16 + hi * 4];
            vu1.q[1] = *(const unsigned long long*)&Vt[(16 + lo) * 132 + k16 + 16 + hi * 4];
            f32x4 csf0 = *(const f32x4*)&csfl[gj + hi * 4];
            f32x4 csf1 = *(const f32x4*)&csfl[gj + 16 + hi * 4];
            f32x4 mk0 = *(const f32x4*)&mkl[gj + hi * 4];
            f32x4 mk1 = *(const f32x4*)&mkl[gj + 16 + hi * 4];
            f32x4 c0, c1;
#pragma unroll
            for (int e = 0; e < 4; ++e) {
                c0[e] = fmaf(csb, csf0[e], mk0[e]);
                c1[e] = fmaf(csb, csf1[e], mk1[e]);
            }
            f32x4 s0 = __builtin_amdgcn_mfma_f32_16x16x32_bf16(kf0, qf, c0, 0, 0, 0);
            f32x4 s1 = __builtin_amdgcn_mfma_f32_16x16x32_bf16(kf1, qf, c1, 0, 0, 0);
            float p[8];
#pragma unroll
            for (int r = 0; r < 4; ++r) p[r] = exp2f(s0[r]);
#pragma unroll
            for (int r = 0; r < 4; ++r) p[4 + r] = exp2f(s1[r]);
            // tridiagonal alpha correction (rare; scalar window test)
            if (gj <= i0 + 16 && gj + 32 >= i0) {
#pragma unroll
                for (int r = 0; r < 8; ++r) {
                    int jr = gj + ((r & 4) ? 16 : 0) + hi * 4 + (r & 3);
                    int dij = jr - iq;
                    if (dij == 1 || dij == -1) {
                        float ce = (jr >= 1 && iq <= 510) ? clg[jr] : clg[iq];
                        p[r] *= exp2f(ka * ce);
                    }
                }
            }
            lsum += ((p[0] + p[1]) + (p[2] + p[3])) + ((p[4] + p[5]) + (p[6] + p[7]));
            pu.wd[0] = cvt_pk_bf16(p[0], p[1]);
            pu.wd[1] = cvt_pk_bf16(p[2], p[3]);
            pu.wd[2] = cvt_pk_bf16(p[4], p[5]);
            pu.wd[3] = cvt_pk_bf16(p[6], p[7]);
            acc0 = __builtin_amdgcn_mfma_f32_16x16x32_bf16(vu0.v, pu.v, acc0, 0, 0, 0);
            acc1 = __builtin_amdgcn_mfma_f32_16x16x32_bf16(vu1.v, pu.v, acc1, 0, 0, 0);
        }
    }
    {
        float ls = lsum;
        ls += __shfl_xor(ls, 16);
        ls += __shfl_xor(ls, 32);
        const float inv = 1.f / fmaxf(ls, 1e-35f);
        unsigned long long oa =
              (unsigned long long)cvt_pk_bf16(acc0[0] * inv, acc0[1] * inv)
            | ((unsigned long long)cvt_pk_bf16(acc0[2] * inv, acc0[3] * inv) << 32);
        unsigned long long ob2 =
              (unsigned long long)cvt_pk_bf16(acc1[0] * inv, acc1[1] * inv)
            | ((unsigned long long)cvt_pk_bf16(acc1[2] * inv, acc1[3] * inv) << 32);
        *(unsigned long long*)(Ob + base + (size_t)iq * 256 + hi * 4) = oa;
        *(unsigned long long*)(Ob + base + (size_t)iq * 256 + 16 + hi * 4) = ob2;
    }
}

// ---------------------------------------------------------------------------
extern "C" void kernel_launch(void* const* d_in, const int* in_sizes, int n_in,
                              void* d_out, int out_size, void* d_ws, size_t ws_size,
                              hipStream_t stream) {
    const float* x         = (const float*)d_in[0];
    const float* c_local   = (const float*)d_in[1];
    const float* c_sink    = (const float*)d_in[2];
    const float* W_in      = (const float*)d_in[3];
    const float* b_in      = (const float*)d_in[4];
    const float* cls_token = (const float*)d_in[5];
    const float* pe_proj_W = (const float*)d_in[6];
    const float* pe_proj_b = (const float*)d_in[7];
    const float* pe_ln_g   = (const float*)d_in[8];
    const float* pe_ln_b   = (const float*)d_in[9];
    const float* pe_gain   = (const float*)d_in[10];
    const float* attn_Wqkv = (const float*)d_in[11];
    const float* attn_bqkv = (const float*)d_in[12];
    const float* attn_Wo   = (const float*)d_in[13];
    const float* attn_bo   = (const float*)d_in[14];
    const float* ff_W1     = (const float*)d_in[15];
    const float* ff_b1     = (const float*)d_in[16];
    const float* ff_W2     = (const float*)d_in[17];
    const float* ff_b2     = (const float*)d_in[18];
    const float* ln1_g     = (const float*)d_in[19];
    const float* ln1_b     = (const float*)d_in[20];
    const float* ln2_g     = (const float*)d_in[21];
    const float* ln2_b     = (const float*)d_in[22];
    const float* alpha     = (const float*)d_in[23];
    const float* beta      = (const float*)d_in[24];
    const float* corr_fl   = (const float*)d_in[25];
    const float* out_ln_g  = (const float*)d_in[26];
    const float* out_ln_b  = (const float*)d_in[27];
    const int*   lengths   = (const int*)d_in[28];
    float* out = (float*)d_out;

    // float region (layout identical to round-8 passing run)
    float* h     = (float*)d_ws;              // 4,194,304
    float* clb   = h + 4194304;               // 16384
    float* csfb  = clb + 16384;
    float* padfb = csfb + 16384;
    float* peWt  = padfb + 16384;             // 70656
    float* PEpos = peWt + 70656;              // 131072
    float* bbf   = PEpos + 131072;            // in old 8,388,608-float region
    // bf16 region — weights AFTER the full 16,777,216-short f-span at Q_bf
    unsigned short* u_bf = (unsigned short*)(bbf + 8388608);
    unsigned short* xb_bf = u_bf;             // alias: xb dead before layer loop
    unsigned short* Q_bf = u_bf + 4194304;
    unsigned short* K_bf = Q_bf + 4194304;
    unsigned short* V_bf = K_bf + 4194304;
    unsigned short* f_bf = Q_bf;              // alias: spans Q..Q+16777216
    unsigned short* o_bf = u_bf;              // alias (lifetimes disjoint)
    unsigned short* wq_bf = Q_bf + 16777216;  // after f's span
    unsigned short* wo_bf = wq_bf + 589824;
    unsigned short* w1_bf = wo_bf + 196608;
    unsigned short* w2_bf = w1_bf + 786432;
    unsigned short* win_bf = w2_bf + 786432;  // 16384

    transpose_kernel<<<276, 256, 0, stream>>>(pe_proj_W, peWt);
    cvt_bf16_kernel<<<576, 256, 0, stream>>>(attn_Wqkv, wq_bf, 589824);
    cvt_bf16_kernel<<<192, 256, 0, stream>>>(attn_Wo, wo_bf, 196608);
    cvt_bf16_kernel<<<768, 256, 0, stream>>>(ff_W1, w1_bf, 786432);
    cvt_bf16_kernel<<<768, 256, 0, stream>>>(ff_W2, w2_bf, 786432);
    cvt_bf16_kernel<<<16, 256, 0, stream>>>(W_in, win_bf, 16384);
    xb_kernel<<<2048, 256, 0, stream>>>(x, xb_bf);
    pepos_kernel<<<512, 256, 0, stream>>>(peWt, pe_proj_b, PEpos);
    gemm_bf16_kernel<3><<<dim3(4, 128), 256, 0, stream>>>(
        xb_bf, win_bf, b_in, bbf, nullptr, nullptr, nullptr, 16384, 256, 64);
    prep_lite_kernel<<<2048, 256, 0, stream>>>(
        c_local, c_sink, bbf, cls_token, PEpos, peWt + 65536,
        pe_ln_g, pe_ln_b, pe_gain, corr_fl, lengths, h, clb, csfb, padfb);

    for (int l = 0; l < 3; ++l) {
        ln_bf_kernel<<<4096, 256, 0, stream>>>(h, ln1_g + 256 * l, ln1_b + 256 * l, u_bf);
        gemm128_kernel<0><<<dim3(6, 128), 256, 0, stream>>>(
            u_bf, wq_bf + (size_t)l * 196608, attn_bqkv + 768 * l,
            Q_bf, K_bf, V_bf, 16384, 768, 256);
        attn_mfma_kernel<<<2048, 256, 0, stream>>>(Q_bf, K_bf, V_bf, clb, csfb,
                                                   padfb, alpha, beta, o_bf);
        gemm_bf16_kernel<1><<<dim3(4, 128), 256, 0, stream>>>(
            o_bf, wo_bf + (size_t)l * 65536, attn_bo + 256 * l, h,
            nullptr, nullptr, nullptr, 16384, 256, 256);
        ln_bf_kernel<<<4096, 256, 0, stream>>>(h, ln2_g + 256 * l, ln2_b + 256 * l, u_bf);
        gemm128_kernel<2><<<dim3(8, 128), 256, 0, stream>>>(
            u_bf, w1_bf + (size_t)l * 262144, ff_b1 + 1024 * l,
            f_bf, nullptr, nullptr, 16384, 1024, 256);
        gemm_bf16_kernel<1><<<dim3(4, 128), 256, 0, stream>>>(
            f_bf, w2_bf + (size_t)l * 262144, ff_b2 + 256 * l, h,
            nullptr, nullptr, nullptr, 16384, 256, 1024);
    }
    out_ln_kernel<<<8, 256, 0, stream>>>(h, out_ln_g, out_ln_b, out);
}

// Round 10
// 475.586 us; speedup vs baseline: 46.2771x; 1.0673x over previous
//
#include <hip/hip_runtime.h>
#include <math.h>

// B=32, L=512 (incl CLS), D=256, H=8, dh=32, N_LAYERS=3, D_FF=1024, tokens=16384

typedef __attribute__((ext_vector_type(4))) float f32x4;
typedef __attribute__((ext_vector_type(8))) short bf16x8;

__device__ __forceinline__ unsigned short f2bf(float f) {
    unsigned u = __builtin_bit_cast(unsigned, f);
    u += 0x7fff + ((u >> 16) & 1);
    return (unsigned short)(u >> 16);
}
__device__ __forceinline__ unsigned cvt_pk_bf16(float a, float b) {
    unsigned r;
    asm("v_cvt_pk_bf16_f32 %0, %1, %2" : "=v"(r) : "v"(a), "v"(b));
    return r;
}
__device__ __forceinline__ float gelu_f(float v) {
    return v * 0.5f * (1.0f + erff(v * 0.70710678118654752f));
}
__device__ __forceinline__ void gload16(const void* g, void* l) {
    __builtin_amdgcn_global_load_lds(
        (const __attribute__((address_space(1))) unsigned int*)g,
        (__attribute__((address_space(3))) unsigned int*)l, 16, 0, 0);
}

// ---------------------------------------------------------------------------
// Transpose pe_proj_W [256,276] -> peWt [276,256]
__global__ __launch_bounds__(256) void transpose_kernel(
    const float* __restrict__ peW, float* __restrict__ peWt)
{
    int j = blockIdx.x * 256 + threadIdx.x;
    if (j < 70656) {
        int f = j >> 8, dd = j & 255;
        peWt[j] = peW[dd * 276 + f];
    }
}

// ---------------------------------------------------------------------------
__global__ __launch_bounds__(256) void cvt_bf16_kernel(
    const float* __restrict__ s, unsigned short* __restrict__ d, int n)
{
    int i = (blockIdx.x * 256 + threadIdx.x) * 4;
    if (i >= n) return;
    float4 v = *(const float4*)(s + i);
    unsigned long long pk = (unsigned long long)f2bf(v.x)
        | ((unsigned long long)f2bf(v.y) << 16)
        | ((unsigned long long)f2bf(v.z) << 32)
        | ((unsigned long long)f2bf(v.w) << 48);
    *(unsigned long long*)(d + i) = pk;
}

// ---------------------------------------------------------------------------
// xb [16384,64] bf16 = x rows (CLS rows zero)
__global__ __launch_bounds__(256) void xb_kernel(
    const float* __restrict__ x, unsigned short* __restrict__ xb)
{
    int idx = blockIdx.x * 256 + threadIdx.x;   // over 524288 u32 pairs
    int tok = idx >> 5, c2 = idx & 31;
    int b = tok >> 9, l = tok & 511;
    unsigned r = 0;
    if (l > 0) {
        float2 v = *(const float2*)(x + ((size_t)b * 511 + l - 1) * 64 + 2 * c2);
        r = cvt_pk_bf16(v.x, v.y);
    }
    *(unsigned*)(xb + (size_t)tok * 64 + 2 * c2) = r;
}

// ---------------------------------------------------------------------------
// PEpos[l][d] = pe_b[d] + sum_f sinusoid(l,f) * peWt[f][d]   (position-only part)
__global__ __launch_bounds__(256) void pepos_kernel(
    const float* __restrict__ peWt, const float* __restrict__ pe_b,
    float* __restrict__ PEpos)
{
    __shared__ float ls[256];
    const int l = blockIdx.x, t = threadIdx.x;
    int kk = t >> 1;
    float div = expf((float)(2 * kk) * -0.035977892078032f); // -ln(10000)/256
    float a = (float)l * div;
    ls[t] = (t & 1) ? cosf(a) : sinf(a);
    __syncthreads();
    float acc = pe_b[t];
    for (int f = 0; f < 256; ++f) acc += ls[f] * peWt[f * 256 + t];
    PEpos[l * 256 + t] = acc;
}

// ---------------------------------------------------------------------------
// prep_lite: h = base(bb or cls) + mask * gain * LN(PEpos + feats@W20)
__global__ __launch_bounds__(256) void prep_lite_kernel(
    const float* __restrict__ c_local, const float* __restrict__ c_sink,
    const float* __restrict__ bb, const float* __restrict__ cls_tok,
    const float* __restrict__ PEpos, const float* __restrict__ W20t,
    const float* __restrict__ pe_g, const float* __restrict__ pe_bb,
    const float* __restrict__ pe_gain_p, const float* __restrict__ corr_floor_p,
    const int* __restrict__ lengths,
    float* __restrict__ h, float* __restrict__ clb, float* __restrict__ csfb,
    float* __restrict__ padfb)
{
    __shared__ float zs[8][20];
    __shared__ __align__(16) float pes[8][256];
    __shared__ float mn[8], rsd[8];
    const int t = threadIdx.x;
    const int tok0 = blockIdx.x * 8;
    const int b = tok0 >> 9;
    const int len_b = lengths[b];
    const float cf = *corr_floor_p;
    const float gain = *pe_gain_p;

    float clv[8], csv[8];
    bool mk[8];
#pragma unroll
    for (int k = 0; k < 8; ++k) {
        int l = (tok0 + k) & 511;
        if (l == 0) { clv[k] = 1.f; csv[k] = 1.f; mk[k] = false; }
        else {
            float a = c_local[b * 511 + l - 1];
            float s = c_sink[b * 511 + l - 1];
            clv[k] = fminf(fmaxf(a, 0.f), 1.f);
            csv[k] = fminf(fmaxf(s, 0.f), 1.f);
            mk[k] = (l - 1) >= len_b;
        }
    }
    if (t < 8) {
        int tok = tok0 + t;
        clb[tok] = clv[t];
        csfb[tok] = cf + (1.f - cf) * csv[t];
        padfb[tok] = mk[t] ? 1.f : 0.f;
    }
    if (t < 20) {
#pragma unroll
        for (int k = 0; k < 8; ++k) {
            float cl = clv[k], cs = csv[k];
            float v;
            if (t == 0) v = cl;
            else if (t == 1) v = cs;
            else if (t == 2) v = cl * cs;
            else if (t == 3) v = fabsf(cl - cs);
            else if (t < 12) {
                float c = (float)(t - 4) * (1.f / 7.f);
                float dd = (cl - c) / 0.200001f;
                v = expf(-0.5f * dd * dd);
            } else {
                float c = (float)(t - 12) * (1.f / 7.f);
                float dd = (cs - c) / 0.200001f;
                v = expf(-0.5f * dd * dd);
            }
            zs[k][t] = v;
        }
    }
    __syncthreads();

    float acc[8];
#pragma unroll
    for (int k = 0; k < 8; ++k)
        acc[k] = PEpos[((tok0 + k) & 511) * 256 + t];
    for (int f = 0; f < 20; ++f) {
        float wv = W20t[f * 256 + t];
#pragma unroll
        for (int k = 0; k < 8; ++k) acc[k] += zs[k][f] * wv;
    }
#pragma unroll
    for (int k = 0; k < 8; ++k) pes[k][t] = acc[k];
    __syncthreads();

    {
        int w = t >> 6, lane = t & 63;
#pragma unroll
        for (int p = 0; p < 2; ++p) {
            int k = w + p * 4;
            float4 v = *(const float4*)&pes[k][lane * 4];
            float s = v.x + v.y + v.z + v.w;
            float sq = v.x * v.x + v.y * v.y + v.z * v.z + v.w * v.w;
#pragma unroll
            for (int off = 32; off; off >>= 1) {
                s += __shfl_xor(s, off);
                sq += __shfl_xor(sq, off);
            }
            if (lane == 0) {
                float mean = s * (1.f / 256.f);
                mn[k] = mean;
                rsd[k] = rsqrtf(sq * (1.f / 256.f) - mean * mean + 1e-5f);
            }
        }
    }
    __syncthreads();
    float gv = pe_g[t], bv = pe_bb[t];
#pragma unroll
    for (int k = 0; k < 8; ++k) {
        int l = (tok0 + k) & 511;
        float base = (l == 0) ? cls_tok[t] : bb[(size_t)(tok0 + k) * 256 + t];
        float pe = (pes[k][t] - mn[k]) * rsd[k] * gv + bv;
        pe *= gain;
        if (mk[k]) pe = 0.f;
        h[(size_t)(tok0 + k) * 256 + t] = base + pe;
    }
}

// ---------------------------------------------------------------------------
// LayerNorm D=256, bf16 output: one wave per token, 4 tokens per block
__global__ __launch_bounds__(256) void ln_bf_kernel(
    const float* __restrict__ x, const float* __restrict__ g,
    const float* __restrict__ b, unsigned short* __restrict__ y)
{
    int tok = blockIdx.x * 4 + (threadIdx.x >> 6);
    int lane = threadIdx.x & 63;
    const float* row = x + (size_t)tok * 256;
    float4 v = *(const float4*)(row + lane * 4);
    float s = v.x + v.y + v.z + v.w;
    float sq = v.x * v.x + v.y * v.y + v.z * v.z + v.w * v.w;
#pragma unroll
    for (int off = 32; off; off >>= 1) {
        s += __shfl_xor(s, off);
        sq += __shfl_xor(sq, off);
    }
    float mean = s * (1.f / 256.f);
    float rs = rsqrtf(sq * (1.f / 256.f) - mean * mean + 1e-5f);
    float4 gv = *(const float4*)(g + lane * 4);
    float4 bv = *(const float4*)(b + lane * 4);
    unsigned long long pk =
          (unsigned long long)f2bf((v.x - mean) * rs * gv.x + bv.x)
        | ((unsigned long long)f2bf((v.y - mean) * rs * gv.y + bv.y) << 16)
        | ((unsigned long long)f2bf((v.z - mean) * rs * gv.z + bv.z) << 32)
        | ((unsigned long long)f2bf((v.w - mean) * rs * gv.w + bv.w) << 48);
    *(unsigned long long*)(y + (size_t)tok * 256 + lane * 4) = pk;
}

// Final LN on the 32 CLS rows only (f32 out)
__global__ __launch_bounds__(256) void out_ln_kernel(
    const float* __restrict__ h, const float* __restrict__ g,
    const float* __restrict__ b, float* __restrict__ out)
{
    int tok = blockIdx.x * 4 + (threadIdx.x >> 6);
    int lane = threadIdx.x & 63;
    const float* row = h + (size_t)tok * 512 * 256;
    float4 v = *(const float4*)(row + lane * 4);
    float s = v.x + v.y + v.z + v.w;
    float sq = v.x * v.x + v.y * v.y + v.z * v.z + v.w * v.w;
#pragma unroll
    for (int off = 32; off; off >>= 1) {
        s += __shfl_xor(s, off);
        sq += __shfl_xor(sq, off);
    }
    float mean = s * (1.f / 256.f);
    float rs = rsqrtf(sq * (1.f / 256.f) - mean * mean + 1e-5f);
    float4 gv = *(const float4*)(g + lane * 4);
    float4 bv = *(const float4*)(b + lane * 4);
    float4 o;
    o.x = (v.x - mean) * rs * gv.x + bv.x;
    o.y = (v.y - mean) * rs * gv.y + bv.y;
    o.z = (v.z - mean) * rs * gv.z + bv.z;
    o.w = (v.w - mean) * rs * gv.w + bv.w;
    *(float4*)(out + (size_t)tok * 256 + lane * 4) = o;
}

// ---------------------------------------------------------------------------
// bf16 MFMA GEMM, 128x64 tile (proven): C[M,N] = epi(A @ W^T + bias)
// EPI: 1 = f32 residual accumulate, 3 = plain f32 store
template <int EPI>
__global__ __launch_bounds__(256) void gemm_bf16_kernel(
    const unsigned short* __restrict__ A, const unsigned short* __restrict__ W,
    const float* __restrict__ bias, float* __restrict__ hres,
    unsigned short* __restrict__ o0, unsigned short* __restrict__ o1,
    unsigned short* __restrict__ o2, int M, int N, int K)
{
    __shared__ __align__(16) unsigned short As[128 * 64];
    __shared__ __align__(16) unsigned short Bs[64 * 64];
    const int t = threadIdx.x;
    const int wid = t >> 6, lane = t & 63;
    const int lo = lane & 15, hi = lane >> 4;
    const int wm = wid >> 1, wn = wid & 1;
    const int m0 = blockIdx.y * 128, n0 = blockIdx.x * 64;
    const int lrow = lane >> 3, lc = lane & 7;
    f32x4 acc[4][2] = {};
    for (int k0 = 0; k0 < K; k0 += 64) {
        __syncthreads();
#pragma unroll
        for (int is = 0; is < 4; ++is) {
            int r = wid * 32 + is * 8 + lrow;
            const unsigned short* g = A + (size_t)(m0 + r) * K + k0 + ((lc ^ (r & 7)) * 8);
            gload16(g, &As[(wid * 32 + is * 8) * 64]);
        }
#pragma unroll
        for (int is = 0; is < 2; ++is) {
            int r = wid * 16 + is * 8 + lrow;
            const unsigned short* g = W + (size_t)(n0 + r) * K + k0 + ((lc ^ (r & 7)) * 8);
            gload16(g, &Bs[(wid * 16 + is * 8) * 64]);
        }
        __syncthreads();
#pragma unroll
        for (int kh = 0; kh < 2; ++kh) {
            bf16x8 bfr[2];
#pragma unroll
            for (int nf = 0; nf < 2; ++nf) {
                int r = wn * 32 + nf * 16 + lo;
                bfr[nf] = *(const bf16x8*)&Bs[r * 64 + (((kh * 4 + hi) ^ (r & 7)) * 8)];
            }
#pragma unroll
            for (int mf = 0; mf < 4; ++mf) {
                int r = wm * 64 + mf * 16 + lo;
                bf16x8 afr = *(const bf16x8*)&As[r * 64 + (((kh * 4 + hi) ^ (r & 7)) * 8)];
                acc[mf][0] = __builtin_amdgcn_mfma_f32_16x16x32_bf16(afr, bfr[0], acc[mf][0], 0, 0, 0);
                acc[mf][1] = __builtin_amdgcn_mfma_f32_16x16x32_bf16(afr, bfr[1], acc[mf][1], 0, 0, 0);
            }
        }
    }
#pragma unroll
    for (int mf = 0; mf < 4; ++mf) {
        const int mbase = m0 + wm * 64 + mf * 16 + hi * 4;
#pragma unroll
        for (int nf = 0; nf < 2; ++nf) {
            const int n = n0 + wn * 32 + nf * 16 + lo;
            const float bv = bias[n];
            f32x4 v = acc[mf][nf];
            if constexpr (EPI == 1) {
#pragma unroll
                for (int rg = 0; rg < 4; ++rg) {
                    size_t idx = (size_t)(mbase + rg) * N + n;
                    hres[idx] += v[rg] + bv;
                }
            } else {
#pragma unroll
                for (int rg = 0; rg < 4; ++rg)
                    hres[(size_t)(mbase + rg) * N + n] = v[rg] + bv;
            }
        }
    }
}

// ---------------------------------------------------------------------------
// bf16 MFMA GEMM, 128x128 tile (4 waves, each 64x64): for QKV (EPI=0) and
// FF1 GELU (EPI=2). Same both-sides XOR swizzle staging as the 128x64 kernel.
template <int EPI>
__global__ __launch_bounds__(256) void gemm128_kernel(
    const unsigned short* __restrict__ A, const unsigned short* __restrict__ W,
    const float* __restrict__ bias,
    unsigned short* __restrict__ o0, unsigned short* __restrict__ o1,
    unsigned short* __restrict__ o2, int M, int N, int K)
{
    __shared__ __align__(16) unsigned short As[128 * 64];
    __shared__ __align__(16) unsigned short Bs[128 * 64];
    const int t = threadIdx.x;
    const int wid = t >> 6, lane = t & 63;
    const int lo = lane & 15, hi = lane >> 4;
    const int wm = wid >> 1, wn = wid & 1;
    const int m0 = blockIdx.y * 128, n0 = blockIdx.x * 128;
    const int lrow = lane >> 3, lc = lane & 7;
    f32x4 acc[4][4] = {};
    for (int k0 = 0; k0 < K; k0 += 64) {
        __syncthreads();
#pragma unroll
        for (int is = 0; is < 4; ++is) {
            int r = wid * 32 + is * 8 + lrow;
            const unsigned short* g = A + (size_t)(m0 + r) * K + k0 + ((lc ^ (r & 7)) * 8);
            gload16(g, &As[(wid * 32 + is * 8) * 64]);
        }
#pragma unroll
        for (int is = 0; is < 4; ++is) {
            int r = wid * 32 + is * 8 + lrow;
            const unsigned short* g = W + (size_t)(n0 + r) * K + k0 + ((lc ^ (r & 7)) * 8);
            gload16(g, &Bs[(wid * 32 + is * 8) * 64]);
        }
        __syncthreads();
#pragma unroll
        for (int kh = 0; kh < 2; ++kh) {
            bf16x8 bfr[4];
#pragma unroll
            for (int nf = 0; nf < 4; ++nf) {
                int r = wn * 64 + nf * 16 + lo;
                bfr[nf] = *(const bf16x8*)&Bs[r * 64 + (((kh * 4 + hi) ^ (r & 7)) * 8)];
            }
#pragma unroll
            for (int mf = 0; mf < 4; ++mf) {
                int r = wm * 64 + mf * 16 + lo;
                bf16x8 afr = *(const bf16x8*)&As[r * 64 + (((kh * 4 + hi) ^ (r & 7)) * 8)];
#pragma unroll
                for (int nf = 0; nf < 4; ++nf)
                    acc[mf][nf] = __builtin_amdgcn_mfma_f32_16x16x32_bf16(afr, bfr[nf], acc[mf][nf], 0, 0, 0);
            }
        }
    }
#pragma unroll
    for (int mf = 0; mf < 4; ++mf) {
        const int mbase = m0 + wm * 64 + mf * 16 + hi * 4;
#pragma unroll
        for (int nf = 0; nf < 4; ++nf) {
            const int n = n0 + wn * 64 + nf * 16 + lo;
            const float bv = bias[n];
            f32x4 v = acc[mf][nf];
            if constexpr (EPI == 0) {
                unsigned short* dst = (n < 256) ? o0 : ((n < 512) ? o1 : o2);
                const float qsc = (n < 256)
                    ? (0.17677669529663687f * 1.4426950408889634f) : 1.f;
                const int c = n & 255;
#pragma unroll
                for (int rg = 0; rg < 4; ++rg)
                    dst[(size_t)(mbase + rg) * 256 + c] = f2bf((v[rg] + bv) * qsc);
            } else {
#pragma unroll
                for (int rg = 0; rg < 4; ++rg)
                    o0[(size_t)(mbase + rg) * N + n] = f2bf(gelu_f(v[rg] + bv));
            }
        }
    }
}

// ---------------------------------------------------------------------------
// Fused residual-GEMM + LayerNorm: 64x256 tile (full N=256), 512 threads,
// 8 waves (2 wm x 4 wn, each 32x64). h[r] += A@W^T + bias; u[r] = LN(h[r]).
// LN: per-lane col partials -> 16-lane butterfly -> LDS cross-wave reduce.
__global__ __launch_bounds__(512) void gemm_res_ln_kernel(
    const unsigned short* __restrict__ A, const unsigned short* __restrict__ W,
    const float* __restrict__ bias, float* __restrict__ hres,
    const float* __restrict__ g, const float* __restrict__ bvec,
    unsigned short* __restrict__ u, int K)
{
    __shared__ __align__(16) unsigned short As[64 * 64];
    __shared__ __align__(16) unsigned short Bs[256 * 64];
    __shared__ float red[64][4][2];
    const int t = threadIdx.x;
    const int wid = t >> 6, lane = t & 63;
    const int lo = lane & 15, hi = lane >> 4;
    const int wm = wid >> 2, wn = wid & 3;
    const int m0 = blockIdx.x * 64;
    const int lrow = lane >> 3, lc = lane & 7;
    f32x4 acc[2][4] = {};
    for (int k0 = 0; k0 < K; k0 += 64) {
        __syncthreads();
        {
            int r = wid * 8 + lrow;
            gload16(A + (size_t)(m0 + r) * K + k0 + ((lc ^ (r & 7)) * 8),
                    &As[(wid * 8) * 64]);
        }
#pragma unroll
        for (int is = 0; is < 4; ++is) {
            int r = wid * 32 + is * 8 + lrow;
            gload16(W + (size_t)r * K + k0 + ((lc ^ (r & 7)) * 8),
                    &Bs[(wid * 32 + is * 8) * 64]);
        }
        __syncthreads();
#pragma unroll
        for (int kh = 0; kh < 2; ++kh) {
            bf16x8 bfr[4];
#pragma unroll
            for (int nf = 0; nf < 4; ++nf) {
                int r = wn * 64 + nf * 16 + lo;
                bfr[nf] = *(const bf16x8*)&Bs[r * 64 + (((kh * 4 + hi) ^ (r & 7)) * 8)];
            }
#pragma unroll
            for (int mf = 0; mf < 2; ++mf) {
                int r = wm * 32 + mf * 16 + lo;
                bf16x8 afr = *(const bf16x8*)&As[r * 64 + (((kh * 4 + hi) ^ (r & 7)) * 8)];
#pragma unroll
                for (int nf = 0; nf < 4; ++nf)
                    acc[mf][nf] = __builtin_amdgcn_mfma_f32_16x16x32_bf16(afr, bfr[nf], acc[mf][nf], 0, 0, 0);
            }
        }
    }
    // residual + h write; keep h_new in acc
#pragma unroll
    for (int mf = 0; mf < 2; ++mf) {
#pragma unroll
        for (int nf = 0; nf < 4; ++nf) {
            const int n = wn * 64 + nf * 16 + lo;
            const float bv = bias[n];
            const int rbase = m0 + wm * 32 + mf * 16 + hi * 4;
#pragma unroll
            for (int rg = 0; rg < 4; ++rg) {
                size_t idx = (size_t)(rbase + rg) * 256 + n;
                float hv = acc[mf][nf][rg] + bv + hres[idx];
                hres[idx] = hv;
                acc[mf][nf][rg] = hv;
            }
        }
    }
    // per-row LN stats
#pragma unroll
    for (int mf = 0; mf < 2; ++mf) {
#pragma unroll
        for (int rg = 0; rg < 4; ++rg) {
            float s = ((acc[mf][0][rg] + acc[mf][1][rg]) +
                       (acc[mf][2][rg] + acc[mf][3][rg]));
            float sq = ((acc[mf][0][rg] * acc[mf][0][rg] + acc[mf][1][rg] * acc[mf][1][rg]) +
                        (acc[mf][2][rg] * acc[mf][2][rg] + acc[mf][3][rg] * acc[mf][3][rg]));
#pragma unroll
            for (int off = 1; off < 16; off <<= 1) {
                s += __shfl_xor(s, off);
                sq += __shfl_xor(sq, off);
            }
            if (lo == 0) {
                int rl = wm * 32 + mf * 16 + hi * 4 + rg;
                red[rl][wn][0] = s;
                red[rl][wn][1] = sq;
            }
        }
    }
    __syncthreads();
#pragma unroll
    for (int mf = 0; mf < 2; ++mf) {
#pragma unroll
        for (int rg = 0; rg < 4; ++rg) {
            const int rl = wm * 32 + mf * 16 + hi * 4 + rg;
            float s = (red[rl][0][0] + red[rl][1][0]) + (red[rl][2][0] + red[rl][3][0]);
            float sq = (red[rl][0][1] + red[rl][1][1]) + (red[rl][2][1] + red[rl][3][1]);
            float mean = s * (1.f / 256.f);
            float rs = rsqrtf(sq * (1.f / 256.f) - mean * mean + 1e-5f);
#pragma unroll
            for (int nf = 0; nf < 4; ++nf) {
                const int n = wn * 64 + nf * 16 + lo;
                u[(size_t)(m0 + rl) * 256 + n] =
                    f2bf((acc[mf][nf][rg] - mean) * rs * g[n] + bvec[n]);
            }
        }
    }
}

// ---------------------------------------------------------------------------
// MFMA flash attention v6 (proven round-9): 1 q-group per wave, grid 2048.
__global__ __launch_bounds__(256) void attn_mfma_kernel(
    const unsigned short* __restrict__ Qb, const unsigned short* __restrict__ Kb,
    const unsigned short* __restrict__ Vb, const float* __restrict__ clb,
    const float* __restrict__ csfb, const float* __restrict__ padfb,
    const float* __restrict__ alpha_p, const float* __restrict__ beta_p,
    unsigned short* __restrict__ Ob)
{
    __shared__ __align__(16) unsigned short Kl[128 * 40];   // 10240 B
    __shared__ __align__(16) unsigned short Vt[32 * 132];   // 8448 B
    __shared__ __align__(16) float csfl[512];               // 2 KB
    __shared__ __align__(16) float mkl[512];                // 2 KB
    const int t = threadIdx.x;
    const int swz = ((blockIdx.x & 7) << 8) | (blockIdx.x >> 3);  // XCD chunking
    const int bh = swz >> 3, hf = swz & 7;
    const int b = bh >> 3, hd = bh & 7;
    const size_t base = ((size_t)b * 512) * 256 + hd * 32;
    const int w = t >> 6, lane = t & 63, lo = lane & 15, hi = lane >> 4;
    const float L2E = 1.4426950408889634f;
    const float kb = L2E * (*beta_p);
    const float ka = L2E * (*alpha_p);
    const float* clg = clb + b * 512;

    for (int idx = t; idx < 512; idx += 256) {
        csfl[idx] = csfb[b * 512 + idx];
        mkl[idx] = (padfb[b * 512 + idx] > 0.5f) ? -20000.f : 0.f;
    }

    const int i0 = (hf * 4 + w) * 16;
    const int iq = i0 + lo;
    const bf16x8 qf = *(const bf16x8*)(Qb + base + (size_t)iq * 256 + hi * 8);
    const float csb = kb * csfb[b * 512 + iq];
    f32x4 acc0 = {0.f, 0.f, 0.f, 0.f}, acc1 = {0.f, 0.f, 0.f, 0.f};
    float lsum = 0.f;

    for (int jt = 0; jt < 4; ++jt) {
        __syncthreads();
        for (int idx = t; idx < 512; idx += 256) {       // K tile: 128 rows
            int row = idx >> 2, c4 = idx & 3;
            *(uint4*)&Kl[row * 40 + c4 * 8] =
                *(const uint4*)(Kb + base + (size_t)(jt * 128 + row) * 256 + c4 * 8);
        }
        for (int idx = t; idx < 512; idx += 256) {       // V^T, paired rows
            int pr = idx & 63, c4 = idx >> 6;
            unsigned long long v0 = *(const unsigned long long*)
                (Vb + base + (size_t)(jt * 128 + 2 * pr) * 256 + c4 * 4);
            unsigned long long v1 = *(const unsigned long long*)
                (Vb + base + (size_t)(jt * 128 + 2 * pr + 1) * 256 + c4 * 4);
#pragma unroll
            for (int e = 0; e < 4; ++e) {
                unsigned a = (unsigned)((v0 >> (16 * e)) & 0xffffu);
                unsigned c = (unsigned)((v1 >> (16 * e)) & 0xffffu);
                *(unsigned*)&Vt[(c4 * 4 + e) * 132 + 2 * pr] = a | (c << 16);
            }
        }
        __syncthreads();
#pragma unroll
        for (int ktp = 0; ktp < 4; ++ktp) {
            const int k16 = ktp * 32;             // local j base
            const int gj = jt * 128 + k16;        // global j base
            bf16x8 kf0 = *(const bf16x8*)&Kl[(k16 + lo) * 40 + hi * 8];
            bf16x8 kf1 = *(const bf16x8*)&Kl[(k16 + 16 + lo) * 40 + hi * 8];
            union U16 { unsigned long long q[2]; unsigned wd[4]; bf16x8 v; } vu0, vu1, pu;
            vu0.q[0] = *(const unsigned long long*)&Vt[lo * 132 + k16 + hi * 4];
            vu0.q[1] = *(const unsigned long long*)&Vt[lo * 132 + k16 + 16 + hi * 4];
            vu1.q[0] = *(const unsigned long long*)&Vt[(16 + lo) * 132 + k16 + hi * 4];
            vu1.q[1] = *(const unsigned long long*)&Vt[(16 + lo) * 132 + k16 + 16 + hi * 4];
            f32x4 csf0 = *(const f32x4*)&csfl[gj + hi * 4];
            f32x4 csf1 = *(const f32x4*)&csfl[gj + 16 + hi * 4];
            f32x4 mk0 = *(const f32x4*)&mkl[gj + hi * 4];
            f32x4 mk1 = *(const f32x4*)&mkl[gj + 16 + hi * 4];
            f32x4 c0, c1;
#pragma unroll
            for (int e = 0; e < 4; ++e) {
                c0[e] = fmaf(csb, csf0[e], mk0[e]);
                c1[e] = fmaf(csb, csf1[e], mk1[e]);
            }
            f32x4 s0 = __builtin_amdgcn_mfma_f32_16x16x32_bf16(kf0, qf, c0, 0, 0, 0);
            f32x4 s1 = __builtin_amdgcn_mfma_f32_16x16x32_bf16(kf1, qf, c1, 0, 0, 0);
            float p[8];
#pragma unroll
            for (int r = 0; r < 4; ++r) p[r] = exp2f(s0[r]);
#pragma unroll
            for (int r = 0; r < 4; ++r) p[4 + r] = exp2f(s1[r]);
            // tridiagonal alpha correction (rare; scalar window test)
            if (gj <= i0 + 16 && gj + 32 >= i0) {
#pragma unroll
                for (int r = 0; r < 8; ++r) {
                    int jr = gj + ((r & 4) ? 16 : 0) + hi * 4 + (r & 3);
                    int dij = jr - iq;
                    if (dij == 1 || dij == -1) {
                        float ce = (jr >= 1 && iq <= 510) ? clg[jr] : clg[iq];
                        p[r] *= exp2f(ka * ce);
                    }
                }
            }
            lsum += ((p[0] + p[1]) + (p[2] + p[3])) + ((p[4] + p[5]) + (p[6] + p[7]));
            pu.wd[0] = cvt_pk_bf16(p[0], p[1]);
            pu.wd[1] = cvt_pk_bf16(p[2], p[3]);
            pu.wd[2] = cvt_pk_bf16(p[4], p[5]);
            pu.wd[3] = cvt_pk_bf16(p[6], p[7]);
            acc0 = __builtin_amdgcn_mfma_f32_16x16x32_bf16(vu0.v, pu.v, acc0, 0, 0, 0);
            acc1 = __builtin_amdgcn_mfma_f32_16x16x32_bf16(vu1.v, pu.v, acc1, 0, 0, 0);
        }
    }
    {
        float ls = lsum;
        ls += __shfl_xor(ls, 16);
        ls += __shfl_xor(ls, 32);
        const float inv = 1.f / fmaxf(ls, 1e-35f);
        unsigned long long oa =
              (unsigned long long)cvt_pk_bf16(acc0[0] * inv, acc0[1] * inv)
            | ((unsigned long long)cvt_pk_bf16(acc0[2] * inv, acc0[3] * inv) << 32);
        unsigned long long ob2 =
              (unsigned long long)cvt_pk_bf16(acc1[0] * inv, acc1[1] * inv)
            | ((unsigned long long)cvt_pk_bf16(acc1[2] * inv, acc1[3] * inv) << 32);
        *(unsigned long long*)(Ob + base + (size_t)iq * 256 + hi * 4) = oa;
        *(unsigned long long*)(Ob + base + (size_t)iq * 256 + 16 + hi * 4) = ob2;
    }
}

// ---------------------------------------------------------------------------
extern "C" void kernel_launch(void* const* d_in, const int* in_sizes, int n_in,
                              void* d_out, int out_size, void* d_ws, size_t ws_size,
                              hipStream_t stream) {
    const float* x         = (const float*)d_in[0];
    const float* c_local   = (const float*)d_in[1];
    const float* c_sink    = (const float*)d_in[2];
    const float* W_in      = (const float*)d_in[3];
    const float* b_in      = (const float*)d_in[4];
    const float* cls_token = (const float*)d_in[5];
    const float* pe_proj_W = (const float*)d_in[6];
    const float* pe_proj_b = (const float*)d_in[7];
    const float* pe_ln_g   = (const float*)d_in[8];
    const float* pe_ln_b   = (const float*)d_in[9];
    const float* pe_gain   = (const float*)d_in[10];
    const float* attn_Wqkv = (const float*)d_in[11];
    const float* attn_bqkv = (const float*)d_in[12];
    const float* attn_Wo   = (const float*)d_in[13];
    const float* attn_bo   = (const float*)d_in[14];
    const float* ff_W1     = (const float*)d_in[15];
    const float* ff_b1     = (const float*)d_in[16];
    const float* ff_W2     = (const float*)d_in[17];
    const float* ff_b2     = (const float*)d_in[18];
    const float* ln1_g     = (const float*)d_in[19];
    const float* ln1_b     = (const float*)d_in[20];
    const float* ln2_g     = (const float*)d_in[21];
    const float* ln2_b     = (const float*)d_in[22];
    const float* alpha     = (const float*)d_in[23];
    const float* beta      = (const float*)d_in[24];
    const float* corr_fl   = (const float*)d_in[25];
    const float* out_ln_g  = (const float*)d_in[26];
    const float* out_ln_b  = (const float*)d_in[27];
    const int*   lengths   = (const int*)d_in[28];
    float* out = (float*)d_out;

    // float region (layout identical to round-9 passing run)
    float* h     = (float*)d_ws;              // 4,194,304
    float* clb   = h + 4194304;               // 16384
    float* csfb  = clb + 16384;
    float* padfb = csfb + 16384;
    float* peWt  = padfb + 16384;             // 70656
    float* PEpos = peWt + 70656;              // 131072
    float* bbf   = PEpos + 131072;            // in old 8,388,608-float region
    // bf16 region — weights AFTER the full 16,777,216-short f-span at Q_bf
    unsigned short* u_bf = (unsigned short*)(bbf + 8388608);
    unsigned short* xb_bf = u_bf;             // alias: xb dead before layer loop
    unsigned short* Q_bf = u_bf + 4194304;
    unsigned short* K_bf = Q_bf + 4194304;
    unsigned short* V_bf = K_bf + 4194304;
    unsigned short* f_bf = Q_bf;              // alias: spans Q..Q+16777216
    unsigned short* o_bf = u_bf;              // alias (lifetimes disjoint)
    unsigned short* wq_bf = Q_bf + 16777216;  // after f's span
    unsigned short* wo_bf = wq_bf + 589824;
    unsigned short* w1_bf = wo_bf + 196608;
    unsigned short* w2_bf = w1_bf + 786432;
    unsigned short* win_bf = w2_bf + 786432;  // 16384

    transpose_kernel<<<276, 256, 0, stream>>>(pe_proj_W, peWt);
    cvt_bf16_kernel<<<576, 256, 0, stream>>>(attn_Wqkv, wq_bf, 589824);
    cvt_bf16_kernel<<<192, 256, 0, stream>>>(attn_Wo, wo_bf, 196608);
    cvt_bf16_kernel<<<768, 256, 0, stream>>>(ff_W1, w1_bf, 786432);
    cvt_bf16_kernel<<<768, 256, 0, stream>>>(ff_W2, w2_bf, 786432);
    cvt_bf16_kernel<<<16, 256, 0, stream>>>(W_in, win_bf, 16384);
    xb_kernel<<<2048, 256, 0, stream>>>(x, xb_bf);
    pepos_kernel<<<512, 256, 0, stream>>>(peWt, pe_proj_b, PEpos);
    gemm_bf16_kernel<3><<<dim3(4, 128), 256, 0, stream>>>(
        xb_bf, win_bf, b_in, bbf, nullptr, nullptr, nullptr, 16384, 256, 64);
    prep_lite_kernel<<<2048, 256, 0, stream>>>(
        c_local, c_sink, bbf, cls_token, PEpos, peWt + 65536,
        pe_ln_g, pe_ln_b, pe_gain, corr_fl, lengths, h, clb, csfb, padfb);

    // layer-0 ln1 (standalone); subsequent LNs are fused into GEMM epilogues
    ln_bf_kernel<<<4096, 256, 0, stream>>>(h, ln1_g, ln1_b, u_bf);
    for (int l = 0; l < 3; ++l) {
        gemm128_kernel<0><<<dim3(6, 128), 256, 0, stream>>>(
            u_bf, wq_bf + (size_t)l * 196608, attn_bqkv + 768 * l,
            Q_bf, K_bf, V_bf, 16384, 768, 256);
        attn_mfma_kernel<<<2048, 256, 0, stream>>>(Q_bf, K_bf, V_bf, clb, csfb,
                                                   padfb, alpha, beta, o_bf);
        // Wo residual + fused ln2 -> u
        gemm_res_ln_kernel<<<256, 512, 0, stream>>>(
            o_bf, wo_bf + (size_t)l * 65536, attn_bo + 256 * l, h,
            ln2_g + 256 * l, ln2_b + 256 * l, u_bf, 256);
        gemm128_kernel<2><<<dim3(8, 128), 256, 0, stream>>>(
            u_bf, w1_bf + (size_t)l * 262144, ff_b1 + 1024 * l,
            f_bf, nullptr, nullptr, 16384, 1024, 256);
        if (l < 2) {
            // FF2 residual + fused ln1 of next layer -> u
            gemm_res_ln_kernel<<<256, 512, 0, stream>>>(
                f_bf, w2_bf + (size_t)l * 262144, ff_b2 + 256 * l, h,
                ln1_g + 256 * (l + 1), ln1_b + 256 * (l + 1), u_bf, 1024);
        } else {
            gemm_bf16_kernel<1><<<dim3(4, 128), 256, 0, stream>>>(
                f_bf, w2_bf + (size_t)l * 262144, ff_b2 + 256 * l, h,
                nullptr, nullptr, nullptr, 16384, 256, 1024);
        }
    }
    out_ln_kernel<<<8, 256, 0, stream>>>(h, out_ln_g, out_ln_b, out);
}

// Round 11
// 469.320 us; speedup vs baseline: 46.8950x; 1.0134x over previous
//
#include <hip/hip_runtime.h>
#include <math.h>

// B=32, L=512 (incl CLS), D=256, H=8, dh=32, N_LAYERS=3, D_FF=1024, tokens=16384

typedef __attribute__((ext_vector_type(4))) float f32x4;
typedef __attribute__((ext_vector_type(8))) short bf16x8;

__device__ __forceinline__ unsigned short f2bf(float f) {
    unsigned u = __builtin_bit_cast(unsigned, f);
    u += 0x7fff + ((u >> 16) & 1);
    return (unsigned short)(u >> 16);
}
__device__ __forceinline__ unsigned cvt_pk_bf16(float a, float b) {
    unsigned r;
    asm("v_cvt_pk_bf16_f32 %0, %1, %2" : "=v"(r) : "v"(a), "v"(b));
    return r;
}
__device__ __forceinline__ float gelu_f(float v) {
    return v * 0.5f * (1.0f + erff(v * 0.70710678118654752f));
}
__device__ __forceinline__ void gload16(const void* g, void* l) {
    __builtin_amdgcn_global_load_lds(
        (const __attribute__((address_space(1))) unsigned int*)g,
        (__attribute__((address_space(3))) unsigned int*)l, 16, 0, 0);
}

// ---------------------------------------------------------------------------
// Transpose last-20 feature rows: W20t[f][d] = peW[d][256+f], f<20
__global__ __launch_bounds__(256) void transpose_w20_kernel(
    const float* __restrict__ peW, float* __restrict__ W20t)
{
    int j = blockIdx.x * 256 + threadIdx.x;
    if (j < 5120) {
        int f = j >> 8, dd = j & 255;
        W20t[j] = peW[dd * 276 + 256 + f];
    }
}

// ---------------------------------------------------------------------------
// All 5 weight cvt's in one launch (sizes all multiples of 1024 floats)
__global__ __launch_bounds__(256) void cvt_multi_kernel(
    const float* __restrict__ s0, unsigned short* __restrict__ d0,   // 576 blk
    const float* __restrict__ s1, unsigned short* __restrict__ d1,   // 192
    const float* __restrict__ s2, unsigned short* __restrict__ d2,   // 768
    const float* __restrict__ s3, unsigned short* __restrict__ d3,   // 768
    const float* __restrict__ s4, unsigned short* __restrict__ d4)   // 16
{
    int blk = blockIdx.x;
    const float* s; unsigned short* d; int base;
    if (blk < 576)       { s = s0; d = d0; base = blk; }
    else if (blk < 768)  { s = s1; d = d1; base = blk - 576; }
    else if (blk < 1536) { s = s2; d = d2; base = blk - 768; }
    else if (blk < 2304) { s = s3; d = d3; base = blk - 1536; }
    else                 { s = s4; d = d4; base = blk - 2304; }
    int i = (base * 256 + threadIdx.x) * 4;
    float4 v = *(const float4*)(s + i);
    unsigned long long pk = (unsigned long long)f2bf(v.x)
        | ((unsigned long long)f2bf(v.y) << 16)
        | ((unsigned long long)f2bf(v.z) << 32)
        | ((unsigned long long)f2bf(v.w) << 48);
    *(unsigned long long*)(d + i) = pk;
}

// ---------------------------------------------------------------------------
// peW first-256 features -> bf16 [256 d][256 f]
__global__ __launch_bounds__(256) void cvt_pew_kernel(
    const float* __restrict__ peW, unsigned short* __restrict__ W256)
{
    int i = (blockIdx.x * 256 + threadIdx.x) * 4;   // 65536 elems
    int d = i >> 8, f = i & 255;
    float4 v = *(const float4*)(peW + d * 276 + f);
    unsigned long long pk = (unsigned long long)f2bf(v.x)
        | ((unsigned long long)f2bf(v.y) << 16)
        | ((unsigned long long)f2bf(v.z) << 32)
        | ((unsigned long long)f2bf(v.w) << 48);
    *(unsigned long long*)(W256 + i) = pk;
}

// ---------------------------------------------------------------------------
// Sinusoid table S[l][256] bf16: S[l][2k]=sin(l*div_k), S[l][2k+1]=cos
__global__ __launch_bounds__(128) void sinus_kernel(unsigned short* __restrict__ S)
{
    int l = blockIdx.x, t = threadIdx.x;   // t = pair 0..127
    float div = expf((float)(2 * t) * -0.035977892078032f); // -ln(10000)/256
    float a = (float)l * div;
    *(unsigned*)(S + l * 256 + 2 * t) = cvt_pk_bf16(sinf(a), cosf(a));
}

// ---------------------------------------------------------------------------
// xb [16384,64] bf16 = x rows (CLS rows zero)
__global__ __launch_bounds__(256) void xb_kernel(
    const float* __restrict__ x, unsigned short* __restrict__ xb)
{
    int idx = blockIdx.x * 256 + threadIdx.x;   // over 524288 u32 pairs
    int tok = idx >> 5, c2 = idx & 31;
    int b = tok >> 9, l = tok & 511;
    unsigned r = 0;
    if (l > 0) {
        float2 v = *(const float2*)(x + ((size_t)b * 511 + l - 1) * 64 + 2 * c2);
        r = cvt_pk_bf16(v.x, v.y);
    }
    *(unsigned*)(xb + (size_t)tok * 64 + 2 * c2) = r;
}

// ---------------------------------------------------------------------------
// prep_lite: h = base(bb or cls) + mask * gain * LN(PEpos + feats@W20)
__global__ __launch_bounds__(256) void prep_lite_kernel(
    const float* __restrict__ c_local, const float* __restrict__ c_sink,
    const float* __restrict__ bb, const float* __restrict__ cls_tok,
    const float* __restrict__ PEpos, const float* __restrict__ W20t,
    const float* __restrict__ pe_g, const float* __restrict__ pe_bb,
    const float* __restrict__ pe_gain_p, const float* __restrict__ corr_floor_p,
    const int* __restrict__ lengths,
    float* __restrict__ h, float* __restrict__ clb, float* __restrict__ csfb,
    float* __restrict__ padfb)
{
    __shared__ float zs[8][20];
    __shared__ __align__(16) float pes[8][256];
    __shared__ float mn[8], rsd[8];
    const int t = threadIdx.x;
    const int tok0 = blockIdx.x * 8;
    const int b = tok0 >> 9;
    const int len_b = lengths[b];
    const float cf = *corr_floor_p;
    const float gain = *pe_gain_p;

    float clv[8], csv[8];
    bool mk[8];
#pragma unroll
    for (int k = 0; k < 8; ++k) {
        int l = (tok0 + k) & 511;
        if (l == 0) { clv[k] = 1.f; csv[k] = 1.f; mk[k] = false; }
        else {
            float a = c_local[b * 511 + l - 1];
            float s = c_sink[b * 511 + l - 1];
            clv[k] = fminf(fmaxf(a, 0.f), 1.f);
            csv[k] = fminf(fmaxf(s, 0.f), 1.f);
            mk[k] = (l - 1) >= len_b;
        }
    }
    if (t < 8) {
        int tok = tok0 + t;
        clb[tok] = clv[t];
        csfb[tok] = cf + (1.f - cf) * csv[t];
        padfb[tok] = mk[t] ? 1.f : 0.f;
    }
    if (t < 20) {
#pragma unroll
        for (int k = 0; k < 8; ++k) {
            float cl = clv[k], cs = csv[k];
            float v;
            if (t == 0) v = cl;
            else if (t == 1) v = cs;
            else if (t == 2) v = cl * cs;
            else if (t == 3) v = fabsf(cl - cs);
            else if (t < 12) {
                float c = (float)(t - 4) * (1.f / 7.f);
                float dd = (cl - c) / 0.200001f;
                v = expf(-0.5f * dd * dd);
            } else {
                float c = (float)(t - 12) * (1.f / 7.f);
                float dd = (cs - c) / 0.200001f;
                v = expf(-0.5f * dd * dd);
            }
            zs[k][t] = v;
        }
    }
    __syncthreads();

    float acc[8];
#pragma unroll
    for (int k = 0; k < 8; ++k)
        acc[k] = PEpos[((tok0 + k) & 511) * 256 + t];
    for (int f = 0; f < 20; ++f) {
        float wv = W20t[f * 256 + t];
#pragma unroll
        for (int k = 0; k < 8; ++k) acc[k] += zs[k][f] * wv;
    }
#pragma unroll
    for (int k = 0; k < 8; ++k) pes[k][t] = acc[k];
    __syncthreads();

    {
        int w = t >> 6, lane = t & 63;
#pragma unroll
        for (int p = 0; p < 2; ++p) {
            int k = w + p * 4;
            float4 v = *(const float4*)&pes[k][lane * 4];
            float s = v.x + v.y + v.z + v.w;
            float sq = v.x * v.x + v.y * v.y + v.z * v.z + v.w * v.w;
#pragma unroll
            for (int off = 32; off; off >>= 1) {
                s += __shfl_xor(s, off);
                sq += __shfl_xor(sq, off);
            }
            if (lane == 0) {
                float mean = s * (1.f / 256.f);
                mn[k] = mean;
                rsd[k] = rsqrtf(sq * (1.f / 256.f) - mean * mean + 1e-5f);
            }
        }
    }
    __syncthreads();
    float gv = pe_g[t], bv = pe_bb[t];
#pragma unroll
    for (int k = 0; k < 8; ++k) {
        int l = (tok0 + k) & 511;
        float base = (l == 0) ? cls_tok[t] : bb[(size_t)(tok0 + k) * 256 + t];
        float pe = (pes[k][t] - mn[k]) * rsd[k] * gv + bv;
        pe *= gain;
        if (mk[k]) pe = 0.f;
        h[(size_t)(tok0 + k) * 256 + t] = base + pe;
    }
}

// ---------------------------------------------------------------------------
// LayerNorm D=256, bf16 output: one wave per token, 4 tokens per block
__global__ __launch_bounds__(256) void ln_bf_kernel(
    const float* __restrict__ x, const float* __restrict__ g,
    const float* __restrict__ b, unsigned short* __restrict__ y)
{
    int tok = blockIdx.x * 4 + (threadIdx.x >> 6);
    int lane = threadIdx.x & 63;
    const float* row = x + (size_t)tok * 256;
    float4 v = *(const float4*)(row + lane * 4);
    float s = v.x + v.y + v.z + v.w;
    float sq = v.x * v.x + v.y * v.y + v.z * v.z + v.w * v.w;
#pragma unroll
    for (int off = 32; off; off >>= 1) {
        s += __shfl_xor(s, off);
        sq += __shfl_xor(sq, off);
    }
    float mean = s * (1.f / 256.f);
    float rs = rsqrtf(sq * (1.f / 256.f) - mean * mean + 1e-5f);
    float4 gv = *(const float4*)(g + lane * 4);
    float4 bv = *(const float4*)(b + lane * 4);
    unsigned long long pk =
          (unsigned long long)f2bf((v.x - mean) * rs * gv.x + bv.x)
        | ((unsigned long long)f2bf((v.y - mean) * rs * gv.y + bv.y) << 16)
        | ((unsigned long long)f2bf((v.z - mean) * rs * gv.z + bv.z) << 32)
        | ((unsigned long long)f2bf((v.w - mean) * rs * gv.w + bv.w) << 48);
    *(unsigned long long*)(y + (size_t)tok * 256 + lane * 4) = pk;
}

// Final LN on the 32 CLS rows only (f32 out)
__global__ __launch_bounds__(256) void out_ln_kernel(
    const float* __restrict__ h, const float* __restrict__ g,
    const float* __restrict__ b, float* __restrict__ out)
{
    int tok = blockIdx.x * 4 + (threadIdx.x >> 6);
    int lane = threadIdx.x & 63;
    const float* row = h + (size_t)tok * 512 * 256;
    float4 v = *(const float4*)(row + lane * 4);
    float s = v.x + v.y + v.z + v.w;
    float sq = v.x * v.x + v.y * v.y + v.z * v.z + v.w * v.w;
#pragma unroll
    for (int off = 32; off; off >>= 1) {
        s += __shfl_xor(s, off);
        sq += __shfl_xor(sq, off);
    }
    float mean = s * (1.f / 256.f);
    float rs = rsqrtf(sq * (1.f / 256.f) - mean * mean + 1e-5f);
    float4 gv = *(const float4*)(g + lane * 4);
    float4 bv = *(const float4*)(b + lane * 4);
    float4 o;
    o.x = (v.x - mean) * rs * gv.x + bv.x;
    o.y = (v.y - mean) * rs * gv.y + bv.y;
    o.z = (v.z - mean) * rs * gv.z + bv.z;
    o.w = (v.w - mean) * rs * gv.w + bv.w;
    *(float4*)(out + (size_t)tok * 256 + lane * 4) = o;
}

// ---------------------------------------------------------------------------
// bf16 MFMA GEMM, 128x64 tile (proven): C[M,N] = epi(A @ W^T + bias)
// EPI: 1 = f32 residual accumulate, 3 = plain f32 store
template <int EPI>
__global__ __launch_bounds__(256) void gemm_bf16_kernel(
    const unsigned short* __restrict__ A, const unsigned short* __restrict__ W,
    const float* __restrict__ bias, float* __restrict__ hres,
    unsigned short* __restrict__ o0, unsigned short* __restrict__ o1,
    unsigned short* __restrict__ o2, int M, int N, int K)
{
    __shared__ __align__(16) unsigned short As[128 * 64];
    __shared__ __align__(16) unsigned short Bs[64 * 64];
    const int t = threadIdx.x;
    const int wid = t >> 6, lane = t & 63;
    const int lo = lane & 15, hi = lane >> 4;
    const int wm = wid >> 1, wn = wid & 1;
    const int m0 = blockIdx.y * 128, n0 = blockIdx.x * 64;
    const int lrow = lane >> 3, lc = lane & 7;
    f32x4 acc[4][2] = {};
    for (int k0 = 0; k0 < K; k0 += 64) {
        __syncthreads();
#pragma unroll
        for (int is = 0; is < 4; ++is) {
            int r = wid * 32 + is * 8 + lrow;
            const unsigned short* g = A + (size_t)(m0 + r) * K + k0 + ((lc ^ (r & 7)) * 8);
            gload16(g, &As[(wid * 32 + is * 8) * 64]);
        }
#pragma unroll
        for (int is = 0; is < 2; ++is) {
            int r = wid * 16 + is * 8 + lrow;
            const unsigned short* g = W + (size_t)(n0 + r) * K + k0 + ((lc ^ (r & 7)) * 8);
            gload16(g, &Bs[(wid * 16 + is * 8) * 64]);
        }
        __syncthreads();
#pragma unroll
        for (int kh = 0; kh < 2; ++kh) {
            bf16x8 bfr[2];
#pragma unroll
            for (int nf = 0; nf < 2; ++nf) {
                int r = wn * 32 + nf * 16 + lo;
                bfr[nf] = *(const bf16x8*)&Bs[r * 64 + (((kh * 4 + hi) ^ (r & 7)) * 8)];
            }
#pragma unroll
            for (int mf = 0; mf < 4; ++mf) {
                int r = wm * 64 + mf * 16 + lo;
                bf16x8 afr = *(const bf16x8*)&As[r * 64 + (((kh * 4 + hi) ^ (r & 7)) * 8)];
                acc[mf][0] = __builtin_amdgcn_mfma_f32_16x16x32_bf16(afr, bfr[0], acc[mf][0], 0, 0, 0);
                acc[mf][1] = __builtin_amdgcn_mfma_f32_16x16x32_bf16(afr, bfr[1], acc[mf][1], 0, 0, 0);
            }
        }
    }
#pragma unroll
    for (int mf = 0; mf < 4; ++mf) {
        const int mbase = m0 + wm * 64 + mf * 16 + hi * 4;
#pragma unroll
        for (int nf = 0; nf < 2; ++nf) {
            const int n = n0 + wn * 32 + nf * 16 + lo;
            const float bv = bias[n];
            f32x4 v = acc[mf][nf];
            if constexpr (EPI == 1) {
#pragma unroll
                for (int rg = 0; rg < 4; ++rg) {
                    size_t idx = (size_t)(mbase + rg) * N + n;
                    hres[idx] += v[rg] + bv;
                }
            } else {
#pragma unroll
                for (int rg = 0; rg < 4; ++rg)
                    hres[(size_t)(mbase + rg) * N + n] = v[rg] + bv;
            }
        }
    }
}

// ---------------------------------------------------------------------------
// bf16 MFMA GEMM, 128x128 tile (4 waves, each 64x64): for QKV (EPI=0) and
// FF1 GELU (EPI=2). Same both-sides XOR swizzle staging as the 128x64 kernel.
template <int EPI>
__global__ __launch_bounds__(256) void gemm128_kernel(
    const unsigned short* __restrict__ A, const unsigned short* __restrict__ W,
    const float* __restrict__ bias,
    unsigned short* __restrict__ o0, unsigned short* __restrict__ o1,
    unsigned short* __restrict__ o2, int M, int N, int K)
{
    __shared__ __align__(16) unsigned short As[128 * 64];
    __shared__ __align__(16) unsigned short Bs[128 * 64];
    const int t = threadIdx.x;
    const int wid = t >> 6, lane = t & 63;
    const int lo = lane & 15, hi = lane >> 4;
    const int wm = wid >> 1, wn = wid & 1;
    const int m0 = blockIdx.y * 128, n0 = blockIdx.x * 128;
    const int lrow = lane >> 3, lc = lane & 7;
    f32x4 acc[4][4] = {};
    for (int k0 = 0; k0 < K; k0 += 64) {
        __syncthreads();
#pragma unroll
        for (int is = 0; is < 4; ++is) {
            int r = wid * 32 + is * 8 + lrow;
            const unsigned short* g = A + (size_t)(m0 + r) * K + k0 + ((lc ^ (r & 7)) * 8);
            gload16(g, &As[(wid * 32 + is * 8) * 64]);
        }
#pragma unroll
        for (int is = 0; is < 4; ++is) {
            int r = wid * 32 + is * 8 + lrow;
            const unsigned short* g = W + (size_t)(n0 + r) * K + k0 + ((lc ^ (r & 7)) * 8);
            gload16(g, &Bs[(wid * 32 + is * 8) * 64]);
        }
        __syncthreads();
#pragma unroll
        for (int kh = 0; kh < 2; ++kh) {
            bf16x8 bfr[4];
#pragma unroll
            for (int nf = 0; nf < 4; ++nf) {
                int r = wn * 64 + nf * 16 + lo;
                bfr[nf] = *(const bf16x8*)&Bs[r * 64 + (((kh * 4 + hi) ^ (r & 7)) * 8)];
            }
#pragma unroll
            for (int mf = 0; mf < 4; ++mf) {
                int r = wm * 64 + mf * 16 + lo;
                bf16x8 afr = *(const bf16x8*)&As[r * 64 + (((kh * 4 + hi) ^ (r & 7)) * 8)];
#pragma unroll
                for (int nf = 0; nf < 4; ++nf)
                    acc[mf][nf] = __builtin_amdgcn_mfma_f32_16x16x32_bf16(afr, bfr[nf], acc[mf][nf], 0, 0, 0);
            }
        }
    }
#pragma unroll
    for (int mf = 0; mf < 4; ++mf) {
        const int mbase = m0 + wm * 64 + mf * 16 + hi * 4;
#pragma unroll
        for (int nf = 0; nf < 4; ++nf) {
            const int n = n0 + wn * 64 + nf * 16 + lo;
            const float bv = bias[n];
            f32x4 v = acc[mf][nf];
            if constexpr (EPI == 0) {
                unsigned short* dst = (n < 256) ? o0 : ((n < 512) ? o1 : o2);
                const float qsc = (n < 256)
                    ? (0.17677669529663687f * 1.4426950408889634f) : 1.f;
                const int c = n & 255;
#pragma unroll
                for (int rg = 0; rg < 4; ++rg)
                    dst[(size_t)(mbase + rg) * 256 + c] = f2bf((v[rg] + bv) * qsc);
            } else {
#pragma unroll
                for (int rg = 0; rg < 4; ++rg)
                    o0[(size_t)(mbase + rg) * N + n] = f2bf(gelu_f(v[rg] + bv));
            }
        }
    }
}

// ---------------------------------------------------------------------------
// Fused residual-GEMM + LayerNorm (proven round-10): 64x256 tile, 512 threads.
__global__ __launch_bounds__(512) void gemm_res_ln_kernel(
    const unsigned short* __restrict__ A, const unsigned short* __restrict__ W,
    const float* __restrict__ bias, float* __restrict__ hres,
    const float* __restrict__ g, const float* __restrict__ bvec,
    unsigned short* __restrict__ u, int K)
{
    __shared__ __align__(16) unsigned short As[64 * 64];
    __shared__ __align__(16) unsigned short Bs[256 * 64];
    __shared__ float red[64][4][2];
    const int t = threadIdx.x;
    const int wid = t >> 6, lane = t & 63;
    const int lo = lane & 15, hi = lane >> 4;
    const int wm = wid >> 2, wn = wid & 3;
    const int m0 = blockIdx.x * 64;
    const int lrow = lane >> 3, lc = lane & 7;
    f32x4 acc[2][4] = {};
    for (int k0 = 0; k0 < K; k0 += 64) {
        __syncthreads();
        {
            int r = wid * 8 + lrow;
            gload16(A + (size_t)(m0 + r) * K + k0 + ((lc ^ (r & 7)) * 8),
                    &As[(wid * 8) * 64]);
        }
#pragma unroll
        for (int is = 0; is < 4; ++is) {
            int r = wid * 32 + is * 8 + lrow;
            gload16(W + (size_t)r * K + k0 + ((lc ^ (r & 7)) * 8),
                    &Bs[(wid * 32 + is * 8) * 64]);
        }
        __syncthreads();
#pragma unroll
        for (int kh = 0; kh < 2; ++kh) {
            bf16x8 bfr[4];
#pragma unroll
            for (int nf = 0; nf < 4; ++nf) {
                int r = wn * 64 + nf * 16 + lo;
                bfr[nf] = *(const bf16x8*)&Bs[r * 64 + (((kh * 4 + hi) ^ (r & 7)) * 8)];
            }
#pragma unroll
            for (int mf = 0; mf < 2; ++mf) {
                int r = wm * 32 + mf * 16 + lo;
                bf16x8 afr = *(const bf16x8*)&As[r * 64 + (((kh * 4 + hi) ^ (r & 7)) * 8)];
#pragma unroll
                for (int nf = 0; nf < 4; ++nf)
                    acc[mf][nf] = __builtin_amdgcn_mfma_f32_16x16x32_bf16(afr, bfr[nf], acc[mf][nf], 0, 0, 0);
            }
        }
    }
#pragma unroll
    for (int mf = 0; mf < 2; ++mf) {
#pragma unroll
        for (int nf = 0; nf < 4; ++nf) {
            const int n = wn * 64 + nf * 16 + lo;
            const float bv = bias[n];
            const int rbase = m0 + wm * 32 + mf * 16 + hi * 4;
#pragma unroll
            for (int rg = 0; rg < 4; ++rg) {
                size_t idx = (size_t)(rbase + rg) * 256 + n;
                float hv = acc[mf][nf][rg] + bv + hres[idx];
                hres[idx] = hv;
                acc[mf][nf][rg] = hv;
            }
        }
    }
#pragma unroll
    for (int mf = 0; mf < 2; ++mf) {
#pragma unroll
        for (int rg = 0; rg < 4; ++rg) {
            float s = ((acc[mf][0][rg] + acc[mf][1][rg]) +
                       (acc[mf][2][rg] + acc[mf][3][rg]));
            float sq = ((acc[mf][0][rg] * acc[mf][0][rg] + acc[mf][1][rg] * acc[mf][1][rg]) +
                        (acc[mf][2][rg] * acc[mf][2][rg] + acc[mf][3][rg] * acc[mf][3][rg]));
#pragma unroll
            for (int off = 1; off < 16; off <<= 1) {
                s += __shfl_xor(s, off);
                sq += __shfl_xor(sq, off);
            }
            if (lo == 0) {
                int rl = wm * 32 + mf * 16 + hi * 4 + rg;
                red[rl][wn][0] = s;
                red[rl][wn][1] = sq;
            }
        }
    }
    __syncthreads();
#pragma unroll
    for (int mf = 0; mf < 2; ++mf) {
#pragma unroll
        for (int rg = 0; rg < 4; ++rg) {
            const int rl = wm * 32 + mf * 16 + hi * 4 + rg;
            float s = (red[rl][0][0] + red[rl][1][0]) + (red[rl][2][0] + red[rl][3][0]);
            float sq = (red[rl][0][1] + red[rl][1][1]) + (red[rl][2][1] + red[rl][3][1]);
            float mean = s * (1.f / 256.f);
            float rs = rsqrtf(sq * (1.f / 256.f) - mean * mean + 1e-5f);
#pragma unroll
            for (int nf = 0; nf < 4; ++nf) {
                const int n = wn * 64 + nf * 16 + lo;
                u[(size_t)(m0 + rl) * 256 + n] =
                    f2bf((acc[mf][nf][rg] - mean) * rs * g[n] + bvec[n]);
            }
        }
    }
}

// ---------------------------------------------------------------------------
// MFMA flash attention v7: per-jt csfj[128] (pad folded in: -1e5), LDS 19.2 KB
// -> 8 blocks/CU. Everything else identical to proven v6.
__global__ __launch_bounds__(256) void attn_mfma_kernel(
    const unsigned short* __restrict__ Qb, const unsigned short* __restrict__ Kb,
    const unsigned short* __restrict__ Vb, const float* __restrict__ clb,
    const float* __restrict__ csfb, const float* __restrict__ padfb,
    const float* __restrict__ alpha_p, const float* __restrict__ beta_p,
    unsigned short* __restrict__ Ob)
{
    __shared__ __align__(16) unsigned short Kl[128 * 40];   // 10240 B
    __shared__ __align__(16) unsigned short Vt[32 * 132];   // 8448 B
    __shared__ __align__(16) float csfj[128];               // 512 B
    const int t = threadIdx.x;
    const int swz = ((blockIdx.x & 7) << 8) | (blockIdx.x >> 3);  // XCD chunking
    const int bh = swz >> 3, hf = swz & 7;
    const int b = bh >> 3, hd = bh & 7;
    const size_t base = ((size_t)b * 512) * 256 + hd * 32;
    const int w = t >> 6, lane = t & 63, lo = lane & 15, hi = lane >> 4;
    const float L2E = 1.4426950408889634f;
    const float kb = L2E * (*beta_p);
    const float ka = L2E * (*alpha_p);
    const float* clg = clb + b * 512;

    const int i0 = (hf * 4 + w) * 16;
    const int iq = i0 + lo;
    const bf16x8 qf = *(const bf16x8*)(Qb + base + (size_t)iq * 256 + hi * 8);
    const float csb = fmaxf(kb * csfb[b * 512 + iq], 1e-3f);
    f32x4 acc0 = {0.f, 0.f, 0.f, 0.f}, acc1 = {0.f, 0.f, 0.f, 0.f};
    float lsum = 0.f;

    for (int jt = 0; jt < 4; ++jt) {
        __syncthreads();
        for (int idx = t; idx < 512; idx += 256) {       // K tile: 128 rows
            int row = idx >> 2, c4 = idx & 3;
            *(uint4*)&Kl[row * 40 + c4 * 8] =
                *(const uint4*)(Kb + base + (size_t)(jt * 128 + row) * 256 + c4 * 8);
        }
        for (int idx = t; idx < 512; idx += 256) {       // V^T, paired rows
            int pr = idx & 63, c4 = idx >> 6;
            unsigned long long v0 = *(const unsigned long long*)
                (Vb + base + (size_t)(jt * 128 + 2 * pr) * 256 + c4 * 4);
            unsigned long long v1 = *(const unsigned long long*)
                (Vb + base + (size_t)(jt * 128 + 2 * pr + 1) * 256 + c4 * 4);
#pragma unroll
            for (int e = 0; e < 4; ++e) {
                unsigned a = (unsigned)((v0 >> (16 * e)) & 0xffffu);
                unsigned c = (unsigned)((v1 >> (16 * e)) & 0xffffu);
                *(unsigned*)&Vt[(c4 * 4 + e) * 132 + 2 * pr] = a | (c << 16);
            }
        }
        if (t < 128) {                                   // csf with pad folded
            int j = jt * 128 + t;
            float cv = csfb[b * 512 + j];
            csfj[t] = (padfb[b * 512 + j] > 0.5f) ? -100000.f : cv;
        }
        __syncthreads();
#pragma unroll
        for (int ktp = 0; ktp < 4; ++ktp) {
            const int k16 = ktp * 32;             // local j base
            const int gj = jt * 128 + k16;        // global j base
            bf16x8 kf0 = *(const bf16x8*)&Kl[(k16 + lo) * 40 + hi * 8];
            bf16x8 kf1 = *(const bf16x8*)&Kl[(k16 + 16 + lo) * 40 + hi * 8];
            union U16 { unsigned long long q[2]; unsigned wd[4]; bf16x8 v; } vu0, vu1, pu;
            vu0.q[0] = *(const unsigned long long*)&Vt[lo * 132 + k16 + hi * 4];
            vu0.q[1] = *(const unsigned long long*)&Vt[lo * 132 + k16 + 16 + hi * 4];
            vu1.q[0] = *(const unsigned long long*)&Vt[(16 + lo) * 132 + k16 + hi * 4];
            vu1.q[1] = *(const unsigned long long*)&Vt[(16 + lo) * 132 + k16 + 16 + hi * 4];
            f32x4 csf0 = *(const f32x4*)&csfj[k16 + hi * 4];
            f32x4 csf1 = *(const f32x4*)&csfj[k16 + 16 + hi * 4];
            f32x4 c0, c1;
#pragma unroll
            for (int e = 0; e < 4; ++e) {
                c0[e] = csb * csf0[e];
                c1[e] = csb * csf1[e];
            }
            f32x4 s0 = __builtin_amdgcn_mfma_f32_16x16x32_bf16(kf0, qf, c0, 0, 0, 0);
            f32x4 s1 = __builtin_amdgcn_mfma_f32_16x16x32_bf16(kf1, qf, c1, 0, 0, 0);
            float p[8];
#pragma unroll
            for (int r = 0; r < 4; ++r) p[r] = exp2f(s0[r]);
#pragma unroll
            for (int r = 0; r < 4; ++r) p[4 + r] = exp2f(s1[r]);
            // tridiagonal alpha correction (rare; scalar window test)
            if (gj <= i0 + 16 && gj + 32 >= i0) {
#pragma unroll
                for (int r = 0; r < 8; ++r) {
                    int jr = gj + ((r & 4) ? 16 : 0) + hi * 4 + (r & 3);
                    int dij = jr - iq;
                    if (dij == 1 || dij == -1) {
                        float ce = (jr >= 1 && iq <= 510) ? clg[jr] : clg[iq];
                        p[r] *= exp2f(ka * ce);
                    }
                }
            }
            lsum += ((p[0] + p[1]) + (p[2] + p[3])) + ((p[4] + p[5]) + (p[6] + p[7]));
            pu.wd[0] = cvt_pk_bf16(p[0], p[1]);
            pu.wd[1] = cvt_pk_bf16(p[2], p[3]);
            pu.wd[2] = cvt_pk_bf16(p[4], p[5]);
            pu.wd[3] = cvt_pk_bf16(p[6], p[7]);
            acc0 = __builtin_amdgcn_mfma_f32_16x16x32_bf16(vu0.v, pu.v, acc0, 0, 0, 0);
            acc1 = __builtin_amdgcn_mfma_f32_16x16x32_bf16(vu1.v, pu.v, acc1, 0, 0, 0);
        }
    }
    {
        float ls = lsum;
        ls += __shfl_xor(ls, 16);
        ls += __shfl_xor(ls, 32);
        const float inv = 1.f / fmaxf(ls, 1e-35f);
        unsigned long long oa =
              (unsigned long long)cvt_pk_bf16(acc0[0] * inv, acc0[1] * inv)
            | ((unsigned long long)cvt_pk_bf16(acc0[2] * inv, acc0[3] * inv) << 32);
        unsigned long long ob2 =
              (unsigned long long)cvt_pk_bf16(acc1[0] * inv, acc1[1] * inv)
            | ((unsigned long long)cvt_pk_bf16(acc1[2] * inv, acc1[3] * inv) << 32);
        *(unsigned long long*)(Ob + base + (size_t)iq * 256 + hi * 4) = oa;
        *(unsigned long long*)(Ob + base + (size_t)iq * 256 + 16 + hi * 4) = ob2;
    }
}

// ---------------------------------------------------------------------------
extern "C" void kernel_launch(void* const* d_in, const int* in_sizes, int n_in,
                              void* d_out, int out_size, void* d_ws, size_t ws_size,
                              hipStream_t stream) {
    const float* x         = (const float*)d_in[0];
    const float* c_local   = (const float*)d_in[1];
    const float* c_sink    = (const float*)d_in[2];
    const float* W_in      = (const float*)d_in[3];
    const float* b_in      = (const float*)d_in[4];
    const float* cls_token = (const float*)d_in[5];
    const float* pe_proj_W = (const float*)d_in[6];
    const float* pe_proj_b = (const float*)d_in[7];
    const float* pe_ln_g   = (const float*)d_in[8];
    const float* pe_ln_b   = (const float*)d_in[9];
    const float* pe_gain   = (const float*)d_in[10];
    const float* attn_Wqkv = (const float*)d_in[11];
    const float* attn_bqkv = (const float*)d_in[12];
    const float* attn_Wo   = (const float*)d_in[13];
    const float* attn_bo   = (const float*)d_in[14];
    const float* ff_W1     = (const float*)d_in[15];
    const float* ff_b1     = (const float*)d_in[16];
    const float* ff_W2     = (const float*)d_in[17];
    const float* ff_b2     = (const float*)d_in[18];
    const float* ln1_g     = (const float*)d_in[19];
    const float* ln1_b     = (const float*)d_in[20];
    const float* ln2_g     = (const float*)d_in[21];
    const float* ln2_b     = (const float*)d_in[22];
    const float* alpha     = (const float*)d_in[23];
    const float* beta      = (const float*)d_in[24];
    const float* corr_fl   = (const float*)d_in[25];
    const float* out_ln_g  = (const float*)d_in[26];
    const float* out_ln_b  = (const float*)d_in[27];
    const int*   lengths   = (const int*)d_in[28];
    float* out = (float*)d_out;

    // float region (same slots as round-10 passing layout; W20t reuses peWt slot)
    float* h     = (float*)d_ws;              // 4,194,304
    float* clb   = h + 4194304;               // 16384
    float* csfb  = clb + 16384;
    float* padfb = csfb + 16384;
    float* W20t  = padfb + 16384;             // first 5120 of old peWt slot
    float* PEpos = W20t + 70656;              // 131072
    float* bbf   = PEpos + 131072;            // old 8,388,608-float region
    // bf16 region — weights AFTER the full 16,777,216-short f-span at Q_bf
    unsigned short* u_bf = (unsigned short*)(bbf + 8388608);
    unsigned short* xb_bf = u_bf;             // alias: xb dead before layer loop
    unsigned short* Q_bf = u_bf + 4194304;
    unsigned short* K_bf = Q_bf + 4194304;
    unsigned short* V_bf = K_bf + 4194304;
    unsigned short* f_bf = Q_bf;              // alias: spans Q..Q+16777216
    unsigned short* o_bf = u_bf;              // alias (lifetimes disjoint)
    unsigned short* wq_bf = Q_bf + 16777216;  // after f's span
    unsigned short* wo_bf = wq_bf + 589824;
    unsigned short* w1_bf = wo_bf + 196608;
    unsigned short* w2_bf = w1_bf + 786432;
    unsigned short* win_bf = w2_bf + 786432;  // 16384
    unsigned short* S_bf   = win_bf + 16384;  // 131072 (sinusoid table)
    unsigned short* w256_bf = S_bf + 131072;  // 65536 (peW first 256 feats)

    cvt_multi_kernel<<<2320, 256, 0, stream>>>(
        attn_Wqkv, wq_bf, attn_Wo, wo_bf, ff_W1, w1_bf, ff_W2, w2_bf, W_in, win_bf);
    cvt_pew_kernel<<<64, 256, 0, stream>>>(pe_proj_W, w256_bf);
    sinus_kernel<<<512, 128, 0, stream>>>(S_bf);
    transpose_w20_kernel<<<20, 256, 0, stream>>>(pe_proj_W, W20t);
    xb_kernel<<<2048, 256, 0, stream>>>(x, xb_bf);
    gemm_bf16_kernel<3><<<dim3(4, 4), 256, 0, stream>>>(
        S_bf, w256_bf, pe_proj_b, PEpos, nullptr, nullptr, nullptr, 512, 256, 256);
    gemm_bf16_kernel<3><<<dim3(4, 128), 256, 0, stream>>>(
        xb_bf, win_bf, b_in, bbf, nullptr, nullptr, nullptr, 16384, 256, 64);
    prep_lite_kernel<<<2048, 256, 0, stream>>>(
        c_local, c_sink, bbf, cls_token, PEpos, W20t,
        pe_ln_g, pe_ln_b, pe_gain, corr_fl, lengths, h, clb, csfb, padfb);

    // layer-0 ln1 (standalone); subsequent LNs are fused into GEMM epilogues
    ln_bf_kernel<<<4096, 256, 0, stream>>>(h, ln1_g, ln1_b, u_bf);
    for (int l = 0; l < 3; ++l) {
        gemm128_kernel<0><<<dim3(6, 128), 256, 0, stream>>>(
            u_bf, wq_bf + (size_t)l * 196608, attn_bqkv + 768 * l,
            Q_bf, K_bf, V_bf, 16384, 768, 256);
        attn_mfma_kernel<<<2048, 256, 0, stream>>>(Q_bf, K_bf, V_bf, clb, csfb,
                                                   padfb, alpha, beta, o_bf);
        gemm_res_ln_kernel<<<256, 512, 0, stream>>>(
            o_bf, wo_bf + (size_t)l * 65536, attn_bo + 256 * l, h,
            ln2_g + 256 * l, ln2_b + 256 * l, u_bf, 256);
        gemm128_kernel<2><<<dim3(8, 128), 256, 0, stream>>>(
            u_bf, w1_bf + (size_t)l * 262144, ff_b1 + 1024 * l,
            f_bf, nullptr, nullptr, 16384, 1024, 256);
        if (l < 2) {
            gemm_res_ln_kernel<<<256, 512, 0, stream>>>(
                f_bf, w2_bf + (size_t)l * 262144, ff_b2 + 256 * l, h,
                ln1_g + 256 * (l + 1), ln1_b + 256 * (l + 1), u_bf, 1024);
        } else {
            gemm_bf16_kernel<1><<<dim3(4, 128), 256, 0, stream>>>(
                f_bf, w2_bf + (size_t)l * 262144, ff_b2 + 256 * l, h,
                nullptr, nullptr, nullptr, 16384, 256, 1024);
        }
    }
    out_ln_kernel<<<8, 256, 0, stream>>>(h, out_ln_g, out_ln_b, out);
}

// Round 12
// 449.188 us; speedup vs baseline: 48.9968x; 1.0448x over previous
//
#include <hip/hip_runtime.h>
#include <math.h>

// B=32, L=512 (incl CLS), D=256, H=8, dh=32, N_LAYERS=3, D_FF=1024, tokens=16384

typedef __attribute__((ext_vector_type(4))) float f32x4;
typedef __attribute__((ext_vector_type(8))) short bf16x8;

__device__ __forceinline__ unsigned short f2bf(float f) {
    unsigned u = __builtin_bit_cast(unsigned, f);
    u += 0x7fff + ((u >> 16) & 1);
    return (unsigned short)(u >> 16);
}
__device__ __forceinline__ unsigned cvt_pk_bf16(float a, float b) {
    unsigned r;
    asm("v_cvt_pk_bf16_f32 %0, %1, %2" : "=v"(r) : "v"(a), "v"(b));
    return r;
}
__device__ __forceinline__ float gelu_f(float v) {
    return v * 0.5f * (1.0f + erff(v * 0.70710678118654752f));
}
__device__ __forceinline__ void gload16(const void* g, void* l) {
    __builtin_amdgcn_global_load_lds(
        (const __attribute__((address_space(1))) unsigned int*)g,
        (__attribute__((address_space(3))) unsigned int*)l, 16, 0, 0);
}

// ---------------------------------------------------------------------------
// Mega setup kernel: all weight cvts + pe transposes + sinusoid + xb, range-
// dispatched by blockIdx (saves 5 launches).
__global__ __launch_bounds__(256) void setup_kernel(
    const float* __restrict__ wq, unsigned short* __restrict__ wq_o,   // 576
    const float* __restrict__ wo, unsigned short* __restrict__ wo_o,   // 192
    const float* __restrict__ w1, unsigned short* __restrict__ w1_o,   // 768
    const float* __restrict__ w2, unsigned short* __restrict__ w2_o,   // 768
    const float* __restrict__ win, unsigned short* __restrict__ win_o, // 16
    const float* __restrict__ peW, unsigned short* __restrict__ w256,  // 64
    float* __restrict__ W20t,                                          // 20
    const float* __restrict__ x, unsigned short* __restrict__ xb,      // 2048
    unsigned short* __restrict__ S)                                    // 256
{
    int blk = blockIdx.x, t = threadIdx.x;
    if (blk < 2304) {  // plain f32->bf16 cvts
        const float* s; unsigned short* d; int base;
        if (blk < 576)       { s = wq; d = wq_o; base = blk; }
        else if (blk < 768)  { s = wo; d = wo_o; base = blk - 576; }
        else if (blk < 1536) { s = w1; d = w1_o; base = blk - 768; }
        else                 { s = w2; d = w2_o; base = blk - 1536; }
        int i = (base * 256 + t) * 4;
        float4 v = *(const float4*)(s + i);
        unsigned long long pk = (unsigned long long)f2bf(v.x)
            | ((unsigned long long)f2bf(v.y) << 16)
            | ((unsigned long long)f2bf(v.z) << 32)
            | ((unsigned long long)f2bf(v.w) << 48);
        *(unsigned long long*)(d + i) = pk;
    } else if (blk < 2320) {  // win
        int i = ((blk - 2304) * 256 + t) * 4;
        float4 v = *(const float4*)(win + i);
        unsigned long long pk = (unsigned long long)f2bf(v.x)
            | ((unsigned long long)f2bf(v.y) << 16)
            | ((unsigned long long)f2bf(v.z) << 32)
            | ((unsigned long long)f2bf(v.w) << 48);
        *(unsigned long long*)(win_o + i) = pk;
    } else if (blk < 2384) {  // peW first-256 feats -> bf16 [256][256]
        int i = ((blk - 2320) * 256 + t) * 4;
        int d = i >> 8, f = i & 255;
        float4 v = *(const float4*)(peW + d * 276 + f);
        unsigned long long pk = (unsigned long long)f2bf(v.x)
            | ((unsigned long long)f2bf(v.y) << 16)
            | ((unsigned long long)f2bf(v.z) << 32)
            | ((unsigned long long)f2bf(v.w) << 48);
        *(unsigned long long*)(w256 + i) = pk;
    } else if (blk < 2404) {  // W20t[f][d] = peW[d][256+f]
        int j = (blk - 2384) * 256 + t;
        int f = j >> 8, dd = j & 255;
        W20t[j] = peW[dd * 276 + 256 + f];
    } else if (blk < 4452) {  // xb
        int idx = (blk - 2404) * 256 + t;
        int tok = idx >> 5, c2 = idx & 31;
        int b = tok >> 9, l = tok & 511;
        unsigned r = 0;
        if (l > 0) {
            float2 v = *(const float2*)(x + ((size_t)b * 511 + l - 1) * 64 + 2 * c2);
            r = cvt_pk_bf16(v.x, v.y);
        }
        *(unsigned*)(xb + (size_t)tok * 64 + 2 * c2) = r;
    } else {  // sinusoid table: 256 blocks x 256 threads = 65536 pairs
        int p = (blk - 4452) * 256 + t;
        int l = p >> 7, k = p & 127;
        float div = expf((float)(2 * k) * -0.035977892078032f);
        float a = (float)l * div;
        *(unsigned*)(S + l * 256 + 2 * k) = cvt_pk_bf16(sinf(a), cosf(a));
    }
}

// ---------------------------------------------------------------------------
// prep_lite: h = base(bb or cls) + mask*gain*LN(PEpos + feats@W20);
// also emits u = LN_l0(h) (fused layer-0 ln1) and cl/csf/pad arrays.
__global__ __launch_bounds__(256) void prep_lite_kernel(
    const float* __restrict__ c_local, const float* __restrict__ c_sink,
    const float* __restrict__ bb, const float* __restrict__ cls_tok,
    const float* __restrict__ PEpos, const float* __restrict__ W20t,
    const float* __restrict__ pe_g, const float* __restrict__ pe_bb,
    const float* __restrict__ pe_gain_p, const float* __restrict__ corr_floor_p,
    const int* __restrict__ lengths, const float* __restrict__ ln1g,
    const float* __restrict__ ln1b,
    float* __restrict__ h, float* __restrict__ clb, float* __restrict__ csfb,
    float* __restrict__ padfb, unsigned short* __restrict__ u)
{
    __shared__ float zs[8][20];
    __shared__ __align__(16) float pes[8][256];
    __shared__ float mn[8], rsd[8];
    const int t = threadIdx.x;
    const int tok0 = blockIdx.x * 8;
    const int b = tok0 >> 9;
    const int len_b = lengths[b];
    const float cf = *corr_floor_p;
    const float gain = *pe_gain_p;

    float clv[8], csv[8];
    bool mk[8];
#pragma unroll
    for (int k = 0; k < 8; ++k) {
        int l = (tok0 + k) & 511;
        if (l == 0) { clv[k] = 1.f; csv[k] = 1.f; mk[k] = false; }
        else {
            float a = c_local[b * 511 + l - 1];
            float s = c_sink[b * 511 + l - 1];
            clv[k] = fminf(fmaxf(a, 0.f), 1.f);
            csv[k] = fminf(fmaxf(s, 0.f), 1.f);
            mk[k] = (l - 1) >= len_b;
        }
    }
    if (t < 8) {
        int tok = tok0 + t;
        clb[tok] = clv[t];
        csfb[tok] = cf + (1.f - cf) * csv[t];
        padfb[tok] = mk[t] ? 1.f : 0.f;
    }
    if (t < 20) {
#pragma unroll
        for (int k = 0; k < 8; ++k) {
            float cl = clv[k], cs = csv[k];
            float v;
            if (t == 0) v = cl;
            else if (t == 1) v = cs;
            else if (t == 2) v = cl * cs;
            else if (t == 3) v = fabsf(cl - cs);
            else if (t < 12) {
                float c = (float)(t - 4) * (1.f / 7.f);
                float dd = (cl - c) / 0.200001f;
                v = expf(-0.5f * dd * dd);
            } else {
                float c = (float)(t - 12) * (1.f / 7.f);
                float dd = (cs - c) / 0.200001f;
                v = expf(-0.5f * dd * dd);
            }
            zs[k][t] = v;
        }
    }
    __syncthreads();

    float acc[8];
#pragma unroll
    for (int k = 0; k < 8; ++k)
        acc[k] = PEpos[((tok0 + k) & 511) * 256 + t];
    for (int f = 0; f < 20; ++f) {
        float wv = W20t[f * 256 + t];
#pragma unroll
        for (int k = 0; k < 8; ++k) acc[k] += zs[k][f] * wv;
    }
#pragma unroll
    for (int k = 0; k < 8; ++k) pes[k][t] = acc[k];
    __syncthreads();

    {
        int w = t >> 6, lane = t & 63;
#pragma unroll
        for (int p = 0; p < 2; ++p) {
            int k = w + p * 4;
            float4 v = *(const float4*)&pes[k][lane * 4];
            float s = v.x + v.y + v.z + v.w;
            float sq = v.x * v.x + v.y * v.y + v.z * v.z + v.w * v.w;
#pragma unroll
            for (int off = 32; off; off >>= 1) {
                s += __shfl_xor(s, off);
                sq += __shfl_xor(sq, off);
            }
            if (lane == 0) {
                float mean = s * (1.f / 256.f);
                mn[k] = mean;
                rsd[k] = rsqrtf(sq * (1.f / 256.f) - mean * mean + 1e-5f);
            }
        }
    }
    __syncthreads();
    float gv = pe_g[t], bv = pe_bb[t];
    float hv[8];
#pragma unroll
    for (int k = 0; k < 8; ++k) {
        int l = (tok0 + k) & 511;
        float base = (l == 0) ? cls_tok[t] : bb[(size_t)(tok0 + k) * 256 + t];
        float pe = (pes[k][t] - mn[k]) * rsd[k] * gv + bv;
        pe *= gain;
        if (mk[k]) pe = 0.f;
        hv[k] = base + pe;
        h[(size_t)(tok0 + k) * 256 + t] = hv[k];
    }
    // fused layer-0 ln1: u = LN(h)
    __syncthreads();
#pragma unroll
    for (int k = 0; k < 8; ++k) pes[k][t] = hv[k];
    __syncthreads();
    {
        int w = t >> 6, lane = t & 63;
#pragma unroll
        for (int p = 0; p < 2; ++p) {
            int k = w + p * 4;
            float4 v = *(const float4*)&pes[k][lane * 4];
            float s = v.x + v.y + v.z + v.w;
            float sq = v.x * v.x + v.y * v.y + v.z * v.z + v.w * v.w;
#pragma unroll
            for (int off = 32; off; off >>= 1) {
                s += __shfl_xor(s, off);
                sq += __shfl_xor(sq, off);
            }
            if (lane == 0) {
                float mean = s * (1.f / 256.f);
                mn[k] = mean;
                rsd[k] = rsqrtf(sq * (1.f / 256.f) - mean * mean + 1e-5f);
            }
        }
    }
    __syncthreads();
    float g1 = ln1g[t], b1 = ln1b[t];
#pragma unroll
    for (int k = 0; k < 8; ++k)
        u[(size_t)(tok0 + k) * 256 + t] = f2bf((hv[k] - mn[k]) * rsd[k] * g1 + b1);
}

// ---------------------------------------------------------------------------
// bf16 MFMA GEMM, 128x64 tile (proven): C[M,N] = A @ W^T + bias (f32 store)
__global__ __launch_bounds__(256) void gemm_bf16_kernel(
    const unsigned short* __restrict__ A, const unsigned short* __restrict__ W,
    const float* __restrict__ bias, float* __restrict__ hres, int M, int N, int K)
{
    __shared__ __align__(16) unsigned short As[128 * 64];
    __shared__ __align__(16) unsigned short Bs[64 * 64];
    const int t = threadIdx.x;
    const int wid = t >> 6, lane = t & 63;
    const int lo = lane & 15, hi = lane >> 4;
    const int wm = wid >> 1, wn = wid & 1;
    const int m0 = blockIdx.y * 128, n0 = blockIdx.x * 64;
    const int lrow = lane >> 3, lc = lane & 7;
    f32x4 acc[4][2] = {};
    for (int k0 = 0; k0 < K; k0 += 64) {
        __syncthreads();
#pragma unroll
        for (int is = 0; is < 4; ++is) {
            int r = wid * 32 + is * 8 + lrow;
            const unsigned short* g = A + (size_t)(m0 + r) * K + k0 + ((lc ^ (r & 7)) * 8);
            gload16(g, &As[(wid * 32 + is * 8) * 64]);
        }
#pragma unroll
        for (int is = 0; is < 2; ++is) {
            int r = wid * 16 + is * 8 + lrow;
            const unsigned short* g = W + (size_t)(n0 + r) * K + k0 + ((lc ^ (r & 7)) * 8);
            gload16(g, &Bs[(wid * 16 + is * 8) * 64]);
        }
        __syncthreads();
#pragma unroll
        for (int kh = 0; kh < 2; ++kh) {
            bf16x8 bfr[2];
#pragma unroll
            for (int nf = 0; nf < 2; ++nf) {
                int r = wn * 32 + nf * 16 + lo;
                bfr[nf] = *(const bf16x8*)&Bs[r * 64 + (((kh * 4 + hi) ^ (r & 7)) * 8)];
            }
#pragma unroll
            for (int mf = 0; mf < 4; ++mf) {
                int r = wm * 64 + mf * 16 + lo;
                bf16x8 afr = *(const bf16x8*)&As[r * 64 + (((kh * 4 + hi) ^ (r & 7)) * 8)];
                acc[mf][0] = __builtin_amdgcn_mfma_f32_16x16x32_bf16(afr, bfr[0], acc[mf][0], 0, 0, 0);
                acc[mf][1] = __builtin_amdgcn_mfma_f32_16x16x32_bf16(afr, bfr[1], acc[mf][1], 0, 0, 0);
            }
        }
    }
#pragma unroll
    for (int mf = 0; mf < 4; ++mf) {
        const int mbase = m0 + wm * 64 + mf * 16 + hi * 4;
#pragma unroll
        for (int nf = 0; nf < 2; ++nf) {
            const int n = n0 + wn * 32 + nf * 16 + lo;
            const float bv = bias[n];
            f32x4 v = acc[mf][nf];
#pragma unroll
            for (int rg = 0; rg < 4; ++rg)
                hres[(size_t)(mbase + rg) * N + n] = v[rg] + bv;
        }
    }
}

// ---------------------------------------------------------------------------
// bf16 MFMA GEMM, 128x128 tile: QKV (EPI=0), FF1 GELU (EPI=2)
template <int EPI>
__global__ __launch_bounds__(256) void gemm128_kernel(
    const unsigned short* __restrict__ A, const unsigned short* __restrict__ W,
    const float* __restrict__ bias,
    unsigned short* __restrict__ o0, unsigned short* __restrict__ o1,
    unsigned short* __restrict__ o2, int M, int N, int K)
{
    __shared__ __align__(16) unsigned short As[128 * 64];
    __shared__ __align__(16) unsigned short Bs[128 * 64];
    const int t = threadIdx.x;
    const int wid = t >> 6, lane = t & 63;
    const int lo = lane & 15, hi = lane >> 4;
    const int wm = wid >> 1, wn = wid & 1;
    const int m0 = blockIdx.y * 128, n0 = blockIdx.x * 128;
    const int lrow = lane >> 3, lc = lane & 7;
    f32x4 acc[4][4] = {};
    for (int k0 = 0; k0 < K; k0 += 64) {
        __syncthreads();
#pragma unroll
        for (int is = 0; is < 4; ++is) {
            int r = wid * 32 + is * 8 + lrow;
            const unsigned short* g = A + (size_t)(m0 + r) * K + k0 + ((lc ^ (r & 7)) * 8);
            gload16(g, &As[(wid * 32 + is * 8) * 64]);
        }
#pragma unroll
        for (int is = 0; is < 4; ++is) {
            int r = wid * 32 + is * 8 + lrow;
            const unsigned short* g = W + (size_t)(n0 + r) * K + k0 + ((lc ^ (r & 7)) * 8);
            gload16(g, &Bs[(wid * 32 + is * 8) * 64]);
        }
        __syncthreads();
#pragma unroll
        for (int kh = 0; kh < 2; ++kh) {
            bf16x8 bfr[4];
#pragma unroll
            for (int nf = 0; nf < 4; ++nf) {
                int r = wn * 64 + nf * 16 + lo;
                bfr[nf] = *(const bf16x8*)&Bs[r * 64 + (((kh * 4 + hi) ^ (r & 7)) * 8)];
            }
#pragma unroll
            for (int mf = 0; mf < 4; ++mf) {
                int r = wm * 64 + mf * 16 + lo;
                bf16x8 afr = *(const bf16x8*)&As[r * 64 + (((kh * 4 + hi) ^ (r & 7)) * 8)];
#pragma unroll
                for (int nf = 0; nf < 4; ++nf)
                    acc[mf][nf] = __builtin_amdgcn_mfma_f32_16x16x32_bf16(afr, bfr[nf], acc[mf][nf], 0, 0, 0);
            }
        }
    }
#pragma unroll
    for (int mf = 0; mf < 4; ++mf) {
        const int mbase = m0 + wm * 64 + mf * 16 + hi * 4;
#pragma unroll
        for (int nf = 0; nf < 4; ++nf) {
            const int n = n0 + wn * 64 + nf * 16 + lo;
            const float bv = bias[n];
            f32x4 v = acc[mf][nf];
            if constexpr (EPI == 0) {
                unsigned short* dst = (n < 256) ? o0 : ((n < 512) ? o1 : o2);
                const float qsc = (n < 256)
                    ? (0.17677669529663687f * 1.4426950408889634f) : 1.f;
                const int c = n & 255;
#pragma unroll
                for (int rg = 0; rg < 4; ++rg)
                    dst[(size_t)(mbase + rg) * 256 + c] = f2bf((v[rg] + bv) * qsc);
            } else {
#pragma unroll
                for (int rg = 0; rg < 4; ++rg)
                    o0[(size_t)(mbase + rg) * N + n] = f2bf(gelu_f(v[rg] + bv));
            }
        }
    }
}

// ---------------------------------------------------------------------------
// Fused residual-GEMM + LayerNorm: 64x256 tile, 512 threads (proven).
// OUT=0: h += GEMM; u = LN(h) bf16.  OUT=1 (final FF2): h dead -> no h store;
// out-LN written f32 for CLS rows only.
template <int OUT>
__global__ __launch_bounds__(512) void gemm_res_ln_kernel(
    const unsigned short* __restrict__ A, const unsigned short* __restrict__ W,
    const float* __restrict__ bias, float* __restrict__ hres,
    const float* __restrict__ g, const float* __restrict__ bvec,
    unsigned short* __restrict__ u, float* __restrict__ outp, int K)
{
    __shared__ __align__(16) unsigned short As[64 * 64];
    __shared__ __align__(16) unsigned short Bs[256 * 64];
    __shared__ float red[64][4][2];
    const int t = threadIdx.x;
    const int wid = t >> 6, lane = t & 63;
    const int lo = lane & 15, hi = lane >> 4;
    const int wm = wid >> 2, wn = wid & 3;
    const int m0 = blockIdx.x * 64;
    const int lrow = lane >> 3, lc = lane & 7;
    f32x4 acc[2][4] = {};
    for (int k0 = 0; k0 < K; k0 += 64) {
        __syncthreads();
        {
            int r = wid * 8 + lrow;
            gload16(A + (size_t)(m0 + r) * K + k0 + ((lc ^ (r & 7)) * 8),
                    &As[(wid * 8) * 64]);
        }
#pragma unroll
        for (int is = 0; is < 4; ++is) {
            int r = wid * 32 + is * 8 + lrow;
            gload16(W + (size_t)r * K + k0 + ((lc ^ (r & 7)) * 8),
                    &Bs[(wid * 32 + is * 8) * 64]);
        }
        __syncthreads();
#pragma unroll
        for (int kh = 0; kh < 2; ++kh) {
            bf16x8 bfr[4];
#pragma unroll
            for (int nf = 0; nf < 4; ++nf) {
                int r = wn * 64 + nf * 16 + lo;
                bfr[nf] = *(const bf16x8*)&Bs[r * 64 + (((kh * 4 + hi) ^ (r & 7)) * 8)];
            }
#pragma unroll
            for (int mf = 0; mf < 2; ++mf) {
                int r = wm * 32 + mf * 16 + lo;
                bf16x8 afr = *(const bf16x8*)&As[r * 64 + (((kh * 4 + hi) ^ (r & 7)) * 8)];
#pragma unroll
                for (int nf = 0; nf < 4; ++nf)
                    acc[mf][nf] = __builtin_amdgcn_mfma_f32_16x16x32_bf16(afr, bfr[nf], acc[mf][nf], 0, 0, 0);
            }
        }
    }
#pragma unroll
    for (int mf = 0; mf < 2; ++mf) {
#pragma unroll
        for (int nf = 0; nf < 4; ++nf) {
            const int n = wn * 64 + nf * 16 + lo;
            const float bv = bias[n];
            const int rbase = m0 + wm * 32 + mf * 16 + hi * 4;
#pragma unroll
            for (int rg = 0; rg < 4; ++rg) {
                size_t idx = (size_t)(rbase + rg) * 256 + n;
                float hv = acc[mf][nf][rg] + bv + hres[idx];
                if constexpr (OUT == 0) hres[idx] = hv;
                acc[mf][nf][rg] = hv;
            }
        }
    }
#pragma unroll
    for (int mf = 0; mf < 2; ++mf) {
#pragma unroll
        for (int rg = 0; rg < 4; ++rg) {
            float s = ((acc[mf][0][rg] + acc[mf][1][rg]) +
                       (acc[mf][2][rg] + acc[mf][3][rg]));
            float sq = ((acc[mf][0][rg] * acc[mf][0][rg] + acc[mf][1][rg] * acc[mf][1][rg]) +
                        (acc[mf][2][rg] * acc[mf][2][rg] + acc[mf][3][rg] * acc[mf][3][rg]));
#pragma unroll
            for (int off = 1; off < 16; off <<= 1) {
                s += __shfl_xor(s, off);
                sq += __shfl_xor(sq, off);
            }
            if (lo == 0) {
                int rl = wm * 32 + mf * 16 + hi * 4 + rg;
                red[rl][wn][0] = s;
                red[rl][wn][1] = sq;
            }
        }
    }
    __syncthreads();
#pragma unroll
    for (int mf = 0; mf < 2; ++mf) {
#pragma unroll
        for (int rg = 0; rg < 4; ++rg) {
            const int rl = wm * 32 + mf * 16 + hi * 4 + rg;
            float s = (red[rl][0][0] + red[rl][1][0]) + (red[rl][2][0] + red[rl][3][0]);
            float sq = (red[rl][0][1] + red[rl][1][1]) + (red[rl][2][1] + red[rl][3][1]);
            float mean = s * (1.f / 256.f);
            float rs = rsqrtf(sq * (1.f / 256.f) - mean * mean + 1e-5f);
            if constexpr (OUT == 1) {
                const int row = m0 + rl;
                if ((row & 511) == 0) {
#pragma unroll
                    for (int nf = 0; nf < 4; ++nf) {
                        const int n = wn * 64 + nf * 16 + lo;
                        outp[(size_t)(row >> 9) * 256 + n] =
                            (acc[mf][nf][rg] - mean) * rs * g[n] + bvec[n];
                    }
                }
            } else {
#pragma unroll
                for (int nf = 0; nf < 4; ++nf) {
                    const int n = wn * 64 + nf * 16 + lo;
                    u[(size_t)(m0 + rl) * 256 + n] =
                        f2bf((acc[mf][nf][rg] - mean) * rs * g[n] + bvec[n]);
                }
            }
        }
    }
}

// ---------------------------------------------------------------------------
// MFMA flash attention v8: = proven v7 + v_perm V-transpose staging.
__global__ __launch_bounds__(256) void attn_mfma_kernel(
    const unsigned short* __restrict__ Qb, const unsigned short* __restrict__ Kb,
    const unsigned short* __restrict__ Vb, const float* __restrict__ clb,
    const float* __restrict__ csfb, const float* __restrict__ padfb,
    const float* __restrict__ alpha_p, const float* __restrict__ beta_p,
    unsigned short* __restrict__ Ob)
{
    __shared__ __align__(16) unsigned short Kl[128 * 40];   // 10240 B
    __shared__ __align__(16) unsigned short Vt[32 * 132];   // 8448 B
    __shared__ __align__(16) float csfj[128];               // 512 B
    const int t = threadIdx.x;
    const int swz = ((blockIdx.x & 7) << 8) | (blockIdx.x >> 3);  // XCD chunking
    const int bh = swz >> 3, hf = swz & 7;
    const int b = bh >> 3, hd = bh & 7;
    const size_t base = ((size_t)b * 512) * 256 + hd * 32;
    const int w = t >> 6, lane = t & 63, lo = lane & 15, hi = lane >> 4;
    const float L2E = 1.4426950408889634f;
    const float kb = L2E * (*beta_p);
    const float ka = L2E * (*alpha_p);
    const float* clg = clb + b * 512;

    const int i0 = (hf * 4 + w) * 16;
    const int iq = i0 + lo;
    const bf16x8 qf = *(const bf16x8*)(Qb + base + (size_t)iq * 256 + hi * 8);
    const float csb = fmaxf(kb * csfb[b * 512 + iq], 1e-3f);
    f32x4 acc0 = {0.f, 0.f, 0.f, 0.f}, acc1 = {0.f, 0.f, 0.f, 0.f};
    float lsum = 0.f;

    for (int jt = 0; jt < 4; ++jt) {
        __syncthreads();
        for (int idx = t; idx < 512; idx += 256) {       // K tile: 128 rows
            int row = idx >> 2, c4 = idx & 3;
            *(uint4*)&Kl[row * 40 + c4 * 8] =
                *(const uint4*)(Kb + base + (size_t)(jt * 128 + row) * 256 + c4 * 8);
        }
        for (int idx = t; idx < 512; idx += 256) {       // V^T via v_perm
            int pr = idx & 63, c4 = idx >> 6;
            const unsigned* vp0 = (const unsigned*)
                (Vb + base + (size_t)(jt * 128 + 2 * pr) * 256 + c4 * 4);
            const unsigned* vp1 = (const unsigned*)
                (Vb + base + (size_t)(jt * 128 + 2 * pr + 1) * 256 + c4 * 4);
            unsigned v0lo = vp0[0], v0hi = vp0[1];
            unsigned v1lo = vp1[0], v1hi = vp1[1];
            *(unsigned*)&Vt[(c4 * 4 + 0) * 132 + 2 * pr] =
                __builtin_amdgcn_perm(v1lo, v0lo, 0x05040100u);
            *(unsigned*)&Vt[(c4 * 4 + 1) * 132 + 2 * pr] =
                __builtin_amdgcn_perm(v1lo, v0lo, 0x07060302u);
            *(unsigned*)&Vt[(c4 * 4 + 2) * 132 + 2 * pr] =
                __builtin_amdgcn_perm(v1hi, v0hi, 0x05040100u);
            *(unsigned*)&Vt[(c4 * 4 + 3) * 132 + 2 * pr] =
                __builtin_amdgcn_perm(v1hi, v0hi, 0x07060302u);
        }
        if (t < 128) {                                   // csf with pad folded
            int j = jt * 128 + t;
            float cv = csfb[b * 512 + j];
            csfj[t] = (padfb[b * 512 + j] > 0.5f) ? -100000.f : cv;
        }
        __syncthreads();
#pragma unroll
        for (int ktp = 0; ktp < 4; ++ktp) {
            const int k16 = ktp * 32;             // local j base
            const int gj = jt * 128 + k16;        // global j base
            bf16x8 kf0 = *(const bf16x8*)&Kl[(k16 + lo) * 40 + hi * 8];
            bf16x8 kf1 = *(const bf16x8*)&Kl[(k16 + 16 + lo) * 40 + hi * 8];
            union U16 { unsigned long long q[2]; unsigned wd[4]; bf16x8 v; } vu0, vu1, pu;
            vu0.q[0] = *(const unsigned long long*)&Vt[lo * 132 + k16 + hi * 4];
            vu0.q[1] = *(const unsigned long long*)&Vt[lo * 132 + k16 + 16 + hi * 4];
            vu1.q[0] = *(const unsigned long long*)&Vt[(16 + lo) * 132 + k16 + hi * 4];
            vu1.q[1] = *(const unsigned long long*)&Vt[(16 + lo) * 132 + k16 + 16 + hi * 4];
            f32x4 csf0 = *(const f32x4*)&csfj[k16 + hi * 4];
            f32x4 csf1 = *(const f32x4*)&csfj[k16 + 16 + hi * 4];
            f32x4 c0, c1;
#pragma unroll
            for (int e = 0; e < 4; ++e) {
                c0[e] = csb * csf0[e];
                c1[e] = csb * csf1[e];
            }
            f32x4 s0 = __builtin_amdgcn_mfma_f32_16x16x32_bf16(kf0, qf, c0, 0, 0, 0);
            f32x4 s1 = __builtin_amdgcn_mfma_f32_16x16x32_bf16(kf1, qf, c1, 0, 0, 0);
            float p[8];
#pragma unroll
            for (int r = 0; r < 4; ++r) p[r] = exp2f(s0[r]);
#pragma unroll
            for (int r = 0; r < 4; ++r) p[4 + r] = exp2f(s1[r]);
            // tridiagonal alpha correction (rare; scalar window test)
            if (gj <= i0 + 16 && gj + 32 >= i0) {
#pragma unroll
                for (int r = 0; r < 8; ++r) {
                    int jr = gj + ((r & 4) ? 16 : 0) + hi * 4 + (r & 3);
                    int dij = jr - iq;
                    if (dij == 1 || dij == -1) {
                        float ce = (jr >= 1 && iq <= 510) ? clg[jr] : clg[iq];
                        p[r] *= exp2f(ka * ce);
                    }
                }
            }
            lsum += ((p[0] + p[1]) + (p[2] + p[3])) + ((p[4] + p[5]) + (p[6] + p[7]));
            pu.wd[0] = cvt_pk_bf16(p[0], p[1]);
            pu.wd[1] = cvt_pk_bf16(p[2], p[3]);
            pu.wd[2] = cvt_pk_bf16(p[4], p[5]);
            pu.wd[3] = cvt_pk_bf16(p[6], p[7]);
            acc0 = __builtin_amdgcn_mfma_f32_16x16x32_bf16(vu0.v, pu.v, acc0, 0, 0, 0);
            acc1 = __builtin_amdgcn_mfma_f32_16x16x32_bf16(vu1.v, pu.v, acc1, 0, 0, 0);
        }
    }
    {
        float ls = lsum;
        ls += __shfl_xor(ls, 16);
        ls += __shfl_xor(ls, 32);
        const float inv = 1.f / fmaxf(ls, 1e-35f);
        unsigned long long oa =
              (unsigned long long)cvt_pk_bf16(acc0[0] * inv, acc0[1] * inv)
            | ((unsigned long long)cvt_pk_bf16(acc0[2] * inv, acc0[3] * inv) << 32);
        unsigned long long ob2 =
              (unsigned long long)cvt_pk_bf16(acc1[0] * inv, acc1[1] * inv)
            | ((unsigned long long)cvt_pk_bf16(acc1[2] * inv, acc1[3] * inv) << 32);
        *(unsigned long long*)(Ob + base + (size_t)iq * 256 + hi * 4) = oa;
        *(unsigned long long*)(Ob + base + (size_t)iq * 256 + 16 + hi * 4) = ob2;
    }
}

// ---------------------------------------------------------------------------
extern "C" void kernel_launch(void* const* d_in, const int* in_sizes, int n_in,
                              void* d_out, int out_size, void* d_ws, size_t ws_size,
                              hipStream_t stream) {
    const float* x         = (const float*)d_in[0];
    const float* c_local   = (const float*)d_in[1];
    const float* c_sink    = (const float*)d_in[2];
    const float* W_in      = (const float*)d_in[3];
    const float* b_in      = (const float*)d_in[4];
    const float* cls_token = (const float*)d_in[5];
    const float* pe_proj_W = (const float*)d_in[6];
    const float* pe_proj_b = (const float*)d_in[7];
    const float* pe_ln_g   = (const float*)d_in[8];
    const float* pe_ln_b   = (const float*)d_in[9];
    const float* pe_gain   = (const float*)d_in[10];
    const float* attn_Wqkv = (const float*)d_in[11];
    const float* attn_bqkv = (const float*)d_in[12];
    const float* attn_Wo   = (const float*)d_in[13];
    const float* attn_bo   = (const float*)d_in[14];
    const float* ff_W1     = (const float*)d_in[15];
    const float* ff_b1     = (const float*)d_in[16];
    const float* ff_W2     = (const float*)d_in[17];
    const float* ff_b2     = (const float*)d_in[18];
    const float* ln1_g     = (const float*)d_in[19];
    const float* ln1_b     = (const float*)d_in[20];
    const float* ln2_g     = (const float*)d_in[21];
    const float* ln2_b     = (const float*)d_in[22];
    const float* alpha     = (const float*)d_in[23];
    const float* beta      = (const float*)d_in[24];
    const float* corr_fl   = (const float*)d_in[25];
    const float* out_ln_g  = (const float*)d_in[26];
    const float* out_ln_b  = (const float*)d_in[27];
    const int*   lengths   = (const int*)d_in[28];
    float* out = (float*)d_out;

    // float region (same slots as round-11 passing layout)
    float* h     = (float*)d_ws;              // 4,194,304
    float* clb   = h + 4194304;               // 16384
    float* csfb  = clb + 16384;
    float* padfb = csfb + 16384;
    float* W20t  = padfb + 16384;             // 5120 (in old peWt slot)
    float* PEpos = W20t + 70656;              // 131072
    float* bbf   = PEpos + 131072;            // old 8,388,608-float region
    // bf16 region — weights AFTER the full 16,777,216-short f-span at Q_bf
    unsigned short* u_bf = (unsigned short*)(bbf + 8388608);
    unsigned short* xb_bf = u_bf;             // alias: xb dead before layer loop
    unsigned short* Q_bf = u_bf + 4194304;
    unsigned short* K_bf = Q_bf + 4194304;
    unsigned short* V_bf = K_bf + 4194304;
    unsigned short* f_bf = Q_bf;              // alias: spans Q..Q+16777216
    unsigned short* o_bf = u_bf;              // alias (lifetimes disjoint)
    unsigned short* wq_bf = Q_bf + 16777216;  // after f's span
    unsigned short* wo_bf = wq_bf + 589824;
    unsigned short* w1_bf = wo_bf + 196608;
    unsigned short* w2_bf = w1_bf + 786432;
    unsigned short* win_bf = w2_bf + 786432;  // 16384
    unsigned short* S_bf   = win_bf + 16384;  // 131072 (sinusoid table)
    unsigned short* w256_bf = S_bf + 131072;  // 65536

    setup_kernel<<<4708, 256, 0, stream>>>(
        attn_Wqkv, wq_bf, attn_Wo, wo_bf, ff_W1, w1_bf, ff_W2, w2_bf,
        W_in, win_bf, pe_proj_W, w256_bf, W20t, x, xb_bf, S_bf);
    gemm_bf16_kernel<<<dim3(4, 4), 256, 0, stream>>>(
        S_bf, w256_bf, pe_proj_b, PEpos, 512, 256, 256);
    gemm_bf16_kernel<<<dim3(4, 128), 256, 0, stream>>>(
        xb_bf, win_bf, b_in, bbf, 16384, 256, 64);
    prep_lite_kernel<<<2048, 256, 0, stream>>>(
        c_local, c_sink, bbf, cls_token, PEpos, W20t,
        pe_ln_g, pe_ln_b, pe_gain, corr_fl, lengths, ln1_g, ln1_b,
        h, clb, csfb, padfb, u_bf);

    for (int l = 0; l < 3; ++l) {
        gemm128_kernel<0><<<dim3(6, 128), 256, 0, stream>>>(
            u_bf, wq_bf + (size_t)l * 196608, attn_bqkv + 768 * l,
            Q_bf, K_bf, V_bf, 16384, 768, 256);
        attn_mfma_kernel<<<2048, 256, 0, stream>>>(Q_bf, K_bf, V_bf, clb, csfb,
                                                   padfb, alpha, beta, o_bf);
        gemm_res_ln_kernel<0><<<256, 512, 0, stream>>>(
            o_bf, wo_bf + (size_t)l * 65536, attn_bo + 256 * l, h,
            ln2_g + 256 * l, ln2_b + 256 * l, u_bf, nullptr, 256);
        gemm128_kernel<2><<<dim3(8, 128), 256, 0, stream>>>(
            u_bf, w1_bf + (size_t)l * 262144, ff_b1 + 1024 * l,
            f_bf, nullptr, nullptr, 16384, 1024, 256);
        if (l < 2) {
            gemm_res_ln_kernel<0><<<256, 512, 0, stream>>>(
                f_bf, w2_bf + (size_t)l * 262144, ff_b2 + 256 * l, h,
                ln1_g + 256 * (l + 1), ln1_b + 256 * (l + 1), u_bf, nullptr, 1024);
        } else {
            gemm_res_ln_kernel<1><<<256, 512, 0, stream>>>(
                f_bf, w2_bf + (size_t)l * 262144, ff_b2 + 256 * l, h,
                out_ln_g, out_ln_b, nullptr, out, 1024);
        }
    }
}

// Round 13
// 422.594 us; speedup vs baseline: 52.0802x; 1.0629x over previous
//
#include <hip/hip_runtime.h>
#include <math.h>

// B=32, L=512 (incl CLS), D=256, H=8, dh=32, N_LAYERS=3, D_FF=1024, tokens=16384

typedef __attribute__((ext_vector_type(4))) float f32x4;
typedef __attribute__((ext_vector_type(8))) short bf16x8;

__device__ __forceinline__ unsigned short f2bf(float f) {
    unsigned u = __builtin_bit_cast(unsigned, f);
    u += 0x7fff + ((u >> 16) & 1);
    return (unsigned short)(u >> 16);
}
__device__ __forceinline__ unsigned cvt_pk_bf16(float a, float b) {
    unsigned r;
    asm("v_cvt_pk_bf16_f32 %0, %1, %2" : "=v"(r) : "v"(a), "v"(b));
    return r;
}
__device__ __forceinline__ float gelu_f(float v) {
    return v * 0.5f * (1.0f + erff(v * 0.70710678118654752f));
}
__device__ __forceinline__ void gload16(const void* g, void* l) {
    __builtin_amdgcn_global_load_lds(
        (const __attribute__((address_space(1))) unsigned int*)g,
        (__attribute__((address_space(3))) unsigned int*)l, 16, 0, 0);
}

// ---------------------------------------------------------------------------
// Mega setup kernel: all weight cvts + pe transposes + sinusoid + xb.
__global__ __launch_bounds__(256) void setup_kernel(
    const float* __restrict__ wq, unsigned short* __restrict__ wq_o,   // 576
    const float* __restrict__ wo, unsigned short* __restrict__ wo_o,   // 192
    const float* __restrict__ w1, unsigned short* __restrict__ w1_o,   // 768
    const float* __restrict__ w2, unsigned short* __restrict__ w2_o,   // 768
    const float* __restrict__ win, unsigned short* __restrict__ win_o, // 16
    const float* __restrict__ peW, unsigned short* __restrict__ w256,  // 64
    float* __restrict__ W20t,                                          // 20
    const float* __restrict__ x, unsigned short* __restrict__ xb,      // 2048
    unsigned short* __restrict__ S)                                    // 256
{
    int blk = blockIdx.x, t = threadIdx.x;
    if (blk < 2304) {  // plain f32->bf16 cvts
        const float* s; unsigned short* d; int base;
        if (blk < 576)       { s = wq; d = wq_o; base = blk; }
        else if (blk < 768)  { s = wo; d = wo_o; base = blk - 576; }
        else if (blk < 1536) { s = w1; d = w1_o; base = blk - 768; }
        else                 { s = w2; d = w2_o; base = blk - 1536; }
        int i = (base * 256 + t) * 4;
        float4 v = *(const float4*)(s + i);
        unsigned long long pk = (unsigned long long)f2bf(v.x)
            | ((unsigned long long)f2bf(v.y) << 16)
            | ((unsigned long long)f2bf(v.z) << 32)
            | ((unsigned long long)f2bf(v.w) << 48);
        *(unsigned long long*)(d + i) = pk;
    } else if (blk < 2320) {  // win
        int i = ((blk - 2304) * 256 + t) * 4;
        float4 v = *(const float4*)(win + i);
        unsigned long long pk = (unsigned long long)f2bf(v.x)
            | ((unsigned long long)f2bf(v.y) << 16)
            | ((unsigned long long)f2bf(v.z) << 32)
            | ((unsigned long long)f2bf(v.w) << 48);
        *(unsigned long long*)(win_o + i) = pk;
    } else if (blk < 2384) {  // peW first-256 feats -> bf16 [256][256]
        int i = ((blk - 2320) * 256 + t) * 4;
        int d = i >> 8, f = i & 255;
        float4 v = *(const float4*)(peW + d * 276 + f);
        unsigned long long pk = (unsigned long long)f2bf(v.x)
            | ((unsigned long long)f2bf(v.y) << 16)
            | ((unsigned long long)f2bf(v.z) << 32)
            | ((unsigned long long)f2bf(v.w) << 48);
        *(unsigned long long*)(w256 + i) = pk;
    } else if (blk < 2404) {  // W20t[f][d] = peW[d][256+f]
        int j = (blk - 2384) * 256 + t;
        int f = j >> 8, dd = j & 255;
        W20t[j] = peW[dd * 276 + 256 + f];
    } else if (blk < 4452) {  // xb
        int idx = (blk - 2404) * 256 + t;
        int tok = idx >> 5, c2 = idx & 31;
        int b = tok >> 9, l = tok & 511;
        unsigned r = 0;
        if (l > 0) {
            float2 v = *(const float2*)(x + ((size_t)b * 511 + l - 1) * 64 + 2 * c2);
            r = cvt_pk_bf16(v.x, v.y);
        }
        *(unsigned*)(xb + (size_t)tok * 64 + 2 * c2) = r;
    } else {  // sinusoid table
        int p = (blk - 4452) * 256 + t;
        int l = p >> 7, k = p & 127;
        float div = expf((float)(2 * k) * -0.035977892078032f);
        float a = (float)l * div;
        *(unsigned*)(S + l * 256 + 2 * k) = cvt_pk_bf16(sinf(a), cosf(a));
    }
}

// ---------------------------------------------------------------------------
// prep_lite: h = base + mask*gain*LN(PEpos + feats@W20); u = LN_l0(h); arrays.
__global__ __launch_bounds__(256) void prep_lite_kernel(
    const float* __restrict__ c_local, const float* __restrict__ c_sink,
    const float* __restrict__ bb, const float* __restrict__ cls_tok,
    const float* __restrict__ PEpos, const float* __restrict__ W20t,
    const float* __restrict__ pe_g, const float* __restrict__ pe_bb,
    const float* __restrict__ pe_gain_p, const float* __restrict__ corr_floor_p,
    const int* __restrict__ lengths, const float* __restrict__ ln1g,
    const float* __restrict__ ln1b,
    float* __restrict__ h, float* __restrict__ clb, float* __restrict__ csfb,
    float* __restrict__ padfb, unsigned short* __restrict__ u)
{
    __shared__ float zs[8][20];
    __shared__ __align__(16) float pes[8][256];
    __shared__ float mn[8], rsd[8];
    const int t = threadIdx.x;
    const int tok0 = blockIdx.x * 8;
    const int b = tok0 >> 9;
    const int len_b = lengths[b];
    const float cf = *corr_floor_p;
    const float gain = *pe_gain_p;

    float clv[8], csv[8];
    bool mk[8];
#pragma unroll
    for (int k = 0; k < 8; ++k) {
        int l = (tok0 + k) & 511;
        if (l == 0) { clv[k] = 1.f; csv[k] = 1.f; mk[k] = false; }
        else {
            float a = c_local[b * 511 + l - 1];
            float s = c_sink[b * 511 + l - 1];
            clv[k] = fminf(fmaxf(a, 0.f), 1.f);
            csv[k] = fminf(fmaxf(s, 0.f), 1.f);
            mk[k] = (l - 1) >= len_b;
        }
    }
    if (t < 8) {
        int tok = tok0 + t;
        clb[tok] = clv[t];
        csfb[tok] = cf + (1.f - cf) * csv[t];
        padfb[tok] = mk[t] ? 1.f : 0.f;
    }
    if (t < 20) {
#pragma unroll
        for (int k = 0; k < 8; ++k) {
            float cl = clv[k], cs = csv[k];
            float v;
            if (t == 0) v = cl;
            else if (t == 1) v = cs;
            else if (t == 2) v = cl * cs;
            else if (t == 3) v = fabsf(cl - cs);
            else if (t < 12) {
                float c = (float)(t - 4) * (1.f / 7.f);
                float dd = (cl - c) / 0.200001f;
                v = expf(-0.5f * dd * dd);
            } else {
                float c = (float)(t - 12) * (1.f / 7.f);
                float dd = (cs - c) / 0.200001f;
                v = expf(-0.5f * dd * dd);
            }
            zs[k][t] = v;
        }
    }
    __syncthreads();

    float acc[8];
#pragma unroll
    for (int k = 0; k < 8; ++k)
        acc[k] = PEpos[((tok0 + k) & 511) * 256 + t];
    for (int f = 0; f < 20; ++f) {
        float wv = W20t[f * 256 + t];
#pragma unroll
        for (int k = 0; k < 8; ++k) acc[k] += zs[k][f] * wv;
    }
#pragma unroll
    for (int k = 0; k < 8; ++k) pes[k][t] = acc[k];
    __syncthreads();

    {
        int w = t >> 6, lane = t & 63;
#pragma unroll
        for (int p = 0; p < 2; ++p) {
            int k = w + p * 4;
            float4 v = *(const float4*)&pes[k][lane * 4];
            float s = v.x + v.y + v.z + v.w;
            float sq = v.x * v.x + v.y * v.y + v.z * v.z + v.w * v.w;
#pragma unroll
            for (int off = 32; off; off >>= 1) {
                s += __shfl_xor(s, off);
                sq += __shfl_xor(sq, off);
            }
            if (lane == 0) {
                float mean = s * (1.f / 256.f);
                mn[k] = mean;
                rsd[k] = rsqrtf(sq * (1.f / 256.f) - mean * mean + 1e-5f);
            }
        }
    }
    __syncthreads();
    float gv = pe_g[t], bv = pe_bb[t];
    float hv[8];
#pragma unroll
    for (int k = 0; k < 8; ++k) {
        int l = (tok0 + k) & 511;
        float base = (l == 0) ? cls_tok[t] : bb[(size_t)(tok0 + k) * 256 + t];
        float pe = (pes[k][t] - mn[k]) * rsd[k] * gv + bv;
        pe *= gain;
        if (mk[k]) pe = 0.f;
        hv[k] = base + pe;
        h[(size_t)(tok0 + k) * 256 + t] = hv[k];
    }
    __syncthreads();
#pragma unroll
    for (int k = 0; k < 8; ++k) pes[k][t] = hv[k];
    __syncthreads();
    {
        int w = t >> 6, lane = t & 63;
#pragma unroll
        for (int p = 0; p < 2; ++p) {
            int k = w + p * 4;
            float4 v = *(const float4*)&pes[k][lane * 4];
            float s = v.x + v.y + v.z + v.w;
            float sq = v.x * v.x + v.y * v.y + v.z * v.z + v.w * v.w;
#pragma unroll
            for (int off = 32; off; off >>= 1) {
                s += __shfl_xor(s, off);
                sq += __shfl_xor(sq, off);
            }
            if (lane == 0) {
                float mean = s * (1.f / 256.f);
                mn[k] = mean;
                rsd[k] = rsqrtf(sq * (1.f / 256.f) - mean * mean + 1e-5f);
            }
        }
    }
    __syncthreads();
    float g1 = ln1g[t], b1 = ln1b[t];
#pragma unroll
    for (int k = 0; k < 8; ++k)
        u[(size_t)(tok0 + k) * 256 + t] = f2bf((hv[k] - mn[k]) * rsd[k] * g1 + b1);
}

// ---------------------------------------------------------------------------
// bf16 MFMA GEMM, 128x64 tile (proven): C[M,N] = A @ W^T + bias (f32 store)
__global__ __launch_bounds__(256) void gemm_bf16_kernel(
    const unsigned short* __restrict__ A, const unsigned short* __restrict__ W,
    const float* __restrict__ bias, float* __restrict__ hres, int M, int N, int K)
{
    __shared__ __align__(16) unsigned short As[128 * 64];
    __shared__ __align__(16) unsigned short Bs[64 * 64];
    const int t = threadIdx.x;
    const int wid = t >> 6, lane = t & 63;
    const int lo = lane & 15, hi = lane >> 4;
    const int wm = wid >> 1, wn = wid & 1;
    const int m0 = blockIdx.y * 128, n0 = blockIdx.x * 64;
    const int lrow = lane >> 3, lc = lane & 7;
    f32x4 acc[4][2] = {};
    for (int k0 = 0; k0 < K; k0 += 64) {
        __syncthreads();
#pragma unroll
        for (int is = 0; is < 4; ++is) {
            int r = wid * 32 + is * 8 + lrow;
            const unsigned short* g = A + (size_t)(m0 + r) * K + k0 + ((lc ^ (r & 7)) * 8);
            gload16(g, &As[(wid * 32 + is * 8) * 64]);
        }
#pragma unroll
        for (int is = 0; is < 2; ++is) {
            int r = wid * 16 + is * 8 + lrow;
            const unsigned short* g = W + (size_t)(n0 + r) * K + k0 + ((lc ^ (r & 7)) * 8);
            gload16(g, &Bs[(wid * 16 + is * 8) * 64]);
        }
        __syncthreads();
#pragma unroll
        for (int kh = 0; kh < 2; ++kh) {
            bf16x8 bfr[2];
#pragma unroll
            for (int nf = 0; nf < 2; ++nf) {
                int r = wn * 32 + nf * 16 + lo;
                bfr[nf] = *(const bf16x8*)&Bs[r * 64 + (((kh * 4 + hi) ^ (r & 7)) * 8)];
            }
#pragma unroll
            for (int mf = 0; mf < 4; ++mf) {
                int r = wm * 64 + mf * 16 + lo;
                bf16x8 afr = *(const bf16x8*)&As[r * 64 + (((kh * 4 + hi) ^ (r & 7)) * 8)];
                acc[mf][0] = __builtin_amdgcn_mfma_f32_16x16x32_bf16(afr, bfr[0], acc[mf][0], 0, 0, 0);
                acc[mf][1] = __builtin_amdgcn_mfma_f32_16x16x32_bf16(afr, bfr[1], acc[mf][1], 0, 0, 0);
            }
        }
    }
#pragma unroll
    for (int mf = 0; mf < 4; ++mf) {
        const int mbase = m0 + wm * 64 + mf * 16 + hi * 4;
#pragma unroll
        for (int nf = 0; nf < 2; ++nf) {
            const int n = n0 + wn * 32 + nf * 16 + lo;
            const float bv = bias[n];
            f32x4 v = acc[mf][nf];
#pragma unroll
            for (int rg = 0; rg < 4; ++rg)
                hres[(size_t)(mbase + rg) * N + n] = v[rg] + bv;
        }
    }
}

// ---------------------------------------------------------------------------
// bf16 MFMA GEMM, 128x128 tile: QKV (EPI=0), FF1 GELU (EPI=2)
template <int EPI>
__global__ __launch_bounds__(256) void gemm128_kernel(
    const unsigned short* __restrict__ A, const unsigned short* __restrict__ W,
    const float* __restrict__ bias,
    unsigned short* __restrict__ o0, unsigned short* __restrict__ o1,
    unsigned short* __restrict__ o2, int M, int N, int K)
{
    __shared__ __align__(16) unsigned short As[128 * 64];
    __shared__ __align__(16) unsigned short Bs[128 * 64];
    const int t = threadIdx.x;
    const int wid = t >> 6, lane = t & 63;
    const int lo = lane & 15, hi = lane >> 4;
    const int wm = wid >> 1, wn = wid & 1;
    const int m0 = blockIdx.y * 128, n0 = blockIdx.x * 128;
    const int lrow = lane >> 3, lc = lane & 7;
    f32x4 acc[4][4] = {};
    for (int k0 = 0; k0 < K; k0 += 64) {
        __syncthreads();
#pragma unroll
        for (int is = 0; is < 4; ++is) {
            int r = wid * 32 + is * 8 + lrow;
            const unsigned short* g = A + (size_t)(m0 + r) * K + k0 + ((lc ^ (r & 7)) * 8);
            gload16(g, &As[(wid * 32 + is * 8) * 64]);
        }
#pragma unroll
        for (int is = 0; is < 4; ++is) {
            int r = wid * 32 + is * 8 + lrow;
            const unsigned short* g = W + (size_t)(n0 + r) * K + k0 + ((lc ^ (r & 7)) * 8);
            gload16(g, &Bs[(wid * 32 + is * 8) * 64]);
        }
        __syncthreads();
#pragma unroll
        for (int kh = 0; kh < 2; ++kh) {
            bf16x8 bfr[4];
#pragma unroll
            for (int nf = 0; nf < 4; ++nf) {
                int r = wn * 64 + nf * 16 + lo;
                bfr[nf] = *(const bf16x8*)&Bs[r * 64 + (((kh * 4 + hi) ^ (r & 7)) * 8)];
            }
#pragma unroll
            for (int mf = 0; mf < 4; ++mf) {
                int r = wm * 64 + mf * 16 + lo;
                bf16x8 afr = *(const bf16x8*)&As[r * 64 + (((kh * 4 + hi) ^ (r & 7)) * 8)];
#pragma unroll
                for (int nf = 0; nf < 4; ++nf)
                    acc[mf][nf] = __builtin_amdgcn_mfma_f32_16x16x32_bf16(afr, bfr[nf], acc[mf][nf], 0, 0, 0);
            }
        }
    }
#pragma unroll
    for (int mf = 0; mf < 4; ++mf) {
        const int mbase = m0 + wm * 64 + mf * 16 + hi * 4;
#pragma unroll
        for (int nf = 0; nf < 4; ++nf) {
            const int n = n0 + wn * 64 + nf * 16 + lo;
            const float bv = bias[n];
            f32x4 v = acc[mf][nf];
            if constexpr (EPI == 0) {
                unsigned short* dst = (n < 256) ? o0 : ((n < 512) ? o1 : o2);
                const float qsc = (n < 256)
                    ? (0.17677669529663687f * 1.4426950408889634f) : 1.f;
                const int c = n & 255;
#pragma unroll
                for (int rg = 0; rg < 4; ++rg)
                    dst[(size_t)(mbase + rg) * 256 + c] = f2bf((v[rg] + bv) * qsc);
            } else {
#pragma unroll
                for (int rg = 0; rg < 4; ++rg)
                    o0[(size_t)(mbase + rg) * N + n] = f2bf(gelu_f(v[rg] + bv));
            }
        }
    }
}

// ---------------------------------------------------------------------------
// Fused residual-GEMM + LayerNorm v2: 32x256 tile (grid 512 = 2 blocks/CU),
// 512 threads, 8 waves (2 wm x 4 wn, each 16x64). Same staging/LN math as the
// proven 64-row version; only the M-tiling changed.
// OUT=0: h += GEMM; u = LN(h).  OUT=1: final FF2 -> out-LN CLS rows only.
template <int OUT>
__global__ __launch_bounds__(512) void gemm_res_ln_kernel(
    const unsigned short* __restrict__ A, const unsigned short* __restrict__ W,
    const float* __restrict__ bias, float* __restrict__ hres,
    const float* __restrict__ g, const float* __restrict__ bvec,
    unsigned short* __restrict__ u, float* __restrict__ outp, int K)
{
    __shared__ __align__(16) unsigned short As[32 * 64];
    __shared__ __align__(16) unsigned short Bs[256 * 64];
    __shared__ float red[32][4][2];
    const int t = threadIdx.x;
    const int wid = t >> 6, lane = t & 63;
    const int lo = lane & 15, hi = lane >> 4;
    const int wm = wid >> 2, wn = wid & 3;
    const int m0 = blockIdx.x * 32;
    const int lrow = lane >> 3, lc = lane & 7;
    f32x4 acc[4] = {};
    for (int k0 = 0; k0 < K; k0 += 64) {
        __syncthreads();
        if (wid < 4) {
            int r = wid * 8 + lrow;
            gload16(A + (size_t)(m0 + r) * K + k0 + ((lc ^ (r & 7)) * 8),
                    &As[(wid * 8) * 64]);
        }
#pragma unroll
        for (int is = 0; is < 4; ++is) {
            int r = wid * 32 + is * 8 + lrow;
            gload16(W + (size_t)r * K + k0 + ((lc ^ (r & 7)) * 8),
                    &Bs[(wid * 32 + is * 8) * 64]);
        }
        __syncthreads();
#pragma unroll
        for (int kh = 0; kh < 2; ++kh) {
            bf16x8 bfr[4];
#pragma unroll
            for (int nf = 0; nf < 4; ++nf) {
                int r = wn * 64 + nf * 16 + lo;
                bfr[nf] = *(const bf16x8*)&Bs[r * 64 + (((kh * 4 + hi) ^ (r & 7)) * 8)];
            }
            {
                int r = wm * 16 + lo;
                bf16x8 afr = *(const bf16x8*)&As[r * 64 + (((kh * 4 + hi) ^ (r & 7)) * 8)];
#pragma unroll
                for (int nf = 0; nf < 4; ++nf)
                    acc[nf] = __builtin_amdgcn_mfma_f32_16x16x32_bf16(afr, bfr[nf], acc[nf], 0, 0, 0);
            }
        }
    }
#pragma unroll
    for (int nf = 0; nf < 4; ++nf) {
        const int n = wn * 64 + nf * 16 + lo;
        const float bv = bias[n];
        const int rbase = m0 + wm * 16 + hi * 4;
#pragma unroll
        for (int rg = 0; rg < 4; ++rg) {
            size_t idx = (size_t)(rbase + rg) * 256 + n;
            float hv = acc[nf][rg] + bv + hres[idx];
            if constexpr (OUT == 0) hres[idx] = hv;
            acc[nf][rg] = hv;
        }
    }
#pragma unroll
    for (int rg = 0; rg < 4; ++rg) {
        float s = ((acc[0][rg] + acc[1][rg]) + (acc[2][rg] + acc[3][rg]));
        float sq = ((acc[0][rg] * acc[0][rg] + acc[1][rg] * acc[1][rg]) +
                    (acc[2][rg] * acc[2][rg] + acc[3][rg] * acc[3][rg]));
#pragma unroll
        for (int off = 1; off < 16; off <<= 1) {
            s += __shfl_xor(s, off);
            sq += __shfl_xor(sq, off);
        }
        if (lo == 0) {
            int rl = wm * 16 + hi * 4 + rg;
            red[rl][wn][0] = s;
            red[rl][wn][1] = sq;
        }
    }
    __syncthreads();
#pragma unroll
    for (int rg = 0; rg < 4; ++rg) {
        const int rl = wm * 16 + hi * 4 + rg;
        float s = (red[rl][0][0] + red[rl][1][0]) + (red[rl][2][0] + red[rl][3][0]);
        float sq = (red[rl][0][1] + red[rl][1][1]) + (red[rl][2][1] + red[rl][3][1]);
        float mean = s * (1.f / 256.f);
        float rs = rsqrtf(sq * (1.f / 256.f) - mean * mean + 1e-5f);
        if constexpr (OUT == 1) {
            const int row = m0 + rl;
            if ((row & 511) == 0) {
#pragma unroll
                for (int nf = 0; nf < 4; ++nf) {
                    const int n = wn * 64 + nf * 16 + lo;
                    outp[(size_t)(row >> 9) * 256 + n] =
                        (acc[nf][rg] - mean) * rs * g[n] + bvec[n];
                }
            }
        } else {
#pragma unroll
            for (int nf = 0; nf < 4; ++nf) {
                const int n = wn * 64 + nf * 16 + lo;
                u[(size_t)(m0 + rl) * 256 + n] =
                    f2bf((acc[nf][rg] - mean) * rs * g[n] + bvec[n]);
            }
        }
    }
}

// ---------------------------------------------------------------------------
// MFMA flash attention v8 (proven round-12): v_perm V-transpose staging.
__global__ __launch_bounds__(256) void attn_mfma_kernel(
    const unsigned short* __restrict__ Qb, const unsigned short* __restrict__ Kb,
    const unsigned short* __restrict__ Vb, const float* __restrict__ clb,
    const float* __restrict__ csfb, const float* __restrict__ padfb,
    const float* __restrict__ alpha_p, const float* __restrict__ beta_p,
    unsigned short* __restrict__ Ob)
{
    __shared__ __align__(16) unsigned short Kl[128 * 40];   // 10240 B
    __shared__ __align__(16) unsigned short Vt[32 * 132];   // 8448 B
    __shared__ __align__(16) float csfj[128];               // 512 B
    const int t = threadIdx.x;
    const int swz = ((blockIdx.x & 7) << 8) | (blockIdx.x >> 3);  // XCD chunking
    const int bh = swz >> 3, hf = swz & 7;
    const int b = bh >> 3, hd = bh & 7;
    const size_t base = ((size_t)b * 512) * 256 + hd * 32;
    const int w = t >> 6, lane = t & 63, lo = lane & 15, hi = lane >> 4;
    const float L2E = 1.4426950408889634f;
    const float kb = L2E * (*beta_p);
    const float ka = L2E * (*alpha_p);
    const float* clg = clb + b * 512;

    const int i0 = (hf * 4 + w) * 16;
    const int iq = i0 + lo;
    const bf16x8 qf = *(const bf16x8*)(Qb + base + (size_t)iq * 256 + hi * 8);
    const float csb = fmaxf(kb * csfb[b * 512 + iq], 1e-3f);
    f32x4 acc0 = {0.f, 0.f, 0.f, 0.f}, acc1 = {0.f, 0.f, 0.f, 0.f};
    float lsum = 0.f;

    for (int jt = 0; jt < 4; ++jt) {
        __syncthreads();
        for (int idx = t; idx < 512; idx += 256) {       // K tile: 128 rows
            int row = idx >> 2, c4 = idx & 3;
            *(uint4*)&Kl[row * 40 + c4 * 8] =
                *(const uint4*)(Kb + base + (size_t)(jt * 128 + row) * 256 + c4 * 8);
        }
        for (int idx = t; idx < 512; idx += 256) {       // V^T via v_perm
            int pr = idx & 63, c4 = idx >> 6;
            const unsigned* vp0 = (const unsigned*)
                (Vb + base + (size_t)(jt * 128 + 2 * pr) * 256 + c4 * 4);
            const unsigned* vp1 = (const unsigned*)
                (Vb + base + (size_t)(jt * 128 + 2 * pr + 1) * 256 + c4 * 4);
            unsigned v0lo = vp0[0], v0hi = vp0[1];
            unsigned v1lo = vp1[0], v1hi = vp1[1];
            *(unsigned*)&Vt[(c4 * 4 + 0) * 132 + 2 * pr] =
                __builtin_amdgcn_perm(v1lo, v0lo, 0x05040100u);
            *(unsigned*)&Vt[(c4 * 4 + 1) * 132 + 2 * pr] =
                __builtin_amdgcn_perm(v1lo, v0lo, 0x07060302u);
            *(unsigned*)&Vt[(c4 * 4 + 2) * 132 + 2 * pr] =
                __builtin_amdgcn_perm(v1hi, v0hi, 0x05040100u);
            *(unsigned*)&Vt[(c4 * 4 + 3) * 132 + 2 * pr] =
                __builtin_amdgcn_perm(v1hi, v0hi, 0x07060302u);
        }
        if (t < 128) {                                   // csf with pad folded
            int j = jt * 128 + t;
            float cv = csfb[b * 512 + j];
            csfj[t] = (padfb[b * 512 + j] > 0.5f) ? -100000.f : cv;
        }
        __syncthreads();
#pragma unroll
        for (int ktp = 0; ktp < 4; ++ktp) {
            const int k16 = ktp * 32;             // local j base
            const int gj = jt * 128 + k16;        // global j base
            bf16x8 kf0 = *(const bf16x8*)&Kl[(k16 + lo) * 40 + hi * 8];
            bf16x8 kf1 = *(const bf16x8*)&Kl[(k16 + 16 + lo) * 40 + hi * 8];
            union U16 { unsigned long long q[2]; unsigned wd[4]; bf16x8 v; } vu0, vu1, pu;
            vu0.q[0] = *(const unsigned long long*)&Vt[lo * 132 + k16 + hi * 4];
            vu0.q[1] = *(const unsigned long long*)&Vt[lo * 132 + k16 + 16 + hi * 4];
            vu1.q[0] = *(const unsigned long long*)&Vt[(16 + lo) * 132 + k16 + hi * 4];
            vu1.q[1] = *(const unsigned long long*)&Vt[(16 + lo) * 132 + k16 + 16 + hi * 4];
            f32x4 csf0 = *(const f32x4*)&csfj[k16 + hi * 4];
            f32x4 csf1 = *(const f32x4*)&csfj[k16 + 16 + hi * 4];
            f32x4 c0, c1;
#pragma unroll
            for (int e = 0; e < 4; ++e) {
                c0[e] = csb * csf0[e];
                c1[e] = csb * csf1[e];
            }
            f32x4 s0 = __builtin_amdgcn_mfma_f32_16x16x32_bf16(kf0, qf, c0, 0, 0, 0);
            f32x4 s1 = __builtin_amdgcn_mfma_f32_16x16x32_bf16(kf1, qf, c1, 0, 0, 0);
            float p[8];
#pragma unroll
            for (int r = 0; r < 4; ++r) p[r] = exp2f(s0[r]);
#pragma unroll
            for (int r = 0; r < 4; ++r) p[4 + r] = exp2f(s1[r]);
            if (gj <= i0 + 16 && gj + 32 >= i0) {
#pragma unroll
                for (int r = 0; r < 8; ++r) {
                    int jr = gj + ((r & 4) ? 16 : 0) + hi * 4 + (r & 3);
                    int dij = jr - iq;
                    if (dij == 1 || dij == -1) {
                        float ce = (jr >= 1 && iq <= 510) ? clg[jr] : clg[iq];
                        p[r] *= exp2f(ka * ce);
                    }
                }
            }
            lsum += ((p[0] + p[1]) + (p[2] + p[3])) + ((p[4] + p[5]) + (p[6] + p[7]));
            pu.wd[0] = cvt_pk_bf16(p[0], p[1]);
            pu.wd[1] = cvt_pk_bf16(p[2], p[3]);
            pu.wd[2] = cvt_pk_bf16(p[4], p[5]);
            pu.wd[3] = cvt_pk_bf16(p[6], p[7]);
            acc0 = __builtin_amdgcn_mfma_f32_16x16x32_bf16(vu0.v, pu.v, acc0, 0, 0, 0);
            acc1 = __builtin_amdgcn_mfma_f32_16x16x32_bf16(vu1.v, pu.v, acc1, 0, 0, 0);
        }
    }
    {
        float ls = lsum;
        ls += __shfl_xor(ls, 16);
        ls += __shfl_xor(ls, 32);
        const float inv = 1.f / fmaxf(ls, 1e-35f);
        unsigned long long oa =
              (unsigned long long)cvt_pk_bf16(acc0[0] * inv, acc0[1] * inv)
            | ((unsigned long long)cvt_pk_bf16(acc0[2] * inv, acc0[3] * inv) << 32);
        unsigned long long ob2 =
              (unsigned long long)cvt_pk_bf16(acc1[0] * inv, acc1[1] * inv)
            | ((unsigned long long)cvt_pk_bf16(acc1[2] * inv, acc1[3] * inv) << 32);
        *(unsigned long long*)(Ob + base + (size_t)iq * 256 + hi * 4) = oa;
        *(unsigned long long*)(Ob + base + (size_t)iq * 256 + 16 + hi * 4) = ob2;
    }
}

// ---------------------------------------------------------------------------
extern "C" void kernel_launch(void* const* d_in, const int* in_sizes, int n_in,
                              void* d_out, int out_size, void* d_ws, size_t ws_size,
                              hipStream_t stream) {
    const float* x         = (const float*)d_in[0];
    const float* c_local   = (const float*)d_in[1];
    const float* c_sink    = (const float*)d_in[2];
    const float* W_in      = (const float*)d_in[3];
    const float* b_in      = (const float*)d_in[4];
    const float* cls_token = (const float*)d_in[5];
    const float* pe_proj_W = (const float*)d_in[6];
    const float* pe_proj_b = (const float*)d_in[7];
    const float* pe_ln_g   = (const float*)d_in[8];
    const float* pe_ln_b   = (const float*)d_in[9];
    const float* pe_gain   = (const float*)d_in[10];
    const float* attn_Wqkv = (const float*)d_in[11];
    const float* attn_bqkv = (const float*)d_in[12];
    const float* attn_Wo   = (const float*)d_in[13];
    const float* attn_bo   = (const float*)d_in[14];
    const float* ff_W1     = (const float*)d_in[15];
    const float* ff_b1     = (const float*)d_in[16];
    const float* ff_W2     = (const float*)d_in[17];
    const float* ff_b2     = (const float*)d_in[18];
    const float* ln1_g     = (const float*)d_in[19];
    const float* ln1_b     = (const float*)d_in[20];
    const float* ln2_g     = (const float*)d_in[21];
    const float* ln2_b     = (const float*)d_in[22];
    const float* alpha     = (const float*)d_in[23];
    const float* beta      = (const float*)d_in[24];
    const float* corr_fl   = (const float*)d_in[25];
    const float* out_ln_g  = (const float*)d_in[26];
    const float* out_ln_b  = (const float*)d_in[27];
    const int*   lengths   = (const int*)d_in[28];
    float* out = (float*)d_out;

    // float region (same slots as round-12 passing layout)
    float* h     = (float*)d_ws;              // 4,194,304
    float* clb   = h + 4194304;               // 16384
    float* csfb  = clb + 16384;
    float* padfb = csfb + 16384;
    float* W20t  = padfb + 16384;             // 5120 (in old peWt slot)
    float* PEpos = W20t + 70656;              // 131072
    float* bbf   = PEpos + 131072;            // old 8,388,608-float region
    // bf16 region — weights AFTER the full 16,777,216-short f-span at Q_bf
    unsigned short* u_bf = (unsigned short*)(bbf + 8388608);
    unsigned short* xb_bf = u_bf;             // alias: xb dead before layer loop
    unsigned short* Q_bf = u_bf + 4194304;
    unsigned short* K_bf = Q_bf + 4194304;
    unsigned short* V_bf = K_bf + 4194304;
    unsigned short* f_bf = Q_bf;              // alias: spans Q..Q+16777216
    unsigned short* o_bf = u_bf;              // alias (lifetimes disjoint)
    unsigned short* wq_bf = Q_bf + 16777216;  // after f's span
    unsigned short* wo_bf = wq_bf + 589824;
    unsigned short* w1_bf = wo_bf + 196608;
    unsigned short* w2_bf = w1_bf + 786432;
    unsigned short* win_bf = w2_bf + 786432;  // 16384
    unsigned short* S_bf   = win_bf + 16384;  // 131072 (sinusoid table)
    unsigned short* w256_bf = S_bf + 131072;  // 65536

    setup_kernel<<<4708, 256, 0, stream>>>(
        attn_Wqkv, wq_bf, attn_Wo, wo_bf, ff_W1, w1_bf, ff_W2, w2_bf,
        W_in, win_bf, pe_proj_W, w256_bf, W20t, x, xb_bf, S_bf);
    gemm_bf16_kernel<<<dim3(4, 4), 256, 0, stream>>>(
        S_bf, w256_bf, pe_proj_b, PEpos, 512, 256, 256);
    gemm_bf16_kernel<<<dim3(4, 128), 256, 0, stream>>>(
        xb_bf, win_bf, b_in, bbf, 16384, 256, 64);
    prep_lite_kernel<<<2048, 256, 0, stream>>>(
        c_local, c_sink, bbf, cls_token, PEpos, W20t,
        pe_ln_g, pe_ln_b, pe_gain, corr_fl, lengths, ln1_g, ln1_b,
        h, clb, csfb, padfb, u_bf);

    for (int l = 0; l < 3; ++l) {
        gemm128_kernel<0><<<dim3(6, 128), 256, 0, stream>>>(
            u_bf, wq_bf + (size_t)l * 196608, attn_bqkv + 768 * l,
            Q_bf, K_bf, V_bf, 16384, 768, 256);
        attn_mfma_kernel<<<2048, 256, 0, stream>>>(Q_bf, K_bf, V_bf, clb, csfb,
                                                   padfb, alpha, beta, o_bf);
        gemm_res_ln_kernel<0><<<512, 512, 0, stream>>>(
            o_bf, wo_bf + (size_t)l * 65536, attn_bo + 256 * l, h,
            ln2_g + 256 * l, ln2_b + 256 * l, u_bf, nullptr, 256);
        gemm128_kernel<2><<<dim3(8, 128), 256, 0, stream>>>(
            u_bf, w1_bf + (size_t)l * 262144, ff_b1 + 1024 * l,
            f_bf, nullptr, nullptr, 16384, 1024, 256);
        if (l < 2) {
            gemm_res_ln_kernel<0><<<512, 512, 0, stream>>>(
                f_bf, w2_bf + (size_t)l * 262144, ff_b2 + 256 * l, h,
                ln1_g + 256 * (l + 1), ln1_b + 256 * (l + 1), u_bf, nullptr, 1024);
        } else {
            gemm_res_ln_kernel<1><<<512, 512, 0, stream>>>(
                f_bf, w2_bf + (size_t)l * 262144, ff_b2 + 256 * l, h,
                out_ln_g, out_ln_b, nullptr, out, 1024);
        }
    }
}

// Round 14
// 385.143 us; speedup vs baseline: 57.1445x; 1.0972x over previous
//
#include <hip/hip_runtime.h>
#include <math.h>

// B=32, L=512 (incl CLS), D=256, H=8, dh=32, N_LAYERS=3, D_FF=1024, tokens=16384
// Length-aware: rows past lengths[b] are provably dead (CLS-only output,
// exactly-zero attention weights for padded columns) -> tiles skipped.

typedef __attribute__((ext_vector_type(4))) float f32x4;
typedef __attribute__((ext_vector_type(8))) short bf16x8;

__device__ __forceinline__ unsigned short f2bf(float f) {
    unsigned u = __builtin_bit_cast(unsigned, f);
    u += 0x7fff + ((u >> 16) & 1);
    return (unsigned short)(u >> 16);
}
__device__ __forceinline__ unsigned cvt_pk_bf16(float a, float b) {
    unsigned r;
    asm("v_cvt_pk_bf16_f32 %0, %1, %2" : "=v"(r) : "v"(a), "v"(b));
    return r;
}
__device__ __forceinline__ float gelu_f(float v) {
    return v * 0.5f * (1.0f + erff(v * 0.70710678118654752f));
}
__device__ __forceinline__ void gload16(const void* g, void* l) {
    __builtin_amdgcn_global_load_lds(
        (const __attribute__((address_space(1))) unsigned int*)g,
        (__attribute__((address_space(3))) unsigned int*)l, 16, 0, 0);
}

// ---------------------------------------------------------------------------
// Mega setup kernel: all weight cvts + pe transposes + sinusoid + xb.
__global__ __launch_bounds__(256) void setup_kernel(
    const float* __restrict__ wq, unsigned short* __restrict__ wq_o,   // 576
    const float* __restrict__ wo, unsigned short* __restrict__ wo_o,   // 192
    const float* __restrict__ w1, unsigned short* __restrict__ w1_o,   // 768
    const float* __restrict__ w2, unsigned short* __restrict__ w2_o,   // 768
    const float* __restrict__ win, unsigned short* __restrict__ win_o, // 16
    const float* __restrict__ peW, unsigned short* __restrict__ w256,  // 64
    float* __restrict__ W20t,                                          // 20
    const float* __restrict__ x, unsigned short* __restrict__ xb,      // 2048
    unsigned short* __restrict__ S)                                    // 256
{
    int blk = blockIdx.x, t = threadIdx.x;
    if (blk < 2304) {  // plain f32->bf16 cvts
        const float* s; unsigned short* d; int base;
        if (blk < 576)       { s = wq; d = wq_o; base = blk; }
        else if (blk < 768)  { s = wo; d = wo_o; base = blk - 576; }
        else if (blk < 1536) { s = w1; d = w1_o; base = blk - 768; }
        else                 { s = w2; d = w2_o; base = blk - 1536; }
        int i = (base * 256 + t) * 4;
        float4 v = *(const float4*)(s + i);
        unsigned long long pk = (unsigned long long)f2bf(v.x)
            | ((unsigned long long)f2bf(v.y) << 16)
            | ((unsigned long long)f2bf(v.z) << 32)
            | ((unsigned long long)f2bf(v.w) << 48);
        *(unsigned long long*)(d + i) = pk;
    } else if (blk < 2320) {  // win
        int i = ((blk - 2304) * 256 + t) * 4;
        float4 v = *(const float4*)(win + i);
        unsigned long long pk = (unsigned long long)f2bf(v.x)
            | ((unsigned long long)f2bf(v.y) << 16)
            | ((unsigned long long)f2bf(v.z) << 32)
            | ((unsigned long long)f2bf(v.w) << 48);
        *(unsigned long long*)(win_o + i) = pk;
    } else if (blk < 2384) {  // peW first-256 feats -> bf16 [256][256]
        int i = ((blk - 2320) * 256 + t) * 4;
        int d = i >> 8, f = i & 255;
        float4 v = *(const float4*)(peW + d * 276 + f);
        unsigned long long pk = (unsigned long long)f2bf(v.x)
            | ((unsigned long long)f2bf(v.y) << 16)
            | ((unsigned long long)f2bf(v.z) << 32)
            | ((unsigned long long)f2bf(v.w) << 48);
        *(unsigned long long*)(w256 + i) = pk;
    } else if (blk < 2404) {  // W20t[f][d] = peW[d][256+f]
        int j = (blk - 2384) * 256 + t;
        int f = j >> 8, dd = j & 255;
        W20t[j] = peW[dd * 276 + 256 + f];
    } else if (blk < 4452) {  // xb
        int idx = (blk - 2404) * 256 + t;
        int tok = idx >> 5, c2 = idx & 31;
        int b = tok >> 9, l = tok & 511;
        unsigned r = 0;
        if (l > 0) {
            float2 v = *(const float2*)(x + ((size_t)b * 511 + l - 1) * 64 + 2 * c2);
            r = cvt_pk_bf16(v.x, v.y);
        }
        *(unsigned*)(xb + (size_t)tok * 64 + 2 * c2) = r;
    } else {  // sinusoid table
        int p = (blk - 4452) * 256 + t;
        int l = p >> 7, k = p & 127;
        float div = expf((float)(2 * k) * -0.035977892078032f);
        float a = (float)l * div;
        *(unsigned*)(S + l * 256 + 2 * k) = cvt_pk_bf16(sinf(a), cosf(a));
    }
}

// ---------------------------------------------------------------------------
// prep_lite: h = base + mask*gain*LN(PEpos + feats@W20); u = LN_l0(h); arrays.
__global__ __launch_bounds__(256) void prep_lite_kernel(
    const float* __restrict__ c_local, const float* __restrict__ c_sink,
    const float* __restrict__ bb, const float* __restrict__ cls_tok,
    const float* __restrict__ PEpos, const float* __restrict__ W20t,
    const float* __restrict__ pe_g, const float* __restrict__ pe_bb,
    const float* __restrict__ pe_gain_p, const float* __restrict__ corr_floor_p,
    const int* __restrict__ lengths, const float* __restrict__ ln1g,
    const float* __restrict__ ln1b,
    float* __restrict__ h, float* __restrict__ clb, float* __restrict__ csfb,
    float* __restrict__ padfb, unsigned short* __restrict__ u)
{
    __shared__ float zs[8][20];
    __shared__ __align__(16) float pes[8][256];
    __shared__ float mn[8], rsd[8];
    const int t = threadIdx.x;
    const int tok0 = blockIdx.x * 8;
    const int b = tok0 >> 9;
    const int len_b = lengths[b];
    const float cf = *corr_floor_p;
    const float gain = *pe_gain_p;

    float clv[8], csv[8];
    bool mk[8];
#pragma unroll
    for (int k = 0; k < 8; ++k) {
        int l = (tok0 + k) & 511;
        if (l == 0) { clv[k] = 1.f; csv[k] = 1.f; mk[k] = false; }
        else {
            float a = c_local[b * 511 + l - 1];
            float s = c_sink[b * 511 + l - 1];
            clv[k] = fminf(fmaxf(a, 0.f), 1.f);
            csv[k] = fminf(fmaxf(s, 0.f), 1.f);
            mk[k] = (l - 1) >= len_b;
        }
    }
    if (t < 8) {
        int tok = tok0 + t;
        clb[tok] = clv[t];
        csfb[tok] = cf + (1.f - cf) * csv[t];
        padfb[tok] = mk[t] ? 1.f : 0.f;
    }
    if (t < 20) {
#pragma unroll
        for (int k = 0; k < 8; ++k) {
            float cl = clv[k], cs = csv[k];
            float v;
            if (t == 0) v = cl;
            else if (t == 1) v = cs;
            else if (t == 2) v = cl * cs;
            else if (t == 3) v = fabsf(cl - cs);
            else if (t < 12) {
                float c = (float)(t - 4) * (1.f / 7.f);
                float dd = (cl - c) / 0.200001f;
                v = expf(-0.5f * dd * dd);
            } else {
                float c = (float)(t - 12) * (1.f / 7.f);
                float dd = (cs - c) / 0.200001f;
                v = expf(-0.5f * dd * dd);
            }
            zs[k][t] = v;
        }
    }
    __syncthreads();

    float acc[8];
#pragma unroll
    for (int k = 0; k < 8; ++k)
        acc[k] = PEpos[((tok0 + k) & 511) * 256 + t];
    for (int f = 0; f < 20; ++f) {
        float wv = W20t[f * 256 + t];
#pragma unroll
        for (int k = 0; k < 8; ++k) acc[k] += zs[k][f] * wv;
    }
#pragma unroll
    for (int k = 0; k < 8; ++k) pes[k][t] = acc[k];
    __syncthreads();

    {
        int w = t >> 6, lane = t & 63;
#pragma unroll
        for (int p = 0; p < 2; ++p) {
            int k = w + p * 4;
            float4 v = *(const float4*)&pes[k][lane * 4];
            float s = v.x + v.y + v.z + v.w;
            float sq = v.x * v.x + v.y * v.y + v.z * v.z + v.w * v.w;
#pragma unroll
            for (int off = 32; off; off >>= 1) {
                s += __shfl_xor(s, off);
                sq += __shfl_xor(sq, off);
            }
            if (lane == 0) {
                float mean = s * (1.f / 256.f);
                mn[k] = mean;
                rsd[k] = rsqrtf(sq * (1.f / 256.f) - mean * mean + 1e-5f);
            }
        }
    }
    __syncthreads();
    float gv = pe_g[t], bv = pe_bb[t];
    float hv[8];
#pragma unroll
    for (int k = 0; k < 8; ++k) {
        int l = (tok0 + k) & 511;
        float base = (l == 0) ? cls_tok[t] : bb[(size_t)(tok0 + k) * 256 + t];
        float pe = (pes[k][t] - mn[k]) * rsd[k] * gv + bv;
        pe *= gain;
        if (mk[k]) pe = 0.f;
        hv[k] = base + pe;
        h[(size_t)(tok0 + k) * 256 + t] = hv[k];
    }
    __syncthreads();
#pragma unroll
    for (int k = 0; k < 8; ++k) pes[k][t] = hv[k];
    __syncthreads();
    {
        int w = t >> 6, lane = t & 63;
#pragma unroll
        for (int p = 0; p < 2; ++p) {
            int k = w + p * 4;
            float4 v = *(const float4*)&pes[k][lane * 4];
            float s = v.x + v.y + v.z + v.w;
            float sq = v.x * v.x + v.y * v.y + v.z * v.z + v.w * v.w;
#pragma unroll
            for (int off = 32; off; off >>= 1) {
                s += __shfl_xor(s, off);
                sq += __shfl_xor(sq, off);
            }
            if (lane == 0) {
                float mean = s * (1.f / 256.f);
                mn[k] = mean;
                rsd[k] = rsqrtf(sq * (1.f / 256.f) - mean * mean + 1e-5f);
            }
        }
    }
    __syncthreads();
    float g1 = ln1g[t], b1 = ln1b[t];
#pragma unroll
    for (int k = 0; k < 8; ++k)
        u[(size_t)(tok0 + k) * 256 + t] = f2bf((hv[k] - mn[k]) * rsd[k] * g1 + b1);
}

// ---------------------------------------------------------------------------
// bf16 MFMA GEMM, 128x64 tile (proven): C[M,N] = A @ W^T + bias (f32 store)
__global__ __launch_bounds__(256) void gemm_bf16_kernel(
    const unsigned short* __restrict__ A, const unsigned short* __restrict__ W,
    const float* __restrict__ bias, float* __restrict__ hres, int M, int N, int K)
{
    __shared__ __align__(16) unsigned short As[128 * 64];
    __shared__ __align__(16) unsigned short Bs[64 * 64];
    const int t = threadIdx.x;
    const int wid = t >> 6, lane = t & 63;
    const int lo = lane & 15, hi = lane >> 4;
    const int wm = wid >> 1, wn = wid & 1;
    const int m0 = blockIdx.y * 128, n0 = blockIdx.x * 64;
    const int lrow = lane >> 3, lc = lane & 7;
    f32x4 acc[4][2] = {};
    for (int k0 = 0; k0 < K; k0 += 64) {
        __syncthreads();
#pragma unroll
        for (int is = 0; is < 4; ++is) {
            int r = wid * 32 + is * 8 + lrow;
            const unsigned short* g = A + (size_t)(m0 + r) * K + k0 + ((lc ^ (r & 7)) * 8);
            gload16(g, &As[(wid * 32 + is * 8) * 64]);
        }
#pragma unroll
        for (int is = 0; is < 2; ++is) {
            int r = wid * 16 + is * 8 + lrow;
            const unsigned short* g = W + (size_t)(n0 + r) * K + k0 + ((lc ^ (r & 7)) * 8);
            gload16(g, &Bs[(wid * 16 + is * 8) * 64]);
        }
        __syncthreads();
#pragma unroll
        for (int kh = 0; kh < 2; ++kh) {
            bf16x8 bfr[2];
#pragma unroll
            for (int nf = 0; nf < 2; ++nf) {
                int r = wn * 32 + nf * 16 + lo;
                bfr[nf] = *(const bf16x8*)&Bs[r * 64 + (((kh * 4 + hi) ^ (r & 7)) * 8)];
            }
#pragma unroll
            for (int mf = 0; mf < 4; ++mf) {
                int r = wm * 64 + mf * 16 + lo;
                bf16x8 afr = *(const bf16x8*)&As[r * 64 + (((kh * 4 + hi) ^ (r & 7)) * 8)];
                acc[mf][0] = __builtin_amdgcn_mfma_f32_16x16x32_bf16(afr, bfr[0], acc[mf][0], 0, 0, 0);
                acc[mf][1] = __builtin_amdgcn_mfma_f32_16x16x32_bf16(afr, bfr[1], acc[mf][1], 0, 0, 0);
            }
        }
    }
#pragma unroll
    for (int mf = 0; mf < 4; ++mf) {
        const int mbase = m0 + wm * 64 + mf * 16 + hi * 4;
#pragma unroll
        for (int nf = 0; nf < 2; ++nf) {
            const int n = n0 + wn * 32 + nf * 16 + lo;
            const float bv = bias[n];
            f32x4 v = acc[mf][nf];
#pragma unroll
            for (int rg = 0; rg < 4; ++rg)
                hres[(size_t)(mbase + rg) * N + n] = v[rg] + bv;
        }
    }
}

// ---------------------------------------------------------------------------
// bf16 MFMA GEMM, 128x128 tile: QKV (EPI=0), FF1 GELU (EPI=2).
// Length-aware: whole 128-row tile past lengths[b] is dead -> early exit.
template <int EPI>
__global__ __launch_bounds__(256) void gemm128_kernel(
    const unsigned short* __restrict__ A, const unsigned short* __restrict__ W,
    const float* __restrict__ bias, const int* __restrict__ lengths,
    unsigned short* __restrict__ o0, unsigned short* __restrict__ o1,
    unsigned short* __restrict__ o2, int M, int N, int K)
{
    __shared__ __align__(16) unsigned short As[128 * 64];
    __shared__ __align__(16) unsigned short Bs[128 * 64];
    const int m0 = blockIdx.y * 128, n0 = blockIdx.x * 128;
    if ((m0 & 511) > lengths[m0 >> 9]) return;   // dead tile
    const int t = threadIdx.x;
    const int wid = t >> 6, lane = t & 63;
    const int lo = lane & 15, hi = lane >> 4;
    const int wm = wid >> 1, wn = wid & 1;
    const int lrow = lane >> 3, lc = lane & 7;
    f32x4 acc[4][4] = {};
    for (int k0 = 0; k0 < K; k0 += 64) {
        __syncthreads();
#pragma unroll
        for (int is = 0; is < 4; ++is) {
            int r = wid * 32 + is * 8 + lrow;
            const unsigned short* g = A + (size_t)(m0 + r) * K + k0 + ((lc ^ (r & 7)) * 8);
            gload16(g, &As[(wid * 32 + is * 8) * 64]);
        }
#pragma unroll
        for (int is = 0; is < 4; ++is) {
            int r = wid * 32 + is * 8 + lrow;
            const unsigned short* g = W + (size_t)(n0 + r) * K + k0 + ((lc ^ (r & 7)) * 8);
            gload16(g, &Bs[(wid * 32 + is * 8) * 64]);
        }
        __syncthreads();
#pragma unroll
        for (int kh = 0; kh < 2; ++kh) {
            bf16x8 bfr[4];
#pragma unroll
            for (int nf = 0; nf < 4; ++nf) {
                int r = wn * 64 + nf * 16 + lo;
                bfr[nf] = *(const bf16x8*)&Bs[r * 64 + (((kh * 4 + hi) ^ (r & 7)) * 8)];
            }
#pragma unroll
            for (int mf = 0; mf < 4; ++mf) {
                int r = wm * 64 + mf * 16 + lo;
                bf16x8 afr = *(const bf16x8*)&As[r * 64 + (((kh * 4 + hi) ^ (r & 7)) * 8)];
#pragma unroll
                for (int nf = 0; nf < 4; ++nf)
                    acc[mf][nf] = __builtin_amdgcn_mfma_f32_16x16x32_bf16(afr, bfr[nf], acc[mf][nf], 0, 0, 0);
            }
        }
    }
#pragma unroll
    for (int mf = 0; mf < 4; ++mf) {
        const int mbase = m0 + wm * 64 + mf * 16 + hi * 4;
#pragma unroll
        for (int nf = 0; nf < 4; ++nf) {
            const int n = n0 + wn * 64 + nf * 16 + lo;
            const float bv = bias[n];
            f32x4 v = acc[mf][nf];
            if constexpr (EPI == 0) {
                unsigned short* dst = (n < 256) ? o0 : ((n < 512) ? o1 : o2);
                const float qsc = (n < 256)
                    ? (0.17677669529663687f * 1.4426950408889634f) : 1.f;
                const int c = n & 255;
#pragma unroll
                for (int rg = 0; rg < 4; ++rg)
                    dst[(size_t)(mbase + rg) * 256 + c] = f2bf((v[rg] + bv) * qsc);
            } else {
#pragma unroll
                for (int rg = 0; rg < 4; ++rg)
                    o0[(size_t)(mbase + rg) * N + n] = f2bf(gelu_f(v[rg] + bv));
            }
        }
    }
}

// ---------------------------------------------------------------------------
// Fused residual-GEMM + LayerNorm (proven round-13 32x256 tile), length-aware.
// OUT=0: h += GEMM; u = LN(h).  OUT=1: final FF2 -> out-LN CLS rows only.
template <int OUT>
__global__ __launch_bounds__(512) void gemm_res_ln_kernel(
    const unsigned short* __restrict__ A, const unsigned short* __restrict__ W,
    const float* __restrict__ bias, float* __restrict__ hres,
    const float* __restrict__ g, const float* __restrict__ bvec,
    const int* __restrict__ lengths,
    unsigned short* __restrict__ u, float* __restrict__ outp, int K)
{
    __shared__ __align__(16) unsigned short As[32 * 64];
    __shared__ __align__(16) unsigned short Bs[256 * 64];
    __shared__ float red[32][4][2];
    const int m0 = blockIdx.x * 32;
    if ((m0 & 511) > lengths[m0 >> 9]) return;   // dead tile
    const int t = threadIdx.x;
    const int wid = t >> 6, lane = t & 63;
    const int lo = lane & 15, hi = lane >> 4;
    const int wm = wid >> 2, wn = wid & 3;
    const int lrow = lane >> 3, lc = lane & 7;
    f32x4 acc[4] = {};
    for (int k0 = 0; k0 < K; k0 += 64) {
        __syncthreads();
        if (wid < 4) {
            int r = wid * 8 + lrow;
            gload16(A + (size_t)(m0 + r) * K + k0 + ((lc ^ (r & 7)) * 8),
                    &As[(wid * 8) * 64]);
        }
#pragma unroll
        for (int is = 0; is < 4; ++is) {
            int r = wid * 32 + is * 8 + lrow;
            gload16(W + (size_t)r * K + k0 + ((lc ^ (r & 7)) * 8),
                    &Bs[(wid * 32 + is * 8) * 64]);
        }
        __syncthreads();
#pragma unroll
        for (int kh = 0; kh < 2; ++kh) {
            bf16x8 bfr[4];
#pragma unroll
            for (int nf = 0; nf < 4; ++nf) {
                int r = wn * 64 + nf * 16 + lo;
                bfr[nf] = *(const bf16x8*)&Bs[r * 64 + (((kh * 4 + hi) ^ (r & 7)) * 8)];
            }
            {
                int r = wm * 16 + lo;
                bf16x8 afr = *(const bf16x8*)&As[r * 64 + (((kh * 4 + hi) ^ (r & 7)) * 8)];
#pragma unroll
                for (int nf = 0; nf < 4; ++nf)
                    acc[nf] = __builtin_amdgcn_mfma_f32_16x16x32_bf16(afr, bfr[nf], acc[nf], 0, 0, 0);
            }
        }
    }
#pragma unroll
    for (int nf = 0; nf < 4; ++nf) {
        const int n = wn * 64 + nf * 16 + lo;
        const float bv = bias[n];
        const int rbase = m0 + wm * 16 + hi * 4;
#pragma unroll
        for (int rg = 0; rg < 4; ++rg) {
            size_t idx = (size_t)(rbase + rg) * 256 + n;
            float hv = acc[nf][rg] + bv + hres[idx];
            if constexpr (OUT == 0) hres[idx] = hv;
            acc[nf][rg] = hv;
        }
    }
#pragma unroll
    for (int rg = 0; rg < 4; ++rg) {
        float s = ((acc[0][rg] + acc[1][rg]) + (acc[2][rg] + acc[3][rg]));
        float sq = ((acc[0][rg] * acc[0][rg] + acc[1][rg] * acc[1][rg]) +
                    (acc[2][rg] * acc[2][rg] + acc[3][rg] * acc[3][rg]));
#pragma unroll
        for (int off = 1; off < 16; off <<= 1) {
            s += __shfl_xor(s, off);
            sq += __shfl_xor(sq, off);
        }
        if (lo == 0) {
            int rl = wm * 16 + hi * 4 + rg;
            red[rl][wn][0] = s;
            red[rl][wn][1] = sq;
        }
    }
    __syncthreads();
#pragma unroll
    for (int rg = 0; rg < 4; ++rg) {
        const int rl = wm * 16 + hi * 4 + rg;
        float s = (red[rl][0][0] + red[rl][1][0]) + (red[rl][2][0] + red[rl][3][0]);
        float sq = (red[rl][0][1] + red[rl][1][1]) + (red[rl][2][1] + red[rl][3][1]);
        float mean = s * (1.f / 256.f);
        float rs = rsqrtf(sq * (1.f / 256.f) - mean * mean + 1e-5f);
        if constexpr (OUT == 1) {
            const int row = m0 + rl;
            if ((row & 511) == 0) {
#pragma unroll
                for (int nf = 0; nf < 4; ++nf) {
                    const int n = wn * 64 + nf * 16 + lo;
                    outp[(size_t)(row >> 9) * 256 + n] =
                        (acc[nf][rg] - mean) * rs * g[n] + bvec[n];
                }
            }
        } else {
#pragma unroll
            for (int nf = 0; nf < 4; ++nf) {
                const int n = wn * 64 + nf * 16 + lo;
                u[(size_t)(m0 + rl) * 256 + n] =
                    f2bf((acc[nf][rg] - mean) * rs * g[n] + bvec[n]);
            }
        }
    }
}

// ---------------------------------------------------------------------------
// MFMA flash attention v9: proven v8 + length-aware (skip dead q-blocks,
// trim kv loop to ceil((len+1)/128) tiles; skipped p's were exact zeros).
__global__ __launch_bounds__(256) void attn_mfma_kernel(
    const unsigned short* __restrict__ Qb, const unsigned short* __restrict__ Kb,
    const unsigned short* __restrict__ Vb, const float* __restrict__ clb,
    const float* __restrict__ csfb, const float* __restrict__ padfb,
    const float* __restrict__ alpha_p, const float* __restrict__ beta_p,
    const int* __restrict__ lengths, unsigned short* __restrict__ Ob)
{
    __shared__ __align__(16) unsigned short Kl[128 * 40];   // 10240 B
    __shared__ __align__(16) unsigned short Vt[32 * 132];   // 8448 B
    __shared__ __align__(16) float csfj[128];               // 512 B
    const int t = threadIdx.x;
    const int swz = ((blockIdx.x & 7) << 8) | (blockIdx.x >> 3);  // XCD chunking
    const int bh = swz >> 3, hf = swz & 7;
    const int b = bh >> 3, hd = bh & 7;
    const int len_b = lengths[b];
    if (hf * 64 > len_b) return;                 // dead q-tile
    const int njt = (len_b + 128) >> 7;          // ceil((len_b+1)/128)
    const size_t base = ((size_t)b * 512) * 256 + hd * 32;
    const int w = t >> 6, lane = t & 63, lo = lane & 15, hi = lane >> 4;
    const float L2E = 1.4426950408889634f;
    const float kb = L2E * (*beta_p);
    const float ka = L2E * (*alpha_p);
    const float* clg = clb + b * 512;

    const int i0 = (hf * 4 + w) * 16;
    const int iq = i0 + lo;
    const bf16x8 qf = *(const bf16x8*)(Qb + base + (size_t)iq * 256 + hi * 8);
    const float csb = fmaxf(kb * csfb[b * 512 + iq], 1e-3f);
    f32x4 acc0 = {0.f, 0.f, 0.f, 0.f}, acc1 = {0.f, 0.f, 0.f, 0.f};
    float lsum = 0.f;

    for (int jt = 0; jt < njt; ++jt) {
        __syncthreads();
        for (int idx = t; idx < 512; idx += 256) {       // K tile: 128 rows
            int row = idx >> 2, c4 = idx & 3;
            *(uint4*)&Kl[row * 40 + c4 * 8] =
                *(const uint4*)(Kb + base + (size_t)(jt * 128 + row) * 256 + c4 * 8);
        }
        for (int idx = t; idx < 512; idx += 256) {       // V^T via v_perm
            int pr = idx & 63, c4 = idx >> 6;
            const unsigned* vp0 = (const unsigned*)
                (Vb + base + (size_t)(jt * 128 + 2 * pr) * 256 + c4 * 4);
            const unsigned* vp1 = (const unsigned*)
                (Vb + base + (size_t)(jt * 128 + 2 * pr + 1) * 256 + c4 * 4);
            unsigned v0lo = vp0[0], v0hi = vp0[1];
            unsigned v1lo = vp1[0], v1hi = vp1[1];
            *(unsigned*)&Vt[(c4 * 4 + 0) * 132 + 2 * pr] =
                __builtin_amdgcn_perm(v1lo, v0lo, 0x05040100u);
            *(unsigned*)&Vt[(c4 * 4 + 1) * 132 + 2 * pr] =
                __builtin_amdgcn_perm(v1lo, v0lo, 0x07060302u);
            *(unsigned*)&Vt[(c4 * 4 + 2) * 132 + 2 * pr] =
                __builtin_amdgcn_perm(v1hi, v0hi, 0x05040100u);
            *(unsigned*)&Vt[(c4 * 4 + 3) * 132 + 2 * pr] =
                __builtin_amdgcn_perm(v1hi, v0hi, 0x07060302u);
        }
        if (t < 128) {                                   // csf with pad folded
            int j = jt * 128 + t;
            float cv = csfb[b * 512 + j];
            csfj[t] = (padfb[b * 512 + j] > 0.5f) ? -100000.f : cv;
        }
        __syncthreads();
#pragma unroll
        for (int ktp = 0; ktp < 4; ++ktp) {
            const int k16 = ktp * 32;             // local j base
            const int gj = jt * 128 + k16;        // global j base
            bf16x8 kf0 = *(const bf16x8*)&Kl[(k16 + lo) * 40 + hi * 8];
            bf16x8 kf1 = *(const bf16x8*)&Kl[(k16 + 16 + lo) * 40 + hi * 8];
            union U16 { unsigned long long q[2]; unsigned wd[4]; bf16x8 v; } vu0, vu1, pu;
            vu0.q[0] = *(const unsigned long long*)&Vt[lo * 132 + k16 + hi * 4];
            vu0.q[1] = *(const unsigned long long*)&Vt[lo * 132 + k16 + 16 + hi * 4];
            vu1.q[0] = *(const unsigned long long*)&Vt[(16 + lo) * 132 + k16 + hi * 4];
            vu1.q[1] = *(const unsigned long long*)&Vt[(16 + lo) * 132 + k16 + 16 + hi * 4];
            f32x4 csf0 = *(const f32x4*)&csfj[k16 + hi * 4];
            f32x4 csf1 = *(const f32x4*)&csfj[k16 + 16 + hi * 4];
            f32x4 c0, c1;
#pragma unroll
            for (int e = 0; e < 4; ++e) {
                c0[e] = csb * csf0[e];
                c1[e] = csb * csf1[e];
            }
            f32x4 s0 = __builtin_amdgcn_mfma_f32_16x16x32_bf16(kf0, qf, c0, 0, 0, 0);
            f32x4 s1 = __builtin_amdgcn_mfma_f32_16x16x32_bf16(kf1, qf, c1, 0, 0, 0);
            float p[8];
#pragma unroll
            for (int r = 0; r < 4; ++r) p[r] = exp2f(s0[r]);
#pragma unroll
            for (int r = 0; r < 4; ++r) p[4 + r] = exp2f(s1[r]);
            if (gj <= i0 + 16 && gj + 32 >= i0) {
#pragma unroll
                for (int r = 0; r < 8; ++r) {
                    int jr = gj + ((r & 4) ? 16 : 0) + hi * 4 + (r & 3);
                    int dij = jr - iq;
                    if (dij == 1 || dij == -1) {
                        float ce = (jr >= 1 && iq <= 510) ? clg[jr] : clg[iq];
                        p[r] *= exp2f(ka * ce);
                    }
                }
            }
            lsum += ((p[0] + p[1]) + (p[2] + p[3])) + ((p[4] + p[5]) + (p[6] + p[7]));
            pu.wd[0] = cvt_pk_bf16(p[0], p[1]);
            pu.wd[1] = cvt_pk_bf16(p[2], p[3]);
            pu.wd[2] = cvt_pk_bf16(p[4], p[5]);
            pu.wd[3] = cvt_pk_bf16(p[6], p[7]);
            acc0 = __builtin_amdgcn_mfma_f32_16x16x32_bf16(vu0.v, pu.v, acc0, 0, 0, 0);
            acc1 = __builtin_amdgcn_mfma_f32_16x16x32_bf16(vu1.v, pu.v, acc1, 0, 0, 0);
        }
    }
    {
        float ls = lsum;
        ls += __shfl_xor(ls, 16);
        ls += __shfl_xor(ls, 32);
        const float inv = 1.f / fmaxf(ls, 1e-35f);
        unsigned long long oa =
              (unsigned long long)cvt_pk_bf16(acc0[0] * inv, acc0[1] * inv)
            | ((unsigned long long)cvt_pk_bf16(acc0[2] * inv, acc0[3] * inv) << 32);
        unsigned long long ob2 =
              (unsigned long long)cvt_pk_bf16(acc1[0] * inv, acc1[1] * inv)
            | ((unsigned long long)cvt_pk_bf16(acc1[2] * inv, acc1[3] * inv) << 32);
        *(unsigned long long*)(Ob + base + (size_t)iq * 256 + hi * 4) = oa;
        *(unsigned long long*)(Ob + base + (size_t)iq * 256 + 16 + hi * 4) = ob2;
    }
}

// ---------------------------------------------------------------------------
extern "C" void kernel_launch(void* const* d_in, const int* in_sizes, int n_in,
                              void* d_out, int out_size, void* d_ws, size_t ws_size,
                              hipStream_t stream) {
    const float* x         = (const float*)d_in[0];
    const float* c_local   = (const float*)d_in[1];
    const float* c_sink    = (const float*)d_in[2];
    const float* W_in      = (const float*)d_in[3];
    const float* b_in      = (const float*)d_in[4];
    const float* cls_token = (const float*)d_in[5];
    const float* pe_proj_W = (const float*)d_in[6];
    const float* pe_proj_b = (const float*)d_in[7];
    const float* pe_ln_g   = (const float*)d_in[8];
    const float* pe_ln_b   = (const float*)d_in[9];
    const float* pe_gain   = (const float*)d_in[10];
    const float* attn_Wqkv = (const float*)d_in[11];
    const float* attn_bqkv = (const float*)d_in[12];
    const float* attn_Wo   = (const float*)d_in[13];
    const float* attn_bo   = (const float*)d_in[14];
    const float* ff_W1     = (const float*)d_in[15];
    const float* ff_b1     = (const float*)d_in[16];
    const float* ff_W2     = (const float*)d_in[17];
    const float* ff_b2     = (const float*)d_in[18];
    const float* ln1_g     = (const float*)d_in[19];
    const float* ln1_b     = (const float*)d_in[20];
    const float* ln2_g     = (const float*)d_in[21];
    const float* ln2_b     = (const float*)d_in[22];
    const float* alpha     = (const float*)d_in[23];
    const float* beta      = (const float*)d_in[24];
    const float* corr_fl   = (const float*)d_in[25];
    const float* out_ln_g  = (const float*)d_in[26];
    const float* out_ln_b  = (const float*)d_in[27];
    const int*   lengths   = (const int*)d_in[28];
    float* out = (float*)d_out;

    // float region (same slots as round-13 passing layout)
    float* h     = (float*)d_ws;              // 4,194,304
    float* clb   = h + 4194304;               // 16384
    float* csfb  = clb + 16384;
    float* padfb = csfb + 16384;
    float* W20t  = padfb + 16384;             // 5120 (in old peWt slot)
    float* PEpos = W20t + 70656;              // 131072
    float* bbf   = PEpos + 131072;            // old 8,388,608-float region
    // bf16 region — weights AFTER the full 16,777,216-short f-span at Q_bf
    unsigned short* u_bf = (unsigned short*)(bbf + 8388608);
    unsigned short* xb_bf = u_bf;             // alias: xb dead before layer loop
    unsigned short* Q_bf = u_bf + 4194304;
    unsigned short* K_bf = Q_bf + 4194304;
    unsigned short* V_bf = K_bf + 4194304;
    unsigned short* f_bf = Q_bf;              // alias: spans Q..Q+16777216
    unsigned short* o_bf = u_bf;              // alias (lifetimes disjoint)
    unsigned short* wq_bf = Q_bf + 16777216;  // after f's span
    unsigned short* wo_bf = wq_bf + 589824;
    unsigned short* w1_bf = wo_bf + 196608;
    unsigned short* w2_bf = w1_bf + 786432;
    unsigned short* win_bf = w2_bf + 786432;  // 16384
    unsigned short* S_bf   = win_bf + 16384;  // 131072 (sinusoid table)
    unsigned short* w256_bf = S_bf + 131072;  // 65536

    setup_kernel<<<4708, 256, 0, stream>>>(
        attn_Wqkv, wq_bf, attn_Wo, wo_bf, ff_W1, w1_bf, ff_W2, w2_bf,
        W_in, win_bf, pe_proj_W, w256_bf, W20t, x, xb_bf, S_bf);
    gemm_bf16_kernel<<<dim3(4, 4), 256, 0, stream>>>(
        S_bf, w256_bf, pe_proj_b, PEpos, 512, 256, 256);
    gemm_bf16_kernel<<<dim3(4, 128), 256, 0, stream>>>(
        xb_bf, win_bf, b_in, bbf, 16384, 256, 64);
    prep_lite_kernel<<<2048, 256, 0, stream>>>(
        c_local, c_sink, bbf, cls_token, PEpos, W20t,
        pe_ln_g, pe_ln_b, pe_gain, corr_fl, lengths, ln1_g, ln1_b,
        h, clb, csfb, padfb, u_bf);

    for (int l = 0; l < 3; ++l) {
        gemm128_kernel<0><<<dim3(6, 128), 256, 0, stream>>>(
            u_bf, wq_bf + (size_t)l * 196608, attn_bqkv + 768 * l, lengths,
            Q_bf, K_bf, V_bf, 16384, 768, 256);
        attn_mfma_kernel<<<2048, 256, 0, stream>>>(Q_bf, K_bf, V_bf, clb, csfb,
                                                   padfb, alpha, beta, lengths, o_bf);
        gemm_res_ln_kernel<0><<<512, 512, 0, stream>>>(
            o_bf, wo_bf + (size_t)l * 65536, attn_bo + 256 * l, h,
            ln2_g + 256 * l, ln2_b + 256 * l, lengths, u_bf, nullptr, 256);
        gemm128_kernel<2><<<dim3(8, 128), 256, 0, stream>>>(
            u_bf, w1_bf + (size_t)l * 262144, ff_b1 + 1024 * l, lengths,
            f_bf, nullptr, nullptr, 16384, 1024, 256);
        if (l < 2) {
            gemm_res_ln_kernel<0><<<512, 512, 0, stream>>>(
                f_bf, w2_bf + (size_t)l * 262144, ff_b2 + 256 * l, h,
                ln1_g + 256 * (l + 1), ln1_b + 256 * (l + 1), lengths, u_bf, nullptr, 1024);
        } else {
            gemm_res_ln_kernel<1><<<512, 512, 0, stream>>>(
                f_bf, w2_bf + (size_t)l * 262144, ff_b2 + 256 * l, h,
                out_ln_g, out_ln_b, lengths, nullptr, out, 1024);
        }
    }
}

// Round 15
// 339.864 us; speedup vs baseline: 64.7575x; 1.1332x over previous
//
#include <hip/hip_runtime.h>
#include <math.h>

// B=32, L=512 (incl CLS), D=256, H=8, dh=32, N_LAYERS=3, D_FF=1024, tokens=16384
// Length-aware: rows past lengths[b] are provably dead (CLS-only output,
// exactly-zero attention weights for padded columns) -> tiles skipped.

typedef __attribute__((ext_vector_type(4))) float f32x4;
typedef __attribute__((ext_vector_type(8))) short bf16x8;

__device__ __forceinline__ unsigned short f2bf(float f) {
    unsigned u = __builtin_bit_cast(unsigned, f);
    u += 0x7fff + ((u >> 16) & 1);
    return (unsigned short)(u >> 16);
}
__device__ __forceinline__ unsigned cvt_pk_bf16(float a, float b) {
    unsigned r;
    asm("v_cvt_pk_bf16_f32 %0, %1, %2" : "=v"(r) : "v"(a), "v"(b));
    return r;
}
__device__ __forceinline__ float gelu_f(float v) {
    return v * 0.5f * (1.0f + erff(v * 0.70710678118654752f));
}
__device__ __forceinline__ void gload16(const void* g, void* l) {
    __builtin_amdgcn_global_load_lds(
        (const __attribute__((address_space(1))) unsigned int*)g,
        (__attribute__((address_space(3))) unsigned int*)l, 16, 0, 0);
}

// ---------------------------------------------------------------------------
// Mega setup kernel: all weight cvts + pe transposes + sinusoid + xb.
__global__ __launch_bounds__(256) void setup_kernel(
    const float* __restrict__ wq, unsigned short* __restrict__ wq_o,   // 576
    const float* __restrict__ wo, unsigned short* __restrict__ wo_o,   // 192
    const float* __restrict__ w1, unsigned short* __restrict__ w1_o,   // 768
    const float* __restrict__ w2, unsigned short* __restrict__ w2_o,   // 768
    const float* __restrict__ win, unsigned short* __restrict__ win_o, // 16
    const float* __restrict__ peW, unsigned short* __restrict__ w256,  // 64
    float* __restrict__ W20t,                                          // 20
    const float* __restrict__ x, unsigned short* __restrict__ xb,      // 2048
    unsigned short* __restrict__ S)                                    // 256
{
    int blk = blockIdx.x, t = threadIdx.x;
    if (blk < 2304) {  // plain f32->bf16 cvts
        const float* s; unsigned short* d; int base;
        if (blk < 576)       { s = wq; d = wq_o; base = blk; }
        else if (blk < 768)  { s = wo; d = wo_o; base = blk - 576; }
        else if (blk < 1536) { s = w1; d = w1_o; base = blk - 768; }
        else                 { s = w2; d = w2_o; base = blk - 1536; }
        int i = (base * 256 + t) * 4;
        float4 v = *(const float4*)(s + i);
        unsigned long long pk = (unsigned long long)f2bf(v.x)
            | ((unsigned long long)f2bf(v.y) << 16)
            | ((unsigned long long)f2bf(v.z) << 32)
            | ((unsigned long long)f2bf(v.w) << 48);
        *(unsigned long long*)(d + i) = pk;
    } else if (blk < 2320) {  // win
        int i = ((blk - 2304) * 256 + t) * 4;
        float4 v = *(const float4*)(win + i);
        unsigned long long pk = (unsigned long long)f2bf(v.x)
            | ((unsigned long long)f2bf(v.y) << 16)
            | ((unsigned long long)f2bf(v.z) << 32)
            | ((unsigned long long)f2bf(v.w) << 48);
        *(unsigned long long*)(win_o + i) = pk;
    } else if (blk < 2384) {  // peW first-256 feats -> bf16 [256][256]
        int i = ((blk - 2320) * 256 + t) * 4;
        int d = i >> 8, f = i & 255;
        float4 v = *(const float4*)(peW + d * 276 + f);
        unsigned long long pk = (unsigned long long)f2bf(v.x)
            | ((unsigned long long)f2bf(v.y) << 16)
            | ((unsigned long long)f2bf(v.z) << 32)
            | ((unsigned long long)f2bf(v.w) << 48);
        *(unsigned long long*)(w256 + i) = pk;
    } else if (blk < 2404) {  // W20t[f][d] = peW[d][256+f]
        int j = (blk - 2384) * 256 + t;
        int f = j >> 8, dd = j & 255;
        W20t[j] = peW[dd * 276 + 256 + f];
    } else if (blk < 4452) {  // xb
        int idx = (blk - 2404) * 256 + t;
        int tok = idx >> 5, c2 = idx & 31;
        int b = tok >> 9, l = tok & 511;
        unsigned r = 0;
        if (l > 0) {
            float2 v = *(const float2*)(x + ((size_t)b * 511 + l - 1) * 64 + 2 * c2);
            r = cvt_pk_bf16(v.x, v.y);
        }
        *(unsigned*)(xb + (size_t)tok * 64 + 2 * c2) = r;
    } else {  // sinusoid table
        int p = (blk - 4452) * 256 + t;
        int l = p >> 7, k = p & 127;
        float div = expf((float)(2 * k) * -0.035977892078032f);
        float a = (float)l * div;
        *(unsigned*)(S + l * 256 + 2 * k) = cvt_pk_bf16(sinf(a), cosf(a));
    }
}

// ---------------------------------------------------------------------------
// prep_lite: arrays for ALL tokens; h/u only for live 8-row groups.
__global__ __launch_bounds__(256) void prep_lite_kernel(
    const float* __restrict__ c_local, const float* __restrict__ c_sink,
    const float* __restrict__ bb, const float* __restrict__ cls_tok,
    const float* __restrict__ PEpos, const float* __restrict__ W20t,
    const float* __restrict__ pe_g, const float* __restrict__ pe_bb,
    const float* __restrict__ pe_gain_p, const float* __restrict__ corr_floor_p,
    const int* __restrict__ lengths, const float* __restrict__ ln1g,
    const float* __restrict__ ln1b,
    float* __restrict__ h, float* __restrict__ clb, float* __restrict__ csfb,
    float* __restrict__ padfb, unsigned short* __restrict__ u)
{
    __shared__ float zs[8][20];
    __shared__ __align__(16) float pes[8][256];
    __shared__ float mn[8], rsd[8];
    const int t = threadIdx.x;
    const int tok0 = blockIdx.x * 8;
    const int b = tok0 >> 9;
    const int len_b = lengths[b];
    const float cf = *corr_floor_p;
    const float gain = *pe_gain_p;

    float clv[8], csv[8];
    bool mk[8];
#pragma unroll
    for (int k = 0; k < 8; ++k) {
        int l = (tok0 + k) & 511;
        if (l == 0) { clv[k] = 1.f; csv[k] = 1.f; mk[k] = false; }
        else {
            float a = c_local[b * 511 + l - 1];
            float s = c_sink[b * 511 + l - 1];
            clv[k] = fminf(fmaxf(a, 0.f), 1.f);
            csv[k] = fminf(fmaxf(s, 0.f), 1.f);
            mk[k] = (l - 1) >= len_b;
        }
    }
    if (t < 8) {
        int tok = tok0 + t;
        clb[tok] = clv[t];
        csfb[tok] = cf + (1.f - cf) * csv[t];
        padfb[tok] = mk[t] ? 1.f : 0.f;
    }
    // dead group: mask arrays written above are all that's needed
    if ((tok0 & 511) > len_b) return;
    if (t < 20) {
#pragma unroll
        for (int k = 0; k < 8; ++k) {
            float cl = clv[k], cs = csv[k];
            float v;
            if (t == 0) v = cl;
            else if (t == 1) v = cs;
            else if (t == 2) v = cl * cs;
            else if (t == 3) v = fabsf(cl - cs);
            else if (t < 12) {
                float c = (float)(t - 4) * (1.f / 7.f);
                float dd = (cl - c) / 0.200001f;
                v = expf(-0.5f * dd * dd);
            } else {
                float c = (float)(t - 12) * (1.f / 7.f);
                float dd = (cs - c) / 0.200001f;
                v = expf(-0.5f * dd * dd);
            }
            zs[k][t] = v;
        }
    }
    __syncthreads();

    float acc[8];
#pragma unroll
    for (int k = 0; k < 8; ++k)
        acc[k] = PEpos[((tok0 + k) & 511) * 256 + t];
    for (int f = 0; f < 20; ++f) {
        float wv = W20t[f * 256 + t];
#pragma unroll
        for (int k = 0; k < 8; ++k) acc[k] += zs[k][f] * wv;
    }
#pragma unroll
    for (int k = 0; k < 8; ++k) pes[k][t] = acc[k];
    __syncthreads();

    {
        int w = t >> 6, lane = t & 63;
#pragma unroll
        for (int p = 0; p < 2; ++p) {
            int k = w + p * 4;
            float4 v = *(const float4*)&pes[k][lane * 4];
            float s = v.x + v.y + v.z + v.w;
            float sq = v.x * v.x + v.y * v.y + v.z * v.z + v.w * v.w;
#pragma unroll
            for (int off = 32; off; off >>= 1) {
                s += __shfl_xor(s, off);
                sq += __shfl_xor(sq, off);
            }
            if (lane == 0) {
                float mean = s * (1.f / 256.f);
                mn[k] = mean;
                rsd[k] = rsqrtf(sq * (1.f / 256.f) - mean * mean + 1e-5f);
            }
        }
    }
    __syncthreads();
    float gv = pe_g[t], bv = pe_bb[t];
    float hv[8];
#pragma unroll
    for (int k = 0; k < 8; ++k) {
        int l = (tok0 + k) & 511;
        float base = (l == 0) ? cls_tok[t] : bb[(size_t)(tok0 + k) * 256 + t];
        float pe = (pes[k][t] - mn[k]) * rsd[k] * gv + bv;
        pe *= gain;
        if (mk[k]) pe = 0.f;
        hv[k] = base + pe;
        h[(size_t)(tok0 + k) * 256 + t] = hv[k];
    }
    __syncthreads();
#pragma unroll
    for (int k = 0; k < 8; ++k) pes[k][t] = hv[k];
    __syncthreads();
    {
        int w = t >> 6, lane = t & 63;
#pragma unroll
        for (int p = 0; p < 2; ++p) {
            int k = w + p * 4;
            float4 v = *(const float4*)&pes[k][lane * 4];
            float s = v.x + v.y + v.z + v.w;
            float sq = v.x * v.x + v.y * v.y + v.z * v.z + v.w * v.w;
#pragma unroll
            for (int off = 32; off; off >>= 1) {
                s += __shfl_xor(s, off);
                sq += __shfl_xor(sq, off);
            }
            if (lane == 0) {
                float mean = s * (1.f / 256.f);
                mn[k] = mean;
                rsd[k] = rsqrtf(sq * (1.f / 256.f) - mean * mean + 1e-5f);
            }
        }
    }
    __syncthreads();
    float g1 = ln1g[t], b1 = ln1b[t];
#pragma unroll
    for (int k = 0; k < 8; ++k)
        u[(size_t)(tok0 + k) * 256 + t] = f2bf((hv[k] - mn[k]) * rsd[k] * g1 + b1);
}

// ---------------------------------------------------------------------------
// bf16 MFMA GEMM, 128x64 tile (proven): C[M,N] = A @ W^T + bias (f32 store).
// Optional length-skip (lengths != nullptr, 128-aligned M tiles).
__global__ __launch_bounds__(256) void gemm_bf16_kernel(
    const unsigned short* __restrict__ A, const unsigned short* __restrict__ W,
    const float* __restrict__ bias, float* __restrict__ hres,
    const int* __restrict__ lengths, int M, int N, int K)
{
    __shared__ __align__(16) unsigned short As[128 * 64];
    __shared__ __align__(16) unsigned short Bs[64 * 64];
    const int m0 = blockIdx.y * 128, n0 = blockIdx.x * 64;
    if (lengths && (m0 & 511) > lengths[m0 >> 9]) return;
    const int t = threadIdx.x;
    const int wid = t >> 6, lane = t & 63;
    const int lo = lane & 15, hi = lane >> 4;
    const int wm = wid >> 1, wn = wid & 1;
    const int lrow = lane >> 3, lc = lane & 7;
    f32x4 acc[4][2] = {};
    for (int k0 = 0; k0 < K; k0 += 64) {
        __syncthreads();
#pragma unroll
        for (int is = 0; is < 4; ++is) {
            int r = wid * 32 + is * 8 + lrow;
            const unsigned short* g = A + (size_t)(m0 + r) * K + k0 + ((lc ^ (r & 7)) * 8);
            gload16(g, &As[(wid * 32 + is * 8) * 64]);
        }
#pragma unroll
        for (int is = 0; is < 2; ++is) {
            int r = wid * 16 + is * 8 + lrow;
            const unsigned short* g = W + (size_t)(n0 + r) * K + k0 + ((lc ^ (r & 7)) * 8);
            gload16(g, &Bs[(wid * 16 + is * 8) * 64]);
        }
        __syncthreads();
#pragma unroll
        for (int kh = 0; kh < 2; ++kh) {
            bf16x8 bfr[2];
#pragma unroll
            for (int nf = 0; nf < 2; ++nf) {
                int r = wn * 32 + nf * 16 + lo;
                bfr[nf] = *(const bf16x8*)&Bs[r * 64 + (((kh * 4 + hi) ^ (r & 7)) * 8)];
            }
#pragma unroll
            for (int mf = 0; mf < 4; ++mf) {
                int r = wm * 64 + mf * 16 + lo;
                bf16x8 afr = *(const bf16x8*)&As[r * 64 + (((kh * 4 + hi) ^ (r & 7)) * 8)];
                acc[mf][0] = __builtin_amdgcn_mfma_f32_16x16x32_bf16(afr, bfr[0], acc[mf][0], 0, 0, 0);
                acc[mf][1] = __builtin_amdgcn_mfma_f32_16x16x32_bf16(afr, bfr[1], acc[mf][1], 0, 0, 0);
            }
        }
    }
#pragma unroll
    for (int mf = 0; mf < 4; ++mf) {
        const int mbase = m0 + wm * 64 + mf * 16 + hi * 4;
#pragma unroll
        for (int nf = 0; nf < 2; ++nf) {
            const int n = n0 + wn * 32 + nf * 16 + lo;
            const float bv = bias[n];
            f32x4 v = acc[mf][nf];
#pragma unroll
            for (int rg = 0; rg < 4; ++rg)
                hres[(size_t)(mbase + rg) * N + n] = v[rg] + bv;
        }
    }
}

// ---------------------------------------------------------------------------
// bf16 MFMA GEMM, 64x128 tile (4 waves 2x2, each 32x64): QKV (EPI=0),
// FF1 GELU (EPI=2). 64-aligned length-skip; LDS 24 KB -> better residency.
template <int EPI>
__global__ __launch_bounds__(256) void gemm64_kernel(
    const unsigned short* __restrict__ A, const unsigned short* __restrict__ W,
    const float* __restrict__ bias, const int* __restrict__ lengths,
    unsigned short* __restrict__ o0, unsigned short* __restrict__ o1,
    unsigned short* __restrict__ o2, int M, int N, int K)
{
    __shared__ __align__(16) unsigned short As[64 * 64];
    __shared__ __align__(16) unsigned short Bs[128 * 64];
    const int m0 = blockIdx.y * 64, n0 = blockIdx.x * 128;
    if ((m0 & 511) > lengths[m0 >> 9]) return;   // dead tile
    const int t = threadIdx.x;
    const int wid = t >> 6, lane = t & 63;
    const int lo = lane & 15, hi = lane >> 4;
    const int wm = wid >> 1, wn = wid & 1;
    const int lrow = lane >> 3, lc = lane & 7;
    f32x4 acc[2][4] = {};
    for (int k0 = 0; k0 < K; k0 += 64) {
        __syncthreads();
#pragma unroll
        for (int is = 0; is < 2; ++is) {
            int r = wid * 16 + is * 8 + lrow;
            const unsigned short* g = A + (size_t)(m0 + r) * K + k0 + ((lc ^ (r & 7)) * 8);
            gload16(g, &As[(wid * 16 + is * 8) * 64]);
        }
#pragma unroll
        for (int is = 0; is < 4; ++is) {
            int r = wid * 32 + is * 8 + lrow;
            const unsigned short* g = W + (size_t)(n0 + r) * K + k0 + ((lc ^ (r & 7)) * 8);
            gload16(g, &Bs[(wid * 32 + is * 8) * 64]);
        }
        __syncthreads();
#pragma unroll
        for (int kh = 0; kh < 2; ++kh) {
            bf16x8 bfr[4];
#pragma unroll
            for (int nf = 0; nf < 4; ++nf) {
                int r = wn * 64 + nf * 16 + lo;
                bfr[nf] = *(const bf16x8*)&Bs[r * 64 + (((kh * 4 + hi) ^ (r & 7)) * 8)];
            }
#pragma unroll
            for (int mf = 0; mf < 2; ++mf) {
                int r = wm * 32 + mf * 16 + lo;
                bf16x8 afr = *(const bf16x8*)&As[r * 64 + (((kh * 4 + hi) ^ (r & 7)) * 8)];
#pragma unroll
                for (int nf = 0; nf < 4; ++nf)
                    acc[mf][nf] = __builtin_amdgcn_mfma_f32_16x16x32_bf16(afr, bfr[nf], acc[mf][nf], 0, 0, 0);
            }
        }
    }
#pragma unroll
    for (int mf = 0; mf < 2; ++mf) {
        const int mbase = m0 + wm * 32 + mf * 16 + hi * 4;
#pragma unroll
        for (int nf = 0; nf < 4; ++nf) {
            const int n = n0 + wn * 64 + nf * 16 + lo;
            const float bv = bias[n];
            f32x4 v = acc[mf][nf];
            if constexpr (EPI == 0) {
                unsigned short* dst = (n < 256) ? o0 : ((n < 512) ? o1 : o2);
                const float qsc = (n < 256)
                    ? (0.17677669529663687f * 1.4426950408889634f) : 1.f;
                const int c = n & 255;
#pragma unroll
                for (int rg = 0; rg < 4; ++rg)
                    dst[(size_t)(mbase + rg) * 256 + c] = f2bf((v[rg] + bv) * qsc);
            } else {
#pragma unroll
                for (int rg = 0; rg < 4; ++rg)
                    o0[(size_t)(mbase + rg) * N + n] = f2bf(gelu_f(v[rg] + bv));
            }
        }
    }
}

// ---------------------------------------------------------------------------
// Fused residual-GEMM + LayerNorm (proven 32x256 tile), length-aware.
// OUT=0: h += GEMM; u = LN(h).  OUT=1: final FF2 -> out-LN CLS rows only.
template <int OUT>
__global__ __launch_bounds__(512) void gemm_res_ln_kernel(
    const unsigned short* __restrict__ A, const unsigned short* __restrict__ W,
    const float* __restrict__ bias, float* __restrict__ hres,
    const float* __restrict__ g, const float* __restrict__ bvec,
    const int* __restrict__ lengths,
    unsigned short* __restrict__ u, float* __restrict__ outp, int K)
{
    __shared__ __align__(16) unsigned short As[32 * 64];
    __shared__ __align__(16) unsigned short Bs[256 * 64];
    __shared__ float red[32][4][2];
    const int m0 = blockIdx.x * 32;
    if ((m0 & 511) > lengths[m0 >> 9]) return;   // dead tile
    const int t = threadIdx.x;
    const int wid = t >> 6, lane = t & 63;
    const int lo = lane & 15, hi = lane >> 4;
    const int wm = wid >> 2, wn = wid & 3;
    const int lrow = lane >> 3, lc = lane & 7;
    f32x4 acc[4] = {};
    for (int k0 = 0; k0 < K; k0 += 64) {
        __syncthreads();
        if (wid < 4) {
            int r = wid * 8 + lrow;
            gload16(A + (size_t)(m0 + r) * K + k0 + ((lc ^ (r & 7)) * 8),
                    &As[(wid * 8) * 64]);
        }
#pragma unroll
        for (int is = 0; is < 4; ++is) {
            int r = wid * 32 + is * 8 + lrow;
            gload16(W + (size_t)r * K + k0 + ((lc ^ (r & 7)) * 8),
                    &Bs[(wid * 32 + is * 8) * 64]);
        }
        __syncthreads();
#pragma unroll
        for (int kh = 0; kh < 2; ++kh) {
            bf16x8 bfr[4];
#pragma unroll
            for (int nf = 0; nf < 4; ++nf) {
                int r = wn * 64 + nf * 16 + lo;
                bfr[nf] = *(const bf16x8*)&Bs[r * 64 + (((kh * 4 + hi) ^ (r & 7)) * 8)];
            }
            {
                int r = wm * 16 + lo;
                bf16x8 afr = *(const bf16x8*)&As[r * 64 + (((kh * 4 + hi) ^ (r & 7)) * 8)];
#pragma unroll
                for (int nf = 0; nf < 4; ++nf)
                    acc[nf] = __builtin_amdgcn_mfma_f32_16x16x32_bf16(afr, bfr[nf], acc[nf], 0, 0, 0);
            }
        }
    }
#pragma unroll
    for (int nf = 0; nf < 4; ++nf) {
        const int n = wn * 64 + nf * 16 + lo;
        const float bv = bias[n];
        const int rbase = m0 + wm * 16 + hi * 4;
#pragma unroll
        for (int rg = 0; rg < 4; ++rg) {
            size_t idx = (size_t)(rbase + rg) * 256 + n;
            float hv = acc[nf][rg] + bv + hres[idx];
            if constexpr (OUT == 0) hres[idx] = hv;
            acc[nf][rg] = hv;
        }
    }
#pragma unroll
    for (int rg = 0; rg < 4; ++rg) {
        float s = ((acc[0][rg] + acc[1][rg]) + (acc[2][rg] + acc[3][rg]));
        float sq = ((acc[0][rg] * acc[0][rg] + acc[1][rg] * acc[1][rg]) +
                    (acc[2][rg] * acc[2][rg] + acc[3][rg] * acc[3][rg]));
#pragma unroll
        for (int off = 1; off < 16; off <<= 1) {
            s += __shfl_xor(s, off);
            sq += __shfl_xor(sq, off);
        }
        if (lo == 0) {
            int rl = wm * 16 + hi * 4 + rg;
            red[rl][wn][0] = s;
            red[rl][wn][1] = sq;
        }
    }
    __syncthreads();
#pragma unroll
    for (int rg = 0; rg < 4; ++rg) {
        const int rl = wm * 16 + hi * 4 + rg;
        float s = (red[rl][0][0] + red[rl][1][0]) + (red[rl][2][0] + red[rl][3][0]);
        float sq = (red[rl][0][1] + red[rl][1][1]) + (red[rl][2][1] + red[rl][3][1]);
        float mean = s * (1.f / 256.f);
        float rs = rsqrtf(sq * (1.f / 256.f) - mean * mean + 1e-5f);
        if constexpr (OUT == 1) {
            const int row = m0 + rl;
            if ((row & 511) == 0) {
#pragma unroll
                for (int nf = 0; nf < 4; ++nf) {
                    const int n = wn * 64 + nf * 16 + lo;
                    outp[(size_t)(row >> 9) * 256 + n] =
                        (acc[nf][rg] - mean) * rs * g[n] + bvec[n];
                }
            }
        } else {
#pragma unroll
            for (int nf = 0; nf < 4; ++nf) {
                const int n = wn * 64 + nf * 16 + lo;
                u[(size_t)(m0 + rl) * 256 + n] =
                    f2bf((acc[nf][rg] - mean) * rs * g[n] + bvec[n]);
            }
        }
    }
}

// ---------------------------------------------------------------------------
// MFMA flash attention v9 (proven round-14): length-aware, v_perm staging.
__global__ __launch_bounds__(256) void attn_mfma_kernel(
    const unsigned short* __restrict__ Qb, const unsigned short* __restrict__ Kb,
    const unsigned short* __restrict__ Vb, const float* __restrict__ clb,
    const float* __restrict__ csfb, const float* __restrict__ padfb,
    const float* __restrict__ alpha_p, const float* __restrict__ beta_p,
    const int* __restrict__ lengths, unsigned short* __restrict__ Ob)
{
    __shared__ __align__(16) unsigned short Kl[128 * 40];   // 10240 B
    __shared__ __align__(16) unsigned short Vt[32 * 132];   // 8448 B
    __shared__ __align__(16) float csfj[128];               // 512 B
    const int t = threadIdx.x;
    const int swz = ((blockIdx.x & 7) << 8) | (blockIdx.x >> 3);  // XCD chunking
    const int bh = swz >> 3, hf = swz & 7;
    const int b = bh >> 3, hd = bh & 7;
    const int len_b = lengths[b];
    if (hf * 64 > len_b) return;                 // dead q-tile
    const int njt = (len_b + 128) >> 7;          // ceil((len_b+1)/128)
    const size_t base = ((size_t)b * 512) * 256 + hd * 32;
    const int w = t >> 6, lane = t & 63, lo = lane & 15, hi = lane >> 4;
    const float L2E = 1.4426950408889634f;
    const float kb = L2E * (*beta_p);
    const float ka = L2E * (*alpha_p);
    const float* clg = clb + b * 512;

    const int i0 = (hf * 4 + w) * 16;
    const int iq = i0 + lo;
    const bf16x8 qf = *(const bf16x8*)(Qb + base + (size_t)iq * 256 + hi * 8);
    const float csb = fmaxf(kb * csfb[b * 512 + iq], 1e-3f);
    f32x4 acc0 = {0.f, 0.f, 0.f, 0.f}, acc1 = {0.f, 0.f, 0.f, 0.f};
    float lsum = 0.f;

    for (int jt = 0; jt < njt; ++jt) {
        __syncthreads();
        for (int idx = t; idx < 512; idx += 256) {       // K tile: 128 rows
            int row = idx >> 2, c4 = idx & 3;
            *(uint4*)&Kl[row * 40 + c4 * 8] =
                *(const uint4*)(Kb + base + (size_t)(jt * 128 + row) * 256 + c4 * 8);
        }
        for (int idx = t; idx < 512; idx += 256) {       // V^T via v_perm
            int pr = idx & 63, c4 = idx >> 6;
            const unsigned* vp0 = (const unsigned*)
                (Vb + base + (size_t)(jt * 128 + 2 * pr) * 256 + c4 * 4);
            const unsigned* vp1 = (const unsigned*)
                (Vb + base + (size_t)(jt * 128 + 2 * pr + 1) * 256 + c4 * 4);
            unsigned v0lo = vp0[0], v0hi = vp0[1];
            unsigned v1lo = vp1[0], v1hi = vp1[1];
            *(unsigned*)&Vt[(c4 * 4 + 0) * 132 + 2 * pr] =
                __builtin_amdgcn_perm(v1lo, v0lo, 0x05040100u);
            *(unsigned*)&Vt[(c4 * 4 + 1) * 132 + 2 * pr] =
                __builtin_amdgcn_perm(v1lo, v0lo, 0x07060302u);
            *(unsigned*)&Vt[(c4 * 4 + 2) * 132 + 2 * pr] =
                __builtin_amdgcn_perm(v1hi, v0hi, 0x05040100u);
            *(unsigned*)&Vt[(c4 * 4 + 3) * 132 + 2 * pr] =
                __builtin_amdgcn_perm(v1hi, v0hi, 0x07060302u);
        }
        if (t < 128) {                                   // csf with pad folded
            int j = jt * 128 + t;
            float cv = csfb[b * 512 + j];
            csfj[t] = (padfb[b * 512 + j] > 0.5f) ? -100000.f : cv;
        }
        __syncthreads();
#pragma unroll
        for (int ktp = 0; ktp < 4; ++ktp) {
            const int k16 = ktp * 32;             // local j base
            const int gj = jt * 128 + k16;        // global j base
            bf16x8 kf0 = *(const bf16x8*)&Kl[(k16 + lo) * 40 + hi * 8];
            bf16x8 kf1 = *(const bf16x8*)&Kl[(k16 + 16 + lo) * 40 + hi * 8];
            union U16 { unsigned long long q[2]; unsigned wd[4]; bf16x8 v; } vu0, vu1, pu;
            vu0.q[0] = *(const unsigned long long*)&Vt[lo * 132 + k16 + hi * 4];
            vu0.q[1] = *(const unsigned long long*)&Vt[lo * 132 + k16 + 16 + hi * 4];
            vu1.q[0] = *(const unsigned long long*)&Vt[(16 + lo) * 132 + k16 + hi * 4];
            vu1.q[1] = *(const unsigned long long*)&Vt[(16 + lo) * 132 + k16 + 16 + hi * 4];
            f32x4 csf0 = *(const f32x4*)&csfj[k16 + hi * 4];
            f32x4 csf1 = *(const f32x4*)&csfj[k16 + 16 + hi * 4];
            f32x4 c0, c1;
#pragma unroll
            for (int e = 0; e < 4; ++e) {
                c0[e] = csb * csf0[e];
                c1[e] = csb * csf1[e];
            }
            f32x4 s0 = __builtin_amdgcn_mfma_f32_16x16x32_bf16(kf0, qf, c0, 0, 0, 0);
            f32x4 s1 = __builtin_amdgcn_mfma_f32_16x16x32_bf16(kf1, qf, c1, 0, 0, 0);
            float p[8];
#pragma unroll
            for (int r = 0; r < 4; ++r) p[r] = exp2f(s0[r]);
#pragma unroll
            for (int r = 0; r < 4; ++r) p[4 + r] = exp2f(s1[r]);
            if (gj <= i0 + 16 && gj + 32 >= i0) {
#pragma unroll
                for (int r = 0; r < 8; ++r) {
                    int jr = gj + ((r & 4) ? 16 : 0) + hi * 4 + (r & 3);
                    int dij = jr - iq;
                    if (dij == 1 || dij == -1) {
                        float ce = (jr >= 1 && iq <= 510) ? clg[jr] : clg[iq];
                        p[r] *= exp2f(ka * ce);
                    }
                }
            }
            lsum += ((p[0] + p[1]) + (p[2] + p[3])) + ((p[4] + p[5]) + (p[6] + p[7]));
            pu.wd[0] = cvt_pk_bf16(p[0], p[1]);
            pu.wd[1] = cvt_pk_bf16(p[2], p[3]);
            pu.wd[2] = cvt_pk_bf16(p[4], p[5]);
            pu.wd[3] = cvt_pk_bf16(p[6], p[7]);
            acc0 = __builtin_amdgcn_mfma_f32_16x16x32_bf16(vu0.v, pu.v, acc0, 0, 0, 0);
            acc1 = __builtin_amdgcn_mfma_f32_16x16x32_bf16(vu1.v, pu.v, acc1, 0, 0, 0);
        }
    }
    {
        float ls = lsum;
        ls += __shfl_xor(ls, 16);
        ls += __shfl_xor(ls, 32);
        const float inv = 1.f / fmaxf(ls, 1e-35f);
        unsigned long long oa =
              (unsigned long long)cvt_pk_bf16(acc0[0] * inv, acc0[1] * inv)
            | ((unsigned long long)cvt_pk_bf16(acc0[2] * inv, acc0[3] * inv) << 32);
        unsigned long long ob2 =
              (unsigned long long)cvt_pk_bf16(acc1[0] * inv, acc1[1] * inv)
            | ((unsigned long long)cvt_pk_bf16(acc1[2] * inv, acc1[3] * inv) << 32);
        *(unsigned long long*)(Ob + base + (size_t)iq * 256 + hi * 4) = oa;
        *(unsigned long long*)(Ob + base + (size_t)iq * 256 + 16 + hi * 4) = ob2;
    }
}

// ---------------------------------------------------------------------------
extern "C" void kernel_launch(void* const* d_in, const int* in_sizes, int n_in,
                              void* d_out, int out_size, void* d_ws, size_t ws_size,
                              hipStream_t stream) {
    const float* x         = (const float*)d_in[0];
    const float* c_local   = (const float*)d_in[1];
    const float* c_sink    = (const float*)d_in[2];
    const float* W_in      = (const float*)d_in[3];
    const float* b_in      = (const float*)d_in[4];
    const float* cls_token = (const float*)d_in[5];
    const float* pe_proj_W = (const float*)d_in[6];
    const float* pe_proj_b = (const float*)d_in[7];
    const float* pe_ln_g   = (const float*)d_in[8];
    const float* pe_ln_b   = (const float*)d_in[9];
    const float* pe_gain   = (const float*)d_in[10];
    const float* attn_Wqkv = (const float*)d_in[11];
    const float* attn_bqkv = (const float*)d_in[12];
    const float* attn_Wo   = (const float*)d_in[13];
    const float* attn_bo   = (const float*)d_in[14];
    const float* ff_W1     = (const float*)d_in[15];
    const float* ff_b1     = (const float*)d_in[16];
    const float* ff_W2     = (const float*)d_in[17];
    const float* ff_b2     = (const float*)d_in[18];
    const float* ln1_g     = (const float*)d_in[19];
    const float* ln1_b     = (const float*)d_in[20];
    const float* ln2_g     = (const float*)d_in[21];
    const float* ln2_b     = (const float*)d_in[22];
    const float* alpha     = (const float*)d_in[23];
    const float* beta      = (const float*)d_in[24];
    const float* corr_fl   = (const float*)d_in[25];
    const float* out_ln_g  = (const float*)d_in[26];
    const float* out_ln_b  = (const float*)d_in[27];
    const int*   lengths   = (const int*)d_in[28];
    float* out = (float*)d_out;

    // float region (same slots as round-14 passing layout)
    float* h     = (float*)d_ws;              // 4,194,304
    float* clb   = h + 4194304;               // 16384
    float* csfb  = clb + 16384;
    float* padfb = csfb + 16384;
    float* W20t  = padfb + 16384;             // 5120 (in old peWt slot)
    float* PEpos = W20t + 70656;              // 131072
    float* bbf   = PEpos + 131072;            // old 8,388,608-float region
    // bf16 region — weights AFTER the full 16,777,216-short f-span at Q_bf
    unsigned short* u_bf = (unsigned short*)(bbf + 8388608);
    unsigned short* xb_bf = u_bf;             // alias: xb dead before layer loop
    unsigned short* Q_bf = u_bf + 4194304;
    unsigned short* K_bf = Q_bf + 4194304;
    unsigned short* V_bf = K_bf + 4194304;
    unsigned short* f_bf = Q_bf;              // alias: spans Q..Q+16777216
    unsigned short* o_bf = u_bf;              // alias (lifetimes disjoint)
    unsigned short* wq_bf = Q_bf + 16777216;  // after f's span
    unsigned short* wo_bf = wq_bf + 589824;
    unsigned short* w1_bf = wo_bf + 196608;
    unsigned short* w2_bf = w1_bf + 786432;
    unsigned short* win_bf = w2_bf + 786432;  // 16384
    unsigned short* S_bf   = win_bf + 16384;  // 131072 (sinusoid table)
    unsigned short* w256_bf = S_bf + 131072;  // 65536

    setup_kernel<<<4708, 256, 0, stream>>>(
        attn_Wqkv, wq_bf, attn_Wo, wo_bf, ff_W1, w1_bf, ff_W2, w2_bf,
        W_in, win_bf, pe_proj_W, w256_bf, W20t, x, xb_bf, S_bf);
    gemm_bf16_kernel<<<dim3(4, 4), 256, 0, stream>>>(
        S_bf, w256_bf, pe_proj_b, PEpos, nullptr, 512, 256, 256);
    gemm_bf16_kernel<<<dim3(4, 128), 256, 0, stream>>>(
        xb_bf, win_bf, b_in, bbf, lengths, 16384, 256, 64);
    prep_lite_kernel<<<2048, 256, 0, stream>>>(
        c_local, c_sink, bbf, cls_token, PEpos, W20t,
        pe_ln_g, pe_ln_b, pe_gain, corr_fl, lengths, ln1_g, ln1_b,
        h, clb, csfb, padfb, u_bf);

    for (int l = 0; l < 3; ++l) {
        gemm64_kernel<0><<<dim3(6, 256), 256, 0, stream>>>(
            u_bf, wq_bf + (size_t)l * 196608, attn_bqkv + 768 * l, lengths,
            Q_bf, K_bf, V_bf, 16384, 768, 256);
        attn_mfma_kernel<<<2048, 256, 0, stream>>>(Q_bf, K_bf, V_bf, clb, csfb,
                                                   padfb, alpha, beta, lengths, o_bf);
        gemm_res_ln_kernel<0><<<512, 512, 0, stream>>>(
            o_bf, wo_bf + (size_t)l * 65536, attn_bo + 256 * l, h,
            ln2_g + 256 * l, ln2_b + 256 * l, lengths, u_bf, nullptr, 256);
        gemm64_kernel<2><<<dim3(8, 256), 256, 0, stream>>>(
            u_bf, w1_bf + (size_t)l * 262144, ff_b1 + 1024 * l, lengths,
            f_bf, nullptr, nullptr, 16384, 1024, 256);
        if (l < 2) {
            gemm_res_ln_kernel<0><<<512, 512, 0, stream>>>(
                f_bf, w2_bf + (size_t)l * 262144, ff_b2 + 256 * l, h,
                ln1_g + 256 * (l + 1), ln1_b + 256 * (l + 1), lengths, u_bf, nullptr, 1024);
        } else {
            gemm_res_ln_kernel<1><<<512, 512, 0, stream>>>(
                f_bf, w2_bf + (size_t)l * 262144, ff_b2 + 256 * l, h,
                out_ln_g, out_ln_b, lengths, nullptr, out, 1024);
        }
    }
}